// Round 1
// baseline (1695.528 us; speedup 1.0000x reference)
//
#include <hip/hip_runtime.h>
#include <hip/hip_bf16.h>

typedef unsigned short u16;
typedef __attribute__((ext_vector_type(4))) float f32x4;
typedef __attribute__((ext_vector_type(8))) short bf16x8;
typedef __attribute__((ext_vector_type(4))) short bf16x4;

#define TLEN 2048
#define NHEAD 16
#define HD 1024

__device__ inline u16 f2bf(float f) {
  unsigned x = __float_as_uint(f);
  return (u16)((x + 0x7fffu + ((x >> 16) & 1u)) >> 16);
}
__device__ inline float bf2f(u16 u) { return __uint_as_float(((unsigned)u) << 16); }

__device__ inline float wave_sum(float x) {
  x += __shfl_xor(x, 1);  x += __shfl_xor(x, 2);  x += __shfl_xor(x, 4);
  x += __shfl_xor(x, 8);  x += __shfl_xor(x, 16); x += __shfl_xor(x, 32);
  return x;
}

__device__ inline void storev(float* p, float v) { *p = v; }
__device__ inline void storev(u16* p, float v)   { *p = f2bf(v); }

// ---------------------------------------------------------------- fp32 -> bf16
__global__ __launch_bounds__(256) void cvt_bf16(const float* __restrict__ in,
                                                u16* __restrict__ out, int n4) {
  int i = blockIdx.x * 256 + threadIdx.x;
  if (i >= n4) return;
  float4 v = *(const float4*)(in + (size_t)i * 4);
  ushort4 u;
  u.x = f2bf(v.x); u.y = f2bf(v.y); u.z = f2bf(v.z); u.w = f2bf(v.w);
  *(ushort4*)(out + (size_t)i * 4) = u;
}

// ------------------------------------------------- bf16 MFMA linear: C = A*W^T
// A [M,K] bf16 row-major, W [N,K] bf16 row-major. 128x128 tile, BK=64,
// 4 waves (2x2), 16x16x32 MFMA, global_load_lds w=16 staging.
template <typename OutT>
__global__ __launch_bounds__(256) void gemm_lin(
    const u16* __restrict__ A,
    const u16* __restrict__ W0p, const u16* __restrict__ W1p,
    const u16* __restrict__ W2p, const u16* __restrict__ W3p,
    OutT* __restrict__ C0, OutT* __restrict__ C1,
    OutT* __restrict__ C2, OutT* __restrict__ C3,
    int M, int N, int K) {
  const u16* W; OutT* C;
  switch (blockIdx.z) {
    case 0: W = W0p; C = C0; break;
    case 1: W = W1p; C = C1; break;
    case 2: W = W2p; C = C2; break;
    default: W = W3p; C = C3; break;
  }
  const int tid = threadIdx.x;
  const int lane = tid & 63, wid = tid >> 6;
  const int wr = wid >> 1, wc = wid & 1;
  const int fr = lane & 15, fq = lane >> 4;
  const int row0 = blockIdx.y * 128, col0 = blockIdx.x * 128;
  __shared__ __align__(16) u16 As[128 * 64];
  __shared__ __align__(16) u16 Bs[128 * 64];
  f32x4 acc[4][4] = {};
  for (int k0 = 0; k0 < K; k0 += 64) {
#pragma unroll
    for (int it = 0; it < 4; ++it) {
      const int c = it * 256 + tid;
      const int r = c >> 3, cc = c & 7;
      __builtin_amdgcn_global_load_lds(
          (const __attribute__((address_space(1))) void*)(A + (size_t)(row0 + r) * K + k0 + cc * 8),
          (__attribute__((address_space(3))) void*)((char*)As + (it * 256 + wid * 64) * 16),
          16, 0, 0);
      __builtin_amdgcn_global_load_lds(
          (const __attribute__((address_space(1))) void*)(W + (size_t)(col0 + r) * K + k0 + cc * 8),
          (__attribute__((address_space(3))) void*)((char*)Bs + (it * 256 + wid * 64) * 16),
          16, 0, 0);
    }
    __syncthreads();
#pragma unroll
    for (int kk = 0; kk < 2; ++kk) {
      bf16x8 af[4], bfr[4];
#pragma unroll
      for (int m = 0; m < 4; ++m) {
        const u16* p = &As[(wr * 64 + m * 16 + fr) * 64 + kk * 32 + fq * 4];
        bf16x4 lo = *(const bf16x4*)p;
        bf16x4 hi = *(const bf16x4*)(p + 16);
        bf16x8 v = {lo[0], lo[1], lo[2], lo[3], hi[0], hi[1], hi[2], hi[3]};
        af[m] = v;
      }
#pragma unroll
      for (int n = 0; n < 4; ++n) {
        const u16* p = &Bs[(wc * 64 + n * 16 + fr) * 64 + kk * 32 + fq * 4];
        bf16x4 lo = *(const bf16x4*)p;
        bf16x4 hi = *(const bf16x4*)(p + 16);
        bf16x8 v = {lo[0], lo[1], lo[2], lo[3], hi[0], hi[1], hi[2], hi[3]};
        bfr[n] = v;
      }
#pragma unroll
      for (int m = 0; m < 4; ++m)
#pragma unroll
        for (int n = 0; n < 4; ++n)
          acc[m][n] = __builtin_amdgcn_mfma_f32_16x16x32_bf16(af[m], bfr[n], acc[m][n], 0, 0, 0);
    }
    __syncthreads();
  }
#pragma unroll
  for (int m = 0; m < 4; ++m)
#pragma unroll
    for (int n = 0; n < 4; ++n)
#pragma unroll
      for (int r = 0; r < 4; ++r) {
        const int gr = row0 + wr * 64 + m * 16 + fq * 4 + r;
        const int gc = col0 + wc * 64 + n * 16 + fr;
        storev(&C[(size_t)gr * N + gc], acc[m][n][r]);
      }
}

// --------------------------------------- fp32 beta/g projections (N=32, exact)
__global__ __launch_bounds__(256) void small_proj(
    const float* __restrict__ hidden, const float* __restrict__ Wb,
    const float* __restrict__ Wa, const float* __restrict__ A_log,
    const float* __restrict__ dt_bias, float* __restrict__ bbuf,
    float* __restrict__ gbuf) {
  const int col = threadIdx.x & 31, rowi = threadIdx.x >> 5;
  const int row = blockIdx.x * 8 + rowi;
  const int h = col & 15;
  const float* w = (col < 16 ? Wb : Wa) + (size_t)h * HD;
  const float* x = hidden + (size_t)row * HD;
  float s = 0.f;
#pragma unroll 4
  for (int k2 = 0; k2 < 256; ++k2) {
    float4 xv = *(const float4*)(x + k2 * 4);
    float4 wv = *(const float4*)(w + k2 * 4);
    s += xv.x * wv.x + xv.y * wv.y + xv.z * wv.z + xv.w * wv.w;
  }
  if (col < 16) {
    bbuf[row * NHEAD + h] = 1.f / (1.f + __expf(-s));
  } else {
    float xs = s + dt_bias[h];
    float sp = (xs > 20.f) ? xs : log1pf(__expf(xs));
    gbuf[row * NHEAD + h] = -__expf(A_log[h]) * sp;
  }
}

// ----------------------- causal dwconv(K=4) + silu (+ l2norm for q/k), fp32 out
// mode: 0 = q (l2norm * d^-0.5), 1 = k (l2norm), 2 = v (none)
__global__ __launch_bounds__(256) void conv_norm(
    const u16* __restrict__ xin, const float* __restrict__ cw,
    float* __restrict__ out, const int mode) {
  const int flat = blockIdx.x * 256 + threadIdx.x;
  const int c = flat & (HD - 1);
  const int bt = flat >> 10;
  const int t = bt & (TLEN - 1);
  const float4 w = *(const float4*)(cw + c * 4);
  float acc = w.w * bf2f(xin[flat]);
  if (t >= 1) acc += w.z * bf2f(xin[flat - HD]);
  if (t >= 2) acc += w.y * bf2f(xin[flat - 2 * HD]);
  if (t >= 3) acc += w.x * bf2f(xin[flat - 3 * HD]);
  float y = acc / (1.f + __expf(-acc));
  if (mode < 2) {
    float s = wave_sum(y * y);
    y *= rsqrtf(s + 1e-6f);
    if (mode == 0) y *= 0.125f;  // d^-0.5, d=64
  }
  out[flat] = y;
}

// ------------------------------------------------- gated delta-rule scan
// One wave per (b,h,j-column): lane = row i of S[:,j]. Column-independent
// recurrence; pred needs a 64-lane reduce each step; o-reduce deferred x8.
__global__ __launch_bounds__(256) void scan_kernel(
    const float* __restrict__ qn, const float* __restrict__ kn,
    const float* __restrict__ vn, const float* __restrict__ gbuf,
    const float* __restrict__ bbuf, float* __restrict__ obuf) {
  const int bid = blockIdx.x;           // 512 blocks
  const int idx = bid >> 3;
  const int bh = (bid & 7) + 8 * (idx >> 4);   // XCD-grouped: same (b,h) -> same XCD
  const int cg = idx & 15;
  const int b = bh >> 4, h = bh & 15;
  const int lane = threadIdx.x & 63, wid = threadIdx.x >> 6;
  const int j = cg * 4 + wid;
  const size_t rb = (size_t)(b * TLEN) * NHEAD + h;
  const float* kp = kn + rb * 64 + lane;
  const float* qp = qn + rb * 64 + lane;
  const float* vp = vn + rb * 64 + j;
  const float* gp = gbuf + rb;
  const float* bp = bbuf + rb;
  float* op = obuf + rb * 64 + j;
  float S = 0.f;
  float kq[8], qq[8], vv[8], gg[8], bb[8], opart[8];
#pragma unroll
  for (int p = 0; p < 8; ++p) {
    kq[p] = kp[(size_t)p * 1024]; qq[p] = qp[(size_t)p * 1024];
    vv[p] = vp[(size_t)p * 1024];
    gg[p] = gp[(size_t)p * 16];   bb[p] = bp[(size_t)p * 16];
  }
  for (int t0 = 0; t0 < TLEN; t0 += 8) {
#pragma unroll
    for (int p = 0; p < 8; ++p) {
      const int t = t0 + p;
      const float kv = kq[p], qv = qq[p], vj = vv[p], g = gg[p], bt = bb[p];
      if (t + 8 < TLEN) {
        kq[p] = kp[(size_t)(t + 8) * 1024]; qq[p] = qp[(size_t)(t + 8) * 1024];
        vv[p] = vp[(size_t)(t + 8) * 1024];
        gg[p] = gp[(size_t)(t + 8) * 16];   bb[p] = bp[(size_t)(t + 8) * 16];
      }
      S *= __expf(g);
      float pr = kv * S;
      pr += __shfl_xor(pr, 1); pr += __shfl_xor(pr, 2); pr += __shfl_xor(pr, 4);
      pr += __shfl_xor(pr, 8); pr += __shfl_xor(pr, 16); pr += __shfl_xor(pr, 32);
      const float dv = (vj - pr) * bt;
      S += kv * dv;
      opart[p] = qv * S;          // o-reduction deferred (o doesn't feed S)
    }
#pragma unroll
    for (int p = 0; p < 8; ++p) {
      float o = opart[p];
      o += __shfl_xor(o, 1); o += __shfl_xor(o, 2); o += __shfl_xor(o, 4);
      o += __shfl_xor(o, 8); o += __shfl_xor(o, 16); o += __shfl_xor(o, 32);
      opart[p] = o;
    }
    if (lane == 0) {
#pragma unroll
      for (int p = 0; p < 8; ++p) op[(size_t)(t0 + p) * 1024] = opart[p];
    }
  }
}

// ------------------------------------------- gated RMSNorm epilogue -> bf16
__global__ __launch_bounds__(256) void rms_gate(
    const float* __restrict__ obuf, const u16* __restrict__ gatep,
    const float* __restrict__ norm_w, u16* __restrict__ outb) {
  const int flat = blockIdx.x * 256 + threadIdx.x;
  const int d = flat & 63;
  const float o = obuf[flat];
  const float s = wave_sum(o * o);
  const float inv = rsqrtf(s * (1.0f / 64.0f) + 1e-5f);
  const float gt = bf2f(gatep[flat]);
  const float res = o * inv * norm_w[d] * (gt / (1.f + __expf(-gt)));
  outb[flat] = f2bf(res);
}

extern "C" void kernel_launch(void* const* d_in, const int* in_sizes, int n_in,
                              void* d_out, int out_size, void* d_ws, size_t ws_size,
                              hipStream_t stream) {
  const float* hidden = (const float*)d_in[0];
  const float* Wq     = (const float*)d_in[1];
  const float* Wk     = (const float*)d_in[2];
  const float* Wv     = (const float*)d_in[3];
  const float* cq     = (const float*)d_in[4];
  const float* ck     = (const float*)d_in[5];
  const float* cv     = (const float*)d_in[6];
  const float* Wb     = (const float*)d_in[7];
  const float* Wa     = (const float*)d_in[8];
  const float* A_log  = (const float*)d_in[9];
  const float* dtb    = (const float*)d_in[10];
  const float* Wg     = (const float*)d_in[11];
  const float* nw     = (const float*)d_in[12];
  const float* Wo     = (const float*)d_in[13];

  const size_t SZ_H_BF = (size_t)4096 * 1024 * 2;  // 8 MB
  const size_t SZ_W_BF = (size_t)1024 * 1024 * 2;  // 2 MB
  const size_t SZ_P_BF = (size_t)4096 * 1024 * 2;  // 8 MB
  const size_t SZ_F32  = (size_t)4096 * 1024 * 4;  // 16 MB
  const size_t SZ_GB   = (size_t)4096 * 16 * 4;    // 256 KB

  char* p = (char*)d_ws;
  u16* h_bf = (u16*)p;  p += SZ_H_BF;
  u16* wq_b = (u16*)p;  p += SZ_W_BF;
  u16* wk_b = (u16*)p;  p += SZ_W_BF;
  u16* wv_b = (u16*)p;  p += SZ_W_BF;
  u16* wg_b = (u16*)p;  p += SZ_W_BF;
  u16* wo_b = (u16*)p;  p += SZ_W_BF;
  u16* qp_b = (u16*)p;  p += SZ_P_BF;
  u16* kp_b = (u16*)p;  p += SZ_P_BF;
  u16* vp_b = (u16*)p;  p += SZ_P_BF;
  u16* gp_b = (u16*)p;  p += SZ_P_BF;
  float* qn   = (float*)p;  p += SZ_F32;
  float* kn   = (float*)p;  p += SZ_F32;
  float* vn   = (float*)p;  p += SZ_F32;
  float* gbuf = (float*)p;  p += SZ_GB;
  float* bbuf = (float*)p;  p += SZ_GB;
  float* obuf = (float*)qp_b;  // alias qp+kp (16 MB), dead after convs
  u16*   of_b = (u16*)vp_b;    // alias vp (8 MB), dead after conv_v

  cvt_bf16<<<4096, 256, 0, stream>>>(hidden, h_bf, 1048576);
  cvt_bf16<<<1024, 256, 0, stream>>>(Wq, wq_b, 262144);
  cvt_bf16<<<1024, 256, 0, stream>>>(Wk, wk_b, 262144);
  cvt_bf16<<<1024, 256, 0, stream>>>(Wv, wv_b, 262144);
  cvt_bf16<<<1024, 256, 0, stream>>>(Wg, wg_b, 262144);
  cvt_bf16<<<1024, 256, 0, stream>>>(Wo, wo_b, 262144);

  gemm_lin<u16><<<dim3(8, 32, 4), 256, 0, stream>>>(
      h_bf, wq_b, wk_b, wv_b, wg_b, qp_b, kp_b, vp_b, gp_b, 4096, 1024, 1024);

  small_proj<<<512, 256, 0, stream>>>(hidden, Wb, Wa, A_log, dtb, bbuf, gbuf);

  conv_norm<<<16384, 256, 0, stream>>>(qp_b, cq, qn, 0);
  conv_norm<<<16384, 256, 0, stream>>>(kp_b, ck, kn, 1);
  conv_norm<<<16384, 256, 0, stream>>>(vp_b, cv, vn, 2);

  scan_kernel<<<512, 256, 0, stream>>>(qn, kn, vn, gbuf, bbuf, obuf);

  rms_gate<<<16384, 256, 0, stream>>>(obuf, gp_b, nw, of_b);

  gemm_lin<float><<<dim3(8, 32, 1), 256, 0, stream>>>(
      of_b, wo_b, wo_b, wo_b, wo_b,
      (float*)d_out, (float*)d_out, (float*)d_out, (float*)d_out, 4096, 1024, 1024);
}

// Round 2
// 767.061 us; speedup vs baseline: 2.2104x; 2.2104x over previous
//
#include <hip/hip_runtime.h>
#include <hip/hip_bf16.h>

typedef unsigned short u16;
typedef __attribute__((ext_vector_type(4))) float f32x4;
typedef __attribute__((ext_vector_type(8))) short bf16x8;
typedef __attribute__((ext_vector_type(4))) short bf16x4;

#define TLEN 2048
#define NHEAD 16
#define HD 1024

__device__ inline u16 f2bf(float f) {
  unsigned x = __float_as_uint(f);
  return (u16)((x + 0x7fffu + ((x >> 16) & 1u)) >> 16);
}
__device__ inline float bf2f(u16 u) { return __uint_as_float(((unsigned)u) << 16); }

__device__ inline float wave_sum(float x) {
  x += __shfl_xor(x, 1);  x += __shfl_xor(x, 2);  x += __shfl_xor(x, 4);
  x += __shfl_xor(x, 8);  x += __shfl_xor(x, 16); x += __shfl_xor(x, 32);
  return x;
}

__device__ inline void storev(float* p, float v) { *p = v; }
__device__ inline void storev(u16* p, float v)   { *p = f2bf(v); }

// ---------------------------------------------------------------- fp32 -> bf16
__global__ __launch_bounds__(256) void cvt_bf16(const float* __restrict__ in,
                                                u16* __restrict__ out, int n4) {
  int i = blockIdx.x * 256 + threadIdx.x;
  if (i >= n4) return;
  float4 v = *(const float4*)(in + (size_t)i * 4);
  ushort4 u;
  u.x = f2bf(v.x); u.y = f2bf(v.y); u.z = f2bf(v.z); u.w = f2bf(v.w);
  *(ushort4*)(out + (size_t)i * 4) = u;
}

// ------------------------------------------------- bf16 MFMA linear: C = A*W^T
template <typename OutT>
__global__ __launch_bounds__(256) void gemm_lin(
    const u16* __restrict__ A,
    const u16* __restrict__ W0p, const u16* __restrict__ W1p,
    const u16* __restrict__ W2p, const u16* __restrict__ W3p,
    OutT* __restrict__ C0, OutT* __restrict__ C1,
    OutT* __restrict__ C2, OutT* __restrict__ C3,
    int M, int N, int K) {
  const u16* W; OutT* C;
  switch (blockIdx.z) {
    case 0: W = W0p; C = C0; break;
    case 1: W = W1p; C = C1; break;
    case 2: W = W2p; C = C2; break;
    default: W = W3p; C = C3; break;
  }
  const int tid = threadIdx.x;
  const int lane = tid & 63, wid = tid >> 6;
  const int wr = wid >> 1, wc = wid & 1;
  const int fr = lane & 15, fq = lane >> 4;
  const int row0 = blockIdx.y * 128, col0 = blockIdx.x * 128;
  __shared__ __align__(16) u16 As[128 * 64];
  __shared__ __align__(16) u16 Bs[128 * 64];
  f32x4 acc[4][4] = {};
  for (int k0 = 0; k0 < K; k0 += 64) {
#pragma unroll
    for (int it = 0; it < 4; ++it) {
      const int c = it * 256 + tid;
      const int r = c >> 3, cc = c & 7;
      __builtin_amdgcn_global_load_lds(
          (const __attribute__((address_space(1))) void*)(A + (size_t)(row0 + r) * K + k0 + cc * 8),
          (__attribute__((address_space(3))) void*)((char*)As + (it * 256 + wid * 64) * 16),
          16, 0, 0);
      __builtin_amdgcn_global_load_lds(
          (const __attribute__((address_space(1))) void*)(W + (size_t)(col0 + r) * K + k0 + cc * 8),
          (__attribute__((address_space(3))) void*)((char*)Bs + (it * 256 + wid * 64) * 16),
          16, 0, 0);
    }
    __syncthreads();
#pragma unroll
    for (int kk = 0; kk < 2; ++kk) {
      bf16x8 af[4], bfr[4];
#pragma unroll
      for (int m = 0; m < 4; ++m) {
        const u16* p = &As[(wr * 64 + m * 16 + fr) * 64 + kk * 32 + fq * 4];
        bf16x4 lo = *(const bf16x4*)p;
        bf16x4 hi = *(const bf16x4*)(p + 16);
        bf16x8 v = {lo[0], lo[1], lo[2], lo[3], hi[0], hi[1], hi[2], hi[3]};
        af[m] = v;
      }
#pragma unroll
      for (int n = 0; n < 4; ++n) {
        const u16* p = &Bs[(wc * 64 + n * 16 + fr) * 64 + kk * 32 + fq * 4];
        bf16x4 lo = *(const bf16x4*)p;
        bf16x4 hi = *(const bf16x4*)(p + 16);
        bf16x8 v = {lo[0], lo[1], lo[2], lo[3], hi[0], hi[1], hi[2], hi[3]};
        bfr[n] = v;
      }
#pragma unroll
      for (int m = 0; m < 4; ++m)
#pragma unroll
        for (int n = 0; n < 4; ++n)
          acc[m][n] = __builtin_amdgcn_mfma_f32_16x16x32_bf16(af[m], bfr[n], acc[m][n], 0, 0, 0);
    }
    __syncthreads();
  }
#pragma unroll
  for (int m = 0; m < 4; ++m)
#pragma unroll
    for (int n = 0; n < 4; ++n)
#pragma unroll
      for (int r = 0; r < 4; ++r) {
        const int gr = row0 + wr * 64 + m * 16 + fq * 4 + r;
        const int gc = col0 + wc * 64 + n * 16 + fr;
        storev(&C[(size_t)gr * N + gc], acc[m][n][r]);
      }
}

// --------------------------------------- fp32 beta/g projections (N=32, exact)
__global__ __launch_bounds__(256) void small_proj(
    const float* __restrict__ hidden, const float* __restrict__ Wb,
    const float* __restrict__ Wa, const float* __restrict__ A_log,
    const float* __restrict__ dt_bias, float* __restrict__ bbuf,
    float* __restrict__ gbuf) {
  const int col = threadIdx.x & 31, rowi = threadIdx.x >> 5;
  const int row = blockIdx.x * 8 + rowi;
  const int h = col & 15;
  const float* w = (col < 16 ? Wb : Wa) + (size_t)h * HD;
  const float* x = hidden + (size_t)row * HD;
  float s = 0.f;
#pragma unroll 4
  for (int k2 = 0; k2 < 256; ++k2) {
    float4 xv = *(const float4*)(x + k2 * 4);
    float4 wv = *(const float4*)(w + k2 * 4);
    s += xv.x * wv.x + xv.y * wv.y + xv.z * wv.z + xv.w * wv.w;
  }
  if (col < 16) {
    bbuf[row * NHEAD + h] = 1.f / (1.f + __expf(-s));
  } else {
    float xs = s + dt_bias[h];
    float sp = (xs > 20.f) ? xs : log1pf(__expf(xs));
    gbuf[row * NHEAD + h] = -__expf(A_log[h]) * sp;
  }
}

// ----------------------- causal dwconv(K=4) + silu (+ l2norm for q/k), bf16 out
__global__ __launch_bounds__(256) void conv_norm(
    const u16* __restrict__ xin, const float* __restrict__ cw,
    u16* __restrict__ out, const int mode) {
  const int flat = blockIdx.x * 256 + threadIdx.x;
  const int c = flat & (HD - 1);
  const int bt = flat >> 10;
  const int t = bt & (TLEN - 1);
  const float4 w = *(const float4*)(cw + c * 4);
  float acc = w.w * bf2f(xin[flat]);
  if (t >= 1) acc += w.z * bf2f(xin[flat - HD]);
  if (t >= 2) acc += w.y * bf2f(xin[flat - 2 * HD]);
  if (t >= 3) acc += w.x * bf2f(xin[flat - 3 * HD]);
  float y = acc / (1.f + __expf(-acc));
  if (mode < 2) {
    float s = wave_sum(y * y);
    y *= rsqrtf(s + 1e-6f);
    if (mode == 0) y *= 0.125f;  // d^-0.5, d=64
  }
  out[flat] = f2bf(y);
}

// ===================== chunk-parallel gated delta rule =======================
// Per chunk (C=64): b=cumsum(g); A=KK^T; M=I+tril(diag(beta)A.*E);
// u=M^-1(beta V); W=M^-1(diag(beta) K*e^b);
// P = e^{b63} I - K2^T W ; U = K2^T u   (K2_s = k_s e^{b63-b_s})
// G = (QK^T).*E_incl ; R = diag(e^b)Q - G W ; Y = G u
// Then: S_{c+1} = P S_c + U (phase B);  O = R S_c + Y (phase C).
__global__ __launch_bounds__(256) void chunk_local(
    const u16* __restrict__ qn, const u16* __restrict__ kn, const u16* __restrict__ vn,
    const float* __restrict__ gbuf, const float* __restrict__ bbuf,
    float* __restrict__ Pg, float* __restrict__ Ug,
    float* __restrict__ Rg, float* __restrict__ Yg) {
  extern __shared__ float sm[];
  float* Ks = sm;                 // [64][65]
  float* Qs = sm + 4160;
  float* As = sm + 8320;          // M, later G
  float* us = sm + 12480;
  float* Ws = sm + 16640;
  float* bcs = sm + 20800;        // 64
  float* bet = sm + 20864;
  float* e2v = sm + 20928;
  float* Bv  = sm + 20992;

  const int bid = blockIdx.x;            // bh*32 + c
  const int c = bid & 31, bh = bid >> 5;
  const int b = bh >> 4, h = bh & 15;
  const int tid = threadIdx.x;
  const int t0g = b * TLEN + c * 64;

  if (tid < 64) {
    const size_t gi = (size_t)(t0g + tid) * NHEAD + h;
    bet[tid] = bbuf[gi];
    float v = gbuf[gi];
#pragma unroll
    for (int ofs = 1; ofs < 64; ofs <<= 1) {
      float tt = __shfl_up(v, ofs);
      if (tid >= ofs) v += tt;
    }
    bcs[tid] = v;
  }
  __syncthreads();
  if (tid < 64) {
    const float blast = bcs[63];
    Bv[tid]  = __expf(bcs[tid]);
    e2v[tid] = __expf(blast - bcs[tid]);
  }
  __syncthreads();

  // stage K, Q, us = beta*V, Ws = beta*e^b*K
#pragma unroll
  for (int i = 0; i < 4; ++i) {
    const int e4 = tid + 256 * i;                 // 0..1023
    const int r = e4 >> 4, d0 = (e4 & 15) * 4;
    const size_t ga = ((size_t)(t0g + r) * NHEAD + h) * 64 + d0;
    const ushort4 kq = *(const ushort4*)(kn + ga);
    const ushort4 qq = *(const ushort4*)(qn + ga);
    const ushort4 vq = *(const ushort4*)(vn + ga);
    const float bR = bet[r], wsc = bR * Bv[r];
    const float k0 = bf2f(kq.x), k1 = bf2f(kq.y), k2 = bf2f(kq.z), k3 = bf2f(kq.w);
    float* kr = Ks + r * 65 + d0;
    kr[0] = k0; kr[1] = k1; kr[2] = k2; kr[3] = k3;
    float* wr = Ws + r * 65 + d0;
    wr[0] = wsc * k0; wr[1] = wsc * k1; wr[2] = wsc * k2; wr[3] = wsc * k3;
    float* qr = Qs + r * 65 + d0;
    qr[0] = bf2f(qq.x); qr[1] = bf2f(qq.y); qr[2] = bf2f(qq.z); qr[3] = bf2f(qq.w);
    float* ur = us + r * 65 + d0;
    ur[0] = bR * bf2f(vq.x); ur[1] = bR * bf2f(vq.y);
    ur[2] = bR * bf2f(vq.z); ur[3] = bR * bf2f(vq.w);
  }
  __syncthreads();

  const int tr = tid >> 4, tc = tid & 15;
  // ---- A = K K^T -> masked M into As
  {
    float acc[4][4] = {};
    for (int d = 0; d < 64; ++d) {
      float a0 = Ks[(4*tr+0)*65+d], a1 = Ks[(4*tr+1)*65+d],
            a2 = Ks[(4*tr+2)*65+d], a3 = Ks[(4*tr+3)*65+d];
      float b0 = Ks[(4*tc+0)*65+d], b1 = Ks[(4*tc+1)*65+d],
            b2 = Ks[(4*tc+2)*65+d], b3 = Ks[(4*tc+3)*65+d];
      acc[0][0]+=a0*b0; acc[0][1]+=a0*b1; acc[0][2]+=a0*b2; acc[0][3]+=a0*b3;
      acc[1][0]+=a1*b0; acc[1][1]+=a1*b1; acc[1][2]+=a1*b2; acc[1][3]+=a1*b3;
      acc[2][0]+=a2*b0; acc[2][1]+=a2*b1; acc[2][2]+=a2*b2; acc[2][3]+=a2*b3;
      acc[3][0]+=a3*b0; acc[3][1]+=a3*b1; acc[3][2]+=a3*b2; acc[3][3]+=a3*b3;
    }
#pragma unroll
    for (int i = 0; i < 4; ++i)
#pragma unroll
      for (int j = 0; j < 4; ++j) {
        const int t = 4*tr+i, s = 4*tc+j;
        As[t*65+s] = (s < t) ? bet[t] * __expf(bcs[t] - bcs[s]) * acc[i][j] : 0.f;
      }
  }
  __syncthreads();

  // ---- forward substitution: solve M u = us, M W = Ws (in place)
  for (int t = 1; t < 64; ++t) {
    if (tid < 128) {
      const int j = tid & 63;
      float* buf = (tid >= 64) ? Ws : us;
      float acc = buf[t*65+j];
      for (int s = 0; s < t; ++s) acc -= As[t*65+s] * buf[s*65+j];
      buf[t*65+j] = acc;
    }
    __syncthreads();
  }

  const size_t off = (size_t)bid * 4096;
  // ---- P = Blast*I - K2^T W ; U = K2^T u
  {
    float accP[4][4] = {}, accU[4][4] = {};
    for (int s = 0; s < 64; ++s) {
      const float es = e2v[s];
      float k0 = Ks[s*65+4*tr+0]*es, k1 = Ks[s*65+4*tr+1]*es,
            k2 = Ks[s*65+4*tr+2]*es, k3 = Ks[s*65+4*tr+3]*es;
      float w0 = Ws[s*65+4*tc+0], w1 = Ws[s*65+4*tc+1],
            w2 = Ws[s*65+4*tc+2], w3 = Ws[s*65+4*tc+3];
      float u0 = us[s*65+4*tc+0], u1 = us[s*65+4*tc+1],
            u2 = us[s*65+4*tc+2], u3 = us[s*65+4*tc+3];
      accP[0][0]+=k0*w0; accP[0][1]+=k0*w1; accP[0][2]+=k0*w2; accP[0][3]+=k0*w3;
      accP[1][0]+=k1*w0; accP[1][1]+=k1*w1; accP[1][2]+=k1*w2; accP[1][3]+=k1*w3;
      accP[2][0]+=k2*w0; accP[2][1]+=k2*w1; accP[2][2]+=k2*w2; accP[2][3]+=k2*w3;
      accP[3][0]+=k3*w0; accP[3][1]+=k3*w1; accP[3][2]+=k3*w2; accP[3][3]+=k3*w3;
      accU[0][0]+=k0*u0; accU[0][1]+=k0*u1; accU[0][2]+=k0*u2; accU[0][3]+=k0*u3;
      accU[1][0]+=k1*u0; accU[1][1]+=k1*u1; accU[1][2]+=k1*u2; accU[1][3]+=k1*u3;
      accU[2][0]+=k2*u0; accU[2][1]+=k2*u1; accU[2][2]+=k2*u2; accU[2][3]+=k2*u3;
      accU[3][0]+=k3*u0; accU[3][1]+=k3*u1; accU[3][2]+=k3*u2; accU[3][3]+=k3*u3;
    }
    const float bl = Bv[63];
#pragma unroll
    for (int i = 0; i < 4; ++i) {
      const int a = 4*tr+i;
      float4 pv, uv;
      pv.x = ((a == 4*tc+0) ? bl : 0.f) - accP[i][0];
      pv.y = ((a == 4*tc+1) ? bl : 0.f) - accP[i][1];
      pv.z = ((a == 4*tc+2) ? bl : 0.f) - accP[i][2];
      pv.w = ((a == 4*tc+3) ? bl : 0.f) - accP[i][3];
      uv.x = accU[i][0]; uv.y = accU[i][1]; uv.z = accU[i][2]; uv.w = accU[i][3];
      *(float4*)(Pg + off + a*64 + 4*tc) = pv;
      *(float4*)(Ug + off + a*64 + 4*tc) = uv;
    }
  }
  // ---- G = (Q K^T) .* E_incl  into As (M is dead; all threads past solve barrier)
  {
    float acc[4][4] = {};
    for (int d = 0; d < 64; ++d) {
      float a0 = Qs[(4*tr+0)*65+d], a1 = Qs[(4*tr+1)*65+d],
            a2 = Qs[(4*tr+2)*65+d], a3 = Qs[(4*tr+3)*65+d];
      float b0 = Ks[(4*tc+0)*65+d], b1 = Ks[(4*tc+1)*65+d],
            b2 = Ks[(4*tc+2)*65+d], b3 = Ks[(4*tc+3)*65+d];
      acc[0][0]+=a0*b0; acc[0][1]+=a0*b1; acc[0][2]+=a0*b2; acc[0][3]+=a0*b3;
      acc[1][0]+=a1*b0; acc[1][1]+=a1*b1; acc[1][2]+=a1*b2; acc[1][3]+=a1*b3;
      acc[2][0]+=a2*b0; acc[2][1]+=a2*b1; acc[2][2]+=a2*b2; acc[2][3]+=a2*b3;
      acc[3][0]+=a3*b0; acc[3][1]+=a3*b1; acc[3][2]+=a3*b2; acc[3][3]+=a3*b3;
    }
#pragma unroll
    for (int i = 0; i < 4; ++i)
#pragma unroll
      for (int j = 0; j < 4; ++j) {
        const int t = 4*tr+i, s = 4*tc+j;
        As[t*65+s] = (s <= t) ? acc[i][j] * __expf(bcs[t] - bcs[s]) : 0.f;
      }
  }
  __syncthreads();
  // ---- R = diag(e^b)Q - G W ; Y = G u
  {
    float accR[4][4] = {}, accY[4][4] = {};
    for (int s = 0; s < 64; ++s) {
      float g0 = As[(4*tr+0)*65+s], g1 = As[(4*tr+1)*65+s],
            g2 = As[(4*tr+2)*65+s], g3 = As[(4*tr+3)*65+s];
      float w0 = Ws[s*65+4*tc+0], w1 = Ws[s*65+4*tc+1],
            w2 = Ws[s*65+4*tc+2], w3 = Ws[s*65+4*tc+3];
      float u0 = us[s*65+4*tc+0], u1 = us[s*65+4*tc+1],
            u2 = us[s*65+4*tc+2], u3 = us[s*65+4*tc+3];
      accR[0][0]+=g0*w0; accR[0][1]+=g0*w1; accR[0][2]+=g0*w2; accR[0][3]+=g0*w3;
      accR[1][0]+=g1*w0; accR[1][1]+=g1*w1; accR[1][2]+=g1*w2; accR[1][3]+=g1*w3;
      accR[2][0]+=g2*w0; accR[2][1]+=g2*w1; accR[2][2]+=g2*w2; accR[2][3]+=g2*w3;
      accR[3][0]+=g3*w0; accR[3][1]+=g3*w1; accR[3][2]+=g3*w2; accR[3][3]+=g3*w3;
      accY[0][0]+=g0*u0; accY[0][1]+=g0*u1; accY[0][2]+=g0*u2; accY[0][3]+=g0*u3;
      accY[1][0]+=g1*u0; accY[1][1]+=g1*u1; accY[1][2]+=g1*u2; accY[1][3]+=g1*u3;
      accY[2][0]+=g2*u0; accY[2][1]+=g2*u1; accY[2][2]+=g2*u2; accY[2][3]+=g2*u3;
      accY[3][0]+=g3*u0; accY[3][1]+=g3*u1; accY[3][2]+=g3*u2; accY[3][3]+=g3*u3;
    }
#pragma unroll
    for (int i = 0; i < 4; ++i) {
      const int t = 4*tr+i;
      const float bt = Bv[t];
      float4 rv, yv;
      rv.x = bt*Qs[t*65+4*tc+0] - accR[i][0];
      rv.y = bt*Qs[t*65+4*tc+1] - accR[i][1];
      rv.z = bt*Qs[t*65+4*tc+2] - accR[i][2];
      rv.w = bt*Qs[t*65+4*tc+3] - accR[i][3];
      yv.x = accY[i][0]; yv.y = accY[i][1]; yv.z = accY[i][2]; yv.w = accY[i][3];
      *(float4*)(Rg + off + t*64 + 4*tc) = rv;
      *(float4*)(Yg + off + t*64 + 4*tc) = yv;
    }
  }
}

// ---- phase B: S_{c+1} = P_c S_c + U_c ; store S_in per chunk. 128 blocks.
__global__ __launch_bounds__(256) void state_step(
    const float* __restrict__ Pg, const float* __restrict__ Ug,
    float* __restrict__ Sst) {
  __shared__ float Ps[64 * 65];
  __shared__ float Sc[64 * 20];
  const int blk = blockIdx.x;
  const int bh = blk >> 2, j0 = (blk & 3) * 16;
  const int tid = threadIdx.x;
  for (int i = tid; i < 64 * 20; i += 256) Sc[i] = 0.f;
  const int a = tid >> 2, jb = (tid & 3) * 4;
  __syncthreads();
  for (int c = 0; c < 32; ++c) {
    const size_t off = ((size_t)bh * 32 + c) * 4096;
#pragma unroll
    for (int i = 0; i < 4; ++i) {
      const int e = tid + 256 * i;          // 1024 entries (64 x 16)
      const int rr = e >> 4, jj = e & 15;
      Sst[off + rr * 64 + j0 + jj] = Sc[rr * 20 + jj];
    }
#pragma unroll
    for (int i = 0; i < 16; ++i) {
      const int e = tid + 256 * i;
      Ps[(e >> 6) * 65 + (e & 63)] = Pg[off + e];
    }
    __syncthreads();
    float4 acc = *(const float4*)(Ug + off + a * 64 + j0 + jb);
    for (int k = 0; k < 64; ++k) {
      const float pv = Ps[a * 65 + k];
      const float4 sv = *(const float4*)(&Sc[k * 20 + jb]);
      acc.x += pv * sv.x; acc.y += pv * sv.y;
      acc.z += pv * sv.z; acc.w += pv * sv.w;
    }
    __syncthreads();
    *(float4*)(&Sc[a * 20 + jb]) = acc;
    __syncthreads();
  }
}

// ---- phase C: O = R S_in + Y   (1024 parallel blocks)
__global__ __launch_bounds__(256) void chunk_out(
    const float* __restrict__ Rg, const float* __restrict__ Yg,
    const float* __restrict__ Sst, float* __restrict__ obuf) {
  __shared__ float Rs[64 * 65];
  __shared__ float Ss[64 * 65];
  const int bid = blockIdx.x;
  const int c = bid & 31, bh = bid >> 5, b = bh >> 4, h = bh & 15;
  const int tid = threadIdx.x;
  const size_t off = (size_t)bid * 4096;
#pragma unroll
  for (int i = 0; i < 16; ++i) {
    const int e = tid + 256 * i;
    Rs[(e >> 6) * 65 + (e & 63)] = Rg[off + e];
    Ss[(e >> 6) * 65 + (e & 63)] = Sst[off + e];
  }
  __syncthreads();
  const int tr = tid >> 4, tc = tid & 15;
  float acc[4][4];
#pragma unroll
  for (int i = 0; i < 4; ++i) {
    const float4 y = *(const float4*)(Yg + off + (4*tr+i)*64 + 4*tc);
    acc[i][0] = y.x; acc[i][1] = y.y; acc[i][2] = y.z; acc[i][3] = y.w;
  }
  for (int k = 0; k < 64; ++k) {
    float r0 = Rs[(4*tr+0)*65+k], r1 = Rs[(4*tr+1)*65+k],
          r2 = Rs[(4*tr+2)*65+k], r3 = Rs[(4*tr+3)*65+k];
    float s0 = Ss[k*65+4*tc+0], s1 = Ss[k*65+4*tc+1],
          s2 = Ss[k*65+4*tc+2], s3 = Ss[k*65+4*tc+3];
    acc[0][0]+=r0*s0; acc[0][1]+=r0*s1; acc[0][2]+=r0*s2; acc[0][3]+=r0*s3;
    acc[1][0]+=r1*s0; acc[1][1]+=r1*s1; acc[1][2]+=r1*s2; acc[1][3]+=r1*s3;
    acc[2][0]+=r2*s0; acc[2][1]+=r2*s1; acc[2][2]+=r2*s2; acc[2][3]+=r2*s3;
    acc[3][0]+=r3*s0; acc[3][1]+=r3*s1; acc[3][2]+=r3*s2; acc[3][3]+=r3*s3;
  }
#pragma unroll
  for (int i = 0; i < 4; ++i) {
    const int t = 4*tr+i;
    float4 ov; ov.x = acc[i][0]; ov.y = acc[i][1]; ov.z = acc[i][2]; ov.w = acc[i][3];
    *(float4*)(obuf + ((size_t)(b * TLEN + c * 64 + t) * NHEAD + h) * 64 + 4*tc) = ov;
  }
}

// ------------------------------------------- gated RMSNorm epilogue -> bf16
__global__ __launch_bounds__(256) void rms_gate(
    const float* __restrict__ obuf, const u16* __restrict__ gatep,
    const float* __restrict__ norm_w, u16* __restrict__ outb) {
  const int flat = blockIdx.x * 256 + threadIdx.x;
  const int d = flat & 63;
  const float o = obuf[flat];
  const float s = wave_sum(o * o);
  const float inv = rsqrtf(s * (1.0f / 64.0f) + 1e-5f);
  const float gt = bf2f(gatep[flat]);
  const float res = o * inv * norm_w[d] * (gt / (1.f + __expf(-gt)));
  outb[flat] = f2bf(res);
}

extern "C" void kernel_launch(void* const* d_in, const int* in_sizes, int n_in,
                              void* d_out, int out_size, void* d_ws, size_t ws_size,
                              hipStream_t stream) {
  const float* hidden = (const float*)d_in[0];
  const float* Wq     = (const float*)d_in[1];
  const float* Wk     = (const float*)d_in[2];
  const float* Wv     = (const float*)d_in[3];
  const float* cq     = (const float*)d_in[4];
  const float* ck     = (const float*)d_in[5];
  const float* cv     = (const float*)d_in[6];
  const float* Wb     = (const float*)d_in[7];
  const float* Wa     = (const float*)d_in[8];
  const float* A_log  = (const float*)d_in[9];
  const float* dtb    = (const float*)d_in[10];
  const float* Wg     = (const float*)d_in[11];
  const float* nw     = (const float*)d_in[12];
  const float* Wo     = (const float*)d_in[13];

  char* p = (char*)d_ws;
  const size_t MB = 1u << 20;
  u16* h_bf = (u16*)(p + 0 * MB);     // 8 MB   (dead after gemm #1)
  u16* wq_b = (u16*)(p + 8 * MB);     // 2 MB
  u16* wk_b = (u16*)(p + 10 * MB);
  u16* wv_b = (u16*)(p + 12 * MB);
  u16* wg_b = (u16*)(p + 14 * MB);
  float* Pg = (float*)(p + 0 * MB);   // 16 MB, aliases h_bf..wg_b (dead then)
  u16* wo_b = (u16*)(p + 16 * MB);    // 2 MB (live till end)
  u16* qp_b = (u16*)(p + 18 * MB);    // 8 MB
  u16* kp_b = (u16*)(p + 26 * MB);    // 8 MB
  u16* vp_b = (u16*)(p + 34 * MB);    // 8 MB
  u16* gp_b = (u16*)(p + 42 * MB);    // 8 MB (live till rms_gate)
  float* obuf = (float*)qp_b;         // 16 MB, aliases qp+kp (dead after convs)
  u16*   of_b = vp_b;                 // 8 MB, aliases vp (dead after conv v)
  u16* qn_b = (u16*)(p + 50 * MB);    // 8 MB
  u16* kn_b = (u16*)(p + 58 * MB);
  u16* vn_b = (u16*)(p + 66 * MB);
  float* gbuf = (float*)(p + 74 * MB);        // 256 KB
  float* bbuf = (float*)(p + 74 * MB + 262144);
  float* Ug  = (float*)(p + 75 * MB);  // 16 MB
  float* Rg  = (float*)(p + 91 * MB);  // 16 MB
  float* Yg  = (float*)(p + 107 * MB); // 16 MB
  float* Sst = (float*)(p + 123 * MB); // 16 MB  (total 139 MB)

  cvt_bf16<<<4096, 256, 0, stream>>>(hidden, h_bf, 1048576);
  cvt_bf16<<<1024, 256, 0, stream>>>(Wq, wq_b, 262144);
  cvt_bf16<<<1024, 256, 0, stream>>>(Wk, wk_b, 262144);
  cvt_bf16<<<1024, 256, 0, stream>>>(Wv, wv_b, 262144);
  cvt_bf16<<<1024, 256, 0, stream>>>(Wg, wg_b, 262144);
  cvt_bf16<<<1024, 256, 0, stream>>>(Wo, wo_b, 262144);

  gemm_lin<u16><<<dim3(8, 32, 4), 256, 0, stream>>>(
      h_bf, wq_b, wk_b, wv_b, wg_b, qp_b, kp_b, vp_b, gp_b, 4096, 1024, 1024);

  small_proj<<<512, 256, 0, stream>>>(hidden, Wb, Wa, A_log, dtb, bbuf, gbuf);

  conv_norm<<<16384, 256, 0, stream>>>(qp_b, cq, qn_b, 0);
  conv_norm<<<16384, 256, 0, stream>>>(kp_b, ck, kn_b, 1);
  conv_norm<<<16384, 256, 0, stream>>>(vp_b, cv, vn_b, 2);

  const int lds_bytes = (5 * 64 * 65 + 256) * 4;  // 84224
  hipFuncSetAttribute((const void*)chunk_local,
                      hipFuncAttributeMaxDynamicSharedMemorySize, lds_bytes);
  chunk_local<<<1024, 256, lds_bytes, stream>>>(qn_b, kn_b, vn_b, gbuf, bbuf,
                                                Pg, Ug, Rg, Yg);
  state_step<<<128, 256, 0, stream>>>(Pg, Ug, Sst);
  chunk_out<<<1024, 256, 0, stream>>>(Rg, Yg, Sst, obuf);

  rms_gate<<<16384, 256, 0, stream>>>(obuf, gp_b, nw, of_b);

  gemm_lin<float><<<dim3(8, 32, 1), 256, 0, stream>>>(
      of_b, wo_b, wo_b, wo_b, wo_b,
      (float*)d_out, (float*)d_out, (float*)d_out, (float*)d_out, 4096, 1024, 1024);
}

// Round 3
// 408.536 us; speedup vs baseline: 4.1503x; 1.8776x over previous
//
#include <hip/hip_runtime.h>
#include <hip/hip_bf16.h>

typedef unsigned short u16;
typedef __attribute__((ext_vector_type(4))) float f32x4;
typedef __attribute__((ext_vector_type(8))) short bf16x8;

#define TLEN 2048
#define NHEAD 16
#define HD 1024

__device__ inline u16 f2bf(float f) {
  unsigned x = __float_as_uint(f);
  return (u16)((x + 0x7fffu + ((x >> 16) & 1u)) >> 16);
}
__device__ inline float bf2f(u16 u) { return __uint_as_float(((unsigned)u) << 16); }

__device__ inline float wave_sum(float x) {
  x += __shfl_xor(x, 1);  x += __shfl_xor(x, 2);  x += __shfl_xor(x, 4);
  x += __shfl_xor(x, 8);  x += __shfl_xor(x, 16); x += __shfl_xor(x, 32);
  return x;
}

__device__ inline void storev(float* p, float v) { *p = v; }
__device__ inline void storev(u16* p, float v)   { *p = f2bf(v); }

// ------------------------------------------------- fused fp32 -> bf16 converts
__global__ __launch_bounds__(256) void cvt_all(
    const float* __restrict__ h,  const float* __restrict__ wq,
    const float* __restrict__ wk, const float* __restrict__ wv,
    const float* __restrict__ wg, const float* __restrict__ wo,
    u16* __restrict__ dh,  u16* __restrict__ dwq, u16* __restrict__ dwk,
    u16* __restrict__ dwv, u16* __restrict__ dwg, u16* __restrict__ dwo) {
  const int b = blockIdx.x;
  const float* s; u16* d; size_t i;
  if (b < 4096) { s = h; d = dh; i = (size_t)b * 256 + threadIdx.x; }
  else {
    const int wsel = (b - 4096) >> 10;
    i = (size_t)((b - 4096) & 1023) * 256 + threadIdx.x;
    switch (wsel) {
      case 0: s = wq; d = dwq; break;
      case 1: s = wk; d = dwk; break;
      case 2: s = wv; d = dwv; break;
      case 3: s = wg; d = dwg; break;
      default: s = wo; d = dwo; break;
    }
  }
  float4 v = *(const float4*)(s + i * 4);
  ushort4 u;
  u.x = f2bf(v.x); u.y = f2bf(v.y); u.z = f2bf(v.z); u.w = f2bf(v.w);
  *(ushort4*)(d + i * 4) = u;
}

// ------------------------------------------------- bf16 MFMA linear: C = A*W^T
// Tile = (MT*32) x 128, BK=64, 4 waves (2x2), 16x16x32 MFMA.
// Contiguous 16B fragments (k-permutation consistent across A/B) +
// XOR slot swizzle: pre-swizzled global source (T21) + swizzled ds_read_b128.
template <typename OutT, int MT>
__global__ __launch_bounds__(256) void gemm_lin(
    const u16* __restrict__ A,
    const u16* __restrict__ W0p, const u16* __restrict__ W1p,
    const u16* __restrict__ W2p, const u16* __restrict__ W3p,
    OutT* __restrict__ C0, OutT* __restrict__ C1,
    OutT* __restrict__ C2, OutT* __restrict__ C3,
    int M, int N, int K) {
  const u16* W; OutT* C;
  switch (blockIdx.z) {
    case 0: W = W0p; C = C0; break;
    case 1: W = W1p; C = C1; break;
    case 2: W = W2p; C = C2; break;
    default: W = W3p; C = C3; break;
  }
  const int tid = threadIdx.x;
  const int lane = tid & 63, wid = tid >> 6;
  const int wr = wid >> 1, wc = wid & 1;
  const int fr = lane & 15, fq = lane >> 4;
  const int row0 = blockIdx.y * (MT * 32), col0 = blockIdx.x * 128;
  __shared__ __align__(16) u16 As[MT * 32 * 64];
  __shared__ __align__(16) u16 Bs[128 * 64];

  const u16* aSrc[MT]; const u16* bSrc[4];
#pragma unroll
  for (int it = 0; it < MT; ++it) {
    const int c = it * 256 + tid;
    const int r = c >> 3, cc = c & 7, sc = cc ^ (r & 7);
    aSrc[it] = A + (size_t)(row0 + r) * K + sc * 8;
  }
#pragma unroll
  for (int it = 0; it < 4; ++it) {
    const int c = it * 256 + tid;
    const int r = c >> 3, cc = c & 7, sc = cc ^ (r & 7);
    bSrc[it] = W + (size_t)(col0 + r) * K + sc * 8;
  }
  int aOff[MT][2], bOff[4][2];
#pragma unroll
  for (int m = 0; m < MT; ++m)
#pragma unroll
    for (int kk = 0; kk < 2; ++kk) {
      const int ra = wr * (MT * 16) + m * 16 + fr;
      aOff[m][kk] = ra * 128 + ((((kk << 2) | fq) ^ (fr & 7)) << 4);
    }
#pragma unroll
  for (int n = 0; n < 4; ++n)
#pragma unroll
    for (int kk = 0; kk < 2; ++kk) {
      const int rb = wc * 64 + n * 16 + fr;
      bOff[n][kk] = rb * 128 + ((((kk << 2) | fq) ^ (fr & 7)) << 4);
    }

  f32x4 acc[MT][4] = {};
  for (int k0 = 0; k0 < K; k0 += 64) {
#pragma unroll
    for (int it = 0; it < MT; ++it)
      __builtin_amdgcn_global_load_lds(
          (const __attribute__((address_space(1))) void*)(aSrc[it] + k0),
          (__attribute__((address_space(3))) void*)((char*)As + (it * 256 + wid * 64) * 16),
          16, 0, 0);
#pragma unroll
    for (int it = 0; it < 4; ++it)
      __builtin_amdgcn_global_load_lds(
          (const __attribute__((address_space(1))) void*)(bSrc[it] + k0),
          (__attribute__((address_space(3))) void*)((char*)Bs + (it * 256 + wid * 64) * 16),
          16, 0, 0);
    __syncthreads();
#pragma unroll
    for (int kk = 0; kk < 2; ++kk) {
      bf16x8 af[MT], bfr[4];
#pragma unroll
      for (int m = 0; m < MT; ++m)
        af[m] = *(const bf16x8*)((const char*)As + aOff[m][kk]);
#pragma unroll
      for (int n = 0; n < 4; ++n)
        bfr[n] = *(const bf16x8*)((const char*)Bs + bOff[n][kk]);
#pragma unroll
      for (int m = 0; m < MT; ++m)
#pragma unroll
        for (int n = 0; n < 4; ++n)
          acc[m][n] = __builtin_amdgcn_mfma_f32_16x16x32_bf16(af[m], bfr[n], acc[m][n], 0, 0, 0);
    }
    __syncthreads();
  }
#pragma unroll
  for (int m = 0; m < MT; ++m)
#pragma unroll
    for (int n = 0; n < 4; ++n)
#pragma unroll
      for (int r = 0; r < 4; ++r) {
        const int gr = row0 + wr * (MT * 16) + m * 16 + fq * 4 + r;
        const int gc = col0 + wc * 64 + n * 16 + fr;
        storev(&C[(size_t)gr * N + gc], acc[m][n][r]);
      }
}

// --------------------------------------- fp32 beta/g projections (N=32, exact)
__global__ __launch_bounds__(256) void small_proj(
    const float* __restrict__ hidden, const float* __restrict__ Wb,
    const float* __restrict__ Wa, const float* __restrict__ A_log,
    const float* __restrict__ dt_bias, float* __restrict__ bbuf,
    float* __restrict__ gbuf) {
  const int col = threadIdx.x & 31, rowi = threadIdx.x >> 5;
  const int row = blockIdx.x * 8 + rowi;
  const int h = col & 15;
  const float* w = (col < 16 ? Wb : Wa) + (size_t)h * HD;
  const float* x = hidden + (size_t)row * HD;
  float s = 0.f;
#pragma unroll 4
  for (int k2 = 0; k2 < 256; ++k2) {
    float4 xv = *(const float4*)(x + k2 * 4);
    float4 wv = *(const float4*)(w + k2 * 4);
    s += xv.x * wv.x + xv.y * wv.y + xv.z * wv.z + xv.w * wv.w;
  }
  if (col < 16) {
    bbuf[row * NHEAD + h] = 1.f / (1.f + __expf(-s));
  } else {
    float xs = s + dt_bias[h];
    float sp = (xs > 20.f) ? xs : log1pf(__expf(xs));
    gbuf[row * NHEAD + h] = -__expf(A_log[h]) * sp;
  }
}

// -------------- fused causal dwconv(K=4)+silu (+l2norm for q/k), q|k|v in one
__global__ __launch_bounds__(256) void conv_norm3(
    const u16* __restrict__ xin, const float* __restrict__ cq,
    const float* __restrict__ ck, const float* __restrict__ cv,
    u16* __restrict__ out) {
  const int gb = blockIdx.x;
  const int mode = gb >> 14;
  const int flat = ((gb & 16383) << 8) + threadIdx.x;
  const u16* x = xin + (size_t)mode * 4194304;
  u16* o = out + (size_t)mode * 4194304;
  const float* cw = (mode == 0) ? cq : ((mode == 1) ? ck : cv);
  const int c = flat & (HD - 1);
  const int bt = flat >> 10;
  const int t = bt & (TLEN - 1);
  const float4 w = *(const float4*)(cw + c * 4);
  float acc = w.w * bf2f(x[flat]);
  if (t >= 1) acc += w.z * bf2f(x[flat - HD]);
  if (t >= 2) acc += w.y * bf2f(x[flat - 2 * HD]);
  if (t >= 3) acc += w.x * bf2f(x[flat - 3 * HD]);
  float y = acc / (1.f + __expf(-acc));
  if (mode < 2) {
    float s = wave_sum(y * y);
    y *= rsqrtf(s + 1e-6f);
    if (mode == 0) y *= 0.125f;  // d^-0.5, d=64
  }
  o[flat] = f2bf(y);
}

// ===================== chunk-parallel gated delta rule =======================
__global__ __launch_bounds__(256) void chunk_local(
    const u16* __restrict__ qn, const u16* __restrict__ kn, const u16* __restrict__ vn,
    const float* __restrict__ gbuf, const float* __restrict__ bbuf,
    float* __restrict__ Pg, float* __restrict__ Ug,
    float* __restrict__ Rg, float* __restrict__ Yg) {
  extern __shared__ float sm[];
  float* Ks = sm;                       // [64][65] f32
  float* As = sm + 4160;                // M, later G
  float* us = sm + 8320;
  float* Ws = sm + 12480;
  u16*  Qh = (u16*)(sm + 16640);        // [64][66] bf16
  float* bcs = sm + 18752;
  float* bet = sm + 18816;
  float* e2v = sm + 18880;
  float* Bv  = sm + 18944;              // end = 19008 floats = 76032 B

  const int bid = blockIdx.x;           // bh*32 + c
  const int c = bid & 31, bh = bid >> 5;
  const int b = bh >> 4, h = bh & 15;
  const int tid = threadIdx.x;
  const int t0g = b * TLEN + c * 64;

  if (tid < 64) {
    const size_t gi = (size_t)(t0g + tid) * NHEAD + h;
    bet[tid] = bbuf[gi];
    float v = gbuf[gi];
#pragma unroll
    for (int ofs = 1; ofs < 64; ofs <<= 1) {
      float tt = __shfl_up(v, ofs);
      if (tid >= ofs) v += tt;
    }
    bcs[tid] = v;
  }
  __syncthreads();
  if (tid < 64) {
    const float blast = bcs[63];
    Bv[tid]  = __expf(bcs[tid]);
    e2v[tid] = __expf(blast - bcs[tid]);
  }
  __syncthreads();

  // stage K (f32), Q (bf16), us = beta*V, Ws = beta*e^b*K
#pragma unroll
  for (int i = 0; i < 4; ++i) {
    const int e4 = tid + 256 * i;
    const int r = e4 >> 4, d0 = (e4 & 15) * 4;
    const size_t ga = ((size_t)(t0g + r) * NHEAD + h) * 64 + d0;
    const ushort4 kq = *(const ushort4*)(kn + ga);
    const ushort4 qq = *(const ushort4*)(qn + ga);
    const ushort4 vq = *(const ushort4*)(vn + ga);
    const float bR = bet[r], wsc = bR * Bv[r];
    const float k0 = bf2f(kq.x), k1 = bf2f(kq.y), k2 = bf2f(kq.z), k3 = bf2f(kq.w);
    float* kr = Ks + r * 65 + d0;
    kr[0] = k0; kr[1] = k1; kr[2] = k2; kr[3] = k3;
    float* wr = Ws + r * 65 + d0;
    wr[0] = wsc * k0; wr[1] = wsc * k1; wr[2] = wsc * k2; wr[3] = wsc * k3;
    u16* qr = Qh + r * 66 + d0;
    qr[0] = qq.x; qr[1] = qq.y; qr[2] = qq.z; qr[3] = qq.w;
    float* ur = us + r * 65 + d0;
    ur[0] = bR * bf2f(vq.x); ur[1] = bR * bf2f(vq.y);
    ur[2] = bR * bf2f(vq.z); ur[3] = bR * bf2f(vq.w);
  }
  __syncthreads();

  const int tr = tid >> 4, tc = tid & 15;
  // ---- A = K K^T -> masked M into As
  {
    float acc[4][4] = {};
    for (int d = 0; d < 64; ++d) {
      float a0 = Ks[(4*tr+0)*65+d], a1 = Ks[(4*tr+1)*65+d],
            a2 = Ks[(4*tr+2)*65+d], a3 = Ks[(4*tr+3)*65+d];
      float b0 = Ks[(4*tc+0)*65+d], b1 = Ks[(4*tc+1)*65+d],
            b2 = Ks[(4*tc+2)*65+d], b3 = Ks[(4*tc+3)*65+d];
      acc[0][0]+=a0*b0; acc[0][1]+=a0*b1; acc[0][2]+=a0*b2; acc[0][3]+=a0*b3;
      acc[1][0]+=a1*b0; acc[1][1]+=a1*b1; acc[1][2]+=a1*b2; acc[1][3]+=a1*b3;
      acc[2][0]+=a2*b0; acc[2][1]+=a2*b1; acc[2][2]+=a2*b2; acc[2][3]+=a2*b3;
      acc[3][0]+=a3*b0; acc[3][1]+=a3*b1; acc[3][2]+=a3*b2; acc[3][3]+=a3*b3;
    }
#pragma unroll
    for (int i = 0; i < 4; ++i)
#pragma unroll
      for (int j = 0; j < 4; ++j) {
        const int t = 4*tr+i, s = 4*tc+j;
        As[t*65+s] = (s < t) ? bet[t] * __expf(bcs[t] - bcs[s]) * acc[i][j] : 0.f;
      }
  }
  __syncthreads();

  // ---- forward substitution: solve M u = us, M W = Ws (in place)
  for (int t = 1; t < 64; ++t) {
    if (tid < 128) {
      const int j = tid & 63;
      float* buf = (tid >= 64) ? Ws : us;
      float acc = buf[t*65+j];
      for (int s = 0; s < t; ++s) acc -= As[t*65+s] * buf[s*65+j];
      buf[t*65+j] = acc;
    }
    __syncthreads();
  }

  const size_t off = (size_t)bid * 4096;
  // ---- P = Blast*I - K2^T W ; U = K2^T u
  {
    float accP[4][4] = {}, accU[4][4] = {};
    for (int s = 0; s < 64; ++s) {
      const float es = e2v[s];
      float k0 = Ks[s*65+4*tr+0]*es, k1 = Ks[s*65+4*tr+1]*es,
            k2 = Ks[s*65+4*tr+2]*es, k3 = Ks[s*65+4*tr+3]*es;
      float w0 = Ws[s*65+4*tc+0], w1 = Ws[s*65+4*tc+1],
            w2 = Ws[s*65+4*tc+2], w3 = Ws[s*65+4*tc+3];
      float u0 = us[s*65+4*tc+0], u1 = us[s*65+4*tc+1],
            u2 = us[s*65+4*tc+2], u3 = us[s*65+4*tc+3];
      accP[0][0]+=k0*w0; accP[0][1]+=k0*w1; accP[0][2]+=k0*w2; accP[0][3]+=k0*w3;
      accP[1][0]+=k1*w0; accP[1][1]+=k1*w1; accP[1][2]+=k1*w2; accP[1][3]+=k1*w3;
      accP[2][0]+=k2*w0; accP[2][1]+=k2*w1; accP[2][2]+=k2*w2; accP[2][3]+=k2*w3;
      accP[3][0]+=k3*w0; accP[3][1]+=k3*w1; accP[3][2]+=k3*w2; accP[3][3]+=k3*w3;
      accU[0][0]+=k0*u0; accU[0][1]+=k0*u1; accU[0][2]+=k0*u2; accU[0][3]+=k0*u3;
      accU[1][0]+=k1*u0; accU[1][1]+=k1*u1; accU[1][2]+=k1*u2; accU[1][3]+=k1*u3;
      accU[2][0]+=k2*u0; accU[2][1]+=k2*u1; accU[2][2]+=k2*u2; accU[2][3]+=k2*u3;
      accU[3][0]+=k3*u0; accU[3][1]+=k3*u1; accU[3][2]+=k3*u2; accU[3][3]+=k3*u3;
    }
    const float bl = Bv[63];
#pragma unroll
    for (int i = 0; i < 4; ++i) {
      const int a = 4*tr+i;
      float4 pv, uv;
      pv.x = ((a == 4*tc+0) ? bl : 0.f) - accP[i][0];
      pv.y = ((a == 4*tc+1) ? bl : 0.f) - accP[i][1];
      pv.z = ((a == 4*tc+2) ? bl : 0.f) - accP[i][2];
      pv.w = ((a == 4*tc+3) ? bl : 0.f) - accP[i][3];
      uv.x = accU[i][0]; uv.y = accU[i][1]; uv.z = accU[i][2]; uv.w = accU[i][3];
      *(float4*)(Pg + off + a*64 + 4*tc) = pv;
      *(float4*)(Ug + off + a*64 + 4*tc) = uv;
    }
  }
  // ---- G = (Q K^T) .* E_incl  into As
  {
    float acc[4][4] = {};
    for (int d = 0; d < 64; ++d) {
      float a0 = bf2f(Qh[(4*tr+0)*66+d]), a1 = bf2f(Qh[(4*tr+1)*66+d]),
            a2 = bf2f(Qh[(4*tr+2)*66+d]), a3 = bf2f(Qh[(4*tr+3)*66+d]);
      float b0 = Ks[(4*tc+0)*65+d], b1 = Ks[(4*tc+1)*65+d],
            b2 = Ks[(4*tc+2)*65+d], b3 = Ks[(4*tc+3)*65+d];
      acc[0][0]+=a0*b0; acc[0][1]+=a0*b1; acc[0][2]+=a0*b2; acc[0][3]+=a0*b3;
      acc[1][0]+=a1*b0; acc[1][1]+=a1*b1; acc[1][2]+=a1*b2; acc[1][3]+=a1*b3;
      acc[2][0]+=a2*b0; acc[2][1]+=a2*b1; acc[2][2]+=a2*b2; acc[2][3]+=a2*b3;
      acc[3][0]+=a3*b0; acc[3][1]+=a3*b1; acc[3][2]+=a3*b2; acc[3][3]+=a3*b3;
    }
#pragma unroll
    for (int i = 0; i < 4; ++i)
#pragma unroll
      for (int j = 0; j < 4; ++j) {
        const int t = 4*tr+i, s = 4*tc+j;
        As[t*65+s] = (s <= t) ? acc[i][j] * __expf(bcs[t] - bcs[s]) : 0.f;
      }
  }
  __syncthreads();
  // ---- R = diag(e^b)Q - G W ; Y = G u
  {
    float accR[4][4] = {}, accY[4][4] = {};
    for (int s = 0; s < 64; ++s) {
      float g0 = As[(4*tr+0)*65+s], g1 = As[(4*tr+1)*65+s],
            g2 = As[(4*tr+2)*65+s], g3 = As[(4*tr+3)*65+s];
      float w0 = Ws[s*65+4*tc+0], w1 = Ws[s*65+4*tc+1],
            w2 = Ws[s*65+4*tc+2], w3 = Ws[s*65+4*tc+3];
      float u0 = us[s*65+4*tc+0], u1 = us[s*65+4*tc+1],
            u2 = us[s*65+4*tc+2], u3 = us[s*65+4*tc+3];
      accR[0][0]+=g0*w0; accR[0][1]+=g0*w1; accR[0][2]+=g0*w2; accR[0][3]+=g0*w3;
      accR[1][0]+=g1*w0; accR[1][1]+=g1*w1; accR[1][2]+=g1*w2; accR[1][3]+=g1*w3;
      accR[2][0]+=g2*w0; accR[2][1]+=g2*w1; accR[2][2]+=g2*w2; accR[2][3]+=g2*w3;
      accR[3][0]+=g3*w0; accR[3][1]+=g3*w1; accR[3][2]+=g3*w2; accR[3][3]+=g3*w3;
      accY[0][0]+=g0*u0; accY[0][1]+=g0*u1; accY[0][2]+=g0*u2; accY[0][3]+=g0*u3;
      accY[1][0]+=g1*u0; accY[1][1]+=g1*u1; accY[1][2]+=g1*u2; accY[1][3]+=g1*u3;
      accY[2][0]+=g2*u0; accY[2][1]+=g2*u1; accY[2][2]+=g2*u2; accY[2][3]+=g2*u3;
      accY[3][0]+=g3*u0; accY[3][1]+=g3*u1; accY[3][2]+=g3*u2; accY[3][3]+=g3*u3;
    }
#pragma unroll
    for (int i = 0; i < 4; ++i) {
      const int t = 4*tr+i;
      const float bt = Bv[t];
      float4 rv, yv;
      rv.x = bt*bf2f(Qh[t*66+4*tc+0]) - accR[i][0];
      rv.y = bt*bf2f(Qh[t*66+4*tc+1]) - accR[i][1];
      rv.z = bt*bf2f(Qh[t*66+4*tc+2]) - accR[i][2];
      rv.w = bt*bf2f(Qh[t*66+4*tc+3]) - accR[i][3];
      yv.x = accY[i][0]; yv.y = accY[i][1]; yv.z = accY[i][2]; yv.w = accY[i][3];
      *(float4*)(Rg + off + t*64 + 4*tc) = rv;
      *(float4*)(Yg + off + t*64 + 4*tc) = yv;
    }
  }
}

// ---- phase B: S_{c+1} = P_c S_c + U_c ; store S_in per chunk. 128 blocks.
__global__ __launch_bounds__(256) void state_step(
    const float* __restrict__ Pg, const float* __restrict__ Ug,
    float* __restrict__ Sst) {
  __shared__ float Ps[64 * 65];
  __shared__ float Sc[64 * 20];
  const int blk = blockIdx.x;
  const int bh = blk >> 2, j0 = (blk & 3) * 16;
  const int tid = threadIdx.x;
  const int a = tid >> 2, jb = (tid & 3) * 4;
  const int pr = tid >> 4, pc = (tid & 15) * 4;
  for (int i = tid; i < 64 * 20; i += 256) Sc[i] = 0.f;
  float4 pre[4];
  {
    const size_t off0 = (size_t)bh * 32 * 4096;
#pragma unroll
    for (int i = 0; i < 4; ++i)
      pre[i] = *(const float4*)(Pg + off0 + (size_t)(i * 16 + pr) * 64 + pc);
  }
  __syncthreads();
  for (int c = 0; c < 32; ++c) {
    const size_t off = ((size_t)bh * 32 + c) * 4096;
#pragma unroll
    for (int i = 0; i < 4; ++i) {
      float* dst = &Ps[(i * 16 + pr) * 65 + pc];
      dst[0] = pre[i].x; dst[1] = pre[i].y; dst[2] = pre[i].z; dst[3] = pre[i].w;
    }
    __syncthreads();
    if (c + 1 < 32) {
      const size_t offn = off + 4096;
#pragma unroll
      for (int i = 0; i < 4; ++i)
        pre[i] = *(const float4*)(Pg + offn + (size_t)(i * 16 + pr) * 64 + pc);
    }
    // write out S_in for this chunk
    *(float4*)(Sst + off + (size_t)a * 64 + j0 + jb) = *(const float4*)(&Sc[a * 20 + jb]);
    float4 acc = *(const float4*)(Ug + off + (size_t)a * 64 + j0 + jb);
    for (int k = 0; k < 64; ++k) {
      const float pv = Ps[a * 65 + k];
      const float4 sv = *(const float4*)(&Sc[k * 20 + jb]);
      acc.x += pv * sv.x; acc.y += pv * sv.y;
      acc.z += pv * sv.z; acc.w += pv * sv.w;
    }
    __syncthreads();
    *(float4*)(&Sc[a * 20 + jb]) = acc;
    __syncthreads();
  }
}

// ---- phase C: O = R S_in + Y   (1024 parallel blocks)
__global__ __launch_bounds__(256) void chunk_out(
    const float* __restrict__ Rg, const float* __restrict__ Yg,
    const float* __restrict__ Sst, float* __restrict__ obuf) {
  __shared__ float Rs[64 * 65];
  __shared__ float Ss[64 * 65];
  const int bid = blockIdx.x;
  const int c = bid & 31, bh = bid >> 5, b = bh >> 4, h = bh & 15;
  const int tid = threadIdx.x;
  const size_t off = (size_t)bid * 4096;
#pragma unroll
  for (int i = 0; i < 4; ++i) {
    const int idx = i * 1024 + tid * 4;
    const int row = idx >> 6, col = idx & 63;
    float4 rv = *(const float4*)(Rg + off + idx);
    float4 sv = *(const float4*)(Sst + off + idx);
    float* rd = &Rs[row * 65 + col];
    rd[0]=rv.x; rd[1]=rv.y; rd[2]=rv.z; rd[3]=rv.w;
    float* sd = &Ss[row * 65 + col];
    sd[0]=sv.x; sd[1]=sv.y; sd[2]=sv.z; sd[3]=sv.w;
  }
  __syncthreads();
  const int tr = tid >> 4, tc = tid & 15;
  float acc[4][4];
#pragma unroll
  for (int i = 0; i < 4; ++i) {
    const float4 y = *(const float4*)(Yg + off + (4*tr+i)*64 + 4*tc);
    acc[i][0] = y.x; acc[i][1] = y.y; acc[i][2] = y.z; acc[i][3] = y.w;
  }
  for (int k = 0; k < 64; ++k) {
    float r0 = Rs[(4*tr+0)*65+k], r1 = Rs[(4*tr+1)*65+k],
          r2 = Rs[(4*tr+2)*65+k], r3 = Rs[(4*tr+3)*65+k];
    float s0 = Ss[k*65+4*tc+0], s1 = Ss[k*65+4*tc+1],
          s2 = Ss[k*65+4*tc+2], s3 = Ss[k*65+4*tc+3];
    acc[0][0]+=r0*s0; acc[0][1]+=r0*s1; acc[0][2]+=r0*s2; acc[0][3]+=r0*s3;
    acc[1][0]+=r1*s0; acc[1][1]+=r1*s1; acc[1][2]+=r1*s2; acc[1][3]+=r1*s3;
    acc[2][0]+=r2*s0; acc[2][1]+=r2*s1; acc[2][2]+=r2*s2; acc[2][3]+=r2*s3;
    acc[3][0]+=r3*s0; acc[3][1]+=r3*s1; acc[3][2]+=r3*s2; acc[3][3]+=r3*s3;
  }
#pragma unroll
  for (int i = 0; i < 4; ++i) {
    const int t = 4*tr+i;
    float4 ov; ov.x = acc[i][0]; ov.y = acc[i][1]; ov.z = acc[i][2]; ov.w = acc[i][3];
    *(float4*)(obuf + ((size_t)(b * TLEN + c * 64 + t) * NHEAD + h) * 64 + 4*tc) = ov;
  }
}

// ------------------------------------------- gated RMSNorm epilogue -> bf16
__global__ __launch_bounds__(256) void rms_gate(
    const float* __restrict__ obuf, const u16* __restrict__ gatep,
    const float* __restrict__ norm_w, u16* __restrict__ outb) {
  const int flat = blockIdx.x * 256 + threadIdx.x;
  const int d = flat & 63;
  const float o = obuf[flat];
  const float s = wave_sum(o * o);
  const float inv = rsqrtf(s * (1.0f / 64.0f) + 1e-5f);
  const float gt = bf2f(gatep[flat]);
  const float res = o * inv * norm_w[d] * (gt / (1.f + __expf(-gt)));
  outb[flat] = f2bf(res);
}

extern "C" void kernel_launch(void* const* d_in, const int* in_sizes, int n_in,
                              void* d_out, int out_size, void* d_ws, size_t ws_size,
                              hipStream_t stream) {
  const float* hidden = (const float*)d_in[0];
  const float* Wq     = (const float*)d_in[1];
  const float* Wk     = (const float*)d_in[2];
  const float* Wv     = (const float*)d_in[3];
  const float* cq     = (const float*)d_in[4];
  const float* ck     = (const float*)d_in[5];
  const float* cv     = (const float*)d_in[6];
  const float* Wb     = (const float*)d_in[7];
  const float* Wa     = (const float*)d_in[8];
  const float* A_log  = (const float*)d_in[9];
  const float* dtb    = (const float*)d_in[10];
  const float* Wg     = (const float*)d_in[11];
  const float* nw     = (const float*)d_in[12];
  const float* Wo     = (const float*)d_in[13];

  char* p = (char*)d_ws;
  const size_t MB = 1u << 20;
  u16* h_bf = (u16*)(p + 0 * MB);     // 8 MB   (dead after gemm #1)
  u16* wq_b = (u16*)(p + 8 * MB);     // 2 MB
  u16* wk_b = (u16*)(p + 10 * MB);
  u16* wv_b = (u16*)(p + 12 * MB);
  u16* wg_b = (u16*)(p + 14 * MB);
  float* Pg = (float*)(p + 0 * MB);   // 16 MB, aliases h_bf..wg_b (dead then)
  u16* wo_b = (u16*)(p + 16 * MB);    // 2 MB (live till end)
  u16* qp_b = (u16*)(p + 18 * MB);    // 8 MB
  u16* kp_b = (u16*)(p + 26 * MB);    // 8 MB
  u16* vp_b = (u16*)(p + 34 * MB);    // 8 MB
  u16* gp_b = (u16*)(p + 42 * MB);    // 8 MB (live till rms_gate)
  float* obuf = (float*)qp_b;         // 16 MB, aliases qp+kp (dead after convs)
  u16*   of_b = vp_b;                 // 8 MB, aliases vp (dead after conv v)
  u16* qn_b = (u16*)(p + 50 * MB);    // 8 MB
  u16* kn_b = (u16*)(p + 58 * MB);
  u16* vn_b = (u16*)(p + 66 * MB);
  float* gbuf = (float*)(p + 74 * MB);        // 256 KB
  float* bbuf = (float*)(p + 74 * MB + 262144);
  float* Ug  = (float*)(p + 75 * MB);  // 16 MB
  float* Rg  = (float*)(p + 91 * MB);  // 16 MB
  float* Yg  = (float*)(p + 107 * MB); // 16 MB
  float* Sst = (float*)(p + 123 * MB); // 16 MB  (total 139 MB)

  cvt_all<<<9216, 256, 0, stream>>>(hidden, Wq, Wk, Wv, Wg, Wo,
                                    h_bf, wq_b, wk_b, wv_b, wg_b, wo_b);

  gemm_lin<u16, 4><<<dim3(8, 32, 4), 256, 0, stream>>>(
      h_bf, wq_b, wk_b, wv_b, wg_b, qp_b, kp_b, vp_b, gp_b, 4096, 1024, 1024);

  small_proj<<<512, 256, 0, stream>>>(hidden, Wb, Wa, A_log, dtb, bbuf, gbuf);

  conv_norm3<<<49152, 256, 0, stream>>>(qp_b, cq, ck, cv, qn_b);

  const int lds_bytes = 19008 * 4;  // 76032 -> 2 blocks/CU
  hipFuncSetAttribute((const void*)chunk_local,
                      hipFuncAttributeMaxDynamicSharedMemorySize, lds_bytes);
  chunk_local<<<1024, 256, lds_bytes, stream>>>(qn_b, kn_b, vn_b, gbuf, bbuf,
                                                Pg, Ug, Rg, Yg);
  state_step<<<128, 256, 0, stream>>>(Pg, Ug, Sst);
  chunk_out<<<1024, 256, 0, stream>>>(Rg, Yg, Sst, obuf);

  rms_gate<<<16384, 256, 0, stream>>>(obuf, gp_b, nw, of_b);

  gemm_lin<float, 2><<<dim3(8, 64, 1), 256, 0, stream>>>(
      of_b, wo_b, wo_b, wo_b, wo_b,
      (float*)d_out, (float*)d_out, (float*)d_out, (float*)d_out, 4096, 1024, 1024);
}

// Round 4
// 355.264 us; speedup vs baseline: 4.7726x; 1.1499x over previous
//
#include <hip/hip_runtime.h>
#include <hip/hip_bf16.h>

typedef unsigned short u16;
typedef __attribute__((ext_vector_type(4))) float f32x4;
typedef __attribute__((ext_vector_type(8))) short bf16x8;

#define TLEN 2048
#define NHEAD 16
#define HD 1024

__device__ inline u16 f2bf(float f) {
  unsigned x = __float_as_uint(f);
  return (u16)((x + 0x7fffu + ((x >> 16) & 1u)) >> 16);
}
__device__ inline float bf2f(u16 u) { return __uint_as_float(((unsigned)u) << 16); }

__device__ inline float wave_sum(float x) {
  x += __shfl_xor(x, 1);  x += __shfl_xor(x, 2);  x += __shfl_xor(x, 4);
  x += __shfl_xor(x, 8);  x += __shfl_xor(x, 16); x += __shfl_xor(x, 32);
  return x;
}

__device__ inline void storev(float* p, float v) { *p = v; }
__device__ inline void storev(u16* p, float v)   { *p = f2bf(v); }

// swizzled byte offset into a [64 rows][64 bf16 = 128B] LDS tile
__device__ inline int swz(int row, int col) {
  return (row << 7) + ((((col >> 3) ^ (row & 7)) << 4)) + ((col & 7) << 1);
}
// MFMA fragment load (16B, kslot = kk*4+fq; k-chunk = kslot*8, same perm for A/B)
__device__ inline bf16x8 frag(const u16* base, int row, int kslot) {
  return *(const bf16x8*)((const char*)base + (row << 7) +
                          (((kslot ^ (row & 7)) << 4)));
}

// ------------------------------------------------- fused fp32 -> bf16 converts
__global__ __launch_bounds__(256) void cvt_all(
    const float* __restrict__ h,  const float* __restrict__ wq,
    const float* __restrict__ wk, const float* __restrict__ wv,
    const float* __restrict__ wg, const float* __restrict__ wo,
    u16* __restrict__ dh,  u16* __restrict__ dwq, u16* __restrict__ dwk,
    u16* __restrict__ dwv, u16* __restrict__ dwg, u16* __restrict__ dwo) {
  const int b = blockIdx.x;
  const float* s; u16* d; size_t i;
  if (b < 4096) { s = h; d = dh; i = (size_t)b * 256 + threadIdx.x; }
  else {
    const int wsel = (b - 4096) >> 10;
    i = (size_t)((b - 4096) & 1023) * 256 + threadIdx.x;
    switch (wsel) {
      case 0: s = wq; d = dwq; break;
      case 1: s = wk; d = dwk; break;
      case 2: s = wv; d = dwv; break;
      case 3: s = wg; d = dwg; break;
      default: s = wo; d = dwo; break;
    }
  }
  float4 v = *(const float4*)(s + i * 4);
  ushort4 u;
  u.x = f2bf(v.x); u.y = f2bf(v.y); u.z = f2bf(v.z); u.w = f2bf(v.w);
  *(ushort4*)(d + i * 4) = u;
}

// ------------------------------------------------- bf16 MFMA linear: C = A*W^T
template <typename OutT, int MT>
__global__ __launch_bounds__(256) void gemm_lin(
    const u16* __restrict__ A,
    const u16* __restrict__ W0p, const u16* __restrict__ W1p,
    const u16* __restrict__ W2p, const u16* __restrict__ W3p,
    OutT* __restrict__ C0, OutT* __restrict__ C1,
    OutT* __restrict__ C2, OutT* __restrict__ C3,
    int M, int N, int K) {
  const u16* W; OutT* C;
  switch (blockIdx.z) {
    case 0: W = W0p; C = C0; break;
    case 1: W = W1p; C = C1; break;
    case 2: W = W2p; C = C2; break;
    default: W = W3p; C = C3; break;
  }
  const int tid = threadIdx.x;
  const int lane = tid & 63, wid = tid >> 6;
  const int wr = wid >> 1, wc = wid & 1;
  const int fr = lane & 15, fq = lane >> 4;
  const int row0 = blockIdx.y * (MT * 32), col0 = blockIdx.x * 128;
  __shared__ __align__(16) u16 As[MT * 32 * 64];
  __shared__ __align__(16) u16 Bs[128 * 64];

  const u16* aSrc[MT]; const u16* bSrc[4];
#pragma unroll
  for (int it = 0; it < MT; ++it) {
    const int c = it * 256 + tid;
    const int r = c >> 3, cc = c & 7, sc = cc ^ (r & 7);
    aSrc[it] = A + (size_t)(row0 + r) * K + sc * 8;
  }
#pragma unroll
  for (int it = 0; it < 4; ++it) {
    const int c = it * 256 + tid;
    const int r = c >> 3, cc = c & 7, sc = cc ^ (r & 7);
    bSrc[it] = W + (size_t)(col0 + r) * K + sc * 8;
  }
  int aOff[MT][2], bOff[4][2];
#pragma unroll
  for (int m = 0; m < MT; ++m)
#pragma unroll
    for (int kk = 0; kk < 2; ++kk) {
      const int ra = wr * (MT * 16) + m * 16 + fr;
      aOff[m][kk] = ra * 128 + ((((kk << 2) | fq) ^ (fr & 7)) << 4);
    }
#pragma unroll
  for (int n = 0; n < 4; ++n)
#pragma unroll
    for (int kk = 0; kk < 2; ++kk) {
      const int rb = wc * 64 + n * 16 + fr;
      bOff[n][kk] = rb * 128 + ((((kk << 2) | fq) ^ (fr & 7)) << 4);
    }

  f32x4 acc[MT][4] = {};
  for (int k0 = 0; k0 < K; k0 += 64) {
#pragma unroll
    for (int it = 0; it < MT; ++it)
      __builtin_amdgcn_global_load_lds(
          (const __attribute__((address_space(1))) void*)(aSrc[it] + k0),
          (__attribute__((address_space(3))) void*)((char*)As + (it * 256 + wid * 64) * 16),
          16, 0, 0);
#pragma unroll
    for (int it = 0; it < 4; ++it)
      __builtin_amdgcn_global_load_lds(
          (const __attribute__((address_space(1))) void*)(bSrc[it] + k0),
          (__attribute__((address_space(3))) void*)((char*)Bs + (it * 256 + wid * 64) * 16),
          16, 0, 0);
    __syncthreads();
#pragma unroll
    for (int kk = 0; kk < 2; ++kk) {
      bf16x8 af[MT], bfr[4];
#pragma unroll
      for (int m = 0; m < MT; ++m)
        af[m] = *(const bf16x8*)((const char*)As + aOff[m][kk]);
#pragma unroll
      for (int n = 0; n < 4; ++n)
        bfr[n] = *(const bf16x8*)((const char*)Bs + bOff[n][kk]);
#pragma unroll
      for (int m = 0; m < MT; ++m)
#pragma unroll
        for (int n = 0; n < 4; ++n)
          acc[m][n] = __builtin_amdgcn_mfma_f32_16x16x32_bf16(af[m], bfr[n], acc[m][n], 0, 0, 0);
    }
    __syncthreads();
  }
#pragma unroll
  for (int m = 0; m < MT; ++m)
#pragma unroll
    for (int n = 0; n < 4; ++n)
#pragma unroll
      for (int r = 0; r < 4; ++r) {
        const int gr = row0 + wr * (MT * 16) + m * 16 + fq * 4 + r;
        const int gc = col0 + wc * 64 + n * 16 + fr;
        storev(&C[(size_t)gr * N + gc], acc[m][n][r]);
      }
}

// --------------------------------------- fp32 beta/g projections (N=32, exact)
__global__ __launch_bounds__(256) void small_proj(
    const float* __restrict__ hidden, const float* __restrict__ Wb,
    const float* __restrict__ Wa, const float* __restrict__ A_log,
    const float* __restrict__ dt_bias, float* __restrict__ bbuf,
    float* __restrict__ gbuf) {
  const int col = threadIdx.x & 31, rowi = threadIdx.x >> 5;
  const int row = blockIdx.x * 8 + rowi;
  const int h = col & 15;
  const float* w = (col < 16 ? Wb : Wa) + (size_t)h * HD;
  const float* x = hidden + (size_t)row * HD;
  float s = 0.f;
#pragma unroll 4
  for (int k2 = 0; k2 < 256; ++k2) {
    float4 xv = *(const float4*)(x + k2 * 4);
    float4 wv = *(const float4*)(w + k2 * 4);
    s += xv.x * wv.x + xv.y * wv.y + xv.z * wv.z + xv.w * wv.w;
  }
  if (col < 16) {
    bbuf[row * NHEAD + h] = 1.f / (1.f + __expf(-s));
  } else {
    float xs = s + dt_bias[h];
    float sp = (xs > 20.f) ? xs : log1pf(__expf(xs));
    gbuf[row * NHEAD + h] = -__expf(A_log[h]) * sp;
  }
}

// ===================== chunk-parallel gated delta rule (MFMA) =================
// Fused: causal dwconv(K=4)+silu+l2norm staging, A=KK^T & G=QK^T via MFMA,
// barrier-free Minv solve (M Minv = I), W/u/P/U/R/Y via MFMA.
__global__ __launch_bounds__(256) void chunk_local(
    const u16* __restrict__ qp, const u16* __restrict__ kp, const u16* __restrict__ vp,
    const float* __restrict__ cq, const float* __restrict__ ck, const float* __restrict__ cv,
    const float* __restrict__ gbuf, const float* __restrict__ bbuf,
    float* __restrict__ Pg, float* __restrict__ Ug,
    float* __restrict__ Rg, float* __restrict__ Yg) {
  __shared__ __align__(16) u16 Kb[64 * 64];
  __shared__ __align__(16) u16 Qb[64 * 64];
  __shared__ __align__(16) u16 K2T[64 * 64];
  __shared__ __align__(16) u16 KWt[64 * 64];   // -> uTh
  __shared__ __align__(16) u16 Vt[64 * 64];    // -> Gb
  __shared__ __align__(16) u16 Zb[64 * 64];    // Minv, row-major [t][s]
  __shared__ __align__(16) u16 Mb[64 * 68];    // bf16 M (strict lower) -> WTh
  __shared__ float bcs[64], bet[64], e2v[64], Bv[64];
  u16* WTh = Mb;
  u16* uTh = KWt;
  u16* Gb  = Vt;

  const int bid = blockIdx.x;            // bh*32 + c
  const int c = bid & 31, bh = bid >> 5;
  const int b = bh >> 4, h = bh & 15;
  const int tid = threadIdx.x;

  // ---- phase 1: decay prefix + Zb row 0 init
  if (tid < 64) {
    const size_t gi = (size_t)((b * TLEN + c * 64) + tid) * NHEAD + h;
    bet[tid] = bbuf[gi];
    float v = gbuf[gi];
#pragma unroll
    for (int ofs = 1; ofs < 64; ofs <<= 1) {
      float tt = __shfl_up(v, ofs);
      if (tid >= ofs) v += tt;
    }
    bcs[tid] = v;
  } else if (tid < 128) {
    const int j = tid - 64;
    *(u16*)((char*)Zb + swz(0, j)) = (j == 0) ? (u16)0x3F80 : (u16)0;
  }
  __syncthreads();
  if (tid < 64) {
    const float blast = bcs[63];
    Bv[tid]  = __expf(bcs[tid]);
    e2v[tid] = __expf(blast - bcs[tid]);
  }
  __syncthreads();

  // ---- phase 2: staging with fused conv+silu+l2norm
  {
    const int dq = (tid & 15) * 4;            // constant channel group
    const int col = h * 64 + dq;
    float4 wq4[4], wk4[4], wv4[4];
#pragma unroll
    for (int jj = 0; jj < 4; ++jj) {
      wq4[jj] = *(const float4*)(cq + (size_t)(col + jj) * 4);
      wk4[jj] = *(const float4*)(ck + (size_t)(col + jj) * 4);
      wv4[jj] = *(const float4*)(cv + (size_t)(col + jj) * 4);
    }
#pragma unroll
    for (int i = 0; i < 4; ++i) {
      const int r = i * 16 + (tid >> 4);
      const int tcur = c * 64 + r;
      ushort4 xq[4], xk[4], xv[4];
#pragma unroll
      for (int m = 0; m < 4; ++m) {
        const int tt = tcur - 3 + m;
        if (tt >= 0) {
          const size_t a = (size_t)(b * TLEN + tt) * HD + col;
          xq[m] = *(const ushort4*)(qp + a);
          xk[m] = *(const ushort4*)(kp + a);
          xv[m] = *(const ushort4*)(vp + a);
        } else {
          xq[m] = ushort4{0, 0, 0, 0}; xk[m] = xq[m]; xv[m] = xq[m];
        }
      }
      float yq[4], yk[4], yv[4];
      float ssq = 0.f, ssk = 0.f;
#pragma unroll
      for (int jj = 0; jj < 4; ++jj) {
        const u16* pq = (const u16*)&xq[0];
        float aq = wq4[jj].x * bf2f(((const u16*)&xq[0])[jj]) +
                   wq4[jj].y * bf2f(((const u16*)&xq[1])[jj]) +
                   wq4[jj].z * bf2f(((const u16*)&xq[2])[jj]) +
                   wq4[jj].w * bf2f(((const u16*)&xq[3])[jj]);
        float ak = wk4[jj].x * bf2f(((const u16*)&xk[0])[jj]) +
                   wk4[jj].y * bf2f(((const u16*)&xk[1])[jj]) +
                   wk4[jj].z * bf2f(((const u16*)&xk[2])[jj]) +
                   wk4[jj].w * bf2f(((const u16*)&xk[3])[jj]);
        float av = wv4[jj].x * bf2f(((const u16*)&xv[0])[jj]) +
                   wv4[jj].y * bf2f(((const u16*)&xv[1])[jj]) +
                   wv4[jj].z * bf2f(((const u16*)&xv[2])[jj]) +
                   wv4[jj].w * bf2f(((const u16*)&xv[3])[jj]);
        yq[jj] = aq / (1.f + __expf(-aq));
        yk[jj] = ak / (1.f + __expf(-ak));
        yv[jj] = av / (1.f + __expf(-av));
        ssq += yq[jj] * yq[jj];
        ssk += yk[jj] * yk[jj];
      }
      ssq += __shfl_xor(ssq, 1); ssq += __shfl_xor(ssq, 2);
      ssq += __shfl_xor(ssq, 4); ssq += __shfl_xor(ssq, 8);
      ssk += __shfl_xor(ssk, 1); ssk += __shfl_xor(ssk, 2);
      ssk += __shfl_xor(ssk, 4); ssk += __shfl_xor(ssk, 8);
      const float qsc = rsqrtf(ssq + 1e-6f) * 0.125f;
      const float ksc = rsqrtf(ssk + 1e-6f);
      const float bR = bet[r], e2R = e2v[r], wscR = bR * Bv[r];
      ushort4 qo, ko;
      float kvf[4];
#pragma unroll
      for (int jj = 0; jj < 4; ++jj) kvf[jj] = yk[jj] * ksc;
      qo.x = f2bf(yq[0] * qsc); qo.y = f2bf(yq[1] * qsc);
      qo.z = f2bf(yq[2] * qsc); qo.w = f2bf(yq[3] * qsc);
      ko.x = f2bf(kvf[0]); ko.y = f2bf(kvf[1]);
      ko.z = f2bf(kvf[2]); ko.w = f2bf(kvf[3]);
      *(ushort4*)((char*)Qb + swz(r, dq)) = qo;
      *(ushort4*)((char*)Kb + swz(r, dq)) = ko;
#pragma unroll
      for (int jj = 0; jj < 4; ++jj) {
        *(u16*)((char*)K2T + swz(dq + jj, r)) = f2bf(kvf[jj] * e2R);
        *(u16*)((char*)KWt + swz(dq + jj, r)) = f2bf(kvf[jj] * wscR);
        *(u16*)((char*)Vt  + swz(dq + jj, r)) = f2bf(yv[jj] * bR);
      }
    }
  }
  __syncthreads();

  const int w = tid >> 6, lane = tid & 63, fr = lane & 15, fq = lane >> 4;
  // ---- phase 3: A = K K^T via MFMA -> masked M (bf16)
  {
    bf16x8 ka0 = frag(Kb, w * 16 + fr, fq);
    bf16x8 ka1 = frag(Kb, w * 16 + fr, 4 + fq);
#pragma unroll
    for (int tc = 0; tc < 4; ++tc) {
      bf16x8 kb0 = frag(Kb, tc * 16 + fr, fq);
      bf16x8 kb1 = frag(Kb, tc * 16 + fr, 4 + fq);
      f32x4 a = {};
      a = __builtin_amdgcn_mfma_f32_16x16x32_bf16(ka0, kb0, a, 0, 0, 0);
      a = __builtin_amdgcn_mfma_f32_16x16x32_bf16(ka1, kb1, a, 0, 0, 0);
#pragma unroll
      for (int rr = 0; rr < 4; ++rr) {
        const int t = w * 16 + fq * 4 + rr, s = tc * 16 + fr;
        const float mv = (s < t) ? bet[t] * __expf(bcs[t] - bcs[s]) * a[rr] : 0.f;
        Mb[t * 68 + s] = f2bf(mv);
      }
    }
  }
  __syncthreads();

  // ---- phase 4: barrier-free solve M Minv = I (lane j owns column j)
  if (tid < 64) {
    const int j = tid;
    for (int t = 1; t < 64; ++t) {
      float acc = (t == j) ? 1.f : 0.f;
      const u16* mrow = Mb + t * 68;
      int s = 0;
      for (; s + 4 <= t; s += 4) {
        ushort4 m4 = *(const ushort4*)(mrow + s);
        acc -= bf2f(m4.x) * bf2f(*(const u16*)((const char*)Zb + swz(s, j)));
        acc -= bf2f(m4.y) * bf2f(*(const u16*)((const char*)Zb + swz(s + 1, j)));
        acc -= bf2f(m4.z) * bf2f(*(const u16*)((const char*)Zb + swz(s + 2, j)));
        acc -= bf2f(m4.w) * bf2f(*(const u16*)((const char*)Zb + swz(s + 3, j)));
      }
      for (; s < t; ++s)
        acc -= bf2f(mrow[s]) * bf2f(*(const u16*)((const char*)Zb + swz(s, j)));
      *(u16*)((char*)Zb + swz(t, j)) = f2bf(acc);
    }
  }
  __syncthreads();

  // ---- phase 5: W = Minv*RHSw, u = Minv*RHSv (transposed out), G = QK^T
  f32x4 accW[4], accu[4], accG[4];
  {
    bf16x8 kw0 = frag(KWt, w * 16 + fr, fq), kw1 = frag(KWt, w * 16 + fr, 4 + fq);
    bf16x8 vt0 = frag(Vt,  w * 16 + fr, fq), vt1 = frag(Vt,  w * 16 + fr, 4 + fq);
    bf16x8 qa0 = frag(Qb,  w * 16 + fr, fq), qa1 = frag(Qb,  w * 16 + fr, 4 + fq);
#pragma unroll
    for (int tc = 0; tc < 4; ++tc) {
      bf16x8 z0 = frag(Zb, tc * 16 + fr, fq), z1 = frag(Zb, tc * 16 + fr, 4 + fq);
      bf16x8 kb0 = frag(Kb, tc * 16 + fr, fq), kb1 = frag(Kb, tc * 16 + fr, 4 + fq);
      f32x4 aw = {}, au = {}, ag = {};
      aw = __builtin_amdgcn_mfma_f32_16x16x32_bf16(kw0, z0, aw, 0, 0, 0);
      aw = __builtin_amdgcn_mfma_f32_16x16x32_bf16(kw1, z1, aw, 0, 0, 0);
      au = __builtin_amdgcn_mfma_f32_16x16x32_bf16(vt0, z0, au, 0, 0, 0);
      au = __builtin_amdgcn_mfma_f32_16x16x32_bf16(vt1, z1, au, 0, 0, 0);
      ag = __builtin_amdgcn_mfma_f32_16x16x32_bf16(qa0, kb0, ag, 0, 0, 0);
      ag = __builtin_amdgcn_mfma_f32_16x16x32_bf16(qa1, kb1, ag, 0, 0, 0);
      accW[tc] = aw; accu[tc] = au; accG[tc] = ag;
    }
  }
  __syncthreads();
  // ---- phase 6: write WTh (over M), uTh (over KWt), Gb (over Vt)
#pragma unroll
  for (int tc = 0; tc < 4; ++tc)
#pragma unroll
    for (int rr = 0; rr < 4; ++rr) {
      const int ro = w * 16 + fq * 4 + rr, co = tc * 16 + fr;
      *(u16*)((char*)WTh + swz(ro, co)) = f2bf(accW[tc][rr]);
      *(u16*)((char*)uTh + swz(ro, co)) = f2bf(accu[tc][rr]);
      const float gv = (co <= ro) ? accG[tc][rr] * __expf(bcs[ro] - bcs[co]) : 0.f;
      *(u16*)((char*)Gb + swz(ro, co)) = f2bf(gv);
    }
  __syncthreads();

  // ---- phase 7: P,U,R,Y via MFMA + epilogue
  {
    bf16x8 k20 = frag(K2T, w * 16 + fr, fq), k21 = frag(K2T, w * 16 + fr, 4 + fq);
    bf16x8 g0  = frag(Gb,  w * 16 + fr, fq), g1  = frag(Gb,  w * 16 + fr, 4 + fq);
    const float bl = Bv[63];
    const size_t off = (size_t)bid * 4096;
#pragma unroll
    for (int tc = 0; tc < 4; ++tc) {
      bf16x8 w0 = frag(WTh, tc * 16 + fr, fq), w1 = frag(WTh, tc * 16 + fr, 4 + fq);
      bf16x8 u0 = frag(uTh, tc * 16 + fr, fq), u1 = frag(uTh, tc * 16 + fr, 4 + fq);
      f32x4 aP = {}, aU = {}, aR = {}, aY = {};
      aP = __builtin_amdgcn_mfma_f32_16x16x32_bf16(k20, w0, aP, 0, 0, 0);
      aP = __builtin_amdgcn_mfma_f32_16x16x32_bf16(k21, w1, aP, 0, 0, 0);
      aU = __builtin_amdgcn_mfma_f32_16x16x32_bf16(k20, u0, aU, 0, 0, 0);
      aU = __builtin_amdgcn_mfma_f32_16x16x32_bf16(k21, u1, aU, 0, 0, 0);
      aR = __builtin_amdgcn_mfma_f32_16x16x32_bf16(g0, w0, aR, 0, 0, 0);
      aR = __builtin_amdgcn_mfma_f32_16x16x32_bf16(g1, w1, aR, 0, 0, 0);
      aY = __builtin_amdgcn_mfma_f32_16x16x32_bf16(g0, u0, aY, 0, 0, 0);
      aY = __builtin_amdgcn_mfma_f32_16x16x32_bf16(g1, u1, aY, 0, 0, 0);
#pragma unroll
      for (int rr = 0; rr < 4; ++rr) {
        const int ar = w * 16 + fq * 4 + rr, cb = tc * 16 + fr;
        Pg[off + ar * 64 + cb] = ((ar == cb) ? bl : 0.f) - aP[rr];
        Ug[off + ar * 64 + cb] = aU[rr];
        const float qv = bf2f(*(const u16*)((const char*)Qb + swz(ar, cb)));
        Rg[off + ar * 64 + cb] = Bv[ar] * qv - aR[rr];
        Yg[off + ar * 64 + cb] = aY[rr];
      }
    }
  }
}

// ---- phase B: S_{c+1} = P_c S_c + U_c ; store S_in per chunk. 128 blocks.
__global__ __launch_bounds__(256) void state_step(
    const float* __restrict__ Pg, const float* __restrict__ Ug,
    float* __restrict__ Sst) {
  __shared__ float Ps[64 * 65];
  __shared__ float Sc[64 * 20];
  const int blk = blockIdx.x;
  const int bh = blk >> 2, j0 = (blk & 3) * 16;
  const int tid = threadIdx.x;
  const int a = tid >> 2, jb = (tid & 3) * 4;
  const int pr = tid >> 4, pc = (tid & 15) * 4;
  for (int i = tid; i < 64 * 20; i += 256) Sc[i] = 0.f;
  float4 pre[4];
  {
    const size_t off0 = (size_t)bh * 32 * 4096;
#pragma unroll
    for (int i = 0; i < 4; ++i)
      pre[i] = *(const float4*)(Pg + off0 + (size_t)(i * 16 + pr) * 64 + pc);
  }
  __syncthreads();
  for (int c = 0; c < 32; ++c) {
    const size_t off = ((size_t)bh * 32 + c) * 4096;
#pragma unroll
    for (int i = 0; i < 4; ++i) {
      float* dst = &Ps[(i * 16 + pr) * 65 + pc];
      dst[0] = pre[i].x; dst[1] = pre[i].y; dst[2] = pre[i].z; dst[3] = pre[i].w;
    }
    __syncthreads();
    if (c + 1 < 32) {
      const size_t offn = off + 4096;
#pragma unroll
      for (int i = 0; i < 4; ++i)
        pre[i] = *(const float4*)(Pg + offn + (size_t)(i * 16 + pr) * 64 + pc);
    }
    *(float4*)(Sst + off + (size_t)a * 64 + j0 + jb) = *(const float4*)(&Sc[a * 20 + jb]);
    float4 acc = *(const float4*)(Ug + off + (size_t)a * 64 + j0 + jb);
    for (int k = 0; k < 64; ++k) {
      const float pv = Ps[a * 65 + k];
      const float4 sv = *(const float4*)(&Sc[k * 20 + jb]);
      acc.x += pv * sv.x; acc.y += pv * sv.y;
      acc.z += pv * sv.z; acc.w += pv * sv.w;
    }
    __syncthreads();
    *(float4*)(&Sc[a * 20 + jb]) = acc;
    __syncthreads();
  }
}

// ---- phase C: O = R S_in + Y   (1024 parallel blocks)
__global__ __launch_bounds__(256) void chunk_out(
    const float* __restrict__ Rg, const float* __restrict__ Yg,
    const float* __restrict__ Sst, float* __restrict__ obuf) {
  __shared__ float Rs[64 * 65];
  __shared__ float Ss[64 * 65];
  const int bid = blockIdx.x;
  const int c = bid & 31, bh = bid >> 5, b = bh >> 4, h = bh & 15;
  const int tid = threadIdx.x;
  const size_t off = (size_t)bid * 4096;
#pragma unroll
  for (int i = 0; i < 4; ++i) {
    const int idx = i * 1024 + tid * 4;
    const int row = idx >> 6, col = idx & 63;
    float4 rv = *(const float4*)(Rg + off + idx);
    float4 sv = *(const float4*)(Sst + off + idx);
    float* rd = &Rs[row * 65 + col];
    rd[0]=rv.x; rd[1]=rv.y; rd[2]=rv.z; rd[3]=rv.w;
    float* sd = &Ss[row * 65 + col];
    sd[0]=sv.x; sd[1]=sv.y; sd[2]=sv.z; sd[3]=sv.w;
  }
  __syncthreads();
  const int tr = tid >> 4, tc = tid & 15;
  float acc[4][4];
#pragma unroll
  for (int i = 0; i < 4; ++i) {
    const float4 y = *(const float4*)(Yg + off + (4*tr+i)*64 + 4*tc);
    acc[i][0] = y.x; acc[i][1] = y.y; acc[i][2] = y.z; acc[i][3] = y.w;
  }
  for (int k = 0; k < 64; ++k) {
    float r0 = Rs[(4*tr+0)*65+k], r1 = Rs[(4*tr+1)*65+k],
          r2 = Rs[(4*tr+2)*65+k], r3 = Rs[(4*tr+3)*65+k];
    float s0 = Ss[k*65+4*tc+0], s1 = Ss[k*65+4*tc+1],
          s2 = Ss[k*65+4*tc+2], s3 = Ss[k*65+4*tc+3];
    acc[0][0]+=r0*s0; acc[0][1]+=r0*s1; acc[0][2]+=r0*s2; acc[0][3]+=r0*s3;
    acc[1][0]+=r1*s0; acc[1][1]+=r1*s1; acc[1][2]+=r1*s2; acc[1][3]+=r1*s3;
    acc[2][0]+=r2*s0; acc[2][1]+=r2*s1; acc[2][2]+=r2*s2; acc[2][3]+=r2*s3;
    acc[3][0]+=r3*s0; acc[3][1]+=r3*s1; acc[3][2]+=r3*s2; acc[3][3]+=r3*s3;
  }
#pragma unroll
  for (int i = 0; i < 4; ++i) {
    const int t = 4*tr+i;
    float4 ov; ov.x = acc[i][0]; ov.y = acc[i][1]; ov.z = acc[i][2]; ov.w = acc[i][3];
    *(float4*)(obuf + ((size_t)(b * TLEN + c * 64 + t) * NHEAD + h) * 64 + 4*tc) = ov;
  }
}

// ------------------------------------------- gated RMSNorm epilogue -> bf16
__global__ __launch_bounds__(256) void rms_gate(
    const float* __restrict__ obuf, const u16* __restrict__ gatep,
    const float* __restrict__ norm_w, u16* __restrict__ outb) {
  const int flat = blockIdx.x * 256 + threadIdx.x;
  const int d = flat & 63;
  const float o = obuf[flat];
  const float s = wave_sum(o * o);
  const float inv = rsqrtf(s * (1.0f / 64.0f) + 1e-5f);
  const float gt = bf2f(gatep[flat]);
  const float res = o * inv * norm_w[d] * (gt / (1.f + __expf(-gt)));
  outb[flat] = f2bf(res);
}

extern "C" void kernel_launch(void* const* d_in, const int* in_sizes, int n_in,
                              void* d_out, int out_size, void* d_ws, size_t ws_size,
                              hipStream_t stream) {
  const float* hidden = (const float*)d_in[0];
  const float* Wq     = (const float*)d_in[1];
  const float* Wk     = (const float*)d_in[2];
  const float* Wv     = (const float*)d_in[3];
  const float* cq     = (const float*)d_in[4];
  const float* ck     = (const float*)d_in[5];
  const float* cv     = (const float*)d_in[6];
  const float* Wb     = (const float*)d_in[7];
  const float* Wa     = (const float*)d_in[8];
  const float* A_log  = (const float*)d_in[9];
  const float* dtb    = (const float*)d_in[10];
  const float* Wg     = (const float*)d_in[11];
  const float* nw     = (const float*)d_in[12];
  const float* Wo     = (const float*)d_in[13];

  char* p = (char*)d_ws;
  const size_t MB = 1u << 20;
  u16* h_bf = (u16*)(p + 0 * MB);     // 8 MB   (dead after gemm #1)
  u16* wq_b = (u16*)(p + 8 * MB);     // 2 MB
  u16* wk_b = (u16*)(p + 10 * MB);
  u16* wv_b = (u16*)(p + 12 * MB);
  u16* wg_b = (u16*)(p + 14 * MB);
  float* Pg = (float*)(p + 0 * MB);   // 16 MB, aliases h_bf..wg_b (dead then)
  u16* wo_b = (u16*)(p + 16 * MB);    // 2 MB (live till end)
  u16* qp_b = (u16*)(p + 18 * MB);    // 8 MB raw q projection (live thru chunk_local)
  u16* kp_b = (u16*)(p + 26 * MB);    // 8 MB
  u16* vp_b = (u16*)(p + 34 * MB);    // 8 MB
  u16* gp_b = (u16*)(p + 42 * MB);    // 8 MB (live till rms_gate)
  float* obuf = (float*)qp_b;         // 16 MB, aliases qp+kp (dead after chunk_local)
  u16*   of_b = vp_b;                 // 8 MB, aliases vp
  float* gbuf = (float*)(p + 50 * MB);        // 256 KB
  float* bbuf = (float*)(p + 50 * MB + 262144);
  float* Ug  = (float*)(p + 51 * MB);  // 16 MB
  float* Rg  = (float*)(p + 67 * MB);  // 16 MB
  float* Yg  = (float*)(p + 83 * MB);  // 16 MB
  float* Sst = (float*)(p + 99 * MB);  // 16 MB  (total 115 MB)

  cvt_all<<<9216, 256, 0, stream>>>(hidden, Wq, Wk, Wv, Wg, Wo,
                                    h_bf, wq_b, wk_b, wv_b, wg_b, wo_b);

  gemm_lin<u16, 4><<<dim3(8, 32, 4), 256, 0, stream>>>(
      h_bf, wq_b, wk_b, wv_b, wg_b, qp_b, kp_b, vp_b, gp_b, 4096, 1024, 1024);

  small_proj<<<512, 256, 0, stream>>>(hidden, Wb, Wa, A_log, dtb, bbuf, gbuf);

  chunk_local<<<1024, 256, 0, stream>>>(qp_b, kp_b, vp_b, cq, ck, cv,
                                        gbuf, bbuf, Pg, Ug, Rg, Yg);
  state_step<<<128, 256, 0, stream>>>(Pg, Ug, Sst);
  chunk_out<<<1024, 256, 0, stream>>>(Rg, Yg, Sst, obuf);

  rms_gate<<<16384, 256, 0, stream>>>(obuf, gp_b, nw, of_b);

  gemm_lin<float, 2><<<dim3(8, 64, 1), 256, 0, stream>>>(
      of_b, wo_b, wo_b, wo_b, wo_b,
      (float*)d_out, (float*)d_out, (float*)d_out, (float*)d_out, 4096, 1024, 1024);
}

// Round 5
// 266.845 us; speedup vs baseline: 6.3540x; 1.3314x over previous
//
#include <hip/hip_runtime.h>
#include <hip/hip_bf16.h>

typedef unsigned short u16;
typedef __attribute__((ext_vector_type(4))) float f32x4;
typedef __attribute__((ext_vector_type(8))) short bf16x8;

#define TLEN 2048
#define NHEAD 16
#define HD 1024

__device__ inline u16 f2bf(float f) {
  unsigned x = __float_as_uint(f);
  return (u16)((x + 0x7fffu + ((x >> 16) & 1u)) >> 16);
}
__device__ inline float bf2f(u16 u) { return __uint_as_float(((unsigned)u) << 16); }

__device__ inline float wave_sum(float x) {
  x += __shfl_xor(x, 1);  x += __shfl_xor(x, 2);  x += __shfl_xor(x, 4);
  x += __shfl_xor(x, 8);  x += __shfl_xor(x, 16); x += __shfl_xor(x, 32);
  return x;
}

__device__ inline void storev(float* p, float v) { *p = v; }
__device__ inline void storev(u16* p, float v)   { *p = f2bf(v); }

// swizzled byte offset into a [64 rows][64 bf16 = 128B] LDS tile
__device__ inline int swz(int row, int col) {
  return (row << 7) + ((((col >> 3) ^ (row & 7)) << 4)) + ((col & 7) << 1);
}
// MFMA fragment load (16B, kslot in 0..7 -> k-chunk kslot*8; same perm A/B)
__device__ inline bf16x8 frag(const u16* base, int row, int kslot) {
  return *(const bf16x8*)((const char*)base + (row << 7) +
                          (((kslot ^ (row & 7)) << 4)));
}

// ------------------------------------------------- fused fp32 -> bf16 converts
__global__ __launch_bounds__(256) void cvt_all(
    const float* __restrict__ h,  const float* __restrict__ wq,
    const float* __restrict__ wk, const float* __restrict__ wv,
    const float* __restrict__ wg, const float* __restrict__ wo,
    u16* __restrict__ dh,  u16* __restrict__ dwq, u16* __restrict__ dwk,
    u16* __restrict__ dwv, u16* __restrict__ dwg, u16* __restrict__ dwo) {
  const int b = blockIdx.x;
  const float* s; u16* d; size_t i;
  if (b < 4096) { s = h; d = dh; i = (size_t)b * 256 + threadIdx.x; }
  else {
    const int wsel = (b - 4096) >> 10;
    i = (size_t)((b - 4096) & 1023) * 256 + threadIdx.x;
    switch (wsel) {
      case 0: s = wq; d = dwq; break;
      case 1: s = wk; d = dwk; break;
      case 2: s = wv; d = dwv; break;
      case 3: s = wg; d = dwg; break;
      default: s = wo; d = dwo; break;
    }
  }
  float4 v = *(const float4*)(s + i * 4);
  ushort4 u;
  u.x = f2bf(v.x); u.y = f2bf(v.y); u.z = f2bf(v.z); u.w = f2bf(v.w);
  *(ushort4*)(d + i * 4) = u;
}

// ------------------------------------------------- bf16 MFMA linear: C = A*W^T
template <typename OutT, int MT>
__global__ __launch_bounds__(256) void gemm_lin(
    const u16* __restrict__ A,
    const u16* __restrict__ W0p, const u16* __restrict__ W1p,
    const u16* __restrict__ W2p, const u16* __restrict__ W3p,
    OutT* __restrict__ C0, OutT* __restrict__ C1,
    OutT* __restrict__ C2, OutT* __restrict__ C3,
    int M, int N, int K) {
  const u16* W; OutT* C;
  switch (blockIdx.z) {
    case 0: W = W0p; C = C0; break;
    case 1: W = W1p; C = C1; break;
    case 2: W = W2p; C = C2; break;
    default: W = W3p; C = C3; break;
  }
  const int tid = threadIdx.x;
  const int lane = tid & 63, wid = tid >> 6;
  const int wr = wid >> 1, wc = wid & 1;
  const int fr = lane & 15, fq = lane >> 4;
  const int row0 = blockIdx.y * (MT * 32), col0 = blockIdx.x * 128;
  __shared__ __align__(16) u16 As[MT * 32 * 64];
  __shared__ __align__(16) u16 Bs[128 * 64];

  const u16* aSrc[MT]; const u16* bSrc[4];
#pragma unroll
  for (int it = 0; it < MT; ++it) {
    const int c = it * 256 + tid;
    const int r = c >> 3, cc = c & 7, sc = cc ^ (r & 7);
    aSrc[it] = A + (size_t)(row0 + r) * K + sc * 8;
  }
#pragma unroll
  for (int it = 0; it < 4; ++it) {
    const int c = it * 256 + tid;
    const int r = c >> 3, cc = c & 7, sc = cc ^ (r & 7);
    bSrc[it] = W + (size_t)(col0 + r) * K + sc * 8;
  }
  int aOff[MT][2], bOff[4][2];
#pragma unroll
  for (int m = 0; m < MT; ++m)
#pragma unroll
    for (int kk = 0; kk < 2; ++kk) {
      const int ra = wr * (MT * 16) + m * 16 + fr;
      aOff[m][kk] = ra * 128 + ((((kk << 2) | fq) ^ (fr & 7)) << 4);
    }
#pragma unroll
  for (int n = 0; n < 4; ++n)
#pragma unroll
    for (int kk = 0; kk < 2; ++kk) {
      const int rb = wc * 64 + n * 16 + fr;
      bOff[n][kk] = rb * 128 + ((((kk << 2) | fq) ^ (fr & 7)) << 4);
    }

  f32x4 acc[MT][4] = {};
  for (int k0 = 0; k0 < K; k0 += 64) {
#pragma unroll
    for (int it = 0; it < MT; ++it)
      __builtin_amdgcn_global_load_lds(
          (const __attribute__((address_space(1))) void*)(aSrc[it] + k0),
          (__attribute__((address_space(3))) void*)((char*)As + (it * 256 + wid * 64) * 16),
          16, 0, 0);
#pragma unroll
    for (int it = 0; it < 4; ++it)
      __builtin_amdgcn_global_load_lds(
          (const __attribute__((address_space(1))) void*)(bSrc[it] + k0),
          (__attribute__((address_space(3))) void*)((char*)Bs + (it * 256 + wid * 64) * 16),
          16, 0, 0);
    __syncthreads();
#pragma unroll
    for (int kk = 0; kk < 2; ++kk) {
      bf16x8 af[MT], bfr[4];
#pragma unroll
      for (int m = 0; m < MT; ++m)
        af[m] = *(const bf16x8*)((const char*)As + aOff[m][kk]);
#pragma unroll
      for (int n = 0; n < 4; ++n)
        bfr[n] = *(const bf16x8*)((const char*)Bs + bOff[n][kk]);
#pragma unroll
      for (int m = 0; m < MT; ++m)
#pragma unroll
        for (int n = 0; n < 4; ++n)
          acc[m][n] = __builtin_amdgcn_mfma_f32_16x16x32_bf16(af[m], bfr[n], acc[m][n], 0, 0, 0);
    }
    __syncthreads();
  }
#pragma unroll
  for (int m = 0; m < MT; ++m)
#pragma unroll
    for (int n = 0; n < 4; ++n)
#pragma unroll
      for (int r = 0; r < 4; ++r) {
        const int gr = row0 + wr * (MT * 16) + m * 16 + fq * 4 + r;
        const int gc = col0 + wc * 64 + n * 16 + fr;
        storev(&C[(size_t)gr * N + gc], acc[m][n][r]);
      }
}

// --------------------------------------- fp32 beta/g projections (N=32, exact)
__global__ __launch_bounds__(256) void small_proj(
    const float* __restrict__ hidden, const float* __restrict__ Wb,
    const float* __restrict__ Wa, const float* __restrict__ A_log,
    const float* __restrict__ dt_bias, float* __restrict__ bbuf,
    float* __restrict__ gbuf) {
  const int col = threadIdx.x & 31, rowi = threadIdx.x >> 5;
  const int row = blockIdx.x * 8 + rowi;
  const int h = col & 15;
  const float* w = (col < 16 ? Wb : Wa) + (size_t)h * HD;
  const float* x = hidden + (size_t)row * HD;
  float s = 0.f;
#pragma unroll 4
  for (int k2 = 0; k2 < 256; ++k2) {
    float4 xv = *(const float4*)(x + k2 * 4);
    float4 wv = *(const float4*)(w + k2 * 4);
    s += xv.x * wv.x + xv.y * wv.y + xv.z * wv.z + xv.w * wv.w;
  }
  if (col < 16) {
    bbuf[row * NHEAD + h] = 1.f / (1.f + __expf(-s));
  } else {
    float xs = s + dt_bias[h];
    float sp = (xs > 20.f) ? xs : log1pf(__expf(xs));
    gbuf[row * NHEAD + h] = -__expf(A_log[h]) * sp;
  }
}

// ===================== chunk-parallel gated delta rule (MFMA) =================
// Fused conv+silu+l2norm staging; A=KK^T, G=QK^T via MFMA; BLOCKED Minv solve:
// per 16-row block, cross-block correction via MFMA (unfinalized Zt rows are
// zero => contribute 0), in-block 16-step substitution in registers with
// broadcast M reads; W/u/P/U/R/Y via MFMA.
__global__ __launch_bounds__(256) void chunk_local(
    const u16* __restrict__ qp, const u16* __restrict__ kp, const u16* __restrict__ vp,
    const float* __restrict__ cq, const float* __restrict__ ck, const float* __restrict__ cv,
    const float* __restrict__ gbuf, const float* __restrict__ bbuf,
    float* __restrict__ Pg, float* __restrict__ Ug,
    float* __restrict__ Rg, float* __restrict__ Yg) {
  __shared__ __align__(16) u16 Kb[64 * 64];
  __shared__ __align__(16) u16 Qb[64 * 64];
  __shared__ __align__(16) u16 K2T[64 * 64];
  __shared__ __align__(16) u16 KWt[64 * 64];   // -> uTh
  __shared__ __align__(16) u16 Vt[64 * 64];    // -> Gb
  __shared__ __align__(16) u16 Zb[64 * 64];    // Minv row-major (swizzled)
  __shared__ __align__(16) u16 Zt[64 * 64];    // Minv transposed (swizzled)
  __shared__ __align__(16) u16 Mb[64 * 72];    // bf16 M (strict lower), stride 72
  __shared__ __align__(16) float Cb[16 * 64];  // correction tile
  __shared__ float bcs[64], bet[64], e2v[64], Bv[64];
  u16* WTh = Mb;
  u16* uTh = KWt;
  u16* Gb  = Vt;

  const int bid = blockIdx.x;            // bh*32 + c
  const int c = bid & 31, bh = bid >> 5;
  const int b = bh >> 4, h = bh & 15;
  const int tid = threadIdx.x;

  // ---- phase 0: zero Zt (unfinalized rows must read as 0 in corrections)
  {
    int* zp = (int*)Zt;
#pragma unroll
    for (int i = 0; i < 8; ++i) zp[tid + 256 * i] = 0;
  }
  // ---- phase 1: decay prefix
  if (tid < 64) {
    const size_t gi = (size_t)((b * TLEN + c * 64) + tid) * NHEAD + h;
    bet[tid] = bbuf[gi];
    float v = gbuf[gi];
#pragma unroll
    for (int ofs = 1; ofs < 64; ofs <<= 1) {
      float tt = __shfl_up(v, ofs);
      if (tid >= ofs) v += tt;
    }
    bcs[tid] = v;
  }
  __syncthreads();
  if (tid < 64) {
    const float blast = bcs[63];
    Bv[tid]  = __expf(bcs[tid]);
    e2v[tid] = __expf(blast - bcs[tid]);
  }
  __syncthreads();

  // ---- phase 2: staging with fused conv+silu+l2norm
  {
    const int dq = (tid & 15) * 4;            // constant channel group
    const int col = h * 64 + dq;
    float4 wq4[4], wk4[4], wv4[4];
#pragma unroll
    for (int jj = 0; jj < 4; ++jj) {
      wq4[jj] = *(const float4*)(cq + (size_t)(col + jj) * 4);
      wk4[jj] = *(const float4*)(ck + (size_t)(col + jj) * 4);
      wv4[jj] = *(const float4*)(cv + (size_t)(col + jj) * 4);
    }
#pragma unroll
    for (int i = 0; i < 4; ++i) {
      const int r = i * 16 + (tid >> 4);
      const int tcur = c * 64 + r;
      ushort4 xq[4], xk[4], xv[4];
#pragma unroll
      for (int m = 0; m < 4; ++m) {
        const int tt = tcur - 3 + m;
        if (tt >= 0) {
          const size_t a = (size_t)(b * TLEN + tt) * HD + col;
          xq[m] = *(const ushort4*)(qp + a);
          xk[m] = *(const ushort4*)(kp + a);
          xv[m] = *(const ushort4*)(vp + a);
        } else {
          xq[m] = ushort4{0, 0, 0, 0}; xk[m] = xq[m]; xv[m] = xq[m];
        }
      }
      float yq[4], yk[4], yv[4];
      float ssq = 0.f, ssk = 0.f;
#pragma unroll
      for (int jj = 0; jj < 4; ++jj) {
        float aq = wq4[jj].x * bf2f(((const u16*)&xq[0])[jj]) +
                   wq4[jj].y * bf2f(((const u16*)&xq[1])[jj]) +
                   wq4[jj].z * bf2f(((const u16*)&xq[2])[jj]) +
                   wq4[jj].w * bf2f(((const u16*)&xq[3])[jj]);
        float ak = wk4[jj].x * bf2f(((const u16*)&xk[0])[jj]) +
                   wk4[jj].y * bf2f(((const u16*)&xk[1])[jj]) +
                   wk4[jj].z * bf2f(((const u16*)&xk[2])[jj]) +
                   wk4[jj].w * bf2f(((const u16*)&xk[3])[jj]);
        float av = wv4[jj].x * bf2f(((const u16*)&xv[0])[jj]) +
                   wv4[jj].y * bf2f(((const u16*)&xv[1])[jj]) +
                   wv4[jj].z * bf2f(((const u16*)&xv[2])[jj]) +
                   wv4[jj].w * bf2f(((const u16*)&xv[3])[jj]);
        yq[jj] = aq / (1.f + __expf(-aq));
        yk[jj] = ak / (1.f + __expf(-ak));
        yv[jj] = av / (1.f + __expf(-av));
        ssq += yq[jj] * yq[jj];
        ssk += yk[jj] * yk[jj];
      }
      ssq += __shfl_xor(ssq, 1); ssq += __shfl_xor(ssq, 2);
      ssq += __shfl_xor(ssq, 4); ssq += __shfl_xor(ssq, 8);
      ssk += __shfl_xor(ssk, 1); ssk += __shfl_xor(ssk, 2);
      ssk += __shfl_xor(ssk, 4); ssk += __shfl_xor(ssk, 8);
      const float qsc = rsqrtf(ssq + 1e-6f) * 0.125f;
      const float ksc = rsqrtf(ssk + 1e-6f);
      const float bR = bet[r], e2R = e2v[r], wscR = bR * Bv[r];
      ushort4 qo, ko;
      float kvf[4];
#pragma unroll
      for (int jj = 0; jj < 4; ++jj) kvf[jj] = yk[jj] * ksc;
      qo.x = f2bf(yq[0] * qsc); qo.y = f2bf(yq[1] * qsc);
      qo.z = f2bf(yq[2] * qsc); qo.w = f2bf(yq[3] * qsc);
      ko.x = f2bf(kvf[0]); ko.y = f2bf(kvf[1]);
      ko.z = f2bf(kvf[2]); ko.w = f2bf(kvf[3]);
      *(ushort4*)((char*)Qb + swz(r, dq)) = qo;
      *(ushort4*)((char*)Kb + swz(r, dq)) = ko;
#pragma unroll
      for (int jj = 0; jj < 4; ++jj) {
        *(u16*)((char*)K2T + swz(dq + jj, r)) = f2bf(kvf[jj] * e2R);
        *(u16*)((char*)KWt + swz(dq + jj, r)) = f2bf(kvf[jj] * wscR);
        *(u16*)((char*)Vt  + swz(dq + jj, r)) = f2bf(yv[jj] * bR);
      }
    }
  }
  __syncthreads();

  const int w = tid >> 6, lane = tid & 63, fr = lane & 15, fq = lane >> 4;
  // ---- phase 3: A = K K^T via MFMA -> masked M (bf16, stride 72)
  {
    bf16x8 ka0 = frag(Kb, w * 16 + fr, fq);
    bf16x8 ka1 = frag(Kb, w * 16 + fr, 4 + fq);
#pragma unroll
    for (int tc = 0; tc < 4; ++tc) {
      bf16x8 kb0 = frag(Kb, tc * 16 + fr, fq);
      bf16x8 kb1 = frag(Kb, tc * 16 + fr, 4 + fq);
      f32x4 a = {};
      a = __builtin_amdgcn_mfma_f32_16x16x32_bf16(ka0, kb0, a, 0, 0, 0);
      a = __builtin_amdgcn_mfma_f32_16x16x32_bf16(ka1, kb1, a, 0, 0, 0);
#pragma unroll
      for (int rr = 0; rr < 4; ++rr) {
        const int t = w * 16 + fq * 4 + rr, s = tc * 16 + fr;
        const float mv = (s < t) ? bet[t] * __expf(bcs[t] - bcs[s]) * a[rr] : 0.f;
        Mb[t * 72 + s] = f2bf(mv);
      }
    }
  }
  __syncthreads();

  // ---- phase 4: BLOCKED solve M Minv = I (4 blocks of 16 rows)
#pragma unroll 1
  for (int bi = 0; bi < 4; ++bi) {
    // cross-block correction C = M[rows bi]*Minv^T over full K=64
    // (Zt rows not yet finalized are zero => contribute nothing)
    {
      const char* mrow = (const char*)Mb + (size_t)(bi * 16 + fr) * 144;
      bf16x8 ma0 = *(const bf16x8*)(mrow + fq * 16);
      bf16x8 ma1 = *(const bf16x8*)(mrow + 64 + fq * 16);
      bf16x8 zt0 = frag(Zt, w * 16 + fr, fq);
      bf16x8 zt1 = frag(Zt, w * 16 + fr, 4 + fq);
      f32x4 a = {};
      a = __builtin_amdgcn_mfma_f32_16x16x32_bf16(ma0, zt0, a, 0, 0, 0);
      a = __builtin_amdgcn_mfma_f32_16x16x32_bf16(ma1, zt1, a, 0, 0, 0);
#pragma unroll
      for (int rr = 0; rr < 4; ++rr)
        Cb[(fq * 4 + rr) * 64 + w * 16 + fr] = a[rr];
    }
    __syncthreads();
    if (tid < 64) {
      const int j = tid;
      float z[16];
#pragma unroll
      for (int t = 0; t < 16; ++t) {
        float acc = ((bi * 16 + t) == j ? 1.f : 0.f) - Cb[t * 64 + j];
        const u16* mrow = Mb + (size_t)(bi * 16 + t) * 72 + bi * 16;
#pragma unroll
        for (int s = 0; s < t; ++s) acc -= bf2f(mrow[s]) * z[s];
        z[t] = acc;
      }
#pragma unroll
      for (int t = 0; t < 16; ++t)
        *(u16*)((char*)Zb + swz(bi * 16 + t, j)) = f2bf(z[t]);
#pragma unroll
      for (int t4 = 0; t4 < 4; ++t4) {
        ushort4 zz;
        zz.x = f2bf(z[t4 * 4 + 0]); zz.y = f2bf(z[t4 * 4 + 1]);
        zz.z = f2bf(z[t4 * 4 + 2]); zz.w = f2bf(z[t4 * 4 + 3]);
        *(ushort4*)((char*)Zt + swz(j, bi * 16 + t4 * 4)) = zz;
      }
    }
    __syncthreads();
  }

  // ---- phase 5: W = Minv*RHSw, u = Minv*RHSv (transposed out), G = QK^T
  f32x4 accW[4], accu[4], accG[4];
  {
    bf16x8 kw0 = frag(KWt, w * 16 + fr, fq), kw1 = frag(KWt, w * 16 + fr, 4 + fq);
    bf16x8 vt0 = frag(Vt,  w * 16 + fr, fq), vt1 = frag(Vt,  w * 16 + fr, 4 + fq);
    bf16x8 qa0 = frag(Qb,  w * 16 + fr, fq), qa1 = frag(Qb,  w * 16 + fr, 4 + fq);
#pragma unroll
    for (int tc = 0; tc < 4; ++tc) {
      bf16x8 z0 = frag(Zb, tc * 16 + fr, fq), z1 = frag(Zb, tc * 16 + fr, 4 + fq);
      bf16x8 kb0 = frag(Kb, tc * 16 + fr, fq), kb1 = frag(Kb, tc * 16 + fr, 4 + fq);
      f32x4 aw = {}, au = {}, ag = {};
      aw = __builtin_amdgcn_mfma_f32_16x16x32_bf16(kw0, z0, aw, 0, 0, 0);
      aw = __builtin_amdgcn_mfma_f32_16x16x32_bf16(kw1, z1, aw, 0, 0, 0);
      au = __builtin_amdgcn_mfma_f32_16x16x32_bf16(vt0, z0, au, 0, 0, 0);
      au = __builtin_amdgcn_mfma_f32_16x16x32_bf16(vt1, z1, au, 0, 0, 0);
      ag = __builtin_amdgcn_mfma_f32_16x16x32_bf16(qa0, kb0, ag, 0, 0, 0);
      ag = __builtin_amdgcn_mfma_f32_16x16x32_bf16(qa1, kb1, ag, 0, 0, 0);
      accW[tc] = aw; accu[tc] = au; accG[tc] = ag;
    }
  }
  __syncthreads();
  // ---- phase 6: write WTh (over Mb), uTh (over KWt), Gb (over Vt)
#pragma unroll
  for (int tc = 0; tc < 4; ++tc)
#pragma unroll
    for (int rr = 0; rr < 4; ++rr) {
      const int ro = w * 16 + fq * 4 + rr, co = tc * 16 + fr;
      *(u16*)((char*)WTh + swz(ro, co)) = f2bf(accW[tc][rr]);
      *(u16*)((char*)uTh + swz(ro, co)) = f2bf(accu[tc][rr]);
      const float gv = (co <= ro) ? accG[tc][rr] * __expf(bcs[ro] - bcs[co]) : 0.f;
      *(u16*)((char*)Gb + swz(ro, co)) = f2bf(gv);
    }
  __syncthreads();

  // ---- phase 7: P,U,R,Y via MFMA + epilogue
  {
    bf16x8 k20 = frag(K2T, w * 16 + fr, fq), k21 = frag(K2T, w * 16 + fr, 4 + fq);
    bf16x8 g0  = frag(Gb,  w * 16 + fr, fq), g1  = frag(Gb,  w * 16 + fr, 4 + fq);
    const float bl = Bv[63];
    const size_t off = (size_t)bid * 4096;
#pragma unroll
    for (int tc = 0; tc < 4; ++tc) {
      bf16x8 w0 = frag(WTh, tc * 16 + fr, fq), w1 = frag(WTh, tc * 16 + fr, 4 + fq);
      bf16x8 u0 = frag(uTh, tc * 16 + fr, fq), u1 = frag(uTh, tc * 16 + fr, 4 + fq);
      f32x4 aP = {}, aU = {}, aR = {}, aY = {};
      aP = __builtin_amdgcn_mfma_f32_16x16x32_bf16(k20, w0, aP, 0, 0, 0);
      aP = __builtin_amdgcn_mfma_f32_16x16x32_bf16(k21, w1, aP, 0, 0, 0);
      aU = __builtin_amdgcn_mfma_f32_16x16x32_bf16(k20, u0, aU, 0, 0, 0);
      aU = __builtin_amdgcn_mfma_f32_16x16x32_bf16(k21, u1, aU, 0, 0, 0);
      aR = __builtin_amdgcn_mfma_f32_16x16x32_bf16(g0, w0, aR, 0, 0, 0);
      aR = __builtin_amdgcn_mfma_f32_16x16x32_bf16(g1, w1, aR, 0, 0, 0);
      aY = __builtin_amdgcn_mfma_f32_16x16x32_bf16(g0, u0, aY, 0, 0, 0);
      aY = __builtin_amdgcn_mfma_f32_16x16x32_bf16(g1, u1, aY, 0, 0, 0);
#pragma unroll
      for (int rr = 0; rr < 4; ++rr) {
        const int ar = w * 16 + fq * 4 + rr, cb = tc * 16 + fr;
        Pg[off + ar * 64 + cb] = ((ar == cb) ? bl : 0.f) - aP[rr];
        Ug[off + ar * 64 + cb] = aU[rr];
        const float qv = bf2f(*(const u16*)((const char*)Qb + swz(ar, cb)));
        Rg[off + ar * 64 + cb] = Bv[ar] * qv - aR[rr];
        Yg[off + ar * 64 + cb] = aY[rr];
      }
    }
  }
}

// ---- phase B: S_{c+1} = P_c S_c + U_c ; store S_in per chunk. 128 blocks.
__global__ __launch_bounds__(256) void state_step(
    const float* __restrict__ Pg, const float* __restrict__ Ug,
    float* __restrict__ Sst) {
  __shared__ float Ps[64 * 65];
  __shared__ float Sc[64 * 20];
  const int blk = blockIdx.x;
  const int bh = blk >> 2, j0 = (blk & 3) * 16;
  const int tid = threadIdx.x;
  const int a = tid >> 2, jb = (tid & 3) * 4;
  const int pr = tid >> 4, pc = (tid & 15) * 4;
  for (int i = tid; i < 64 * 20; i += 256) Sc[i] = 0.f;
  float4 pre[4];
  {
    const size_t off0 = (size_t)bh * 32 * 4096;
#pragma unroll
    for (int i = 0; i < 4; ++i)
      pre[i] = *(const float4*)(Pg + off0 + (size_t)(i * 16 + pr) * 64 + pc);
  }
  __syncthreads();
  for (int c = 0; c < 32; ++c) {
    const size_t off = ((size_t)bh * 32 + c) * 4096;
#pragma unroll
    for (int i = 0; i < 4; ++i) {
      float* dst = &Ps[(i * 16 + pr) * 65 + pc];
      dst[0] = pre[i].x; dst[1] = pre[i].y; dst[2] = pre[i].z; dst[3] = pre[i].w;
    }
    __syncthreads();
    if (c + 1 < 32) {
      const size_t offn = off + 4096;
#pragma unroll
      for (int i = 0; i < 4; ++i)
        pre[i] = *(const float4*)(Pg + offn + (size_t)(i * 16 + pr) * 64 + pc);
    }
    *(float4*)(Sst + off + (size_t)a * 64 + j0 + jb) = *(const float4*)(&Sc[a * 20 + jb]);
    float4 acc = *(const float4*)(Ug + off + (size_t)a * 64 + j0 + jb);
    for (int k = 0; k < 64; ++k) {
      const float pv = Ps[a * 65 + k];
      const float4 sv = *(const float4*)(&Sc[k * 20 + jb]);
      acc.x += pv * sv.x; acc.y += pv * sv.y;
      acc.z += pv * sv.z; acc.w += pv * sv.w;
    }
    __syncthreads();
    *(float4*)(&Sc[a * 20 + jb]) = acc;
    __syncthreads();
  }
}

// ---- phase C: O = R S_in + Y   (1024 parallel blocks)
__global__ __launch_bounds__(256) void chunk_out(
    const float* __restrict__ Rg, const float* __restrict__ Yg,
    const float* __restrict__ Sst, float* __restrict__ obuf) {
  __shared__ float Rs[64 * 65];
  __shared__ float Ss[64 * 65];
  const int bid = blockIdx.x;
  const int c = bid & 31, bh = bid >> 5, b = bh >> 4, h = bh & 15;
  const int tid = threadIdx.x;
  const size_t off = (size_t)bid * 4096;
#pragma unroll
  for (int i = 0; i < 4; ++i) {
    const int idx = i * 1024 + tid * 4;
    const int row = idx >> 6, col = idx & 63;
    float4 rv = *(const float4*)(Rg + off + idx);
    float4 sv = *(const float4*)(Sst + off + idx);
    float* rd = &Rs[row * 65 + col];
    rd[0]=rv.x; rd[1]=rv.y; rd[2]=rv.z; rd[3]=rv.w;
    float* sd = &Ss[row * 65 + col];
    sd[0]=sv.x; sd[1]=sv.y; sd[2]=sv.z; sd[3]=sv.w;
  }
  __syncthreads();
  const int tr = tid >> 4, tc = tid & 15;
  float acc[4][4];
#pragma unroll
  for (int i = 0; i < 4; ++i) {
    const float4 y = *(const float4*)(Yg + off + (4*tr+i)*64 + 4*tc);
    acc[i][0] = y.x; acc[i][1] = y.y; acc[i][2] = y.z; acc[i][3] = y.w;
  }
  for (int k = 0; k < 64; ++k) {
    float r0 = Rs[(4*tr+0)*65+k], r1 = Rs[(4*tr+1)*65+k],
          r2 = Rs[(4*tr+2)*65+k], r3 = Rs[(4*tr+3)*65+k];
    float s0 = Ss[k*65+4*tc+0], s1 = Ss[k*65+4*tc+1],
          s2 = Ss[k*65+4*tc+2], s3 = Ss[k*65+4*tc+3];
    acc[0][0]+=r0*s0; acc[0][1]+=r0*s1; acc[0][2]+=r0*s2; acc[0][3]+=r0*s3;
    acc[1][0]+=r1*s0; acc[1][1]+=r1*s1; acc[1][2]+=r1*s2; acc[1][3]+=r1*s3;
    acc[2][0]+=r2*s0; acc[2][1]+=r2*s1; acc[2][2]+=r2*s2; acc[2][3]+=r2*s3;
    acc[3][0]+=r3*s0; acc[3][1]+=r3*s1; acc[3][2]+=r3*s2; acc[3][3]+=r3*s3;
  }
#pragma unroll
  for (int i = 0; i < 4; ++i) {
    const int t = 4*tr+i;
    float4 ov; ov.x = acc[i][0]; ov.y = acc[i][1]; ov.z = acc[i][2]; ov.w = acc[i][3];
    *(float4*)(obuf + ((size_t)(b * TLEN + c * 64 + t) * NHEAD + h) * 64 + 4*tc) = ov;
  }
}

// ------------------------------------------- gated RMSNorm epilogue -> bf16
__global__ __launch_bounds__(256) void rms_gate(
    const float* __restrict__ obuf, const u16* __restrict__ gatep,
    const float* __restrict__ norm_w, u16* __restrict__ outb) {
  const int flat = blockIdx.x * 256 + threadIdx.x;
  const int d = flat & 63;
  const float o = obuf[flat];
  const float s = wave_sum(o * o);
  const float inv = rsqrtf(s * (1.0f / 64.0f) + 1e-5f);
  const float gt = bf2f(gatep[flat]);
  const float res = o * inv * norm_w[d] * (gt / (1.f + __expf(-gt)));
  outb[flat] = f2bf(res);
}

extern "C" void kernel_launch(void* const* d_in, const int* in_sizes, int n_in,
                              void* d_out, int out_size, void* d_ws, size_t ws_size,
                              hipStream_t stream) {
  const float* hidden = (const float*)d_in[0];
  const float* Wq     = (const float*)d_in[1];
  const float* Wk     = (const float*)d_in[2];
  const float* Wv     = (const float*)d_in[3];
  const float* cq     = (const float*)d_in[4];
  const float* ck     = (const float*)d_in[5];
  const float* cv     = (const float*)d_in[6];
  const float* Wb     = (const float*)d_in[7];
  const float* Wa     = (const float*)d_in[8];
  const float* A_log  = (const float*)d_in[9];
  const float* dtb    = (const float*)d_in[10];
  const float* Wg     = (const float*)d_in[11];
  const float* nw     = (const float*)d_in[12];
  const float* Wo     = (const float*)d_in[13];

  char* p = (char*)d_ws;
  const size_t MB = 1u << 20;
  u16* h_bf = (u16*)(p + 0 * MB);     // 8 MB   (dead after gemm #1)
  u16* wq_b = (u16*)(p + 8 * MB);     // 2 MB
  u16* wk_b = (u16*)(p + 10 * MB);
  u16* wv_b = (u16*)(p + 12 * MB);
  u16* wg_b = (u16*)(p + 14 * MB);
  float* Pg = (float*)(p + 0 * MB);   // 16 MB, aliases h_bf..wg_b (dead then)
  u16* wo_b = (u16*)(p + 16 * MB);    // 2 MB (live till end)
  u16* qp_b = (u16*)(p + 18 * MB);    // 8 MB raw q projection (live thru chunk_local)
  u16* kp_b = (u16*)(p + 26 * MB);    // 8 MB
  u16* vp_b = (u16*)(p + 34 * MB);    // 8 MB
  u16* gp_b = (u16*)(p + 42 * MB);    // 8 MB (live till rms_gate)
  float* obuf = (float*)qp_b;         // 16 MB, aliases qp+kp (dead after chunk_local)
  u16*   of_b = vp_b;                 // 8 MB, aliases vp
  float* gbuf = (float*)(p + 50 * MB);        // 256 KB
  float* bbuf = (float*)(p + 50 * MB + 262144);
  float* Ug  = (float*)(p + 51 * MB);  // 16 MB
  float* Rg  = (float*)(p + 67 * MB);  // 16 MB
  float* Yg  = (float*)(p + 83 * MB);  // 16 MB
  float* Sst = (float*)(p + 99 * MB);  // 16 MB  (total 115 MB)

  cvt_all<<<9216, 256, 0, stream>>>(hidden, Wq, Wk, Wv, Wg, Wo,
                                    h_bf, wq_b, wk_b, wv_b, wg_b, wo_b);

  gemm_lin<u16, 4><<<dim3(8, 32, 4), 256, 0, stream>>>(
      h_bf, wq_b, wk_b, wv_b, wg_b, qp_b, kp_b, vp_b, gp_b, 4096, 1024, 1024);

  small_proj<<<512, 256, 0, stream>>>(hidden, Wb, Wa, A_log, dtb, bbuf, gbuf);

  chunk_local<<<1024, 256, 0, stream>>>(qp_b, kp_b, vp_b, cq, ck, cv,
                                        gbuf, bbuf, Pg, Ug, Rg, Yg);
  state_step<<<128, 256, 0, stream>>>(Pg, Ug, Sst);
  chunk_out<<<1024, 256, 0, stream>>>(Rg, Yg, Sst, obuf);

  rms_gate<<<16384, 256, 0, stream>>>(obuf, gp_b, nw, of_b);

  gemm_lin<float, 2><<<dim3(8, 64, 1), 256, 0, stream>>>(
      of_b, wo_b, wo_b, wo_b, wo_b,
      (float*)d_out, (float*)d_out, (float*)d_out, (float*)d_out, 4096, 1024, 1024);
}

// Round 6
// 209.951 us; speedup vs baseline: 8.0758x; 1.2710x over previous
//
#include <hip/hip_runtime.h>
#include <hip/hip_bf16.h>

typedef unsigned short u16;
typedef __attribute__((ext_vector_type(4))) float f32x4;
typedef __attribute__((ext_vector_type(8))) short bf16x8;

#define TLEN 2048
#define NHEAD 16
#define HD 1024

__device__ inline u16 f2bf(float f) {
  unsigned x = __float_as_uint(f);
  return (u16)((x + 0x7fffu + ((x >> 16) & 1u)) >> 16);
}
__device__ inline float bf2f(u16 u) { return __uint_as_float(((unsigned)u) << 16); }

__device__ inline float wave_sum(float x) {
  x += __shfl_xor(x, 1);  x += __shfl_xor(x, 2);  x += __shfl_xor(x, 4);
  x += __shfl_xor(x, 8);  x += __shfl_xor(x, 16); x += __shfl_xor(x, 32);
  return x;
}

__device__ inline void storev(float* p, float v) { *p = v; }
__device__ inline void storev(u16* p, float v)   { *p = f2bf(v); }

// swizzled byte offset into a [64 rows][64 bf16 = 128B] LDS tile
__device__ inline int swz(int row, int col) {
  return (row << 7) + ((((col >> 3) ^ (row & 7)) << 4)) + ((col & 7) << 1);
}
// MFMA fragment load (16B, kslot in 0..7 -> k-chunk kslot*8; same perm A/B)
__device__ inline bf16x8 frag(const u16* base, int row, int kslot) {
  return *(const bf16x8*)((const char*)base + (row << 7) +
                          (((kslot ^ (row & 7)) << 4)));
}

// ------------------------------------------------- fused fp32 -> bf16 converts
// blocks: [0,4096) hidden -> hi+lo ; [4096,9216) 5 weights -> bf16 ;
// [9216,9248) Wb|Wa concat -> wba hi+lo
__global__ __launch_bounds__(256) void cvt_all(
    const float* __restrict__ h,  const float* __restrict__ wq,
    const float* __restrict__ wk, const float* __restrict__ wv,
    const float* __restrict__ wg, const float* __restrict__ wo,
    const float* __restrict__ Wb, const float* __restrict__ Wa,
    u16* __restrict__ dh,  u16* __restrict__ dhlo,
    u16* __restrict__ dwq, u16* __restrict__ dwk,
    u16* __restrict__ dwv, u16* __restrict__ dwg, u16* __restrict__ dwo,
    u16* __restrict__ dwba_h, u16* __restrict__ dwba_l) {
  const int b = blockIdx.x;
  if (b < 4096) {
    const size_t i = (size_t)b * 256 + threadIdx.x;
    float4 v = *(const float4*)(h + i * 4);
    ushort4 hi, lo;
    hi.x = f2bf(v.x); lo.x = f2bf(v.x - bf2f(hi.x));
    hi.y = f2bf(v.y); lo.y = f2bf(v.y - bf2f(hi.y));
    hi.z = f2bf(v.z); lo.z = f2bf(v.z - bf2f(hi.z));
    hi.w = f2bf(v.w); lo.w = f2bf(v.w - bf2f(hi.w));
    *(ushort4*)(dh + i * 4) = hi;
    *(ushort4*)(dhlo + i * 4) = lo;
  } else if (b < 9216) {
    const int wsel = (b - 4096) >> 10;
    const size_t i = (size_t)((b - 4096) & 1023) * 256 + threadIdx.x;
    const float* s; u16* d;
    switch (wsel) {
      case 0: s = wq; d = dwq; break;
      case 1: s = wk; d = dwk; break;
      case 2: s = wv; d = dwv; break;
      case 3: s = wg; d = dwg; break;
      default: s = wo; d = dwo; break;
    }
    float4 v = *(const float4*)(s + i * 4);
    ushort4 u;
    u.x = f2bf(v.x); u.y = f2bf(v.y); u.z = f2bf(v.z); u.w = f2bf(v.w);
    *(ushort4*)(d + i * 4) = u;
  } else {
    const size_t i = (size_t)(b - 9216) * 256 + threadIdx.x;  // float4 idx, 8192
    const size_t flat = i * 4;
    const float* src = (flat < 16384) ? (Wb + flat) : (Wa + (flat - 16384));
    float4 v = *(const float4*)src;
    ushort4 hi, lo;
    hi.x = f2bf(v.x); lo.x = f2bf(v.x - bf2f(hi.x));
    hi.y = f2bf(v.y); lo.y = f2bf(v.y - bf2f(hi.y));
    hi.z = f2bf(v.z); lo.z = f2bf(v.z - bf2f(hi.z));
    hi.w = f2bf(v.w); lo.w = f2bf(v.w - bf2f(hi.w));
    *(ushort4*)(dwba_h + flat) = hi;
    *(ushort4*)(dwba_l + flat) = lo;
  }
}

// ------------------------------------------------- bf16 MFMA linear: C = A*W^T
template <typename OutT, int MT>
__global__ __launch_bounds__(256) void gemm_lin(
    const u16* __restrict__ A,
    const u16* __restrict__ W0p, const u16* __restrict__ W1p,
    const u16* __restrict__ W2p, const u16* __restrict__ W3p,
    OutT* __restrict__ C0, OutT* __restrict__ C1,
    OutT* __restrict__ C2, OutT* __restrict__ C3,
    int M, int N, int K) {
  const u16* W; OutT* C;
  switch (blockIdx.z) {
    case 0: W = W0p; C = C0; break;
    case 1: W = W1p; C = C1; break;
    case 2: W = W2p; C = C2; break;
    default: W = W3p; C = C3; break;
  }
  const int tid = threadIdx.x;
  const int lane = tid & 63, wid = tid >> 6;
  const int wr = wid >> 1, wc = wid & 1;
  const int fr = lane & 15, fq = lane >> 4;
  const int row0 = blockIdx.y * (MT * 32), col0 = blockIdx.x * 128;
  __shared__ __align__(16) u16 As[MT * 32 * 64];
  __shared__ __align__(16) u16 Bs[128 * 64];

  const u16* aSrc[MT]; const u16* bSrc[4];
#pragma unroll
  for (int it = 0; it < MT; ++it) {
    const int c = it * 256 + tid;
    const int r = c >> 3, cc = c & 7, sc = cc ^ (r & 7);
    aSrc[it] = A + (size_t)(row0 + r) * K + sc * 8;
  }
#pragma unroll
  for (int it = 0; it < 4; ++it) {
    const int c = it * 256 + tid;
    const int r = c >> 3, cc = c & 7, sc = cc ^ (r & 7);
    bSrc[it] = W + (size_t)(col0 + r) * K + sc * 8;
  }
  int aOff[MT][2], bOff[4][2];
#pragma unroll
  for (int m = 0; m < MT; ++m)
#pragma unroll
    for (int kk = 0; kk < 2; ++kk) {
      const int ra = wr * (MT * 16) + m * 16 + fr;
      aOff[m][kk] = ra * 128 + ((((kk << 2) | fq) ^ (fr & 7)) << 4);
    }
#pragma unroll
  for (int n = 0; n < 4; ++n)
#pragma unroll
    for (int kk = 0; kk < 2; ++kk) {
      const int rb = wc * 64 + n * 16 + fr;
      bOff[n][kk] = rb * 128 + ((((kk << 2) | fq) ^ (fr & 7)) << 4);
    }

  f32x4 acc[MT][4] = {};
  for (int k0 = 0; k0 < K; k0 += 64) {
#pragma unroll
    for (int it = 0; it < MT; ++it)
      __builtin_amdgcn_global_load_lds(
          (const __attribute__((address_space(1))) void*)(aSrc[it] + k0),
          (__attribute__((address_space(3))) void*)((char*)As + (it * 256 + wid * 64) * 16),
          16, 0, 0);
#pragma unroll
    for (int it = 0; it < 4; ++it)
      __builtin_amdgcn_global_load_lds(
          (const __attribute__((address_space(1))) void*)(bSrc[it] + k0),
          (__attribute__((address_space(3))) void*)((char*)Bs + (it * 256 + wid * 64) * 16),
          16, 0, 0);
    __syncthreads();
#pragma unroll
    for (int kk = 0; kk < 2; ++kk) {
      bf16x8 af[MT], bfr[4];
#pragma unroll
      for (int m = 0; m < MT; ++m)
        af[m] = *(const bf16x8*)((const char*)As + aOff[m][kk]);
#pragma unroll
      for (int n = 0; n < 4; ++n)
        bfr[n] = *(const bf16x8*)((const char*)Bs + bOff[n][kk]);
#pragma unroll
      for (int m = 0; m < MT; ++m)
#pragma unroll
        for (int n = 0; n < 4; ++n)
          acc[m][n] = __builtin_amdgcn_mfma_f32_16x16x32_bf16(af[m], bfr[n], acc[m][n], 0, 0, 0);
    }
    __syncthreads();
  }
#pragma unroll
  for (int m = 0; m < MT; ++m)
#pragma unroll
    for (int n = 0; n < 4; ++n)
#pragma unroll
      for (int r = 0; r < 4; ++r) {
        const int gr = row0 + wr * (MT * 16) + m * 16 + fq * 4 + r;
        const int gc = col0 + wc * 64 + n * 16 + fr;
        storev(&C[(size_t)gr * N + gc], acc[m][n][r]);
      }
}

// ---------------- beta/g projections via split-precision MFMA skinny GEMM
// C[4096x32] = hidden[4096x1024] . WbWa^T ; s = hi*hi + hi*lo + lo*hi (~fp32)
__global__ __launch_bounds__(256) void small_mfma(
    const u16* __restrict__ hhi, const u16* __restrict__ hlo,
    const u16* __restrict__ whi, const u16* __restrict__ wlo,
    const float* __restrict__ A_log, const float* __restrict__ dtb,
    float* __restrict__ bbuf, float* __restrict__ gbuf) {
  extern __shared__ char smc[];
  u16* Ahi = (u16*)smc;                 // 16 rows x 128 slots x 16B = 32 KB
  u16* Alo = (u16*)(smc + 32768);       // 32 KB
  float* Red = (float*)(smc + 65536);   // [4][16][33] = 8448 B
  const int tid = threadIdx.x;
  const int row0 = blockIdx.x * 16;
  // stage 16x1024 hi+lo; linear LDS dest, pre-swizzled global source (T21)
#pragma unroll
  for (int i = 0; i < 8; ++i) {
    const int slot = tid + 256 * i;
    const int r = slot >> 7, s = slot & 127;
    const int ss = s ^ (r & 7);
    const size_t src = (size_t)(row0 + r) * 1024 + (size_t)ss * 8;
    __builtin_amdgcn_global_load_lds(
        (const __attribute__((address_space(1))) void*)(hhi + src),
        (__attribute__((address_space(3))) void*)(Ahi + (size_t)slot * 8), 16, 0, 0);
    __builtin_amdgcn_global_load_lds(
        (const __attribute__((address_space(1))) void*)(hlo + src),
        (__attribute__((address_space(3))) void*)(Alo + (size_t)slot * 8), 16, 0, 0);
  }
  __syncthreads();
  const int w = tid >> 6, lane = tid & 63, fr = lane & 15, fq = lane >> 4;
  f32x4 acc[2] = {};
#pragma unroll
  for (int kk = 0; kk < 8; ++kk) {
    const int s = w * 32 + kk * 4 + fq;                 // slot within row
    const size_t k = (size_t)w * 256 + kk * 32 + fq * 8;
    const int aoff = ((fr << 7) + (s ^ (fr & 7))) * 8;  // u16 index
    bf16x8 ah = *(const bf16x8*)(Ahi + aoff);
    bf16x8 al = *(const bf16x8*)(Alo + aoff);
#pragma unroll
    for (int ct = 0; ct < 2; ++ct) {
      const size_t boff = (size_t)(ct * 16 + fr) * 1024 + k;
      bf16x8 bh = *(const bf16x8*)(whi + boff);
      bf16x8 bl = *(const bf16x8*)(wlo + boff);
      acc[ct] = __builtin_amdgcn_mfma_f32_16x16x32_bf16(ah, bh, acc[ct], 0, 0, 0);
      acc[ct] = __builtin_amdgcn_mfma_f32_16x16x32_bf16(ah, bl, acc[ct], 0, 0, 0);
      acc[ct] = __builtin_amdgcn_mfma_f32_16x16x32_bf16(al, bh, acc[ct], 0, 0, 0);
    }
  }
#pragma unroll
  for (int ct = 0; ct < 2; ++ct)
#pragma unroll
    for (int rr = 0; rr < 4; ++rr)
      Red[(w * 16 + fq * 4 + rr) * 33 + ct * 16 + fr] = acc[ct][rr];
  __syncthreads();
  if (tid < 128) {
    const int row = tid >> 3, cg = (tid & 7) * 4;
#pragma unroll
    for (int j = 0; j < 4; ++j) {
      const int col = cg + j;
      const float s = Red[(0 * 16 + row) * 33 + col] + Red[(1 * 16 + row) * 33 + col]
                    + Red[(2 * 16 + row) * 33 + col] + Red[(3 * 16 + row) * 33 + col];
      const int grow = row0 + row;
      if (col < 16) {
        bbuf[grow * NHEAD + col] = 1.f / (1.f + __expf(-s));
      } else {
        const int hh = col - 16;
        const float xs = s + dtb[hh];
        const float sp = (xs > 20.f) ? xs : log1pf(__expf(xs));
        gbuf[grow * NHEAD + hh] = -__expf(A_log[hh]) * sp;
      }
    }
  }
}

// ===================== chunk-parallel gated delta rule (MFMA) =================
__global__ __launch_bounds__(256) void chunk_local(
    const u16* __restrict__ qp, const u16* __restrict__ kp, const u16* __restrict__ vp,
    const float* __restrict__ cq, const float* __restrict__ ck, const float* __restrict__ cv,
    const float* __restrict__ gbuf, const float* __restrict__ bbuf,
    float* __restrict__ Pg, float* __restrict__ Ug,
    float* __restrict__ Rg, float* __restrict__ Yg) {
  __shared__ __align__(16) u16 Kb[64 * 64];
  __shared__ __align__(16) u16 Qb[64 * 64];
  __shared__ __align__(16) u16 K2T[64 * 64];
  __shared__ __align__(16) u16 KWt[64 * 64];   // -> uTh
  __shared__ __align__(16) u16 Vt[64 * 64];    // -> Gb
  __shared__ __align__(16) u16 Zb[64 * 64];    // Minv row-major (swizzled)
  __shared__ __align__(16) u16 Zt[64 * 64];    // Minv transposed (swizzled)
  __shared__ __align__(16) u16 Mb[64 * 72];    // bf16 M (strict lower), stride 72
  __shared__ __align__(16) float Cb[16 * 64];  // correction tile
  __shared__ float bcs[64], bet[64], e2v[64], Bv[64];
  u16* WTh = Mb;
  u16* uTh = KWt;
  u16* Gb  = Vt;

  const int bid = blockIdx.x;            // bh*32 + c
  const int c = bid & 31, bh = bid >> 5;
  const int b = bh >> 4, h = bh & 15;
  const int tid = threadIdx.x;

  // ---- phase 0: zero Zt
  {
    int* zp = (int*)Zt;
#pragma unroll
    for (int i = 0; i < 8; ++i) zp[tid + 256 * i] = 0;
  }
  // ---- phase 1: decay prefix
  if (tid < 64) {
    const size_t gi = (size_t)((b * TLEN + c * 64) + tid) * NHEAD + h;
    bet[tid] = bbuf[gi];
    float v = gbuf[gi];
#pragma unroll
    for (int ofs = 1; ofs < 64; ofs <<= 1) {
      float tt = __shfl_up(v, ofs);
      if (tid >= ofs) v += tt;
    }
    bcs[tid] = v;
  }
  __syncthreads();
  if (tid < 64) {
    const float blast = bcs[63];
    Bv[tid]  = __expf(bcs[tid]);
    e2v[tid] = __expf(blast - bcs[tid]);
  }
  __syncthreads();

  // ---- phase 2: staging with fused conv+silu+l2norm
  {
    const int dq = (tid & 15) * 4;            // constant channel group
    const int col = h * 64 + dq;
    float4 wq4[4], wk4[4], wv4[4];
#pragma unroll
    for (int jj = 0; jj < 4; ++jj) {
      wq4[jj] = *(const float4*)(cq + (size_t)(col + jj) * 4);
      wk4[jj] = *(const float4*)(ck + (size_t)(col + jj) * 4);
      wv4[jj] = *(const float4*)(cv + (size_t)(col + jj) * 4);
    }
#pragma unroll
    for (int i = 0; i < 4; ++i) {
      const int r = i * 16 + (tid >> 4);
      const int tcur = c * 64 + r;
      ushort4 xq[4], xk[4], xv[4];
#pragma unroll
      for (int m = 0; m < 4; ++m) {
        const int tt = tcur - 3 + m;
        if (tt >= 0) {
          const size_t a = (size_t)(b * TLEN + tt) * HD + col;
          xq[m] = *(const ushort4*)(qp + a);
          xk[m] = *(const ushort4*)(kp + a);
          xv[m] = *(const ushort4*)(vp + a);
        } else {
          xq[m] = ushort4{0, 0, 0, 0}; xk[m] = xq[m]; xv[m] = xq[m];
        }
      }
      float yq[4], yk[4], yv[4];
      float ssq = 0.f, ssk = 0.f;
#pragma unroll
      for (int jj = 0; jj < 4; ++jj) {
        float aq = wq4[jj].x * bf2f(((const u16*)&xq[0])[jj]) +
                   wq4[jj].y * bf2f(((const u16*)&xq[1])[jj]) +
                   wq4[jj].z * bf2f(((const u16*)&xq[2])[jj]) +
                   wq4[jj].w * bf2f(((const u16*)&xq[3])[jj]);
        float ak = wk4[jj].x * bf2f(((const u16*)&xk[0])[jj]) +
                   wk4[jj].y * bf2f(((const u16*)&xk[1])[jj]) +
                   wk4[jj].z * bf2f(((const u16*)&xk[2])[jj]) +
                   wk4[jj].w * bf2f(((const u16*)&xk[3])[jj]);
        float av = wv4[jj].x * bf2f(((const u16*)&xv[0])[jj]) +
                   wv4[jj].y * bf2f(((const u16*)&xv[1])[jj]) +
                   wv4[jj].z * bf2f(((const u16*)&xv[2])[jj]) +
                   wv4[jj].w * bf2f(((const u16*)&xv[3])[jj]);
        yq[jj] = aq / (1.f + __expf(-aq));
        yk[jj] = ak / (1.f + __expf(-ak));
        yv[jj] = av / (1.f + __expf(-av));
        ssq += yq[jj] * yq[jj];
        ssk += yk[jj] * yk[jj];
      }
      ssq += __shfl_xor(ssq, 1); ssq += __shfl_xor(ssq, 2);
      ssq += __shfl_xor(ssq, 4); ssq += __shfl_xor(ssq, 8);
      ssk += __shfl_xor(ssk, 1); ssk += __shfl_xor(ssk, 2);
      ssk += __shfl_xor(ssk, 4); ssk += __shfl_xor(ssk, 8);
      const float qsc = rsqrtf(ssq + 1e-6f) * 0.125f;
      const float ksc = rsqrtf(ssk + 1e-6f);
      const float bR = bet[r], e2R = e2v[r], wscR = bR * Bv[r];
      ushort4 qo, ko;
      float kvf[4];
#pragma unroll
      for (int jj = 0; jj < 4; ++jj) kvf[jj] = yk[jj] * ksc;
      qo.x = f2bf(yq[0] * qsc); qo.y = f2bf(yq[1] * qsc);
      qo.z = f2bf(yq[2] * qsc); qo.w = f2bf(yq[3] * qsc);
      ko.x = f2bf(kvf[0]); ko.y = f2bf(kvf[1]);
      ko.z = f2bf(kvf[2]); ko.w = f2bf(kvf[3]);
      *(ushort4*)((char*)Qb + swz(r, dq)) = qo;
      *(ushort4*)((char*)Kb + swz(r, dq)) = ko;
#pragma unroll
      for (int jj = 0; jj < 4; ++jj) {
        *(u16*)((char*)K2T + swz(dq + jj, r)) = f2bf(kvf[jj] * e2R);
        *(u16*)((char*)KWt + swz(dq + jj, r)) = f2bf(kvf[jj] * wscR);
        *(u16*)((char*)Vt  + swz(dq + jj, r)) = f2bf(yv[jj] * bR);
      }
    }
  }
  __syncthreads();

  const int w = tid >> 6, lane = tid & 63, fr = lane & 15, fq = lane >> 4;
  // ---- phase 3: A = K K^T via MFMA -> masked M (bf16, stride 72)
  {
    bf16x8 ka0 = frag(Kb, w * 16 + fr, fq);
    bf16x8 ka1 = frag(Kb, w * 16 + fr, 4 + fq);
#pragma unroll
    for (int tc = 0; tc < 4; ++tc) {
      bf16x8 kb0 = frag(Kb, tc * 16 + fr, fq);
      bf16x8 kb1 = frag(Kb, tc * 16 + fr, 4 + fq);
      f32x4 a = {};
      a = __builtin_amdgcn_mfma_f32_16x16x32_bf16(ka0, kb0, a, 0, 0, 0);
      a = __builtin_amdgcn_mfma_f32_16x16x32_bf16(ka1, kb1, a, 0, 0, 0);
#pragma unroll
      for (int rr = 0; rr < 4; ++rr) {
        const int t = w * 16 + fq * 4 + rr, s = tc * 16 + fr;
        const float mv = (s < t) ? bet[t] * __expf(bcs[t] - bcs[s]) * a[rr] : 0.f;
        Mb[t * 72 + s] = f2bf(mv);
      }
    }
  }
  __syncthreads();

  // ---- phase 4: BLOCKED solve M Minv = I (4 blocks of 16 rows)
#pragma unroll 1
  for (int bi = 0; bi < 4; ++bi) {
    {
      const char* mrow = (const char*)Mb + (size_t)(bi * 16 + fr) * 144;
      bf16x8 ma0 = *(const bf16x8*)(mrow + fq * 16);
      bf16x8 ma1 = *(const bf16x8*)(mrow + 64 + fq * 16);
      bf16x8 zt0 = frag(Zt, w * 16 + fr, fq);
      bf16x8 zt1 = frag(Zt, w * 16 + fr, 4 + fq);
      f32x4 a = {};
      a = __builtin_amdgcn_mfma_f32_16x16x32_bf16(ma0, zt0, a, 0, 0, 0);
      a = __builtin_amdgcn_mfma_f32_16x16x32_bf16(ma1, zt1, a, 0, 0, 0);
#pragma unroll
      for (int rr = 0; rr < 4; ++rr)
        Cb[(fq * 4 + rr) * 64 + w * 16 + fr] = a[rr];
    }
    __syncthreads();
    if (tid < 64) {
      const int j = tid;
      float z[16];
#pragma unroll
      for (int t = 0; t < 16; ++t) {
        float acc = ((bi * 16 + t) == j ? 1.f : 0.f) - Cb[t * 64 + j];
        const u16* mrow = Mb + (size_t)(bi * 16 + t) * 72 + bi * 16;
#pragma unroll
        for (int s = 0; s < t; ++s) acc -= bf2f(mrow[s]) * z[s];
        z[t] = acc;
      }
#pragma unroll
      for (int t = 0; t < 16; ++t)
        *(u16*)((char*)Zb + swz(bi * 16 + t, j)) = f2bf(z[t]);
#pragma unroll
      for (int t4 = 0; t4 < 4; ++t4) {
        ushort4 zz;
        zz.x = f2bf(z[t4 * 4 + 0]); zz.y = f2bf(z[t4 * 4 + 1]);
        zz.z = f2bf(z[t4 * 4 + 2]); zz.w = f2bf(z[t4 * 4 + 3]);
        *(ushort4*)((char*)Zt + swz(j, bi * 16 + t4 * 4)) = zz;
      }
    }
    __syncthreads();
  }

  // ---- phase 5: W = Minv*RHSw, u = Minv*RHSv (transposed out), G = QK^T
  f32x4 accW[4], accu[4], accG[4];
  {
    bf16x8 kw0 = frag(KWt, w * 16 + fr, fq), kw1 = frag(KWt, w * 16 + fr, 4 + fq);
    bf16x8 vt0 = frag(Vt,  w * 16 + fr, fq), vt1 = frag(Vt,  w * 16 + fr, 4 + fq);
    bf16x8 qa0 = frag(Qb,  w * 16 + fr, fq), qa1 = frag(Qb,  w * 16 + fr, 4 + fq);
#pragma unroll
    for (int tc = 0; tc < 4; ++tc) {
      bf16x8 z0 = frag(Zb, tc * 16 + fr, fq), z1 = frag(Zb, tc * 16 + fr, 4 + fq);
      bf16x8 kb0 = frag(Kb, tc * 16 + fr, fq), kb1 = frag(Kb, tc * 16 + fr, 4 + fq);
      f32x4 aw = {}, au = {}, ag = {};
      aw = __builtin_amdgcn_mfma_f32_16x16x32_bf16(kw0, z0, aw, 0, 0, 0);
      aw = __builtin_amdgcn_mfma_f32_16x16x32_bf16(kw1, z1, aw, 0, 0, 0);
      au = __builtin_amdgcn_mfma_f32_16x16x32_bf16(vt0, z0, au, 0, 0, 0);
      au = __builtin_amdgcn_mfma_f32_16x16x32_bf16(vt1, z1, au, 0, 0, 0);
      ag = __builtin_amdgcn_mfma_f32_16x16x32_bf16(qa0, kb0, ag, 0, 0, 0);
      ag = __builtin_amdgcn_mfma_f32_16x16x32_bf16(qa1, kb1, ag, 0, 0, 0);
      accW[tc] = aw; accu[tc] = au; accG[tc] = ag;
    }
  }
  __syncthreads();
  // ---- phase 6: write WTh (over Mb), uTh (over KWt), Gb (over Vt)
#pragma unroll
  for (int tc = 0; tc < 4; ++tc)
#pragma unroll
    for (int rr = 0; rr < 4; ++rr) {
      const int ro = w * 16 + fq * 4 + rr, co = tc * 16 + fr;
      *(u16*)((char*)WTh + swz(ro, co)) = f2bf(accW[tc][rr]);
      *(u16*)((char*)uTh + swz(ro, co)) = f2bf(accu[tc][rr]);
      const float gv = (co <= ro) ? accG[tc][rr] * __expf(bcs[ro] - bcs[co]) : 0.f;
      *(u16*)((char*)Gb + swz(ro, co)) = f2bf(gv);
    }
  __syncthreads();

  // ---- phase 7: P,U,R,Y via MFMA + epilogue
  {
    bf16x8 k20 = frag(K2T, w * 16 + fr, fq), k21 = frag(K2T, w * 16 + fr, 4 + fq);
    bf16x8 g0  = frag(Gb,  w * 16 + fr, fq), g1  = frag(Gb,  w * 16 + fr, 4 + fq);
    const float bl = Bv[63];
    const size_t off = (size_t)bid * 4096;
#pragma unroll
    for (int tc = 0; tc < 4; ++tc) {
      bf16x8 w0 = frag(WTh, tc * 16 + fr, fq), w1 = frag(WTh, tc * 16 + fr, 4 + fq);
      bf16x8 u0 = frag(uTh, tc * 16 + fr, fq), u1 = frag(uTh, tc * 16 + fr, 4 + fq);
      f32x4 aP = {}, aU = {}, aR = {}, aY = {};
      aP = __builtin_amdgcn_mfma_f32_16x16x32_bf16(k20, w0, aP, 0, 0, 0);
      aP = __builtin_amdgcn_mfma_f32_16x16x32_bf16(k21, w1, aP, 0, 0, 0);
      aU = __builtin_amdgcn_mfma_f32_16x16x32_bf16(k20, u0, aU, 0, 0, 0);
      aU = __builtin_amdgcn_mfma_f32_16x16x32_bf16(k21, u1, aU, 0, 0, 0);
      aR = __builtin_amdgcn_mfma_f32_16x16x32_bf16(g0, w0, aR, 0, 0, 0);
      aR = __builtin_amdgcn_mfma_f32_16x16x32_bf16(g1, w1, aR, 0, 0, 0);
      aY = __builtin_amdgcn_mfma_f32_16x16x32_bf16(g0, u0, aY, 0, 0, 0);
      aY = __builtin_amdgcn_mfma_f32_16x16x32_bf16(g1, u1, aY, 0, 0, 0);
#pragma unroll
      for (int rr = 0; rr < 4; ++rr) {
        const int ar = w * 16 + fq * 4 + rr, cb = tc * 16 + fr;
        Pg[off + ar * 64 + cb] = ((ar == cb) ? bl : 0.f) - aP[rr];
        Ug[off + ar * 64 + cb] = aU[rr];
        const float qv = bf2f(*(const u16*)((const char*)Qb + swz(ar, cb)));
        Rg[off + ar * 64 + cb] = Bv[ar] * qv - aR[rr];
        Yg[off + ar * 64 + cb] = aY[rr];
      }
    }
  }
}

// ---- phase B: S_{c+1} = P_c S_c + U_c ; store S_in per chunk. 128 blocks.
__global__ __launch_bounds__(256) void state_step(
    const float* __restrict__ Pg, const float* __restrict__ Ug,
    float* __restrict__ Sst) {
  __shared__ float Ps[64 * 65];
  __shared__ float Sc[64 * 20];
  const int blk = blockIdx.x;
  const int bh = blk >> 2, j0 = (blk & 3) * 16;
  const int tid = threadIdx.x;
  const int a = tid >> 2, jb = (tid & 3) * 4;
  const int pr = tid >> 4, pc = (tid & 15) * 4;
  for (int i = tid; i < 64 * 20; i += 256) Sc[i] = 0.f;
  float4 pre[4];
  {
    const size_t off0 = (size_t)bh * 32 * 4096;
#pragma unroll
    for (int i = 0; i < 4; ++i)
      pre[i] = *(const float4*)(Pg + off0 + (size_t)(i * 16 + pr) * 64 + pc);
  }
  __syncthreads();
  for (int c = 0; c < 32; ++c) {
    const size_t off = ((size_t)bh * 32 + c) * 4096;
#pragma unroll
    for (int i = 0; i < 4; ++i) {
      float* dst = &Ps[(i * 16 + pr) * 65 + pc];
      dst[0] = pre[i].x; dst[1] = pre[i].y; dst[2] = pre[i].z; dst[3] = pre[i].w;
    }
    __syncthreads();
    if (c + 1 < 32) {
      const size_t offn = off + 4096;
#pragma unroll
      for (int i = 0; i < 4; ++i)
        pre[i] = *(const float4*)(Pg + offn + (size_t)(i * 16 + pr) * 64 + pc);
    }
    *(float4*)(Sst + off + (size_t)a * 64 + j0 + jb) = *(const float4*)(&Sc[a * 20 + jb]);
    float4 acc = *(const float4*)(Ug + off + (size_t)a * 64 + j0 + jb);
    for (int k = 0; k < 64; ++k) {
      const float pv = Ps[a * 65 + k];
      const float4 sv = *(const float4*)(&Sc[k * 20 + jb]);
      acc.x += pv * sv.x; acc.y += pv * sv.y;
      acc.z += pv * sv.z; acc.w += pv * sv.w;
    }
    __syncthreads();
    *(float4*)(&Sc[a * 20 + jb]) = acc;
    __syncthreads();
  }
}

// ---- phase C: O = R S_in + Y   (1024 parallel blocks)
__global__ __launch_bounds__(256) void chunk_out(
    const float* __restrict__ Rg, const float* __restrict__ Yg,
    const float* __restrict__ Sst, float* __restrict__ obuf) {
  __shared__ float Rs[64 * 65];
  __shared__ float Ss[64 * 65];
  const int bid = blockIdx.x;
  const int c = bid & 31, bh = bid >> 5, b = bh >> 4, h = bh & 15;
  const int tid = threadIdx.x;
  const size_t off = (size_t)bid * 4096;
#pragma unroll
  for (int i = 0; i < 4; ++i) {
    const int idx = i * 1024 + tid * 4;
    const int row = idx >> 6, col = idx & 63;
    float4 rv = *(const float4*)(Rg + off + idx);
    float4 sv = *(const float4*)(Sst + off + idx);
    float* rd = &Rs[row * 65 + col];
    rd[0]=rv.x; rd[1]=rv.y; rd[2]=rv.z; rd[3]=rv.w;
    float* sd = &Ss[row * 65 + col];
    sd[0]=sv.x; sd[1]=sv.y; sd[2]=sv.z; sd[3]=sv.w;
  }
  __syncthreads();
  const int tr = tid >> 4, tc = tid & 15;
  float acc[4][4];
#pragma unroll
  for (int i = 0; i < 4; ++i) {
    const float4 y = *(const float4*)(Yg + off + (4*tr+i)*64 + 4*tc);
    acc[i][0] = y.x; acc[i][1] = y.y; acc[i][2] = y.z; acc[i][3] = y.w;
  }
  for (int k = 0; k < 64; ++k) {
    float r0 = Rs[(4*tr+0)*65+k], r1 = Rs[(4*tr+1)*65+k],
          r2 = Rs[(4*tr+2)*65+k], r3 = Rs[(4*tr+3)*65+k];
    float s0 = Ss[k*65+4*tc+0], s1 = Ss[k*65+4*tc+1],
          s2 = Ss[k*65+4*tc+2], s3 = Ss[k*65+4*tc+3];
    acc[0][0]+=r0*s0; acc[0][1]+=r0*s1; acc[0][2]+=r0*s2; acc[0][3]+=r0*s3;
    acc[1][0]+=r1*s0; acc[1][1]+=r1*s1; acc[1][2]+=r1*s2; acc[1][3]+=r1*s3;
    acc[2][0]+=r2*s0; acc[2][1]+=r2*s1; acc[2][2]+=r2*s2; acc[2][3]+=r2*s3;
    acc[3][0]+=r3*s0; acc[3][1]+=r3*s1; acc[3][2]+=r3*s2; acc[3][3]+=r3*s3;
  }
#pragma unroll
  for (int i = 0; i < 4; ++i) {
    const int t = 4*tr+i;
    float4 ov; ov.x = acc[i][0]; ov.y = acc[i][1]; ov.z = acc[i][2]; ov.w = acc[i][3];
    *(float4*)(obuf + ((size_t)(b * TLEN + c * 64 + t) * NHEAD + h) * 64 + 4*tc) = ov;
  }
}

// ------------------------------------------- gated RMSNorm epilogue -> bf16
__global__ __launch_bounds__(256) void rms_gate(
    const float* __restrict__ obuf, const u16* __restrict__ gatep,
    const float* __restrict__ norm_w, u16* __restrict__ outb) {
  const int flat = blockIdx.x * 256 + threadIdx.x;
  const int d = flat & 63;
  const float o = obuf[flat];
  const float s = wave_sum(o * o);
  const float inv = rsqrtf(s * (1.0f / 64.0f) + 1e-5f);
  const float gt = bf2f(gatep[flat]);
  const float res = o * inv * norm_w[d] * (gt / (1.f + __expf(-gt)));
  outb[flat] = f2bf(res);
}

extern "C" void kernel_launch(void* const* d_in, const int* in_sizes, int n_in,
                              void* d_out, int out_size, void* d_ws, size_t ws_size,
                              hipStream_t stream) {
  const float* hidden = (const float*)d_in[0];
  const float* Wq     = (const float*)d_in[1];
  const float* Wk     = (const float*)d_in[2];
  const float* Wv     = (const float*)d_in[3];
  const float* cq     = (const float*)d_in[4];
  const float* ck     = (const float*)d_in[5];
  const float* cv     = (const float*)d_in[6];
  const float* Wb     = (const float*)d_in[7];
  const float* Wa     = (const float*)d_in[8];
  const float* A_log  = (const float*)d_in[9];
  const float* dtb    = (const float*)d_in[10];
  const float* Wg     = (const float*)d_in[11];
  const float* nw     = (const float*)d_in[12];
  const float* Wo     = (const float*)d_in[13];

  char* p = (char*)d_ws;
  const size_t MB = 1u << 20;
  u16* h_bf = (u16*)(p + 0 * MB);     // 8 MB   (dead after gemm #1 + small_mfma)
  u16* wq_b = (u16*)(p + 8 * MB);     // 2 MB
  u16* wk_b = (u16*)(p + 10 * MB);
  u16* wv_b = (u16*)(p + 12 * MB);
  u16* wg_b = (u16*)(p + 14 * MB);
  float* Pg = (float*)(p + 0 * MB);   // 16 MB, aliases h_bf..wg_b (dead then)
  u16* wo_b = (u16*)(p + 16 * MB);    // 2 MB (live till end)
  u16* qp_b = (u16*)(p + 18 * MB);    // 8 MB raw q projection (live thru chunk_local)
  u16* kp_b = (u16*)(p + 26 * MB);    // 8 MB
  u16* vp_b = (u16*)(p + 34 * MB);    // 8 MB
  u16* gp_b = (u16*)(p + 42 * MB);    // 8 MB (live till rms_gate)
  float* obuf = (float*)qp_b;         // 16 MB, aliases qp+kp (dead after chunk_local)
  u16*   of_b = vp_b;                 // 8 MB, aliases vp
  float* gbuf = (float*)(p + 50 * MB);        // 256 KB
  float* bbuf = (float*)(p + 50 * MB + 262144);
  float* Ug  = (float*)(p + 51 * MB);  // 16 MB
  float* Rg  = (float*)(p + 67 * MB);  // 16 MB
  float* Yg  = (float*)(p + 83 * MB);  // 16 MB
  float* Sst = (float*)(p + 99 * MB);  // 16 MB
  u16* hlo_b = (u16*)(p + 115 * MB);   // 8 MB hidden lo residual
  u16* wba_h = (u16*)(p + 123 * MB);   // 64 KB [32][1024] Wb|Wa hi
  u16* wba_l = (u16*)(p + 123 * MB + 65536);  // 64 KB lo  (total ~123.2 MB)

  cvt_all<<<9248, 256, 0, stream>>>(hidden, Wq, Wk, Wv, Wg, Wo, Wb, Wa,
                                    h_bf, hlo_b, wq_b, wk_b, wv_b, wg_b, wo_b,
                                    wba_h, wba_l);

  gemm_lin<u16, 4><<<dim3(8, 32, 4), 256, 0, stream>>>(
      h_bf, wq_b, wk_b, wv_b, wg_b, qp_b, kp_b, vp_b, gp_b, 4096, 1024, 1024);

  const int sm_lds = 65536 + 8448;   // Ahi+Alo + Red
  hipFuncSetAttribute((const void*)small_mfma,
                      hipFuncAttributeMaxDynamicSharedMemorySize, sm_lds);
  small_mfma<<<256, 256, sm_lds, stream>>>(h_bf, hlo_b, wba_h, wba_l,
                                           A_log, dtb, bbuf, gbuf);

  chunk_local<<<1024, 256, 0, stream>>>(qp_b, kp_b, vp_b, cq, ck, cv,
                                        gbuf, bbuf, Pg, Ug, Rg, Yg);
  state_step<<<128, 256, 0, stream>>>(Pg, Ug, Sst);
  chunk_out<<<1024, 256, 0, stream>>>(Rg, Yg, Sst, obuf);

  rms_gate<<<16384, 256, 0, stream>>>(obuf, gp_b, nw, of_b);

  gemm_lin<float, 2><<<dim3(8, 64, 1), 256, 0, stream>>>(
      of_b, wo_b, wo_b, wo_b, wo_b,
      (float*)d_out, (float*)d_out, (float*)d_out, (float*)d_out, 4096, 1024, 1024);
}

// Round 7
// 186.700 us; speedup vs baseline: 9.0815x; 1.1245x over previous
//
#include <hip/hip_runtime.h>
#include <hip/hip_bf16.h>

typedef unsigned short u16;
typedef __attribute__((ext_vector_type(4))) float f32x4;
typedef __attribute__((ext_vector_type(8))) short bf16x8;

#define TLEN 2048
#define NHEAD 16
#define HD 1024

__device__ inline u16 f2bf(float f) {
  unsigned x = __float_as_uint(f);
  return (u16)((x + 0x7fffu + ((x >> 16) & 1u)) >> 16);
}
__device__ inline float bf2f(u16 u) { return __uint_as_float(((unsigned)u) << 16); }

__device__ inline float wave_sum(float x) {
  x += __shfl_xor(x, 1);  x += __shfl_xor(x, 2);  x += __shfl_xor(x, 4);
  x += __shfl_xor(x, 8);  x += __shfl_xor(x, 16); x += __shfl_xor(x, 32);
  return x;
}

__device__ inline void storev(float* p, float v) { *p = v; }
__device__ inline void storev(u16* p, float v)   { *p = f2bf(v); }

// swizzled byte offset into a [64 rows][64 bf16 = 128B] LDS tile
__device__ inline int swz(int row, int col) {
  return (row << 7) + ((((col >> 3) ^ (row & 7)) << 4)) + ((col & 7) << 1);
}
// MFMA fragment load (16B, kslot in 0..7 -> k-chunk kslot*8; same perm A/B)
__device__ inline bf16x8 frag(const u16* base, int row, int kslot) {
  return *(const bf16x8*)((const char*)base + (row << 7) +
                          (((kslot ^ (row & 7)) << 4)));
}

// ------------------------------------------------- fused fp32 -> bf16 converts
__global__ __launch_bounds__(256) void cvt_all(
    const float* __restrict__ h,  const float* __restrict__ wq,
    const float* __restrict__ wk, const float* __restrict__ wv,
    const float* __restrict__ wg, const float* __restrict__ wo,
    const float* __restrict__ Wb, const float* __restrict__ Wa,
    u16* __restrict__ dh,  u16* __restrict__ dhlo,
    u16* __restrict__ dwq, u16* __restrict__ dwk,
    u16* __restrict__ dwv, u16* __restrict__ dwg, u16* __restrict__ dwo,
    u16* __restrict__ dwba_h, u16* __restrict__ dwba_l) {
  const int b = blockIdx.x;
  if (b < 4096) {
    const size_t i = (size_t)b * 256 + threadIdx.x;
    float4 v = *(const float4*)(h + i * 4);
    ushort4 hi, lo;
    hi.x = f2bf(v.x); lo.x = f2bf(v.x - bf2f(hi.x));
    hi.y = f2bf(v.y); lo.y = f2bf(v.y - bf2f(hi.y));
    hi.z = f2bf(v.z); lo.z = f2bf(v.z - bf2f(hi.z));
    hi.w = f2bf(v.w); lo.w = f2bf(v.w - bf2f(hi.w));
    *(ushort4*)(dh + i * 4) = hi;
    *(ushort4*)(dhlo + i * 4) = lo;
  } else if (b < 9216) {
    const int wsel = (b - 4096) >> 10;
    const size_t i = (size_t)((b - 4096) & 1023) * 256 + threadIdx.x;
    const float* s; u16* d;
    switch (wsel) {
      case 0: s = wq; d = dwq; break;
      case 1: s = wk; d = dwk; break;
      case 2: s = wv; d = dwv; break;
      case 3: s = wg; d = dwg; break;
      default: s = wo; d = dwo; break;
    }
    float4 v = *(const float4*)(s + i * 4);
    ushort4 u;
    u.x = f2bf(v.x); u.y = f2bf(v.y); u.z = f2bf(v.z); u.w = f2bf(v.w);
    *(ushort4*)(d + i * 4) = u;
  } else {
    const size_t i = (size_t)(b - 9216) * 256 + threadIdx.x;
    const size_t flat = i * 4;
    const float* src = (flat < 16384) ? (Wb + flat) : (Wa + (flat - 16384));
    float4 v = *(const float4*)src;
    ushort4 hi, lo;
    hi.x = f2bf(v.x); lo.x = f2bf(v.x - bf2f(hi.x));
    hi.y = f2bf(v.y); lo.y = f2bf(v.y - bf2f(hi.y));
    hi.z = f2bf(v.z); lo.z = f2bf(v.z - bf2f(hi.z));
    hi.w = f2bf(v.w); lo.w = f2bf(v.w - bf2f(hi.w));
    *(ushort4*)(dwba_h + flat) = hi;
    *(ushort4*)(dwba_l + flat) = lo;
  }
}

// ---------------- fused 4-projection GEMM: 256x128 tile, wave-tile 64x128
// Per K-tile per wave: 64 MFMA vs 24 ds_read_b128 (reads/MFMA = 0.375).
__global__ __launch_bounds__(256, 2) void gemm_big(
    const u16* __restrict__ A,
    const u16* __restrict__ W0p, const u16* __restrict__ W1p,
    const u16* __restrict__ W2p, const u16* __restrict__ W3p,
    u16* __restrict__ C0, u16* __restrict__ C1,
    u16* __restrict__ C2, u16* __restrict__ C3,
    int M, int N, int K) {
  const u16* W; u16* C;
  switch (blockIdx.z) {
    case 0: W = W0p; C = C0; break;
    case 1: W = W1p; C = C1; break;
    case 2: W = W2p; C = C2; break;
    default: W = W3p; C = C3; break;
  }
  const int tid = threadIdx.x;
  const int lane = tid & 63, wid = tid >> 6;
  const int fr = lane & 15, fq = lane >> 4;
  const int row0 = blockIdx.y * 256, col0 = blockIdx.x * 128;
  __shared__ __align__(16) u16 As[256 * 64];
  __shared__ __align__(16) u16 Bs[128 * 64];

  const u16* aSrc[8]; const u16* bSrc[4];
#pragma unroll
  for (int it = 0; it < 8; ++it) {
    const int s = it * 256 + tid;
    const int r = s >> 3, cc = s & 7;
    aSrc[it] = A + (size_t)(row0 + r) * K + (cc ^ (r & 7)) * 8;
  }
#pragma unroll
  for (int it = 0; it < 4; ++it) {
    const int s = it * 256 + tid;
    const int r = s >> 3, cc = s & 7;
    bSrc[it] = W + (size_t)(col0 + r) * K + (cc ^ (r & 7)) * 8;
  }
  int aOff[4][2], bOff[8][2];
#pragma unroll
  for (int m = 0; m < 4; ++m)
#pragma unroll
    for (int kk = 0; kk < 2; ++kk) {
      const int ra = wid * 64 + m * 16 + fr;
      aOff[m][kk] = ra * 128 + ((((kk << 2) | fq) ^ (ra & 7)) << 4);
    }
#pragma unroll
  for (int n = 0; n < 8; ++n)
#pragma unroll
    for (int kk = 0; kk < 2; ++kk) {
      const int rb = n * 16 + fr;
      bOff[n][kk] = rb * 128 + ((((kk << 2) | fq) ^ (rb & 7)) << 4);
    }

  f32x4 acc[4][8] = {};
  for (int k0 = 0; k0 < K; k0 += 64) {
#pragma unroll
    for (int it = 0; it < 8; ++it)
      __builtin_amdgcn_global_load_lds(
          (const __attribute__((address_space(1))) void*)(aSrc[it] + k0),
          (__attribute__((address_space(3))) void*)((char*)As + (it * 256 + tid) * 16),
          16, 0, 0);
#pragma unroll
    for (int it = 0; it < 4; ++it)
      __builtin_amdgcn_global_load_lds(
          (const __attribute__((address_space(1))) void*)(bSrc[it] + k0),
          (__attribute__((address_space(3))) void*)((char*)Bs + (it * 256 + tid) * 16),
          16, 0, 0);
    __syncthreads();
#pragma unroll
    for (int kk = 0; kk < 2; ++kk) {
      bf16x8 af[4], bfr[8];
#pragma unroll
      for (int m = 0; m < 4; ++m)
        af[m] = *(const bf16x8*)((const char*)As + aOff[m][kk]);
#pragma unroll
      for (int n = 0; n < 8; ++n)
        bfr[n] = *(const bf16x8*)((const char*)Bs + bOff[n][kk]);
#pragma unroll
      for (int m = 0; m < 4; ++m)
#pragma unroll
        for (int n = 0; n < 8; ++n)
          acc[m][n] = __builtin_amdgcn_mfma_f32_16x16x32_bf16(af[m], bfr[n], acc[m][n], 0, 0, 0);
    }
    __syncthreads();
  }
#pragma unroll
  for (int m = 0; m < 4; ++m)
#pragma unroll
    for (int n = 0; n < 8; ++n)
#pragma unroll
      for (int r = 0; r < 4; ++r) {
        const int gr = row0 + wid * 64 + m * 16 + fq * 4 + r;
        const int gc = col0 + n * 16 + fr;
        C[(size_t)gr * N + gc] = f2bf(acc[m][n][r]);
      }
}

// ------------------------------------------------- bf16 MFMA linear: C = A*W^T
template <typename OutT, int MT>
__global__ __launch_bounds__(256) void gemm_lin(
    const u16* __restrict__ A, const u16* __restrict__ W,
    OutT* __restrict__ C, int M, int N, int K) {
  const int tid = threadIdx.x;
  const int lane = tid & 63, wid = tid >> 6;
  const int wr = wid >> 1, wc = wid & 1;
  const int fr = lane & 15, fq = lane >> 4;
  const int row0 = blockIdx.y * (MT * 32), col0 = blockIdx.x * 128;
  __shared__ __align__(16) u16 As[MT * 32 * 64];
  __shared__ __align__(16) u16 Bs[128 * 64];

  const u16* aSrc[MT]; const u16* bSrc[4];
#pragma unroll
  for (int it = 0; it < MT; ++it) {
    const int c = it * 256 + tid;
    const int r = c >> 3, cc = c & 7, sc = cc ^ (r & 7);
    aSrc[it] = A + (size_t)(row0 + r) * K + sc * 8;
  }
#pragma unroll
  for (int it = 0; it < 4; ++it) {
    const int c = it * 256 + tid;
    const int r = c >> 3, cc = c & 7, sc = cc ^ (r & 7);
    bSrc[it] = W + (size_t)(col0 + r) * K + sc * 8;
  }
  int aOff[MT][2], bOff[4][2];
#pragma unroll
  for (int m = 0; m < MT; ++m)
#pragma unroll
    for (int kk = 0; kk < 2; ++kk) {
      const int ra = wr * (MT * 16) + m * 16 + fr;
      aOff[m][kk] = ra * 128 + ((((kk << 2) | fq) ^ (fr & 7)) << 4);
    }
#pragma unroll
  for (int n = 0; n < 4; ++n)
#pragma unroll
    for (int kk = 0; kk < 2; ++kk) {
      const int rb = wc * 64 + n * 16 + fr;
      bOff[n][kk] = rb * 128 + ((((kk << 2) | fq) ^ (fr & 7)) << 4);
    }

  f32x4 acc[MT][4] = {};
  for (int k0 = 0; k0 < K; k0 += 64) {
#pragma unroll
    for (int it = 0; it < MT; ++it)
      __builtin_amdgcn_global_load_lds(
          (const __attribute__((address_space(1))) void*)(aSrc[it] + k0),
          (__attribute__((address_space(3))) void*)((char*)As + (it * 256 + wid * 64) * 16),
          16, 0, 0);
#pragma unroll
    for (int it = 0; it < 4; ++it)
      __builtin_amdgcn_global_load_lds(
          (const __attribute__((address_space(1))) void*)(bSrc[it] + k0),
          (__attribute__((address_space(3))) void*)((char*)Bs + (it * 256 + wid * 64) * 16),
          16, 0, 0);
    __syncthreads();
#pragma unroll
    for (int kk = 0; kk < 2; ++kk) {
      bf16x8 af[MT], bfr[4];
#pragma unroll
      for (int m = 0; m < MT; ++m)
        af[m] = *(const bf16x8*)((const char*)As + aOff[m][kk]);
#pragma unroll
      for (int n = 0; n < 4; ++n)
        bfr[n] = *(const bf16x8*)((const char*)Bs + bOff[n][kk]);
#pragma unroll
      for (int m = 0; m < MT; ++m)
#pragma unroll
        for (int n = 0; n < 4; ++n)
          acc[m][n] = __builtin_amdgcn_mfma_f32_16x16x32_bf16(af[m], bfr[n], acc[m][n], 0, 0, 0);
    }
    __syncthreads();
  }
#pragma unroll
  for (int m = 0; m < MT; ++m)
#pragma unroll
    for (int n = 0; n < 4; ++n)
#pragma unroll
      for (int r = 0; r < 4; ++r) {
        const int gr = row0 + wr * (MT * 16) + m * 16 + fq * 4 + r;
        const int gc = col0 + wc * 64 + n * 16 + fr;
        storev(&C[(size_t)gr * N + gc], acc[m][n][r]);
      }
}

// ---------------- beta/g projections via split-precision MFMA skinny GEMM
__global__ __launch_bounds__(256) void small_mfma(
    const u16* __restrict__ hhi, const u16* __restrict__ hlo,
    const u16* __restrict__ whi, const u16* __restrict__ wlo,
    const float* __restrict__ A_log, const float* __restrict__ dtb,
    float* __restrict__ bbuf, float* __restrict__ gbuf) {
  extern __shared__ char smc[];
  u16* Ahi = (u16*)smc;
  u16* Alo = (u16*)(smc + 32768);
  float* Red = (float*)(smc + 65536);
  const int tid = threadIdx.x;
  const int row0 = blockIdx.x * 16;
#pragma unroll
  for (int i = 0; i < 8; ++i) {
    const int slot = tid + 256 * i;
    const int r = slot >> 7, s = slot & 127;
    const int ss = s ^ (r & 7);
    const size_t src = (size_t)(row0 + r) * 1024 + (size_t)ss * 8;
    __builtin_amdgcn_global_load_lds(
        (const __attribute__((address_space(1))) void*)(hhi + src),
        (__attribute__((address_space(3))) void*)(Ahi + (size_t)slot * 8), 16, 0, 0);
    __builtin_amdgcn_global_load_lds(
        (const __attribute__((address_space(1))) void*)(hlo + src),
        (__attribute__((address_space(3))) void*)(Alo + (size_t)slot * 8), 16, 0, 0);
  }
  __syncthreads();
  const int w = tid >> 6, lane = tid & 63, fr = lane & 15, fq = lane >> 4;
  f32x4 acc[2] = {};
#pragma unroll
  for (int kk = 0; kk < 8; ++kk) {
    const int s = w * 32 + kk * 4 + fq;
    const size_t k = (size_t)w * 256 + kk * 32 + fq * 8;
    const int aoff = ((fr << 7) + (s ^ (fr & 7))) * 8;
    bf16x8 ah = *(const bf16x8*)(Ahi + aoff);
    bf16x8 al = *(const bf16x8*)(Alo + aoff);
#pragma unroll
    for (int ct = 0; ct < 2; ++ct) {
      const size_t boff = (size_t)(ct * 16 + fr) * 1024 + k;
      bf16x8 bh = *(const bf16x8*)(whi + boff);
      bf16x8 bl = *(const bf16x8*)(wlo + boff);
      acc[ct] = __builtin_amdgcn_mfma_f32_16x16x32_bf16(ah, bh, acc[ct], 0, 0, 0);
      acc[ct] = __builtin_amdgcn_mfma_f32_16x16x32_bf16(ah, bl, acc[ct], 0, 0, 0);
      acc[ct] = __builtin_amdgcn_mfma_f32_16x16x32_bf16(al, bh, acc[ct], 0, 0, 0);
    }
  }
#pragma unroll
  for (int ct = 0; ct < 2; ++ct)
#pragma unroll
    for (int rr = 0; rr < 4; ++rr)
      Red[(w * 16 + fq * 4 + rr) * 33 + ct * 16 + fr] = acc[ct][rr];
  __syncthreads();
  if (tid < 128) {
    const int row = tid >> 3, cg = (tid & 7) * 4;
#pragma unroll
    for (int j = 0; j < 4; ++j) {
      const int col = cg + j;
      const float s = Red[(0 * 16 + row) * 33 + col] + Red[(1 * 16 + row) * 33 + col]
                    + Red[(2 * 16 + row) * 33 + col] + Red[(3 * 16 + row) * 33 + col];
      const int grow = row0 + row;
      if (col < 16) {
        bbuf[grow * NHEAD + col] = 1.f / (1.f + __expf(-s));
      } else {
        const int hh = col - 16;
        const float xs = s + dtb[hh];
        const float sp = (xs > 20.f) ? xs : log1pf(__expf(xs));
        gbuf[grow * NHEAD + hh] = -__expf(A_log[hh]) * sp;
      }
    }
  }
}

// ===================== chunk-parallel gated delta rule (MFMA) =================
__global__ __launch_bounds__(256) void chunk_local(
    const u16* __restrict__ qp, const u16* __restrict__ kp, const u16* __restrict__ vp,
    const float* __restrict__ cq, const float* __restrict__ ck, const float* __restrict__ cv,
    const float* __restrict__ gbuf, const float* __restrict__ bbuf,
    float* __restrict__ Pg, float* __restrict__ Ug,
    float* __restrict__ Rg, float* __restrict__ Yg) {
  __shared__ __align__(16) u16 Kb[64 * 64];
  __shared__ __align__(16) u16 Qb[64 * 64];
  __shared__ __align__(16) u16 K2T[64 * 64];
  __shared__ __align__(16) u16 KWt[64 * 64];   // -> uTh
  __shared__ __align__(16) u16 Vt[64 * 64];    // -> Gb
  __shared__ __align__(16) u16 Zb[64 * 64];
  __shared__ __align__(16) u16 Zt[64 * 64];
  __shared__ __align__(16) u16 Mb[64 * 72];    // -> WTh
  __shared__ __align__(16) float Cb[16 * 64];
  __shared__ float bcs[64], bet[64], e2v[64], Bv[64];
  u16* WTh = Mb;
  u16* uTh = KWt;
  u16* Gb  = Vt;

  const int bid = blockIdx.x;
  const int c = bid & 31, bh = bid >> 5;
  const int b = bh >> 4, h = bh & 15;
  const int tid = threadIdx.x;

  {
    int* zp = (int*)Zt;
#pragma unroll
    for (int i = 0; i < 8; ++i) zp[tid + 256 * i] = 0;
  }
  if (tid < 64) {
    const size_t gi = (size_t)((b * TLEN + c * 64) + tid) * NHEAD + h;
    bet[tid] = bbuf[gi];
    float v = gbuf[gi];
#pragma unroll
    for (int ofs = 1; ofs < 64; ofs <<= 1) {
      float tt = __shfl_up(v, ofs);
      if (tid >= ofs) v += tt;
    }
    bcs[tid] = v;
  }
  __syncthreads();
  if (tid < 64) {
    const float blast = bcs[63];
    Bv[tid]  = __expf(bcs[tid]);
    e2v[tid] = __expf(blast - bcs[tid]);
  }
  __syncthreads();

  // ---- staging with fused conv+silu+l2norm
  {
    const int dq = (tid & 15) * 4;
    const int col = h * 64 + dq;
    float4 wq4[4], wk4[4], wv4[4];
#pragma unroll
    for (int jj = 0; jj < 4; ++jj) {
      wq4[jj] = *(const float4*)(cq + (size_t)(col + jj) * 4);
      wk4[jj] = *(const float4*)(ck + (size_t)(col + jj) * 4);
      wv4[jj] = *(const float4*)(cv + (size_t)(col + jj) * 4);
    }
#pragma unroll
    for (int i = 0; i < 4; ++i) {
      const int r = i * 16 + (tid >> 4);
      const int tcur = c * 64 + r;
      ushort4 xq[4], xk[4], xv[4];
#pragma unroll
      for (int m = 0; m < 4; ++m) {
        const int tt = tcur - 3 + m;
        if (tt >= 0) {
          const size_t a = (size_t)(b * TLEN + tt) * HD + col;
          xq[m] = *(const ushort4*)(qp + a);
          xk[m] = *(const ushort4*)(kp + a);
          xv[m] = *(const ushort4*)(vp + a);
        } else {
          xq[m] = ushort4{0, 0, 0, 0}; xk[m] = xq[m]; xv[m] = xq[m];
        }
      }
      float yq[4], yk[4], yv[4];
      float ssq = 0.f, ssk = 0.f;
#pragma unroll
      for (int jj = 0; jj < 4; ++jj) {
        float aq = wq4[jj].x * bf2f(((const u16*)&xq[0])[jj]) +
                   wq4[jj].y * bf2f(((const u16*)&xq[1])[jj]) +
                   wq4[jj].z * bf2f(((const u16*)&xq[2])[jj]) +
                   wq4[jj].w * bf2f(((const u16*)&xq[3])[jj]);
        float ak = wk4[jj].x * bf2f(((const u16*)&xk[0])[jj]) +
                   wk4[jj].y * bf2f(((const u16*)&xk[1])[jj]) +
                   wk4[jj].z * bf2f(((const u16*)&xk[2])[jj]) +
                   wk4[jj].w * bf2f(((const u16*)&xk[3])[jj]);
        float av = wv4[jj].x * bf2f(((const u16*)&xv[0])[jj]) +
                   wv4[jj].y * bf2f(((const u16*)&xv[1])[jj]) +
                   wv4[jj].z * bf2f(((const u16*)&xv[2])[jj]) +
                   wv4[jj].w * bf2f(((const u16*)&xv[3])[jj]);
        yq[jj] = aq / (1.f + __expf(-aq));
        yk[jj] = ak / (1.f + __expf(-ak));
        yv[jj] = av / (1.f + __expf(-av));
        ssq += yq[jj] * yq[jj];
        ssk += yk[jj] * yk[jj];
      }
      ssq += __shfl_xor(ssq, 1); ssq += __shfl_xor(ssq, 2);
      ssq += __shfl_xor(ssq, 4); ssq += __shfl_xor(ssq, 8);
      ssk += __shfl_xor(ssk, 1); ssk += __shfl_xor(ssk, 2);
      ssk += __shfl_xor(ssk, 4); ssk += __shfl_xor(ssk, 8);
      const float qsc = rsqrtf(ssq + 1e-6f) * 0.125f;
      const float ksc = rsqrtf(ssk + 1e-6f);
      const float bR = bet[r], e2R = e2v[r], wscR = bR * Bv[r];
      ushort4 qo, ko;
      float kvf[4];
#pragma unroll
      for (int jj = 0; jj < 4; ++jj) kvf[jj] = yk[jj] * ksc;
      qo.x = f2bf(yq[0] * qsc); qo.y = f2bf(yq[1] * qsc);
      qo.z = f2bf(yq[2] * qsc); qo.w = f2bf(yq[3] * qsc);
      ko.x = f2bf(kvf[0]); ko.y = f2bf(kvf[1]);
      ko.z = f2bf(kvf[2]); ko.w = f2bf(kvf[3]);
      *(ushort4*)((char*)Qb + swz(r, dq)) = qo;
      *(ushort4*)((char*)Kb + swz(r, dq)) = ko;
#pragma unroll
      for (int jj = 0; jj < 4; ++jj) {
        *(u16*)((char*)K2T + swz(dq + jj, r)) = f2bf(kvf[jj] * e2R);
        *(u16*)((char*)KWt + swz(dq + jj, r)) = f2bf(kvf[jj] * wscR);
        *(u16*)((char*)Vt  + swz(dq + jj, r)) = f2bf(yv[jj] * bR);
      }
    }
  }
  __syncthreads();

  const int w = tid >> 6, lane = tid & 63, fr = lane & 15, fq = lane >> 4;
  // ---- A = K K^T via MFMA -> masked M (bf16, stride 72)
  {
    bf16x8 ka0 = frag(Kb, w * 16 + fr, fq);
    bf16x8 ka1 = frag(Kb, w * 16 + fr, 4 + fq);
#pragma unroll
    for (int tc = 0; tc < 4; ++tc) {
      bf16x8 kb0 = frag(Kb, tc * 16 + fr, fq);
      bf16x8 kb1 = frag(Kb, tc * 16 + fr, 4 + fq);
      f32x4 a = {};
      a = __builtin_amdgcn_mfma_f32_16x16x32_bf16(ka0, kb0, a, 0, 0, 0);
      a = __builtin_amdgcn_mfma_f32_16x16x32_bf16(ka1, kb1, a, 0, 0, 0);
#pragma unroll
      for (int rr = 0; rr < 4; ++rr) {
        const int t = w * 16 + fq * 4 + rr, s = tc * 16 + fr;
        const float mv = (s < t) ? bet[t] * __expf(bcs[t] - bcs[s]) * a[rr] : 0.f;
        Mb[t * 72 + s] = f2bf(mv);
      }
    }
  }
  __syncthreads();

  // ---- BLOCKED solve M Minv = I (4 blocks of 16 rows)
#pragma unroll 1
  for (int bi = 0; bi < 4; ++bi) {
    {
      const char* mrow = (const char*)Mb + (size_t)(bi * 16 + fr) * 144;
      bf16x8 ma0 = *(const bf16x8*)(mrow + fq * 16);
      bf16x8 ma1 = *(const bf16x8*)(mrow + 64 + fq * 16);
      bf16x8 zt0 = frag(Zt, w * 16 + fr, fq);
      bf16x8 zt1 = frag(Zt, w * 16 + fr, 4 + fq);
      f32x4 a = {};
      a = __builtin_amdgcn_mfma_f32_16x16x32_bf16(ma0, zt0, a, 0, 0, 0);
      a = __builtin_amdgcn_mfma_f32_16x16x32_bf16(ma1, zt1, a, 0, 0, 0);
#pragma unroll
      for (int rr = 0; rr < 4; ++rr)
        Cb[(fq * 4 + rr) * 64 + w * 16 + fr] = a[rr];
    }
    __syncthreads();
    if (tid < 64) {
      const int j = tid;
      float z[16];
#pragma unroll
      for (int t = 0; t < 16; ++t) {
        float acc = ((bi * 16 + t) == j ? 1.f : 0.f) - Cb[t * 64 + j];
        const u16* mrow = Mb + (size_t)(bi * 16 + t) * 72 + bi * 16;
#pragma unroll
        for (int s = 0; s < t; ++s) acc -= bf2f(mrow[s]) * z[s];
        z[t] = acc;
      }
#pragma unroll
      for (int t = 0; t < 16; ++t)
        *(u16*)((char*)Zb + swz(bi * 16 + t, j)) = f2bf(z[t]);
#pragma unroll
      for (int t4 = 0; t4 < 4; ++t4) {
        ushort4 zz;
        zz.x = f2bf(z[t4 * 4 + 0]); zz.y = f2bf(z[t4 * 4 + 1]);
        zz.z = f2bf(z[t4 * 4 + 2]); zz.w = f2bf(z[t4 * 4 + 3]);
        *(ushort4*)((char*)Zt + swz(j, bi * 16 + t4 * 4)) = zz;
      }
    }
    __syncthreads();
  }

  // ---- W = Minv*RHSw, u = Minv*RHSv (transposed out), G = QK^T
  f32x4 accW[4], accu[4], accG[4];
  {
    bf16x8 kw0 = frag(KWt, w * 16 + fr, fq), kw1 = frag(KWt, w * 16 + fr, 4 + fq);
    bf16x8 vt0 = frag(Vt,  w * 16 + fr, fq), vt1 = frag(Vt,  w * 16 + fr, 4 + fq);
    bf16x8 qa0 = frag(Qb,  w * 16 + fr, fq), qa1 = frag(Qb,  w * 16 + fr, 4 + fq);
#pragma unroll
    for (int tc = 0; tc < 4; ++tc) {
      bf16x8 z0 = frag(Zb, tc * 16 + fr, fq), z1 = frag(Zb, tc * 16 + fr, 4 + fq);
      bf16x8 kb0 = frag(Kb, tc * 16 + fr, fq), kb1 = frag(Kb, tc * 16 + fr, 4 + fq);
      f32x4 aw = {}, au = {}, ag = {};
      aw = __builtin_amdgcn_mfma_f32_16x16x32_bf16(kw0, z0, aw, 0, 0, 0);
      aw = __builtin_amdgcn_mfma_f32_16x16x32_bf16(kw1, z1, aw, 0, 0, 0);
      au = __builtin_amdgcn_mfma_f32_16x16x32_bf16(vt0, z0, au, 0, 0, 0);
      au = __builtin_amdgcn_mfma_f32_16x16x32_bf16(vt1, z1, au, 0, 0, 0);
      ag = __builtin_amdgcn_mfma_f32_16x16x32_bf16(qa0, kb0, ag, 0, 0, 0);
      ag = __builtin_amdgcn_mfma_f32_16x16x32_bf16(qa1, kb1, ag, 0, 0, 0);
      accW[tc] = aw; accu[tc] = au; accG[tc] = ag;
    }
  }
  __syncthreads();
#pragma unroll
  for (int tc = 0; tc < 4; ++tc)
#pragma unroll
    for (int rr = 0; rr < 4; ++rr) {
      const int ro = w * 16 + fq * 4 + rr, co = tc * 16 + fr;
      *(u16*)((char*)WTh + swz(ro, co)) = f2bf(accW[tc][rr]);
      *(u16*)((char*)uTh + swz(ro, co)) = f2bf(accu[tc][rr]);
      const float gv = (co <= ro) ? accG[tc][rr] * __expf(bcs[ro] - bcs[co]) : 0.f;
      *(u16*)((char*)Gb + swz(ro, co)) = f2bf(gv);
    }
  __syncthreads();

  // ---- P,U,R,Y via MFMA + epilogue
  {
    bf16x8 k20 = frag(K2T, w * 16 + fr, fq), k21 = frag(K2T, w * 16 + fr, 4 + fq);
    bf16x8 g0  = frag(Gb,  w * 16 + fr, fq), g1  = frag(Gb,  w * 16 + fr, 4 + fq);
    const float bl = Bv[63];
    const size_t off = (size_t)bid * 4096;
#pragma unroll
    for (int tc = 0; tc < 4; ++tc) {
      bf16x8 w0 = frag(WTh, tc * 16 + fr, fq), w1 = frag(WTh, tc * 16 + fr, 4 + fq);
      bf16x8 u0 = frag(uTh, tc * 16 + fr, fq), u1 = frag(uTh, tc * 16 + fr, 4 + fq);
      f32x4 aP = {}, aU = {}, aR = {}, aY = {};
      aP = __builtin_amdgcn_mfma_f32_16x16x32_bf16(k20, w0, aP, 0, 0, 0);
      aP = __builtin_amdgcn_mfma_f32_16x16x32_bf16(k21, w1, aP, 0, 0, 0);
      aU = __builtin_amdgcn_mfma_f32_16x16x32_bf16(k20, u0, aU, 0, 0, 0);
      aU = __builtin_amdgcn_mfma_f32_16x16x32_bf16(k21, u1, aU, 0, 0, 0);
      aR = __builtin_amdgcn_mfma_f32_16x16x32_bf16(g0, w0, aR, 0, 0, 0);
      aR = __builtin_amdgcn_mfma_f32_16x16x32_bf16(g1, w1, aR, 0, 0, 0);
      aY = __builtin_amdgcn_mfma_f32_16x16x32_bf16(g0, u0, aY, 0, 0, 0);
      aY = __builtin_amdgcn_mfma_f32_16x16x32_bf16(g1, u1, aY, 0, 0, 0);
#pragma unroll
      for (int rr = 0; rr < 4; ++rr) {
        const int ar = w * 16 + fq * 4 + rr, cb = tc * 16 + fr;
        Pg[off + ar * 64 + cb] = ((ar == cb) ? bl : 0.f) - aP[rr];
        Ug[off + ar * 64 + cb] = aU[rr];
        const float qv = bf2f(*(const u16*)((const char*)Qb + swz(ar, cb)));
        Rg[off + ar * 64 + cb] = Bv[ar] * qv - aR[rr];
        Yg[off + ar * 64 + cb] = aY[rr];
      }
    }
  }
}

// ---- phase B: S_{c+1} = P_c S_c + U_c ; store S_in per chunk. 128 blocks.
__global__ __launch_bounds__(256) void state_step(
    const float* __restrict__ Pg, const float* __restrict__ Ug,
    float* __restrict__ Sst) {
  __shared__ float Ps[64 * 65];
  __shared__ float Sc[64 * 20];
  const int blk = blockIdx.x;
  const int bh = blk >> 2, j0 = (blk & 3) * 16;
  const int tid = threadIdx.x;
  const int a = tid >> 2, jb = (tid & 3) * 4;
  const int pr = tid >> 4, pc = (tid & 15) * 4;
  for (int i = tid; i < 64 * 20; i += 256) Sc[i] = 0.f;
  float4 pre[4];
  {
    const size_t off0 = (size_t)bh * 32 * 4096;
#pragma unroll
    for (int i = 0; i < 4; ++i)
      pre[i] = *(const float4*)(Pg + off0 + (size_t)(i * 16 + pr) * 64 + pc);
  }
  __syncthreads();
  for (int c = 0; c < 32; ++c) {
    const size_t off = ((size_t)bh * 32 + c) * 4096;
#pragma unroll
    for (int i = 0; i < 4; ++i) {
      float* dst = &Ps[(i * 16 + pr) * 65 + pc];
      dst[0] = pre[i].x; dst[1] = pre[i].y; dst[2] = pre[i].z; dst[3] = pre[i].w;
    }
    __syncthreads();
    if (c + 1 < 32) {
      const size_t offn = off + 4096;
#pragma unroll
      for (int i = 0; i < 4; ++i)
        pre[i] = *(const float4*)(Pg + offn + (size_t)(i * 16 + pr) * 64 + pc);
    }
    *(float4*)(Sst + off + (size_t)a * 64 + j0 + jb) = *(const float4*)(&Sc[a * 20 + jb]);
    float4 acc = *(const float4*)(Ug + off + (size_t)a * 64 + j0 + jb);
    for (int k = 0; k < 64; ++k) {
      const float pv = Ps[a * 65 + k];
      const float4 sv = *(const float4*)(&Sc[k * 20 + jb]);
      acc.x += pv * sv.x; acc.y += pv * sv.y;
      acc.z += pv * sv.z; acc.w += pv * sv.w;
    }
    __syncthreads();
    *(float4*)(&Sc[a * 20 + jb]) = acc;
    __syncthreads();
  }
}

// ---- phase C: O = R S_in + Y, fused gated-RMSNorm epilogue -> bf16
__global__ __launch_bounds__(256) void chunk_out(
    const float* __restrict__ Rg, const float* __restrict__ Yg,
    const float* __restrict__ Sst, const u16* __restrict__ gatep,
    const float* __restrict__ norm_w, u16* __restrict__ outb) {
  __shared__ float Rs[64 * 65];
  __shared__ float Ss[64 * 65];
  const int bid = blockIdx.x;
  const int c = bid & 31, bh = bid >> 5, b = bh >> 4, h = bh & 15;
  const int tid = threadIdx.x;
  const size_t off = (size_t)bid * 4096;
#pragma unroll
  for (int i = 0; i < 4; ++i) {
    const int idx = i * 1024 + tid * 4;
    const int row = idx >> 6, col = idx & 63;
    float4 rv = *(const float4*)(Rg + off + idx);
    float4 sv = *(const float4*)(Sst + off + idx);
    float* rd = &Rs[row * 65 + col];
    rd[0]=rv.x; rd[1]=rv.y; rd[2]=rv.z; rd[3]=rv.w;
    float* sd = &Ss[row * 65 + col];
    sd[0]=sv.x; sd[1]=sv.y; sd[2]=sv.z; sd[3]=sv.w;
  }
  __syncthreads();
  const int tr = tid >> 4, tc = tid & 15;
  float acc[4][4];
#pragma unroll
  for (int i = 0; i < 4; ++i) {
    const float4 y = *(const float4*)(Yg + off + (4*tr+i)*64 + 4*tc);
    acc[i][0] = y.x; acc[i][1] = y.y; acc[i][2] = y.z; acc[i][3] = y.w;
  }
  for (int k = 0; k < 64; ++k) {
    float r0 = Rs[(4*tr+0)*65+k], r1 = Rs[(4*tr+1)*65+k],
          r2 = Rs[(4*tr+2)*65+k], r3 = Rs[(4*tr+3)*65+k];
    float s0 = Ss[k*65+4*tc+0], s1 = Ss[k*65+4*tc+1],
          s2 = Ss[k*65+4*tc+2], s3 = Ss[k*65+4*tc+3];
    acc[0][0]+=r0*s0; acc[0][1]+=r0*s1; acc[0][2]+=r0*s2; acc[0][3]+=r0*s3;
    acc[1][0]+=r1*s0; acc[1][1]+=r1*s1; acc[1][2]+=r1*s2; acc[1][3]+=r1*s3;
    acc[2][0]+=r2*s0; acc[2][1]+=r2*s1; acc[2][2]+=r2*s2; acc[2][3]+=r2*s3;
    acc[3][0]+=r3*s0; acc[3][1]+=r3*s1; acc[3][2]+=r3*s2; acc[3][3]+=r3*s3;
  }
  const float4 nw4 = *(const float4*)(norm_w + 4 * tc);
  const size_t btbase = (size_t)(b * TLEN + c * 64);
#pragma unroll
  for (int i = 0; i < 4; ++i) {
    float rs = acc[i][0]*acc[i][0] + acc[i][1]*acc[i][1]
             + acc[i][2]*acc[i][2] + acc[i][3]*acc[i][3];
    rs += __shfl_xor(rs, 1); rs += __shfl_xor(rs, 2);
    rs += __shfl_xor(rs, 4); rs += __shfl_xor(rs, 8);
    const float inv = rsqrtf(rs * (1.0f / 64.0f) + 1e-5f);
    const int t = 4 * tr + i;
    const size_t goff = (btbase + t) * 1024 + h * 64 + 4 * tc;
    const ushort4 gv = *(const ushort4*)(gatep + goff);
    const float g0 = bf2f(gv.x), g1 = bf2f(gv.y), g2 = bf2f(gv.z), g3 = bf2f(gv.w);
    ushort4 ov;
    ov.x = f2bf(acc[i][0] * inv * nw4.x * (g0 / (1.f + __expf(-g0))));
    ov.y = f2bf(acc[i][1] * inv * nw4.y * (g1 / (1.f + __expf(-g1))));
    ov.z = f2bf(acc[i][2] * inv * nw4.z * (g2 / (1.f + __expf(-g2))));
    ov.w = f2bf(acc[i][3] * inv * nw4.w * (g3 / (1.f + __expf(-g3))));
    *(ushort4*)(outb + goff) = ov;
  }
}

extern "C" void kernel_launch(void* const* d_in, const int* in_sizes, int n_in,
                              void* d_out, int out_size, void* d_ws, size_t ws_size,
                              hipStream_t stream) {
  const float* hidden = (const float*)d_in[0];
  const float* Wq     = (const float*)d_in[1];
  const float* Wk     = (const float*)d_in[2];
  const float* Wv     = (const float*)d_in[3];
  const float* cq     = (const float*)d_in[4];
  const float* ck     = (const float*)d_in[5];
  const float* cv     = (const float*)d_in[6];
  const float* Wb     = (const float*)d_in[7];
  const float* Wa     = (const float*)d_in[8];
  const float* A_log  = (const float*)d_in[9];
  const float* dtb    = (const float*)d_in[10];
  const float* Wg     = (const float*)d_in[11];
  const float* nw     = (const float*)d_in[12];
  const float* Wo     = (const float*)d_in[13];

  char* p = (char*)d_ws;
  const size_t MB = 1u << 20;
  u16* h_bf = (u16*)(p + 0 * MB);     // 8 MB
  u16* wq_b = (u16*)(p + 8 * MB);     // 2 MB
  u16* wk_b = (u16*)(p + 10 * MB);
  u16* wv_b = (u16*)(p + 12 * MB);
  u16* wg_b = (u16*)(p + 14 * MB);
  float* Pg = (float*)(p + 0 * MB);   // 16 MB, aliases h_bf..wg_b (dead then)
  u16* wo_b = (u16*)(p + 16 * MB);    // 2 MB (live till end)
  u16* qp_b = (u16*)(p + 18 * MB);    // 8 MB
  u16* kp_b = (u16*)(p + 26 * MB);    // 8 MB
  u16* vp_b = (u16*)(p + 34 * MB);    // 8 MB
  u16* gp_b = (u16*)(p + 42 * MB);    // 8 MB (live till chunk_out)
  u16*   of_b = vp_b;                 // 8 MB, aliases vp (dead after chunk_local)
  float* gbuf = (float*)(p + 50 * MB);
  float* bbuf = (float*)(p + 50 * MB + 262144);
  float* Ug  = (float*)(p + 51 * MB);  // 16 MB
  float* Rg  = (float*)(p + 67 * MB);  // 16 MB
  float* Yg  = (float*)(p + 83 * MB);  // 16 MB
  float* Sst = (float*)(p + 99 * MB);  // 16 MB
  u16* hlo_b = (u16*)(p + 115 * MB);   // 8 MB
  u16* wba_h = (u16*)(p + 123 * MB);   // 64 KB
  u16* wba_l = (u16*)(p + 123 * MB + 65536);  // 64 KB

  cvt_all<<<9248, 256, 0, stream>>>(hidden, Wq, Wk, Wv, Wg, Wo, Wb, Wa,
                                    h_bf, hlo_b, wq_b, wk_b, wv_b, wg_b, wo_b,
                                    wba_h, wba_l);

  gemm_big<<<dim3(8, 16, 4), 256, 0, stream>>>(
      h_bf, wq_b, wk_b, wv_b, wg_b, qp_b, kp_b, vp_b, gp_b, 4096, 1024, 1024);

  const int sm_lds = 65536 + 8448;
  hipFuncSetAttribute((const void*)small_mfma,
                      hipFuncAttributeMaxDynamicSharedMemorySize, sm_lds);
  small_mfma<<<256, 256, sm_lds, stream>>>(h_bf, hlo_b, wba_h, wba_l,
                                           A_log, dtb, bbuf, gbuf);

  chunk_local<<<1024, 256, 0, stream>>>(qp_b, kp_b, vp_b, cq, ck, cv,
                                        gbuf, bbuf, Pg, Ug, Rg, Yg);
  state_step<<<128, 256, 0, stream>>>(Pg, Ug, Sst);
  chunk_out<<<1024, 256, 0, stream>>>(Rg, Yg, Sst, gp_b, nw, of_b);

  gemm_lin<float, 2><<<dim3(8, 64, 1), 256, 0, stream>>>(
      of_b, wo_b, (float*)d_out, 4096, 1024, 1024);
}

// Round 8
// 181.694 us; speedup vs baseline: 9.3318x; 1.0276x over previous
//
#include <hip/hip_runtime.h>
#include <hip/hip_bf16.h>

typedef unsigned short u16;
typedef __attribute__((ext_vector_type(4))) float f32x4;
typedef __attribute__((ext_vector_type(8))) short bf16x8;

#define TLEN 2048
#define NHEAD 16
#define HD 1024

__device__ inline u16 f2bf(float f) {
  unsigned x = __float_as_uint(f);
  return (u16)((x + 0x7fffu + ((x >> 16) & 1u)) >> 16);
}
__device__ inline float bf2f(u16 u) { return __uint_as_float(((unsigned)u) << 16); }

__device__ inline float wave_sum(float x) {
  x += __shfl_xor(x, 1);  x += __shfl_xor(x, 2);  x += __shfl_xor(x, 4);
  x += __shfl_xor(x, 8);  x += __shfl_xor(x, 16); x += __shfl_xor(x, 32);
  return x;
}

__device__ inline void storev(float* p, float v) { *p = v; }
__device__ inline void storev(u16* p, float v)   { *p = f2bf(v); }

// swizzled byte offset into a [64 rows][64 bf16 = 128B] LDS tile
__device__ inline int swz(int row, int col) {
  return (row << 7) + ((((col >> 3) ^ (row & 7)) << 4)) + ((col & 7) << 1);
}
// MFMA fragment load (16B, kslot in 0..7 -> k-chunk kslot*8; same perm A/B)
__device__ inline bf16x8 frag(const u16* base, int row, int kslot) {
  return *(const bf16x8*)((const char*)base + (row << 7) +
                          (((kslot ^ (row & 7)) << 4)));
}

// ------------------------------------------------- fused fp32 -> bf16 converts
__global__ __launch_bounds__(256) void cvt_all(
    const float* __restrict__ h,  const float* __restrict__ wq,
    const float* __restrict__ wk, const float* __restrict__ wv,
    const float* __restrict__ wg, const float* __restrict__ wo,
    const float* __restrict__ Wb, const float* __restrict__ Wa,
    u16* __restrict__ dh,  u16* __restrict__ dhlo,
    u16* __restrict__ dwq, u16* __restrict__ dwk,
    u16* __restrict__ dwv, u16* __restrict__ dwg, u16* __restrict__ dwo,
    u16* __restrict__ dwba_h, u16* __restrict__ dwba_l) {
  const int b = blockIdx.x;
  if (b < 4096) {
    const size_t i = (size_t)b * 256 + threadIdx.x;
    float4 v = *(const float4*)(h + i * 4);
    ushort4 hi, lo;
    hi.x = f2bf(v.x); lo.x = f2bf(v.x - bf2f(hi.x));
    hi.y = f2bf(v.y); lo.y = f2bf(v.y - bf2f(hi.y));
    hi.z = f2bf(v.z); lo.z = f2bf(v.z - bf2f(hi.z));
    hi.w = f2bf(v.w); lo.w = f2bf(v.w - bf2f(hi.w));
    *(ushort4*)(dh + i * 4) = hi;
    *(ushort4*)(dhlo + i * 4) = lo;
  } else if (b < 9216) {
    const int wsel = (b - 4096) >> 10;
    const size_t i = (size_t)((b - 4096) & 1023) * 256 + threadIdx.x;
    const float* s; u16* d;
    switch (wsel) {
      case 0: s = wq; d = dwq; break;
      case 1: s = wk; d = dwk; break;
      case 2: s = wv; d = dwv; break;
      case 3: s = wg; d = dwg; break;
      default: s = wo; d = dwo; break;
    }
    float4 v = *(const float4*)(s + i * 4);
    ushort4 u;
    u.x = f2bf(v.x); u.y = f2bf(v.y); u.z = f2bf(v.z); u.w = f2bf(v.w);
    *(ushort4*)(d + i * 4) = u;
  } else {
    const size_t i = (size_t)(b - 9216) * 256 + threadIdx.x;
    const size_t flat = i * 4;
    const float* src = (flat < 16384) ? (Wb + flat) : (Wa + (flat - 16384));
    float4 v = *(const float4*)src;
    ushort4 hi, lo;
    hi.x = f2bf(v.x); lo.x = f2bf(v.x - bf2f(hi.x));
    hi.y = f2bf(v.y); lo.y = f2bf(v.y - bf2f(hi.y));
    hi.z = f2bf(v.z); lo.z = f2bf(v.z - bf2f(hi.z));
    hi.w = f2bf(v.w); lo.w = f2bf(v.w - bf2f(hi.w));
    *(ushort4*)(dwba_h + flat) = hi;
    *(ushort4*)(dwba_l + flat) = lo;
  }
}

// ---------------- fused 4-projection GEMM: 256x128 tile, wave-tile 64x128
__global__ __launch_bounds__(256, 2) void gemm_big(
    const u16* __restrict__ A,
    const u16* __restrict__ W0p, const u16* __restrict__ W1p,
    const u16* __restrict__ W2p, const u16* __restrict__ W3p,
    u16* __restrict__ C0, u16* __restrict__ C1,
    u16* __restrict__ C2, u16* __restrict__ C3,
    int M, int N, int K) {
  const u16* W; u16* C;
  switch (blockIdx.z) {
    case 0: W = W0p; C = C0; break;
    case 1: W = W1p; C = C1; break;
    case 2: W = W2p; C = C2; break;
    default: W = W3p; C = C3; break;
  }
  const int tid = threadIdx.x;
  const int lane = tid & 63, wid = tid >> 6;
  const int fr = lane & 15, fq = lane >> 4;
  const int row0 = blockIdx.y * 256, col0 = blockIdx.x * 128;
  __shared__ __align__(16) u16 As[256 * 64];
  __shared__ __align__(16) u16 Bs[128 * 64];

  const u16* aSrc[8]; const u16* bSrc[4];
#pragma unroll
  for (int it = 0; it < 8; ++it) {
    const int s = it * 256 + tid;
    const int r = s >> 3, cc = s & 7;
    aSrc[it] = A + (size_t)(row0 + r) * K + (cc ^ (r & 7)) * 8;
  }
#pragma unroll
  for (int it = 0; it < 4; ++it) {
    const int s = it * 256 + tid;
    const int r = s >> 3, cc = s & 7;
    bSrc[it] = W + (size_t)(col0 + r) * K + (cc ^ (r & 7)) * 8;
  }
  int aOff[4][2], bOff[8][2];
#pragma unroll
  for (int m = 0; m < 4; ++m)
#pragma unroll
    for (int kk = 0; kk < 2; ++kk) {
      const int ra = wid * 64 + m * 16 + fr;
      aOff[m][kk] = ra * 128 + ((((kk << 2) | fq) ^ (ra & 7)) << 4);
    }
#pragma unroll
  for (int n = 0; n < 8; ++n)
#pragma unroll
    for (int kk = 0; kk < 2; ++kk) {
      const int rb = n * 16 + fr;
      bOff[n][kk] = rb * 128 + ((((kk << 2) | fq) ^ (rb & 7)) << 4);
    }

  f32x4 acc[4][8] = {};
  for (int k0 = 0; k0 < K; k0 += 64) {
#pragma unroll
    for (int it = 0; it < 8; ++it)
      __builtin_amdgcn_global_load_lds(
          (const __attribute__((address_space(1))) void*)(aSrc[it] + k0),
          (__attribute__((address_space(3))) void*)((char*)As + (it * 256 + tid) * 16),
          16, 0, 0);
#pragma unroll
    for (int it = 0; it < 4; ++it)
      __builtin_amdgcn_global_load_lds(
          (const __attribute__((address_space(1))) void*)(bSrc[it] + k0),
          (__attribute__((address_space(3))) void*)((char*)Bs + (it * 256 + tid) * 16),
          16, 0, 0);
    __syncthreads();
#pragma unroll
    for (int kk = 0; kk < 2; ++kk) {
      bf16x8 af[4], bfr[8];
#pragma unroll
      for (int m = 0; m < 4; ++m)
        af[m] = *(const bf16x8*)((const char*)As + aOff[m][kk]);
#pragma unroll
      for (int n = 0; n < 8; ++n)
        bfr[n] = *(const bf16x8*)((const char*)Bs + bOff[n][kk]);
#pragma unroll
      for (int m = 0; m < 4; ++m)
#pragma unroll
        for (int n = 0; n < 8; ++n)
          acc[m][n] = __builtin_amdgcn_mfma_f32_16x16x32_bf16(af[m], bfr[n], acc[m][n], 0, 0, 0);
    }
    __syncthreads();
  }
#pragma unroll
  for (int m = 0; m < 4; ++m)
#pragma unroll
    for (int n = 0; n < 8; ++n)
#pragma unroll
      for (int r = 0; r < 4; ++r) {
        const int gr = row0 + wid * 64 + m * 16 + fq * 4 + r;
        const int gc = col0 + n * 16 + fr;
        C[(size_t)gr * N + gc] = f2bf(acc[m][n][r]);
      }
}

// ------------------------------------------------- bf16 MFMA linear: C = A*W^T
template <typename OutT, int MT>
__global__ __launch_bounds__(256) void gemm_lin(
    const u16* __restrict__ A, const u16* __restrict__ W,
    OutT* __restrict__ C, int M, int N, int K) {
  const int tid = threadIdx.x;
  const int lane = tid & 63, wid = tid >> 6;
  const int wr = wid >> 1, wc = wid & 1;
  const int fr = lane & 15, fq = lane >> 4;
  const int row0 = blockIdx.y * (MT * 32), col0 = blockIdx.x * 128;
  __shared__ __align__(16) u16 As[MT * 32 * 64];
  __shared__ __align__(16) u16 Bs[128 * 64];

  const u16* aSrc[MT]; const u16* bSrc[4];
#pragma unroll
  for (int it = 0; it < MT; ++it) {
    const int c = it * 256 + tid;
    const int r = c >> 3, cc = c & 7, sc = cc ^ (r & 7);
    aSrc[it] = A + (size_t)(row0 + r) * K + sc * 8;
  }
#pragma unroll
  for (int it = 0; it < 4; ++it) {
    const int c = it * 256 + tid;
    const int r = c >> 3, cc = c & 7, sc = cc ^ (r & 7);
    bSrc[it] = W + (size_t)(col0 + r) * K + sc * 8;
  }
  int aOff[MT][2], bOff[4][2];
#pragma unroll
  for (int m = 0; m < MT; ++m)
#pragma unroll
    for (int kk = 0; kk < 2; ++kk) {
      const int ra = wr * (MT * 16) + m * 16 + fr;
      aOff[m][kk] = ra * 128 + ((((kk << 2) | fq) ^ (fr & 7)) << 4);
    }
#pragma unroll
  for (int n = 0; n < 4; ++n)
#pragma unroll
    for (int kk = 0; kk < 2; ++kk) {
      const int rb = wc * 64 + n * 16 + fr;
      bOff[n][kk] = rb * 128 + ((((kk << 2) | fq) ^ (fr & 7)) << 4);
    }

  f32x4 acc[MT][4] = {};
  for (int k0 = 0; k0 < K; k0 += 64) {
#pragma unroll
    for (int it = 0; it < MT; ++it)
      __builtin_amdgcn_global_load_lds(
          (const __attribute__((address_space(1))) void*)(aSrc[it] + k0),
          (__attribute__((address_space(3))) void*)((char*)As + (it * 256 + wid * 64) * 16),
          16, 0, 0);
#pragma unroll
    for (int it = 0; it < 4; ++it)
      __builtin_amdgcn_global_load_lds(
          (const __attribute__((address_space(1))) void*)(bSrc[it] + k0),
          (__attribute__((address_space(3))) void*)((char*)Bs + (it * 256 + wid * 64) * 16),
          16, 0, 0);
    __syncthreads();
#pragma unroll
    for (int kk = 0; kk < 2; ++kk) {
      bf16x8 af[MT], bfr[4];
#pragma unroll
      for (int m = 0; m < MT; ++m)
        af[m] = *(const bf16x8*)((const char*)As + aOff[m][kk]);
#pragma unroll
      for (int n = 0; n < 4; ++n)
        bfr[n] = *(const bf16x8*)((const char*)Bs + bOff[n][kk]);
#pragma unroll
      for (int m = 0; m < MT; ++m)
#pragma unroll
        for (int n = 0; n < 4; ++n)
          acc[m][n] = __builtin_amdgcn_mfma_f32_16x16x32_bf16(af[m], bfr[n], acc[m][n], 0, 0, 0);
    }
    __syncthreads();
  }
#pragma unroll
  for (int m = 0; m < MT; ++m)
#pragma unroll
    for (int n = 0; n < 4; ++n)
#pragma unroll
      for (int r = 0; r < 4; ++r) {
        const int gr = row0 + wr * (MT * 16) + m * 16 + fq * 4 + r;
        const int gc = col0 + wc * 64 + n * 16 + fr;
        storev(&C[(size_t)gr * N + gc], acc[m][n][r]);
      }
}

// ---------------- beta/g projections via split-precision MFMA skinny GEMM
__global__ __launch_bounds__(256) void small_mfma(
    const u16* __restrict__ hhi, const u16* __restrict__ hlo,
    const u16* __restrict__ whi, const u16* __restrict__ wlo,
    const float* __restrict__ A_log, const float* __restrict__ dtb,
    float* __restrict__ bbuf, float* __restrict__ gbuf) {
  extern __shared__ char smc[];
  u16* Ahi = (u16*)smc;
  u16* Alo = (u16*)(smc + 32768);
  float* Red = (float*)(smc + 65536);
  const int tid = threadIdx.x;
  const int row0 = blockIdx.x * 16;
#pragma unroll
  for (int i = 0; i < 8; ++i) {
    const int slot = tid + 256 * i;
    const int r = slot >> 7, s = slot & 127;
    const int ss = s ^ (r & 7);
    const size_t src = (size_t)(row0 + r) * 1024 + (size_t)ss * 8;
    __builtin_amdgcn_global_load_lds(
        (const __attribute__((address_space(1))) void*)(hhi + src),
        (__attribute__((address_space(3))) void*)(Ahi + (size_t)slot * 8), 16, 0, 0);
    __builtin_amdgcn_global_load_lds(
        (const __attribute__((address_space(1))) void*)(hlo + src),
        (__attribute__((address_space(3))) void*)(Alo + (size_t)slot * 8), 16, 0, 0);
  }
  __syncthreads();
  const int w = tid >> 6, lane = tid & 63, fr = lane & 15, fq = lane >> 4;
  f32x4 acc[2] = {};
#pragma unroll
  for (int kk = 0; kk < 8; ++kk) {
    const int s = w * 32 + kk * 4 + fq;
    const size_t k = (size_t)w * 256 + kk * 32 + fq * 8;
    const int aoff = ((fr << 7) + (s ^ (fr & 7))) * 8;
    bf16x8 ah = *(const bf16x8*)(Ahi + aoff);
    bf16x8 al = *(const bf16x8*)(Alo + aoff);
#pragma unroll
    for (int ct = 0; ct < 2; ++ct) {
      const size_t boff = (size_t)(ct * 16 + fr) * 1024 + k;
      bf16x8 bh = *(const bf16x8*)(whi + boff);
      bf16x8 bl = *(const bf16x8*)(wlo + boff);
      acc[ct] = __builtin_amdgcn_mfma_f32_16x16x32_bf16(ah, bh, acc[ct], 0, 0, 0);
      acc[ct] = __builtin_amdgcn_mfma_f32_16x16x32_bf16(ah, bl, acc[ct], 0, 0, 0);
      acc[ct] = __builtin_amdgcn_mfma_f32_16x16x32_bf16(al, bh, acc[ct], 0, 0, 0);
    }
  }
#pragma unroll
  for (int ct = 0; ct < 2; ++ct)
#pragma unroll
    for (int rr = 0; rr < 4; ++rr)
      Red[(w * 16 + fq * 4 + rr) * 33 + ct * 16 + fr] = acc[ct][rr];
  __syncthreads();
  if (tid < 128) {
    const int row = tid >> 3, cg = (tid & 7) * 4;
#pragma unroll
    for (int j = 0; j < 4; ++j) {
      const int col = cg + j;
      const float s = Red[(0 * 16 + row) * 33 + col] + Red[(1 * 16 + row) * 33 + col]
                    + Red[(2 * 16 + row) * 33 + col] + Red[(3 * 16 + row) * 33 + col];
      const int grow = row0 + row;
      if (col < 16) {
        bbuf[grow * NHEAD + col] = 1.f / (1.f + __expf(-s));
      } else {
        const int hh = col - 16;
        const float xs = s + dtb[hh];
        const float sp = (xs > 20.f) ? xs : log1pf(__expf(xs));
        gbuf[grow * NHEAD + hh] = -__expf(A_log[hh]) * sp;
      }
    }
  }
}

// ===================== chunk-parallel gated delta rule (MFMA) =================
__global__ __launch_bounds__(256) void chunk_local(
    const u16* __restrict__ qp, const u16* __restrict__ kp, const u16* __restrict__ vp,
    const float* __restrict__ cq, const float* __restrict__ ck, const float* __restrict__ cv,
    const float* __restrict__ gbuf, const float* __restrict__ bbuf,
    float* __restrict__ Pg, u16* __restrict__ Ug,
    u16* __restrict__ Rg, u16* __restrict__ Yg) {
  __shared__ __align__(16) u16 Kb[64 * 64];
  __shared__ __align__(16) u16 Qb[64 * 64];
  __shared__ __align__(16) u16 K2T[64 * 64];
  __shared__ __align__(16) u16 KWt[64 * 64];   // -> uTh
  __shared__ __align__(16) u16 Vt[64 * 64];    // -> Gb
  __shared__ __align__(16) u16 Zb[64 * 64];
  __shared__ __align__(16) u16 Zt[64 * 64];
  __shared__ __align__(16) u16 Mb[64 * 72];    // -> WTh
  __shared__ __align__(16) float Cb[16 * 64];
  __shared__ float bcs[64], bet[64], e2v[64], Bv[64];
  u16* WTh = Mb;
  u16* uTh = KWt;
  u16* Gb  = Vt;

  const int bid = blockIdx.x;
  const int c = bid & 31, bh = bid >> 5;
  const int b = bh >> 4, h = bh & 15;
  const int tid = threadIdx.x;

  {
    int* zp = (int*)Zt;
#pragma unroll
    for (int i = 0; i < 8; ++i) zp[tid + 256 * i] = 0;
  }
  if (tid < 64) {
    const size_t gi = (size_t)((b * TLEN + c * 64) + tid) * NHEAD + h;
    bet[tid] = bbuf[gi];
    float v = gbuf[gi];
#pragma unroll
    for (int ofs = 1; ofs < 64; ofs <<= 1) {
      float tt = __shfl_up(v, ofs);
      if (tid >= ofs) v += tt;
    }
    bcs[tid] = v;
  }
  __syncthreads();
  if (tid < 64) {
    const float blast = bcs[63];
    Bv[tid]  = __expf(bcs[tid]);
    e2v[tid] = __expf(blast - bcs[tid]);
  }
  __syncthreads();

  // ---- staging with fused conv+silu+l2norm
  {
    const int dq = (tid & 15) * 4;
    const int col = h * 64 + dq;
    float4 wq4[4], wk4[4], wv4[4];
#pragma unroll
    for (int jj = 0; jj < 4; ++jj) {
      wq4[jj] = *(const float4*)(cq + (size_t)(col + jj) * 4);
      wk4[jj] = *(const float4*)(ck + (size_t)(col + jj) * 4);
      wv4[jj] = *(const float4*)(cv + (size_t)(col + jj) * 4);
    }
#pragma unroll
    for (int i = 0; i < 4; ++i) {
      const int r = i * 16 + (tid >> 4);
      const int tcur = c * 64 + r;
      ushort4 xq[4], xk[4], xv[4];
#pragma unroll
      for (int m = 0; m < 4; ++m) {
        const int tt = tcur - 3 + m;
        if (tt >= 0) {
          const size_t a = (size_t)(b * TLEN + tt) * HD + col;
          xq[m] = *(const ushort4*)(qp + a);
          xk[m] = *(const ushort4*)(kp + a);
          xv[m] = *(const ushort4*)(vp + a);
        } else {
          xq[m] = ushort4{0, 0, 0, 0}; xk[m] = xq[m]; xv[m] = xq[m];
        }
      }
      float yq[4], yk[4], yv[4];
      float ssq = 0.f, ssk = 0.f;
#pragma unroll
      for (int jj = 0; jj < 4; ++jj) {
        float aq = wq4[jj].x * bf2f(((const u16*)&xq[0])[jj]) +
                   wq4[jj].y * bf2f(((const u16*)&xq[1])[jj]) +
                   wq4[jj].z * bf2f(((const u16*)&xq[2])[jj]) +
                   wq4[jj].w * bf2f(((const u16*)&xq[3])[jj]);
        float ak = wk4[jj].x * bf2f(((const u16*)&xk[0])[jj]) +
                   wk4[jj].y * bf2f(((const u16*)&xk[1])[jj]) +
                   wk4[jj].z * bf2f(((const u16*)&xk[2])[jj]) +
                   wk4[jj].w * bf2f(((const u16*)&xk[3])[jj]);
        float av = wv4[jj].x * bf2f(((const u16*)&xv[0])[jj]) +
                   wv4[jj].y * bf2f(((const u16*)&xv[1])[jj]) +
                   wv4[jj].z * bf2f(((const u16*)&xv[2])[jj]) +
                   wv4[jj].w * bf2f(((const u16*)&xv[3])[jj]);
        yq[jj] = aq / (1.f + __expf(-aq));
        yk[jj] = ak / (1.f + __expf(-ak));
        yv[jj] = av / (1.f + __expf(-av));
        ssq += yq[jj] * yq[jj];
        ssk += yk[jj] * yk[jj];
      }
      ssq += __shfl_xor(ssq, 1); ssq += __shfl_xor(ssq, 2);
      ssq += __shfl_xor(ssq, 4); ssq += __shfl_xor(ssq, 8);
      ssk += __shfl_xor(ssk, 1); ssk += __shfl_xor(ssk, 2);
      ssk += __shfl_xor(ssk, 4); ssk += __shfl_xor(ssk, 8);
      const float qsc = rsqrtf(ssq + 1e-6f) * 0.125f;
      const float ksc = rsqrtf(ssk + 1e-6f);
      const float bR = bet[r], e2R = e2v[r], wscR = bR * Bv[r];
      ushort4 qo, ko;
      float kvf[4];
#pragma unroll
      for (int jj = 0; jj < 4; ++jj) kvf[jj] = yk[jj] * ksc;
      qo.x = f2bf(yq[0] * qsc); qo.y = f2bf(yq[1] * qsc);
      qo.z = f2bf(yq[2] * qsc); qo.w = f2bf(yq[3] * qsc);
      ko.x = f2bf(kvf[0]); ko.y = f2bf(kvf[1]);
      ko.z = f2bf(kvf[2]); ko.w = f2bf(kvf[3]);
      *(ushort4*)((char*)Qb + swz(r, dq)) = qo;
      *(ushort4*)((char*)Kb + swz(r, dq)) = ko;
#pragma unroll
      for (int jj = 0; jj < 4; ++jj) {
        *(u16*)((char*)K2T + swz(dq + jj, r)) = f2bf(kvf[jj] * e2R);
        *(u16*)((char*)KWt + swz(dq + jj, r)) = f2bf(kvf[jj] * wscR);
        *(u16*)((char*)Vt  + swz(dq + jj, r)) = f2bf(yv[jj] * bR);
      }
    }
  }
  __syncthreads();

  const int w = tid >> 6, lane = tid & 63, fr = lane & 15, fq = lane >> 4;
  // ---- A = K K^T via MFMA -> masked M (bf16, stride 72)
  {
    bf16x8 ka0 = frag(Kb, w * 16 + fr, fq);
    bf16x8 ka1 = frag(Kb, w * 16 + fr, 4 + fq);
#pragma unroll
    for (int tc = 0; tc < 4; ++tc) {
      bf16x8 kb0 = frag(Kb, tc * 16 + fr, fq);
      bf16x8 kb1 = frag(Kb, tc * 16 + fr, 4 + fq);
      f32x4 a = {};
      a = __builtin_amdgcn_mfma_f32_16x16x32_bf16(ka0, kb0, a, 0, 0, 0);
      a = __builtin_amdgcn_mfma_f32_16x16x32_bf16(ka1, kb1, a, 0, 0, 0);
#pragma unroll
      for (int rr = 0; rr < 4; ++rr) {
        const int t = w * 16 + fq * 4 + rr, s = tc * 16 + fr;
        const float mv = (s < t) ? bet[t] * __expf(bcs[t] - bcs[s]) * a[rr] : 0.f;
        Mb[t * 72 + s] = f2bf(mv);
      }
    }
  }
  __syncthreads();

  // ---- BLOCKED solve M Minv = I (4 blocks of 16 rows)
#pragma unroll 1
  for (int bi = 0; bi < 4; ++bi) {
    {
      const char* mrow = (const char*)Mb + (size_t)(bi * 16 + fr) * 144;
      bf16x8 ma0 = *(const bf16x8*)(mrow + fq * 16);
      bf16x8 ma1 = *(const bf16x8*)(mrow + 64 + fq * 16);
      bf16x8 zt0 = frag(Zt, w * 16 + fr, fq);
      bf16x8 zt1 = frag(Zt, w * 16 + fr, 4 + fq);
      f32x4 a = {};
      a = __builtin_amdgcn_mfma_f32_16x16x32_bf16(ma0, zt0, a, 0, 0, 0);
      a = __builtin_amdgcn_mfma_f32_16x16x32_bf16(ma1, zt1, a, 0, 0, 0);
#pragma unroll
      for (int rr = 0; rr < 4; ++rr)
        Cb[(fq * 4 + rr) * 64 + w * 16 + fr] = a[rr];
    }
    __syncthreads();
    if (tid < 64) {
      const int j = tid;
      float z[16];
#pragma unroll
      for (int t = 0; t < 16; ++t) {
        float acc = ((bi * 16 + t) == j ? 1.f : 0.f) - Cb[t * 64 + j];
        const u16* mrow = Mb + (size_t)(bi * 16 + t) * 72 + bi * 16;
#pragma unroll
        for (int s = 0; s < t; ++s) acc -= bf2f(mrow[s]) * z[s];
        z[t] = acc;
      }
#pragma unroll
      for (int t = 0; t < 16; ++t)
        *(u16*)((char*)Zb + swz(bi * 16 + t, j)) = f2bf(z[t]);
#pragma unroll
      for (int t4 = 0; t4 < 4; ++t4) {
        ushort4 zz;
        zz.x = f2bf(z[t4 * 4 + 0]); zz.y = f2bf(z[t4 * 4 + 1]);
        zz.z = f2bf(z[t4 * 4 + 2]); zz.w = f2bf(z[t4 * 4 + 3]);
        *(ushort4*)((char*)Zt + swz(j, bi * 16 + t4 * 4)) = zz;
      }
    }
    __syncthreads();
  }

  // ---- W = Minv*RHSw, u = Minv*RHSv (transposed out), G = QK^T
  f32x4 accW[4], accu[4], accG[4];
  {
    bf16x8 kw0 = frag(KWt, w * 16 + fr, fq), kw1 = frag(KWt, w * 16 + fr, 4 + fq);
    bf16x8 vt0 = frag(Vt,  w * 16 + fr, fq), vt1 = frag(Vt,  w * 16 + fr, 4 + fq);
    bf16x8 qa0 = frag(Qb,  w * 16 + fr, fq), qa1 = frag(Qb,  w * 16 + fr, 4 + fq);
#pragma unroll
    for (int tc = 0; tc < 4; ++tc) {
      bf16x8 z0 = frag(Zb, tc * 16 + fr, fq), z1 = frag(Zb, tc * 16 + fr, 4 + fq);
      bf16x8 kb0 = frag(Kb, tc * 16 + fr, fq), kb1 = frag(Kb, tc * 16 + fr, 4 + fq);
      f32x4 aw = {}, au = {}, ag = {};
      aw = __builtin_amdgcn_mfma_f32_16x16x32_bf16(kw0, z0, aw, 0, 0, 0);
      aw = __builtin_amdgcn_mfma_f32_16x16x32_bf16(kw1, z1, aw, 0, 0, 0);
      au = __builtin_amdgcn_mfma_f32_16x16x32_bf16(vt0, z0, au, 0, 0, 0);
      au = __builtin_amdgcn_mfma_f32_16x16x32_bf16(vt1, z1, au, 0, 0, 0);
      ag = __builtin_amdgcn_mfma_f32_16x16x32_bf16(qa0, kb0, ag, 0, 0, 0);
      ag = __builtin_amdgcn_mfma_f32_16x16x32_bf16(qa1, kb1, ag, 0, 0, 0);
      accW[tc] = aw; accu[tc] = au; accG[tc] = ag;
    }
  }
  __syncthreads();
#pragma unroll
  for (int tc = 0; tc < 4; ++tc)
#pragma unroll
    for (int rr = 0; rr < 4; ++rr) {
      const int ro = w * 16 + fq * 4 + rr, co = tc * 16 + fr;
      *(u16*)((char*)WTh + swz(ro, co)) = f2bf(accW[tc][rr]);
      *(u16*)((char*)uTh + swz(ro, co)) = f2bf(accu[tc][rr]);
      const float gv = (co <= ro) ? accG[tc][rr] * __expf(bcs[ro] - bcs[co]) : 0.f;
      *(u16*)((char*)Gb + swz(ro, co)) = f2bf(gv);
    }
  __syncthreads();

  // ---- P,U,R,Y via MFMA + epilogue (P fp32; U,R,Y bf16)
  {
    bf16x8 k20 = frag(K2T, w * 16 + fr, fq), k21 = frag(K2T, w * 16 + fr, 4 + fq);
    bf16x8 g0  = frag(Gb,  w * 16 + fr, fq), g1  = frag(Gb,  w * 16 + fr, 4 + fq);
    const float bl = Bv[63];
    const size_t off = (size_t)bid * 4096;
#pragma unroll
    for (int tc = 0; tc < 4; ++tc) {
      bf16x8 w0 = frag(WTh, tc * 16 + fr, fq), w1 = frag(WTh, tc * 16 + fr, 4 + fq);
      bf16x8 u0 = frag(uTh, tc * 16 + fr, fq), u1 = frag(uTh, tc * 16 + fr, 4 + fq);
      f32x4 aP = {}, aU = {}, aR = {}, aY = {};
      aP = __builtin_amdgcn_mfma_f32_16x16x32_bf16(k20, w0, aP, 0, 0, 0);
      aP = __builtin_amdgcn_mfma_f32_16x16x32_bf16(k21, w1, aP, 0, 0, 0);
      aU = __builtin_amdgcn_mfma_f32_16x16x32_bf16(k20, u0, aU, 0, 0, 0);
      aU = __builtin_amdgcn_mfma_f32_16x16x32_bf16(k21, u1, aU, 0, 0, 0);
      aR = __builtin_amdgcn_mfma_f32_16x16x32_bf16(g0, w0, aR, 0, 0, 0);
      aR = __builtin_amdgcn_mfma_f32_16x16x32_bf16(g1, w1, aR, 0, 0, 0);
      aY = __builtin_amdgcn_mfma_f32_16x16x32_bf16(g0, u0, aY, 0, 0, 0);
      aY = __builtin_amdgcn_mfma_f32_16x16x32_bf16(g1, u1, aY, 0, 0, 0);
#pragma unroll
      for (int rr = 0; rr < 4; ++rr) {
        const int ar = w * 16 + fq * 4 + rr, cb = tc * 16 + fr;
        Pg[off + ar * 64 + cb] = ((ar == cb) ? bl : 0.f) - aP[rr];
        Ug[off + ar * 64 + cb] = f2bf(aU[rr]);
        const float qv = bf2f(*(const u16*)((const char*)Qb + swz(ar, cb)));
        Rg[off + ar * 64 + cb] = f2bf(Bv[ar] * qv - aR[rr]);
        Yg[off + ar * 64 + cb] = f2bf(aY[rr]);
      }
    }
  }
}

// ---- phase B: S_{c+1} = P_c S_c + U_c ; store S_in (bf16) per chunk.
__global__ __launch_bounds__(256) void state_step(
    const float* __restrict__ Pg, const u16* __restrict__ Ug,
    u16* __restrict__ Sst) {
  __shared__ float Ps[64 * 65];
  __shared__ float Sc[64 * 20];
  const int blk = blockIdx.x;
  const int bh = blk >> 2, j0 = (blk & 3) * 16;
  const int tid = threadIdx.x;
  const int a = tid >> 2, jb = (tid & 3) * 4;
  const int pr = tid >> 4, pc = (tid & 15) * 4;
  for (int i = tid; i < 64 * 20; i += 256) Sc[i] = 0.f;
  float4 pre[4];
  {
    const size_t off0 = (size_t)bh * 32 * 4096;
#pragma unroll
    for (int i = 0; i < 4; ++i)
      pre[i] = *(const float4*)(Pg + off0 + (size_t)(i * 16 + pr) * 64 + pc);
  }
  __syncthreads();
  for (int c = 0; c < 32; ++c) {
    const size_t off = ((size_t)bh * 32 + c) * 4096;
#pragma unroll
    for (int i = 0; i < 4; ++i) {
      float* dst = &Ps[(i * 16 + pr) * 65 + pc];
      dst[0] = pre[i].x; dst[1] = pre[i].y; dst[2] = pre[i].z; dst[3] = pre[i].w;
    }
    __syncthreads();
    if (c + 1 < 32) {
      const size_t offn = off + 4096;
#pragma unroll
      for (int i = 0; i < 4; ++i)
        pre[i] = *(const float4*)(Pg + offn + (size_t)(i * 16 + pr) * 64 + pc);
    }
    // write S_in (bf16) and accumulate
    const float4 sc4 = *(const float4*)(&Sc[a * 20 + jb]);
    ushort4 so;
    so.x = f2bf(sc4.x); so.y = f2bf(sc4.y); so.z = f2bf(sc4.z); so.w = f2bf(sc4.w);
    *(ushort4*)(Sst + off + (size_t)a * 64 + j0 + jb) = so;
    const ushort4 uv = *(const ushort4*)(Ug + off + (size_t)a * 64 + j0 + jb);
    float4 acc;
    acc.x = bf2f(uv.x); acc.y = bf2f(uv.y); acc.z = bf2f(uv.z); acc.w = bf2f(uv.w);
    for (int k = 0; k < 64; ++k) {
      const float pv = Ps[a * 65 + k];
      const float4 sv = *(const float4*)(&Sc[k * 20 + jb]);
      acc.x += pv * sv.x; acc.y += pv * sv.y;
      acc.z += pv * sv.z; acc.w += pv * sv.w;
    }
    __syncthreads();
    *(float4*)(&Sc[a * 20 + jb]) = acc;
    __syncthreads();
  }
}

// ---- phase C: O = R S_in + Y, fused gated-RMSNorm epilogue -> bf16
__global__ __launch_bounds__(256) void chunk_out(
    const u16* __restrict__ Rg, const u16* __restrict__ Yg,
    const u16* __restrict__ Sst, const u16* __restrict__ gatep,
    const float* __restrict__ norm_w, u16* __restrict__ outb) {
  __shared__ float Rs[64 * 65];
  __shared__ float Ss[64 * 65];
  const int bid = blockIdx.x;
  const int c = bid & 31, bh = bid >> 5, b = bh >> 4, h = bh & 15;
  const int tid = threadIdx.x;
  const size_t off = (size_t)bid * 4096;
#pragma unroll
  for (int i = 0; i < 2; ++i) {
    const int idx = i * 2048 + tid * 8;
    const int row = idx >> 6, col = idx & 63;
    const ushort4 r0 = *(const ushort4*)(Rg + off + idx);
    const ushort4 r1 = *(const ushort4*)(Rg + off + idx + 4);
    const ushort4 s0 = *(const ushort4*)(Sst + off + idx);
    const ushort4 s1 = *(const ushort4*)(Sst + off + idx + 4);
    float* rd = &Rs[row * 65 + col];
    rd[0]=bf2f(r0.x); rd[1]=bf2f(r0.y); rd[2]=bf2f(r0.z); rd[3]=bf2f(r0.w);
    rd[4]=bf2f(r1.x); rd[5]=bf2f(r1.y); rd[6]=bf2f(r1.z); rd[7]=bf2f(r1.w);
    float* sd = &Ss[row * 65 + col];
    sd[0]=bf2f(s0.x); sd[1]=bf2f(s0.y); sd[2]=bf2f(s0.z); sd[3]=bf2f(s0.w);
    sd[4]=bf2f(s1.x); sd[5]=bf2f(s1.y); sd[6]=bf2f(s1.z); sd[7]=bf2f(s1.w);
  }
  __syncthreads();
  const int tr = tid >> 4, tc = tid & 15;
  float acc[4][4];
#pragma unroll
  for (int i = 0; i < 4; ++i) {
    const ushort4 y = *(const ushort4*)(Yg + off + (4*tr+i)*64 + 4*tc);
    acc[i][0] = bf2f(y.x); acc[i][1] = bf2f(y.y);
    acc[i][2] = bf2f(y.z); acc[i][3] = bf2f(y.w);
  }
  for (int k = 0; k < 64; ++k) {
    float r0 = Rs[(4*tr+0)*65+k], r1 = Rs[(4*tr+1)*65+k],
          r2 = Rs[(4*tr+2)*65+k], r3 = Rs[(4*tr+3)*65+k];
    float s0 = Ss[k*65+4*tc+0], s1 = Ss[k*65+4*tc+1],
          s2 = Ss[k*65+4*tc+2], s3 = Ss[k*65+4*tc+3];
    acc[0][0]+=r0*s0; acc[0][1]+=r0*s1; acc[0][2]+=r0*s2; acc[0][3]+=r0*s3;
    acc[1][0]+=r1*s0; acc[1][1]+=r1*s1; acc[1][2]+=r1*s2; acc[1][3]+=r1*s3;
    acc[2][0]+=r2*s0; acc[2][1]+=r2*s1; acc[2][2]+=r2*s2; acc[2][3]+=r2*s3;
    acc[3][0]+=r3*s0; acc[3][1]+=r3*s1; acc[3][2]+=r3*s2; acc[3][3]+=r3*s3;
  }
  const float4 nw4 = *(const float4*)(norm_w + 4 * tc);
  const size_t btbase = (size_t)(b * TLEN + c * 64);
#pragma unroll
  for (int i = 0; i < 4; ++i) {
    float rs = acc[i][0]*acc[i][0] + acc[i][1]*acc[i][1]
             + acc[i][2]*acc[i][2] + acc[i][3]*acc[i][3];
    rs += __shfl_xor(rs, 1); rs += __shfl_xor(rs, 2);
    rs += __shfl_xor(rs, 4); rs += __shfl_xor(rs, 8);
    const float inv = rsqrtf(rs * (1.0f / 64.0f) + 1e-5f);
    const int t = 4 * tr + i;
    const size_t goff = (btbase + t) * 1024 + h * 64 + 4 * tc;
    const ushort4 gv = *(const ushort4*)(gatep + goff);
    const float g0 = bf2f(gv.x), g1 = bf2f(gv.y), g2 = bf2f(gv.z), g3 = bf2f(gv.w);
    ushort4 ov;
    ov.x = f2bf(acc[i][0] * inv * nw4.x * (g0 / (1.f + __expf(-g0))));
    ov.y = f2bf(acc[i][1] * inv * nw4.y * (g1 / (1.f + __expf(-g1))));
    ov.z = f2bf(acc[i][2] * inv * nw4.z * (g2 / (1.f + __expf(-g2))));
    ov.w = f2bf(acc[i][3] * inv * nw4.w * (g3 / (1.f + __expf(-g3))));
    *(ushort4*)(outb + goff) = ov;
  }
}

extern "C" void kernel_launch(void* const* d_in, const int* in_sizes, int n_in,
                              void* d_out, int out_size, void* d_ws, size_t ws_size,
                              hipStream_t stream) {
  const float* hidden = (const float*)d_in[0];
  const float* Wq     = (const float*)d_in[1];
  const float* Wk     = (const float*)d_in[2];
  const float* Wv     = (const float*)d_in[3];
  const float* cq     = (const float*)d_in[4];
  const float* ck     = (const float*)d_in[5];
  const float* cv     = (const float*)d_in[6];
  const float* Wb     = (const float*)d_in[7];
  const float* Wa     = (const float*)d_in[8];
  const float* A_log  = (const float*)d_in[9];
  const float* dtb    = (const float*)d_in[10];
  const float* Wg     = (const float*)d_in[11];
  const float* nw     = (const float*)d_in[12];
  const float* Wo     = (const float*)d_in[13];

  char* p = (char*)d_ws;
  const size_t MB = 1u << 20;
  u16* h_bf = (u16*)(p + 0 * MB);     // 8 MB
  u16* wq_b = (u16*)(p + 8 * MB);     // 2 MB
  u16* wk_b = (u16*)(p + 10 * MB);
  u16* wv_b = (u16*)(p + 12 * MB);
  u16* wg_b = (u16*)(p + 14 * MB);
  float* Pg = (float*)(p + 0 * MB);   // 16 MB fp32, aliases h_bf..wg_b (dead then)
  u16* wo_b = (u16*)(p + 16 * MB);    // 2 MB (live till end)
  u16* qp_b = (u16*)(p + 18 * MB);    // 8 MB
  u16* kp_b = (u16*)(p + 26 * MB);    // 8 MB
  u16* vp_b = (u16*)(p + 34 * MB);    // 8 MB
  u16* gp_b = (u16*)(p + 42 * MB);    // 8 MB (live till chunk_out)
  u16*   of_b = vp_b;                 // 8 MB, aliases vp (dead after chunk_local)
  float* gbuf = (float*)(p + 50 * MB);
  float* bbuf = (float*)(p + 50 * MB + 262144);
  u16* Ug  = (u16*)(p + 51 * MB);     // 8 MB bf16
  u16* Rg  = (u16*)(p + 59 * MB);     // 8 MB bf16
  u16* Yg  = (u16*)(p + 67 * MB);     // 8 MB bf16
  u16* Sst = (u16*)(p + 75 * MB);     // 8 MB bf16
  u16* hlo_b = (u16*)(p + 83 * MB);   // 8 MB
  u16* wba_h = (u16*)(p + 91 * MB);   // 64 KB
  u16* wba_l = (u16*)(p + 91 * MB + 65536);  // 64 KB (total ~91.2 MB)

  cvt_all<<<9248, 256, 0, stream>>>(hidden, Wq, Wk, Wv, Wg, Wo, Wb, Wa,
                                    h_bf, hlo_b, wq_b, wk_b, wv_b, wg_b, wo_b,
                                    wba_h, wba_l);

  gemm_big<<<dim3(8, 16, 4), 256, 0, stream>>>(
      h_bf, wq_b, wk_b, wv_b, wg_b, qp_b, kp_b, vp_b, gp_b, 4096, 1024, 1024);

  const int sm_lds = 65536 + 8448;
  hipFuncSetAttribute((const void*)small_mfma,
                      hipFuncAttributeMaxDynamicSharedMemorySize, sm_lds);
  small_mfma<<<256, 256, sm_lds, stream>>>(h_bf, hlo_b, wba_h, wba_l,
                                           A_log, dtb, bbuf, gbuf);

  chunk_local<<<1024, 256, 0, stream>>>(qp_b, kp_b, vp_b, cq, ck, cv,
                                        gbuf, bbuf, Pg, Ug, Rg, Yg);
  state_step<<<128, 256, 0, stream>>>(Pg, Ug, Sst);
  chunk_out<<<1024, 256, 0, stream>>>(Rg, Yg, Sst, gp_b, nw, of_b);

  gemm_lin<float, 2><<<dim3(8, 64, 1), 256, 0, stream>>>(
      of_b, wo_b, (float*)d_out, 4096, 1024, 1024);
}

// Round 9
// 181.363 us; speedup vs baseline: 9.3488x; 1.0018x over previous
//
#include <hip/hip_runtime.h>
#include <hip/hip_bf16.h>

typedef unsigned short u16;
typedef __attribute__((ext_vector_type(4))) float f32x4;
typedef __attribute__((ext_vector_type(8))) short bf16x8;

#define TLEN 2048
#define NHEAD 16
#define HD 1024

__device__ inline u16 f2bf(float f) {
  unsigned x = __float_as_uint(f);
  return (u16)((x + 0x7fffu + ((x >> 16) & 1u)) >> 16);
}
__device__ inline float bf2f(u16 u) { return __uint_as_float(((unsigned)u) << 16); }

__device__ inline void storev(float* p, float v) { *p = v; }
__device__ inline void storev(u16* p, float v)   { *p = f2bf(v); }

// swizzled byte offset into a [64 rows][64 bf16 = 128B] LDS tile
__device__ inline int swz(int row, int col) {
  return (row << 7) + ((((col >> 3) ^ (row & 7)) << 4)) + ((col & 7) << 1);
}
// MFMA fragment load (16B, kslot in 0..7 -> logical k-chunk kslot*8)
__device__ inline bf16x8 frag(const u16* base, int row, int kslot) {
  return *(const bf16x8*)((const char*)base + (row << 7) +
                          (((kslot ^ (row & 7)) << 4)));
}

// ------------------------------------------------- fused fp32 -> bf16 converts
__global__ __launch_bounds__(256) void cvt_all(
    const float* __restrict__ h,  const float* __restrict__ wq,
    const float* __restrict__ wk, const float* __restrict__ wv,
    const float* __restrict__ wg, const float* __restrict__ wo,
    const float* __restrict__ Wb, const float* __restrict__ Wa,
    u16* __restrict__ dh,  u16* __restrict__ dhlo,
    u16* __restrict__ dwq, u16* __restrict__ dwk,
    u16* __restrict__ dwv, u16* __restrict__ dwg, u16* __restrict__ dwo,
    u16* __restrict__ dwba_h, u16* __restrict__ dwba_l) {
  const int b = blockIdx.x;
  if (b < 4096) {
    const size_t i = (size_t)b * 256 + threadIdx.x;
    float4 v = *(const float4*)(h + i * 4);
    ushort4 hi, lo;
    hi.x = f2bf(v.x); lo.x = f2bf(v.x - bf2f(hi.x));
    hi.y = f2bf(v.y); lo.y = f2bf(v.y - bf2f(hi.y));
    hi.z = f2bf(v.z); lo.z = f2bf(v.z - bf2f(hi.z));
    hi.w = f2bf(v.w); lo.w = f2bf(v.w - bf2f(hi.w));
    *(ushort4*)(dh + i * 4) = hi;
    *(ushort4*)(dhlo + i * 4) = lo;
  } else if (b < 9216) {
    const int wsel = (b - 4096) >> 10;
    const size_t i = (size_t)((b - 4096) & 1023) * 256 + threadIdx.x;
    const float* s; u16* d;
    switch (wsel) {
      case 0: s = wq; d = dwq; break;
      case 1: s = wk; d = dwk; break;
      case 2: s = wv; d = dwv; break;
      case 3: s = wg; d = dwg; break;
      default: s = wo; d = dwo; break;
    }
    float4 v = *(const float4*)(s + i * 4);
    ushort4 u;
    u.x = f2bf(v.x); u.y = f2bf(v.y); u.z = f2bf(v.z); u.w = f2bf(v.w);
    *(ushort4*)(d + i * 4) = u;
  } else {
    const size_t i = (size_t)(b - 9216) * 256 + threadIdx.x;
    const size_t flat = i * 4;
    const float* src = (flat < 16384) ? (Wb + flat) : (Wa + (flat - 16384));
    float4 v = *(const float4*)src;
    ushort4 hi, lo;
    hi.x = f2bf(v.x); lo.x = f2bf(v.x - bf2f(hi.x));
    hi.y = f2bf(v.y); lo.y = f2bf(v.y - bf2f(hi.y));
    hi.z = f2bf(v.z); lo.z = f2bf(v.z - bf2f(hi.z));
    hi.w = f2bf(v.w); lo.w = f2bf(v.w - bf2f(hi.w));
    *(ushort4*)(dwba_h + flat) = hi;
    *(ushort4*)(dwba_l + flat) = lo;
  }
}

// ---------------- fused 4-projection GEMM: 256x128 tile, wave-tile 64x128
__global__ __launch_bounds__(256, 2) void gemm_big(
    const u16* __restrict__ A,
    const u16* __restrict__ W0p, const u16* __restrict__ W1p,
    const u16* __restrict__ W2p, const u16* __restrict__ W3p,
    u16* __restrict__ C0, u16* __restrict__ C1,
    u16* __restrict__ C2, u16* __restrict__ C3,
    int M, int N, int K) {
  const u16* W; u16* C;
  switch (blockIdx.z) {
    case 0: W = W0p; C = C0; break;
    case 1: W = W1p; C = C1; break;
    case 2: W = W2p; C = C2; break;
    default: W = W3p; C = C3; break;
  }
  const int tid = threadIdx.x;
  const int lane = tid & 63, wid = tid >> 6;
  const int fr = lane & 15, fq = lane >> 4;
  const int row0 = blockIdx.y * 256, col0 = blockIdx.x * 128;
  __shared__ __align__(16) u16 As[256 * 64];
  __shared__ __align__(16) u16 Bs[128 * 64];

  const u16* aSrc[8]; const u16* bSrc[4];
#pragma unroll
  for (int it = 0; it < 8; ++it) {
    const int s = it * 256 + tid;
    const int r = s >> 3, cc = s & 7;
    aSrc[it] = A + (size_t)(row0 + r) * K + (cc ^ (r & 7)) * 8;
  }
#pragma unroll
  for (int it = 0; it < 4; ++it) {
    const int s = it * 256 + tid;
    const int r = s >> 3, cc = s & 7;
    bSrc[it] = W + (size_t)(col0 + r) * K + (cc ^ (r & 7)) * 8;
  }
  int aOff[4][2], bOff[8][2];
#pragma unroll
  for (int m = 0; m < 4; ++m)
#pragma unroll
    for (int kk = 0; kk < 2; ++kk) {
      const int ra = wid * 64 + m * 16 + fr;
      aOff[m][kk] = ra * 128 + ((((kk << 2) | fq) ^ (ra & 7)) << 4);
    }
#pragma unroll
  for (int n = 0; n < 8; ++n)
#pragma unroll
    for (int kk = 0; kk < 2; ++kk) {
      const int rb = n * 16 + fr;
      bOff[n][kk] = rb * 128 + ((((kk << 2) | fq) ^ (rb & 7)) << 4);
    }

  f32x4 acc[4][8] = {};
  for (int k0 = 0; k0 < K; k0 += 64) {
#pragma unroll
    for (int it = 0; it < 8; ++it)
      __builtin_amdgcn_global_load_lds(
          (const __attribute__((address_space(1))) void*)(aSrc[it] + k0),
          (__attribute__((address_space(3))) void*)((char*)As + (it * 256 + tid) * 16),
          16, 0, 0);
#pragma unroll
    for (int it = 0; it < 4; ++it)
      __builtin_amdgcn_global_load_lds(
          (const __attribute__((address_space(1))) void*)(bSrc[it] + k0),
          (__attribute__((address_space(3))) void*)((char*)Bs + (it * 256 + tid) * 16),
          16, 0, 0);
    __syncthreads();
#pragma unroll
    for (int kk = 0; kk < 2; ++kk) {
      bf16x8 af[4], bfr[8];
#pragma unroll
      for (int m = 0; m < 4; ++m)
        af[m] = *(const bf16x8*)((const char*)As + aOff[m][kk]);
#pragma unroll
      for (int n = 0; n < 8; ++n)
        bfr[n] = *(const bf16x8*)((const char*)Bs + bOff[n][kk]);
#pragma unroll
      for (int m = 0; m < 4; ++m)
#pragma unroll
        for (int n = 0; n < 8; ++n)
          acc[m][n] = __builtin_amdgcn_mfma_f32_16x16x32_bf16(af[m], bfr[n], acc[m][n], 0, 0, 0);
    }
    __syncthreads();
  }
#pragma unroll
  for (int m = 0; m < 4; ++m)
#pragma unroll
    for (int n = 0; n < 8; ++n)
#pragma unroll
      for (int r = 0; r < 4; ++r) {
        const int gr = row0 + wid * 64 + m * 16 + fq * 4 + r;
        const int gc = col0 + n * 16 + fr;
        C[(size_t)gr * N + gc] = f2bf(acc[m][n][r]);
      }
}

// ------------------------------------------------- bf16 MFMA linear: C = A*W^T
template <typename OutT, int MT>
__global__ __launch_bounds__(256) void gemm_lin(
    const u16* __restrict__ A, const u16* __restrict__ W,
    OutT* __restrict__ C, int M, int N, int K) {
  const int tid = threadIdx.x;
  const int lane = tid & 63, wid = tid >> 6;
  const int wr = wid >> 1, wc = wid & 1;
  const int fr = lane & 15, fq = lane >> 4;
  const int row0 = blockIdx.y * (MT * 32), col0 = blockIdx.x * 128;
  __shared__ __align__(16) u16 As[MT * 32 * 64];
  __shared__ __align__(16) u16 Bs[128 * 64];

  const u16* aSrc[MT]; const u16* bSrc[4];
#pragma unroll
  for (int it = 0; it < MT; ++it) {
    const int c = it * 256 + tid;
    const int r = c >> 3, cc = c & 7, sc = cc ^ (r & 7);
    aSrc[it] = A + (size_t)(row0 + r) * K + sc * 8;
  }
#pragma unroll
  for (int it = 0; it < 4; ++it) {
    const int c = it * 256 + tid;
    const int r = c >> 3, cc = c & 7, sc = cc ^ (r & 7);
    bSrc[it] = W + (size_t)(col0 + r) * K + sc * 8;
  }
  int aOff[MT][2], bOff[4][2];
#pragma unroll
  for (int m = 0; m < MT; ++m)
#pragma unroll
    for (int kk = 0; kk < 2; ++kk) {
      const int ra = wr * (MT * 16) + m * 16 + fr;
      aOff[m][kk] = ra * 128 + ((((kk << 2) | fq) ^ (fr & 7)) << 4);
    }
#pragma unroll
  for (int n = 0; n < 4; ++n)
#pragma unroll
    for (int kk = 0; kk < 2; ++kk) {
      const int rb = wc * 64 + n * 16 + fr;
      bOff[n][kk] = rb * 128 + ((((kk << 2) | fq) ^ (fr & 7)) << 4);
    }

  f32x4 acc[MT][4] = {};
  for (int k0 = 0; k0 < K; k0 += 64) {
#pragma unroll
    for (int it = 0; it < MT; ++it)
      __builtin_amdgcn_global_load_lds(
          (const __attribute__((address_space(1))) void*)(aSrc[it] + k0),
          (__attribute__((address_space(3))) void*)((char*)As + (it * 256 + wid * 64) * 16),
          16, 0, 0);
#pragma unroll
    for (int it = 0; it < 4; ++it)
      __builtin_amdgcn_global_load_lds(
          (const __attribute__((address_space(1))) void*)(bSrc[it] + k0),
          (__attribute__((address_space(3))) void*)((char*)Bs + (it * 256 + wid * 64) * 16),
          16, 0, 0);
    __syncthreads();
#pragma unroll
    for (int kk = 0; kk < 2; ++kk) {
      bf16x8 af[MT], bfr[4];
#pragma unroll
      for (int m = 0; m < MT; ++m)
        af[m] = *(const bf16x8*)((const char*)As + aOff[m][kk]);
#pragma unroll
      for (int n = 0; n < 4; ++n)
        bfr[n] = *(const bf16x8*)((const char*)Bs + bOff[n][kk]);
#pragma unroll
      for (int m = 0; m < MT; ++m)
#pragma unroll
        for (int n = 0; n < 4; ++n)
          acc[m][n] = __builtin_amdgcn_mfma_f32_16x16x32_bf16(af[m], bfr[n], acc[m][n], 0, 0, 0);
    }
    __syncthreads();
  }
#pragma unroll
  for (int m = 0; m < MT; ++m)
#pragma unroll
    for (int n = 0; n < 4; ++n)
#pragma unroll
      for (int r = 0; r < 4; ++r) {
        const int gr = row0 + wr * (MT * 16) + m * 16 + fq * 4 + r;
        const int gc = col0 + wc * 64 + n * 16 + fr;
        storev(&C[(size_t)gr * N + gc], acc[m][n][r]);
      }
}

// ---------------- beta/g projections via split-precision MFMA skinny GEMM
__global__ __launch_bounds__(256) void small_mfma(
    const u16* __restrict__ hhi, const u16* __restrict__ hlo,
    const u16* __restrict__ whi, const u16* __restrict__ wlo,
    const float* __restrict__ A_log, const float* __restrict__ dtb,
    float* __restrict__ bbuf, float* __restrict__ gbuf) {
  extern __shared__ char smc[];
  u16* Ahi = (u16*)smc;
  u16* Alo = (u16*)(smc + 32768);
  float* Red = (float*)(smc + 65536);
  const int tid = threadIdx.x;
  const int row0 = blockIdx.x * 16;
#pragma unroll
  for (int i = 0; i < 8; ++i) {
    const int slot = tid + 256 * i;
    const int r = slot >> 7, s = slot & 127;
    const int ss = s ^ (r & 7);
    const size_t src = (size_t)(row0 + r) * 1024 + (size_t)ss * 8;
    __builtin_amdgcn_global_load_lds(
        (const __attribute__((address_space(1))) void*)(hhi + src),
        (__attribute__((address_space(3))) void*)(Ahi + (size_t)slot * 8), 16, 0, 0);
    __builtin_amdgcn_global_load_lds(
        (const __attribute__((address_space(1))) void*)(hlo + src),
        (__attribute__((address_space(3))) void*)(Alo + (size_t)slot * 8), 16, 0, 0);
  }
  __syncthreads();
  const int w = tid >> 6, lane = tid & 63, fr = lane & 15, fq = lane >> 4;
  f32x4 acc[2] = {};
#pragma unroll
  for (int kk = 0; kk < 8; ++kk) {
    const int s = w * 32 + kk * 4 + fq;
    const size_t k = (size_t)w * 256 + kk * 32 + fq * 8;
    const int aoff = ((fr << 7) + (s ^ (fr & 7))) * 8;
    bf16x8 ah = *(const bf16x8*)(Ahi + aoff);
    bf16x8 al = *(const bf16x8*)(Alo + aoff);
#pragma unroll
    for (int ct = 0; ct < 2; ++ct) {
      const size_t boff = (size_t)(ct * 16 + fr) * 1024 + k;
      bf16x8 bh = *(const bf16x8*)(whi + boff);
      bf16x8 bl = *(const bf16x8*)(wlo + boff);
      acc[ct] = __builtin_amdgcn_mfma_f32_16x16x32_bf16(ah, bh, acc[ct], 0, 0, 0);
      acc[ct] = __builtin_amdgcn_mfma_f32_16x16x32_bf16(ah, bl, acc[ct], 0, 0, 0);
      acc[ct] = __builtin_amdgcn_mfma_f32_16x16x32_bf16(al, bh, acc[ct], 0, 0, 0);
    }
  }
#pragma unroll
  for (int ct = 0; ct < 2; ++ct)
#pragma unroll
    for (int rr = 0; rr < 4; ++rr)
      Red[(w * 16 + fq * 4 + rr) * 33 + ct * 16 + fr] = acc[ct][rr];
  __syncthreads();
  if (tid < 128) {
    const int row = tid >> 3, cg = (tid & 7) * 4;
#pragma unroll
    for (int j = 0; j < 4; ++j) {
      const int col = cg + j;
      const float s = Red[(0 * 16 + row) * 33 + col] + Red[(1 * 16 + row) * 33 + col]
                    + Red[(2 * 16 + row) * 33 + col] + Red[(3 * 16 + row) * 33 + col];
      const int grow = row0 + row;
      if (col < 16) {
        bbuf[grow * NHEAD + col] = 1.f / (1.f + __expf(-s));
      } else {
        const int hh = col - 16;
        const float xs = s + dtb[hh];
        const float sp = (xs > 20.f) ? xs : log1pf(__expf(xs));
        gbuf[grow * NHEAD + hh] = -__expf(A_log[hh]) * sp;
      }
    }
  }
}

// ===================== chunk-parallel gated delta rule (MFMA) =================
__global__ __launch_bounds__(256) void chunk_local(
    const u16* __restrict__ qp, const u16* __restrict__ kp, const u16* __restrict__ vp,
    const float* __restrict__ cq, const float* __restrict__ ck, const float* __restrict__ cv,
    const float* __restrict__ gbuf, const float* __restrict__ bbuf,
    u16* __restrict__ Phi, u16* __restrict__ Plo, u16* __restrict__ Ug,
    u16* __restrict__ Rg, u16* __restrict__ Yg) {
  __shared__ __align__(16) u16 Kb[64 * 64];
  __shared__ __align__(16) u16 Qb[64 * 64];
  __shared__ __align__(16) u16 K2T[64 * 64];
  __shared__ __align__(16) u16 KWt[64 * 64];   // -> uTh
  __shared__ __align__(16) u16 Vt[64 * 64];    // -> Gb
  __shared__ __align__(16) u16 Zb[64 * 64];
  __shared__ __align__(16) u16 Zt[64 * 64];
  __shared__ __align__(16) u16 Mb[64 * 72];    // -> WTh
  __shared__ __align__(16) float Cb[16 * 64];
  __shared__ float bcs[64], bet[64], e2v[64], Bv[64];
  u16* WTh = Mb;
  u16* uTh = KWt;
  u16* Gb  = Vt;

  const int bid = blockIdx.x;
  const int c = bid & 31, bh = bid >> 5;
  const int b = bh >> 4, h = bh & 15;
  const int tid = threadIdx.x;

  {
    int* zp = (int*)Zt;
#pragma unroll
    for (int i = 0; i < 8; ++i) zp[tid + 256 * i] = 0;
  }
  if (tid < 64) {
    const size_t gi = (size_t)((b * TLEN + c * 64) + tid) * NHEAD + h;
    bet[tid] = bbuf[gi];
    float v = gbuf[gi];
#pragma unroll
    for (int ofs = 1; ofs < 64; ofs <<= 1) {
      float tt = __shfl_up(v, ofs);
      if (tid >= ofs) v += tt;
    }
    bcs[tid] = v;
  }
  __syncthreads();
  if (tid < 64) {
    const float blast = bcs[63];
    Bv[tid]  = __expf(bcs[tid]);
    e2v[tid] = __expf(blast - bcs[tid]);
  }
  __syncthreads();

  // ---- staging with fused conv+silu+l2norm
  {
    const int dq = (tid & 15) * 4;
    const int col = h * 64 + dq;
    float4 wq4[4], wk4[4], wv4[4];
#pragma unroll
    for (int jj = 0; jj < 4; ++jj) {
      wq4[jj] = *(const float4*)(cq + (size_t)(col + jj) * 4);
      wk4[jj] = *(const float4*)(ck + (size_t)(col + jj) * 4);
      wv4[jj] = *(const float4*)(cv + (size_t)(col + jj) * 4);
    }
#pragma unroll
    for (int i = 0; i < 4; ++i) {
      const int r = i * 16 + (tid >> 4);
      const int tcur = c * 64 + r;
      ushort4 xq[4], xk[4], xv[4];
#pragma unroll
      for (int m = 0; m < 4; ++m) {
        const int tt = tcur - 3 + m;
        if (tt >= 0) {
          const size_t a = (size_t)(b * TLEN + tt) * HD + col;
          xq[m] = *(const ushort4*)(qp + a);
          xk[m] = *(const ushort4*)(kp + a);
          xv[m] = *(const ushort4*)(vp + a);
        } else {
          xq[m] = ushort4{0, 0, 0, 0}; xk[m] = xq[m]; xv[m] = xq[m];
        }
      }
      float yq[4], yk[4], yv[4];
      float ssq = 0.f, ssk = 0.f;
#pragma unroll
      for (int jj = 0; jj < 4; ++jj) {
        float aq = wq4[jj].x * bf2f(((const u16*)&xq[0])[jj]) +
                   wq4[jj].y * bf2f(((const u16*)&xq[1])[jj]) +
                   wq4[jj].z * bf2f(((const u16*)&xq[2])[jj]) +
                   wq4[jj].w * bf2f(((const u16*)&xq[3])[jj]);
        float ak = wk4[jj].x * bf2f(((const u16*)&xk[0])[jj]) +
                   wk4[jj].y * bf2f(((const u16*)&xk[1])[jj]) +
                   wk4[jj].z * bf2f(((const u16*)&xk[2])[jj]) +
                   wk4[jj].w * bf2f(((const u16*)&xk[3])[jj]);
        float av = wv4[jj].x * bf2f(((const u16*)&xv[0])[jj]) +
                   wv4[jj].y * bf2f(((const u16*)&xv[1])[jj]) +
                   wv4[jj].z * bf2f(((const u16*)&xv[2])[jj]) +
                   wv4[jj].w * bf2f(((const u16*)&xv[3])[jj]);
        yq[jj] = aq / (1.f + __expf(-aq));
        yk[jj] = ak / (1.f + __expf(-ak));
        yv[jj] = av / (1.f + __expf(-av));
        ssq += yq[jj] * yq[jj];
        ssk += yk[jj] * yk[jj];
      }
      ssq += __shfl_xor(ssq, 1); ssq += __shfl_xor(ssq, 2);
      ssq += __shfl_xor(ssq, 4); ssq += __shfl_xor(ssq, 8);
      ssk += __shfl_xor(ssk, 1); ssk += __shfl_xor(ssk, 2);
      ssk += __shfl_xor(ssk, 4); ssk += __shfl_xor(ssk, 8);
      const float qsc = rsqrtf(ssq + 1e-6f) * 0.125f;
      const float ksc = rsqrtf(ssk + 1e-6f);
      const float bR = bet[r], e2R = e2v[r], wscR = bR * Bv[r];
      ushort4 qo, ko;
      float kvf[4];
#pragma unroll
      for (int jj = 0; jj < 4; ++jj) kvf[jj] = yk[jj] * ksc;
      qo.x = f2bf(yq[0] * qsc); qo.y = f2bf(yq[1] * qsc);
      qo.z = f2bf(yq[2] * qsc); qo.w = f2bf(yq[3] * qsc);
      ko.x = f2bf(kvf[0]); ko.y = f2bf(kvf[1]);
      ko.z = f2bf(kvf[2]); ko.w = f2bf(kvf[3]);
      *(ushort4*)((char*)Qb + swz(r, dq)) = qo;
      *(ushort4*)((char*)Kb + swz(r, dq)) = ko;
#pragma unroll
      for (int jj = 0; jj < 4; ++jj) {
        *(u16*)((char*)K2T + swz(dq + jj, r)) = f2bf(kvf[jj] * e2R);
        *(u16*)((char*)KWt + swz(dq + jj, r)) = f2bf(kvf[jj] * wscR);
        *(u16*)((char*)Vt  + swz(dq + jj, r)) = f2bf(yv[jj] * bR);
      }
    }
  }
  __syncthreads();

  const int w = tid >> 6, lane = tid & 63, fr = lane & 15, fq = lane >> 4;
  // ---- A = K K^T via MFMA -> masked M (bf16, stride 72)
  {
    bf16x8 ka0 = frag(Kb, w * 16 + fr, fq);
    bf16x8 ka1 = frag(Kb, w * 16 + fr, 4 + fq);
#pragma unroll
    for (int tc = 0; tc < 4; ++tc) {
      bf16x8 kb0 = frag(Kb, tc * 16 + fr, fq);
      bf16x8 kb1 = frag(Kb, tc * 16 + fr, 4 + fq);
      f32x4 a = {};
      a = __builtin_amdgcn_mfma_f32_16x16x32_bf16(ka0, kb0, a, 0, 0, 0);
      a = __builtin_amdgcn_mfma_f32_16x16x32_bf16(ka1, kb1, a, 0, 0, 0);
#pragma unroll
      for (int rr = 0; rr < 4; ++rr) {
        const int t = w * 16 + fq * 4 + rr, s = tc * 16 + fr;
        const float mv = (s < t) ? bet[t] * __expf(bcs[t] - bcs[s]) * a[rr] : 0.f;
        Mb[t * 72 + s] = f2bf(mv);
      }
    }
  }
  __syncthreads();

  // ---- BLOCKED solve M Minv = I (4 blocks of 16 rows)
#pragma unroll 1
  for (int bi = 0; bi < 4; ++bi) {
    {
      const char* mrow = (const char*)Mb + (size_t)(bi * 16 + fr) * 144;
      bf16x8 ma0 = *(const bf16x8*)(mrow + fq * 16);
      bf16x8 ma1 = *(const bf16x8*)(mrow + 64 + fq * 16);
      bf16x8 zt0 = frag(Zt, w * 16 + fr, fq);
      bf16x8 zt1 = frag(Zt, w * 16 + fr, 4 + fq);
      f32x4 a = {};
      a = __builtin_amdgcn_mfma_f32_16x16x32_bf16(ma0, zt0, a, 0, 0, 0);
      a = __builtin_amdgcn_mfma_f32_16x16x32_bf16(ma1, zt1, a, 0, 0, 0);
#pragma unroll
      for (int rr = 0; rr < 4; ++rr)
        Cb[(fq * 4 + rr) * 64 + w * 16 + fr] = a[rr];
    }
    __syncthreads();
    if (tid < 64) {
      const int j = tid;
      float z[16];
#pragma unroll
      for (int t = 0; t < 16; ++t) {
        float acc = ((bi * 16 + t) == j ? 1.f : 0.f) - Cb[t * 64 + j];
        const u16* mrow = Mb + (size_t)(bi * 16 + t) * 72 + bi * 16;
#pragma unroll
        for (int s = 0; s < t; ++s) acc -= bf2f(mrow[s]) * z[s];
        z[t] = acc;
      }
#pragma unroll
      for (int t = 0; t < 16; ++t)
        *(u16*)((char*)Zb + swz(bi * 16 + t, j)) = f2bf(z[t]);
#pragma unroll
      for (int t4 = 0; t4 < 4; ++t4) {
        ushort4 zz;
        zz.x = f2bf(z[t4 * 4 + 0]); zz.y = f2bf(z[t4 * 4 + 1]);
        zz.z = f2bf(z[t4 * 4 + 2]); zz.w = f2bf(z[t4 * 4 + 3]);
        *(ushort4*)((char*)Zt + swz(j, bi * 16 + t4 * 4)) = zz;
      }
    }
    __syncthreads();
  }

  // ---- W = Minv*RHSw, u = Minv*RHSv (transposed out), G = QK^T
  f32x4 accW[4], accu[4], accG[4];
  {
    bf16x8 kw0 = frag(KWt, w * 16 + fr, fq), kw1 = frag(KWt, w * 16 + fr, 4 + fq);
    bf16x8 vt0 = frag(Vt,  w * 16 + fr, fq), vt1 = frag(Vt,  w * 16 + fr, 4 + fq);
    bf16x8 qa0 = frag(Qb,  w * 16 + fr, fq), qa1 = frag(Qb,  w * 16 + fr, 4 + fq);
#pragma unroll
    for (int tc = 0; tc < 4; ++tc) {
      bf16x8 z0 = frag(Zb, tc * 16 + fr, fq), z1 = frag(Zb, tc * 16 + fr, 4 + fq);
      bf16x8 kb0 = frag(Kb, tc * 16 + fr, fq), kb1 = frag(Kb, tc * 16 + fr, 4 + fq);
      f32x4 aw = {}, au = {}, ag = {};
      aw = __builtin_amdgcn_mfma_f32_16x16x32_bf16(kw0, z0, aw, 0, 0, 0);
      aw = __builtin_amdgcn_mfma_f32_16x16x32_bf16(kw1, z1, aw, 0, 0, 0);
      au = __builtin_amdgcn_mfma_f32_16x16x32_bf16(vt0, z0, au, 0, 0, 0);
      au = __builtin_amdgcn_mfma_f32_16x16x32_bf16(vt1, z1, au, 0, 0, 0);
      ag = __builtin_amdgcn_mfma_f32_16x16x32_bf16(qa0, kb0, ag, 0, 0, 0);
      ag = __builtin_amdgcn_mfma_f32_16x16x32_bf16(qa1, kb1, ag, 0, 0, 0);
      accW[tc] = aw; accu[tc] = au; accG[tc] = ag;
    }
  }
  __syncthreads();
#pragma unroll
  for (int tc = 0; tc < 4; ++tc)
#pragma unroll
    for (int rr = 0; rr < 4; ++rr) {
      const int ro = w * 16 + fq * 4 + rr, co = tc * 16 + fr;
      *(u16*)((char*)WTh + swz(ro, co)) = f2bf(accW[tc][rr]);
      *(u16*)((char*)uTh + swz(ro, co)) = f2bf(accu[tc][rr]);
      const float gv = (co <= ro) ? accG[tc][rr] * __expf(bcs[ro] - bcs[co]) : 0.f;
      *(u16*)((char*)Gb + swz(ro, co)) = f2bf(gv);
    }
  __syncthreads();

  // ---- P,U,R,Y via MFMA + epilogue (P hi/lo bf16; U,R,Y bf16)
  {
    bf16x8 k20 = frag(K2T, w * 16 + fr, fq), k21 = frag(K2T, w * 16 + fr, 4 + fq);
    bf16x8 g0  = frag(Gb,  w * 16 + fr, fq), g1  = frag(Gb,  w * 16 + fr, 4 + fq);
    const float bl = Bv[63];
    const size_t off = (size_t)bid * 4096;
#pragma unroll
    for (int tc = 0; tc < 4; ++tc) {
      bf16x8 w0 = frag(WTh, tc * 16 + fr, fq), w1 = frag(WTh, tc * 16 + fr, 4 + fq);
      bf16x8 u0 = frag(uTh, tc * 16 + fr, fq), u1 = frag(uTh, tc * 16 + fr, 4 + fq);
      f32x4 aP = {}, aU = {}, aR = {}, aY = {};
      aP = __builtin_amdgcn_mfma_f32_16x16x32_bf16(k20, w0, aP, 0, 0, 0);
      aP = __builtin_amdgcn_mfma_f32_16x16x32_bf16(k21, w1, aP, 0, 0, 0);
      aU = __builtin_amdgcn_mfma_f32_16x16x32_bf16(k20, u0, aU, 0, 0, 0);
      aU = __builtin_amdgcn_mfma_f32_16x16x32_bf16(k21, u1, aU, 0, 0, 0);
      aR = __builtin_amdgcn_mfma_f32_16x16x32_bf16(g0, w0, aR, 0, 0, 0);
      aR = __builtin_amdgcn_mfma_f32_16x16x32_bf16(g1, w1, aR, 0, 0, 0);
      aY = __builtin_amdgcn_mfma_f32_16x16x32_bf16(g0, u0, aY, 0, 0, 0);
      aY = __builtin_amdgcn_mfma_f32_16x16x32_bf16(g1, u1, aY, 0, 0, 0);
#pragma unroll
      for (int rr = 0; rr < 4; ++rr) {
        const int ar = w * 16 + fq * 4 + rr, cb = tc * 16 + fr;
        const float pv = ((ar == cb) ? bl : 0.f) - aP[rr];
        const u16 phv = f2bf(pv);
        Phi[off + ar * 64 + cb] = phv;
        Plo[off + ar * 64 + cb] = f2bf(pv - bf2f(phv));
        Ug[off + ar * 64 + cb] = f2bf(aU[rr]);
        const float qv = bf2f(*(const u16*)((const char*)Qb + swz(ar, cb)));
        Rg[off + ar * 64 + cb] = f2bf(Bv[ar] * qv - aR[rr]);
        Yg[off + ar * 64 + cb] = f2bf(aY[rr]);
      }
    }
  }
}

// ---- phase B: S_{c+1} = P_c S_c + U_c via split-precision MFMA.
// 32 blocks (one per b,h), 4 waves. S kept in LDS as S^T hi/lo (dbuf 32 KB).
// A-frags (P hi/lo) read straight from global row-major (k-chunk = kslot,
// consistent with frag()'s logical-k retrieval from swizzled LDS).
__global__ __launch_bounds__(256) void state_step(
    const u16* __restrict__ Phi, const u16* __restrict__ Plo,
    const u16* __restrict__ Ug, u16* __restrict__ Sst) {
  __shared__ __align__(16) u16 Sth[2][64 * 64];
  __shared__ __align__(16) u16 Stl[2][64 * 64];
  const int bh = blockIdx.x;
  const int tid = threadIdx.x;
  const int w = tid >> 6, lane = tid & 63, fr = lane & 15, fq = lane >> 4;
  const size_t bbase = (size_t)bh * 32 * 4096;
  {
    int* p0 = (int*)&Sth[0][0];
    int* p1 = (int*)&Stl[0][0];
#pragma unroll
    for (int i = 0; i < 8; ++i) { p0[tid + 256 * i] = 0; p1[tid + 256 * i] = 0; }
    const ushort4 z4 = {0, 0, 0, 0};
#pragma unroll
    for (int i = 0; i < 4; ++i)
      *(ushort4*)(Sst + bbase + (size_t)tid * 16 + i * 4) = z4;  // S_in[0] = 0
  }
  // preload chunk-0 operands into registers
  bf16x8 ph[2], pl[2];
  float uin[4][4];
#pragma unroll
  for (int kk = 0; kk < 2; ++kk) {
    const size_t ao = bbase + (size_t)(w * 16 + fr) * 64 + (kk * 4 + fq) * 8;
    ph[kk] = *(const bf16x8*)(Phi + ao);
    pl[kk] = *(const bf16x8*)(Plo + ao);
  }
#pragma unroll
  for (int tc = 0; tc < 4; ++tc)
#pragma unroll
    for (int rr = 0; rr < 4; ++rr)
      uin[tc][rr] = bf2f(Ug[bbase + (size_t)(w * 16 + fq * 4 + rr) * 64 + tc * 16 + fr]);
  __syncthreads();
  int cur = 0;
  for (int c = 0; c < 32; ++c) {
    f32x4 acc[4];
    bf16x8 phc[2] = {ph[0], ph[1]}, plc[2] = {pl[0], pl[1]};
#pragma unroll
    for (int tc = 0; tc < 4; ++tc)
#pragma unroll
      for (int rr = 0; rr < 4; ++rr) acc[tc][rr] = uin[tc][rr];
    if (c + 1 < 32) {  // prefetch next chunk's P,U under this chunk's MFMAs
      const size_t off = bbase + (size_t)(c + 1) * 4096;
#pragma unroll
      for (int kk = 0; kk < 2; ++kk) {
        const size_t ao = off + (size_t)(w * 16 + fr) * 64 + (kk * 4 + fq) * 8;
        ph[kk] = *(const bf16x8*)(Phi + ao);
        pl[kk] = *(const bf16x8*)(Plo + ao);
      }
#pragma unroll
      for (int tc = 0; tc < 4; ++tc)
#pragma unroll
        for (int rr = 0; rr < 4; ++rr)
          uin[tc][rr] = bf2f(Ug[off + (size_t)(w * 16 + fq * 4 + rr) * 64 + tc * 16 + fr]);
    }
#pragma unroll
    for (int tc = 0; tc < 4; ++tc) {
#pragma unroll
      for (int kk = 0; kk < 2; ++kk) {
        bf16x8 sh = frag(&Sth[cur][0], tc * 16 + fr, kk * 4 + fq);
        bf16x8 sl = frag(&Stl[cur][0], tc * 16 + fr, kk * 4 + fq);
        acc[tc] = __builtin_amdgcn_mfma_f32_16x16x32_bf16(phc[kk], sh, acc[tc], 0, 0, 0);
        acc[tc] = __builtin_amdgcn_mfma_f32_16x16x32_bf16(phc[kk], sl, acc[tc], 0, 0, 0);
        acc[tc] = __builtin_amdgcn_mfma_f32_16x16x32_bf16(plc[kk], sh, acc[tc], 0, 0, 0);
      }
    }
    const int nxt = cur ^ 1;
    const size_t offn = bbase + (size_t)(c + 1) * 4096;
#pragma unroll
    for (int tc = 0; tc < 4; ++tc)
#pragma unroll
      for (int rr = 0; rr < 4; ++rr) {
        const float v = acc[tc][rr];
        const int row = w * 16 + fq * 4 + rr;   // dk index
        const int col = tc * 16 + fr;           // dv index
        const u16 hv = f2bf(v);
        *(u16*)((char*)&Sth[nxt][0] + swz(col, row)) = hv;
        *(u16*)((char*)&Stl[nxt][0] + swz(col, row)) = f2bf(v - bf2f(hv));
        if (c + 1 < 32) Sst[offn + (size_t)row * 64 + col] = hv;
      }
    cur = nxt;
    __syncthreads();
  }
}

// ---- phase C: O = R S_in + Y, fused gated-RMSNorm epilogue -> bf16
__global__ __launch_bounds__(256) void chunk_out(
    const u16* __restrict__ Rg, const u16* __restrict__ Yg,
    const u16* __restrict__ Sst, const u16* __restrict__ gatep,
    const float* __restrict__ norm_w, u16* __restrict__ outb) {
  __shared__ float Rs[64 * 65];
  __shared__ float Ss[64 * 65];
  const int bid = blockIdx.x;
  const int c = bid & 31, bh = bid >> 5, b = bh >> 4, h = bh & 15;
  const int tid = threadIdx.x;
  const size_t off = (size_t)bid * 4096;
#pragma unroll
  for (int i = 0; i < 2; ++i) {
    const int idx = i * 2048 + tid * 8;
    const int row = idx >> 6, col = idx & 63;
    const ushort4 r0 = *(const ushort4*)(Rg + off + idx);
    const ushort4 r1 = *(const ushort4*)(Rg + off + idx + 4);
    const ushort4 s0 = *(const ushort4*)(Sst + off + idx);
    const ushort4 s1 = *(const ushort4*)(Sst + off + idx + 4);
    float* rd = &Rs[row * 65 + col];
    rd[0]=bf2f(r0.x); rd[1]=bf2f(r0.y); rd[2]=bf2f(r0.z); rd[3]=bf2f(r0.w);
    rd[4]=bf2f(r1.x); rd[5]=bf2f(r1.y); rd[6]=bf2f(r1.z); rd[7]=bf2f(r1.w);
    float* sd = &Ss[row * 65 + col];
    sd[0]=bf2f(s0.x); sd[1]=bf2f(s0.y); sd[2]=bf2f(s0.z); sd[3]=bf2f(s0.w);
    sd[4]=bf2f(s1.x); sd[5]=bf2f(s1.y); sd[6]=bf2f(s1.z); sd[7]=bf2f(s1.w);
  }
  __syncthreads();
  const int tr = tid >> 4, tc = tid & 15;
  float acc[4][4];
#pragma unroll
  for (int i = 0; i < 4; ++i) {
    const ushort4 y = *(const ushort4*)(Yg + off + (4*tr+i)*64 + 4*tc);
    acc[i][0] = bf2f(y.x); acc[i][1] = bf2f(y.y);
    acc[i][2] = bf2f(y.z); acc[i][3] = bf2f(y.w);
  }
  for (int k = 0; k < 64; ++k) {
    float r0 = Rs[(4*tr+0)*65+k], r1 = Rs[(4*tr+1)*65+k],
          r2 = Rs[(4*tr+2)*65+k], r3 = Rs[(4*tr+3)*65+k];
    float s0 = Ss[k*65+4*tc+0], s1 = Ss[k*65+4*tc+1],
          s2 = Ss[k*65+4*tc+2], s3 = Ss[k*65+4*tc+3];
    acc[0][0]+=r0*s0; acc[0][1]+=r0*s1; acc[0][2]+=r0*s2; acc[0][3]+=r0*s3;
    acc[1][0]+=r1*s0; acc[1][1]+=r1*s1; acc[1][2]+=r1*s2; acc[1][3]+=r1*s3;
    acc[2][0]+=r2*s0; acc[2][1]+=r2*s1; acc[2][2]+=r2*s2; acc[2][3]+=r2*s3;
    acc[3][0]+=r3*s0; acc[3][1]+=r3*s1; acc[3][2]+=r3*s2; acc[3][3]+=r3*s3;
  }
  const float4 nw4 = *(const float4*)(norm_w + 4 * tc);
  const size_t btbase = (size_t)(b * TLEN + c * 64);
#pragma unroll
  for (int i = 0; i < 4; ++i) {
    float rs = acc[i][0]*acc[i][0] + acc[i][1]*acc[i][1]
             + acc[i][2]*acc[i][2] + acc[i][3]*acc[i][3];
    rs += __shfl_xor(rs, 1); rs += __shfl_xor(rs, 2);
    rs += __shfl_xor(rs, 4); rs += __shfl_xor(rs, 8);
    const float inv = rsqrtf(rs * (1.0f / 64.0f) + 1e-5f);
    const int t = 4 * tr + i;
    const size_t goff = (btbase + t) * 1024 + h * 64 + 4 * tc;
    const ushort4 gv = *(const ushort4*)(gatep + goff);
    const float g0 = bf2f(gv.x), g1 = bf2f(gv.y), g2 = bf2f(gv.z), g3 = bf2f(gv.w);
    ushort4 ov;
    ov.x = f2bf(acc[i][0] * inv * nw4.x * (g0 / (1.f + __expf(-g0))));
    ov.y = f2bf(acc[i][1] * inv * nw4.y * (g1 / (1.f + __expf(-g1))));
    ov.z = f2bf(acc[i][2] * inv * nw4.z * (g2 / (1.f + __expf(-g2))));
    ov.w = f2bf(acc[i][3] * inv * nw4.w * (g3 / (1.f + __expf(-g3))));
    *(ushort4*)(outb + goff) = ov;
  }
}

extern "C" void kernel_launch(void* const* d_in, const int* in_sizes, int n_in,
                              void* d_out, int out_size, void* d_ws, size_t ws_size,
                              hipStream_t stream) {
  const float* hidden = (const float*)d_in[0];
  const float* Wq     = (const float*)d_in[1];
  const float* Wk     = (const float*)d_in[2];
  const float* Wv     = (const float*)d_in[3];
  const float* cq     = (const float*)d_in[4];
  const float* ck     = (const float*)d_in[5];
  const float* cv     = (const float*)d_in[6];
  const float* Wb     = (const float*)d_in[7];
  const float* Wa     = (const float*)d_in[8];
  const float* A_log  = (const float*)d_in[9];
  const float* dtb    = (const float*)d_in[10];
  const float* Wg     = (const float*)d_in[11];
  const float* nw     = (const float*)d_in[12];
  const float* Wo     = (const float*)d_in[13];

  char* p = (char*)d_ws;
  const size_t MB = 1u << 20;
  u16* h_bf = (u16*)(p + 0 * MB);     // 8 MB (dead after small_mfma)
  u16* wq_b = (u16*)(p + 8 * MB);     // 2 MB
  u16* wk_b = (u16*)(p + 10 * MB);
  u16* wv_b = (u16*)(p + 12 * MB);
  u16* wg_b = (u16*)(p + 14 * MB);
  u16* Phi = (u16*)(p + 0 * MB);      // 8 MB bf16, aliases h_bf (dead then)
  u16* Plo = (u16*)(p + 8 * MB);      // 8 MB bf16, aliases wq..wg (dead then)
  u16* wo_b = (u16*)(p + 16 * MB);    // 2 MB (live till end)
  u16* qp_b = (u16*)(p + 18 * MB);    // 8 MB
  u16* kp_b = (u16*)(p + 26 * MB);    // 8 MB
  u16* vp_b = (u16*)(p + 34 * MB);    // 8 MB
  u16* gp_b = (u16*)(p + 42 * MB);    // 8 MB (live till chunk_out)
  u16*   of_b = vp_b;                 // 8 MB, aliases vp (dead after chunk_local)
  float* gbuf = (float*)(p + 50 * MB);
  float* bbuf = (float*)(p + 50 * MB + 262144);
  u16* Ug  = (u16*)(p + 51 * MB);     // 8 MB bf16
  u16* Rg  = (u16*)(p + 59 * MB);     // 8 MB bf16
  u16* Yg  = (u16*)(p + 67 * MB);     // 8 MB bf16
  u16* Sst = (u16*)(p + 75 * MB);     // 8 MB bf16
  u16* hlo_b = (u16*)(p + 83 * MB);   // 8 MB
  u16* wba_h = (u16*)(p + 91 * MB);   // 64 KB
  u16* wba_l = (u16*)(p + 91 * MB + 65536);  // 64 KB (total ~91.2 MB)

  cvt_all<<<9248, 256, 0, stream>>>(hidden, Wq, Wk, Wv, Wg, Wo, Wb, Wa,
                                    h_bf, hlo_b, wq_b, wk_b, wv_b, wg_b, wo_b,
                                    wba_h, wba_l);

  gemm_big<<<dim3(8, 16, 4), 256, 0, stream>>>(
      h_bf, wq_b, wk_b, wv_b, wg_b, qp_b, kp_b, vp_b, gp_b, 4096, 1024, 1024);

  const int sm_lds = 65536 + 8448;
  hipFuncSetAttribute((const void*)small_mfma,
                      hipFuncAttributeMaxDynamicSharedMemorySize, sm_lds);
  small_mfma<<<256, 256, sm_lds, stream>>>(h_bf, hlo_b, wba_h, wba_l,
                                           A_log, dtb, bbuf, gbuf);

  chunk_local<<<1024, 256, 0, stream>>>(qp_b, kp_b, vp_b, cq, ck, cv,
                                        gbuf, bbuf, Phi, Plo, Ug, Rg, Yg);
  state_step<<<32, 256, 0, stream>>>(Phi, Plo, Ug, Sst);
  chunk_out<<<1024, 256, 0, stream>>>(Rg, Yg, Sst, gp_b, nw, of_b);

  gemm_lin<float, 2><<<dim3(8, 64, 1), 256, 0, stream>>>(
      of_b, wo_b, (float*)d_out, 4096, 1024, 1024);
}

// Round 10
// 170.515 us; speedup vs baseline: 9.9436x; 1.0636x over previous
//
#include <hip/hip_runtime.h>
#include <hip/hip_bf16.h>

typedef unsigned short u16;
typedef __attribute__((ext_vector_type(4))) float f32x4;
typedef __attribute__((ext_vector_type(8))) short bf16x8;

#define TLEN 2048
#define NHEAD 16
#define HD 1024

__device__ inline u16 f2bf(float f) {
  unsigned x = __float_as_uint(f);
  return (u16)((x + 0x7fffu + ((x >> 16) & 1u)) >> 16);
}
__device__ inline float bf2f(u16 u) { return __uint_as_float(((unsigned)u) << 16); }

// packed f32x2 -> bf16x2 (low half = first operand). 1 inst vs ~8.
__device__ inline unsigned pkbf(float lo, float hi) {
  unsigned r;
  asm("v_cvt_pk_bf16_f32 %0, %1, %2" : "=v"(r) : "v"(lo), "v"(hi));
  return r;
}

__device__ inline void storev(float* p, float v) { *p = v; }
__device__ inline void storev(u16* p, float v)   { *p = f2bf(v); }

// swizzle for [64 rows][64 bf16 = 128B] LDS tiles; XOR spreads both row&7
// and row>>3 so transposed (fixed-col) writes don't collide 8-way.
__device__ inline int rowx(int row) { return (row ^ (row >> 3)) & 7; }
__device__ inline int swz(int row, int col) {
  return (row << 7) + (((col >> 3) ^ rowx(row)) << 4) + ((col & 7) << 1);
}
__device__ inline bf16x8 frag(const u16* base, int row, int kslot) {
  return *(const bf16x8*)((const char*)base + (row << 7) +
                          ((kslot ^ rowx(row)) << 4));
}

// ------------------------------------------------- fused fp32 -> bf16 converts
__global__ __launch_bounds__(256) void cvt_all(
    const float* __restrict__ h,  const float* __restrict__ wq,
    const float* __restrict__ wk, const float* __restrict__ wv,
    const float* __restrict__ wg, const float* __restrict__ wo,
    const float* __restrict__ Wb, const float* __restrict__ Wa,
    u16* __restrict__ dh,  u16* __restrict__ dhlo,
    u16* __restrict__ dwq, u16* __restrict__ dwk,
    u16* __restrict__ dwv, u16* __restrict__ dwg, u16* __restrict__ dwo,
    u16* __restrict__ dwba_h, u16* __restrict__ dwba_l) {
  const int b = blockIdx.x;
  if (b < 4096) {
    const size_t i = (size_t)b * 256 + threadIdx.x;
    float4 v = *(const float4*)(h + i * 4);
    ushort4 hi, lo;
    hi.x = f2bf(v.x); lo.x = f2bf(v.x - bf2f(hi.x));
    hi.y = f2bf(v.y); lo.y = f2bf(v.y - bf2f(hi.y));
    hi.z = f2bf(v.z); lo.z = f2bf(v.z - bf2f(hi.z));
    hi.w = f2bf(v.w); lo.w = f2bf(v.w - bf2f(hi.w));
    *(ushort4*)(dh + i * 4) = hi;
    *(ushort4*)(dhlo + i * 4) = lo;
  } else if (b < 9216) {
    const int wsel = (b - 4096) >> 10;
    const size_t i = (size_t)((b - 4096) & 1023) * 256 + threadIdx.x;
    const float* s; u16* d;
    switch (wsel) {
      case 0: s = wq; d = dwq; break;
      case 1: s = wk; d = dwk; break;
      case 2: s = wv; d = dwv; break;
      case 3: s = wg; d = dwg; break;
      default: s = wo; d = dwo; break;
    }
    float4 v = *(const float4*)(s + i * 4);
    ushort4 u;
    u.x = f2bf(v.x); u.y = f2bf(v.y); u.z = f2bf(v.z); u.w = f2bf(v.w);
    *(ushort4*)(d + i * 4) = u;
  } else {
    const size_t i = (size_t)(b - 9216) * 256 + threadIdx.x;
    const size_t flat = i * 4;
    const float* src = (flat < 16384) ? (Wb + flat) : (Wa + (flat - 16384));
    float4 v = *(const float4*)src;
    ushort4 hi, lo;
    hi.x = f2bf(v.x); lo.x = f2bf(v.x - bf2f(hi.x));
    hi.y = f2bf(v.y); lo.y = f2bf(v.y - bf2f(hi.y));
    hi.z = f2bf(v.z); lo.z = f2bf(v.z - bf2f(hi.z));
    hi.w = f2bf(v.w); lo.w = f2bf(v.w - bf2f(hi.w));
    *(ushort4*)(dwba_h + flat) = hi;
    *(ushort4*)(dwba_l + flat) = lo;
  }
}

// ---------------- fused 4-projection GEMM: 256x128 tile, wave-tile 64x128
__global__ __launch_bounds__(256, 2) void gemm_big(
    const u16* __restrict__ A,
    const u16* __restrict__ W0p, const u16* __restrict__ W1p,
    const u16* __restrict__ W2p, const u16* __restrict__ W3p,
    u16* __restrict__ C0, u16* __restrict__ C1,
    u16* __restrict__ C2, u16* __restrict__ C3,
    int M, int N, int K) {
  const u16* W; u16* C;
  switch (blockIdx.z) {
    case 0: W = W0p; C = C0; break;
    case 1: W = W1p; C = C1; break;
    case 2: W = W2p; C = C2; break;
    default: W = W3p; C = C3; break;
  }
  const int tid = threadIdx.x;
  const int lane = tid & 63, wid = tid >> 6;
  const int fr = lane & 15, fq = lane >> 4;
  const int row0 = blockIdx.y * 256, col0 = blockIdx.x * 128;
  __shared__ __align__(16) u16 As[256 * 64];
  __shared__ __align__(16) u16 Bs[128 * 64];

  const u16* aSrc[8]; const u16* bSrc[4];
#pragma unroll
  for (int it = 0; it < 8; ++it) {
    const int s = it * 256 + tid;
    const int r = s >> 3, cc = s & 7;
    aSrc[it] = A + (size_t)(row0 + r) * K + (cc ^ (r & 7)) * 8;
  }
#pragma unroll
  for (int it = 0; it < 4; ++it) {
    const int s = it * 256 + tid;
    const int r = s >> 3, cc = s & 7;
    bSrc[it] = W + (size_t)(col0 + r) * K + (cc ^ (r & 7)) * 8;
  }
  int aOff[4][2], bOff[8][2];
#pragma unroll
  for (int m = 0; m < 4; ++m)
#pragma unroll
    for (int kk = 0; kk < 2; ++kk) {
      const int ra = wid * 64 + m * 16 + fr;
      aOff[m][kk] = ra * 128 + ((((kk << 2) | fq) ^ (ra & 7)) << 4);
    }
#pragma unroll
  for (int n = 0; n < 8; ++n)
#pragma unroll
    for (int kk = 0; kk < 2; ++kk) {
      const int rb = n * 16 + fr;
      bOff[n][kk] = rb * 128 + ((((kk << 2) | fq) ^ (rb & 7)) << 4);
    }

  f32x4 acc[4][8] = {};
  for (int k0 = 0; k0 < K; k0 += 64) {
#pragma unroll
    for (int it = 0; it < 8; ++it)
      __builtin_amdgcn_global_load_lds(
          (const __attribute__((address_space(1))) void*)(aSrc[it] + k0),
          (__attribute__((address_space(3))) void*)((char*)As + (it * 256 + tid) * 16),
          16, 0, 0);
#pragma unroll
    for (int it = 0; it < 4; ++it)
      __builtin_amdgcn_global_load_lds(
          (const __attribute__((address_space(1))) void*)(bSrc[it] + k0),
          (__attribute__((address_space(3))) void*)((char*)Bs + (it * 256 + tid) * 16),
          16, 0, 0);
    __syncthreads();
#pragma unroll
    for (int kk = 0; kk < 2; ++kk) {
      bf16x8 af[4], bfr[8];
#pragma unroll
      for (int m = 0; m < 4; ++m)
        af[m] = *(const bf16x8*)((const char*)As + aOff[m][kk]);
#pragma unroll
      for (int n = 0; n < 8; ++n)
        bfr[n] = *(const bf16x8*)((const char*)Bs + bOff[n][kk]);
#pragma unroll
      for (int m = 0; m < 4; ++m)
#pragma unroll
        for (int n = 0; n < 8; ++n)
          acc[m][n] = __builtin_amdgcn_mfma_f32_16x16x32_bf16(af[m], bfr[n], acc[m][n], 0, 0, 0);
    }
    __syncthreads();
  }
#pragma unroll
  for (int m = 0; m < 4; ++m)
#pragma unroll
    for (int n = 0; n < 8; ++n) {
      const int gr0 = row0 + wid * 64 + m * 16 + fq * 4;
      const int gc = col0 + n * 16 + fr;
      const unsigned c01 = pkbf(acc[m][n][0], acc[m][n][1]);
      const unsigned c23 = pkbf(acc[m][n][2], acc[m][n][3]);
      C[(size_t)(gr0 + 0) * N + gc] = (u16)c01;
      C[(size_t)(gr0 + 1) * N + gc] = (u16)(c01 >> 16);
      C[(size_t)(gr0 + 2) * N + gc] = (u16)c23;
      C[(size_t)(gr0 + 3) * N + gc] = (u16)(c23 >> 16);
    }
}

// ------------------------------------------------- bf16 MFMA linear: C = A*W^T
template <typename OutT, int MT>
__global__ __launch_bounds__(256) void gemm_lin(
    const u16* __restrict__ A, const u16* __restrict__ W,
    OutT* __restrict__ C, int M, int N, int K) {
  const int tid = threadIdx.x;
  const int lane = tid & 63, wid = tid >> 6;
  const int wr = wid >> 1, wc = wid & 1;
  const int fr = lane & 15, fq = lane >> 4;
  const int row0 = blockIdx.y * (MT * 32), col0 = blockIdx.x * 128;
  __shared__ __align__(16) u16 As[MT * 32 * 64];
  __shared__ __align__(16) u16 Bs[128 * 64];

  const u16* aSrc[MT]; const u16* bSrc[4];
#pragma unroll
  for (int it = 0; it < MT; ++it) {
    const int c = it * 256 + tid;
    const int r = c >> 3, cc = c & 7, sc = cc ^ (r & 7);
    aSrc[it] = A + (size_t)(row0 + r) * K + sc * 8;
  }
#pragma unroll
  for (int it = 0; it < 4; ++it) {
    const int c = it * 256 + tid;
    const int r = c >> 3, cc = c & 7, sc = cc ^ (r & 7);
    bSrc[it] = W + (size_t)(col0 + r) * K + sc * 8;
  }
  int aOff[MT][2], bOff[4][2];
#pragma unroll
  for (int m = 0; m < MT; ++m)
#pragma unroll
    for (int kk = 0; kk < 2; ++kk) {
      const int ra = wr * (MT * 16) + m * 16 + fr;
      aOff[m][kk] = ra * 128 + ((((kk << 2) | fq) ^ (fr & 7)) << 4);
    }
#pragma unroll
  for (int n = 0; n < 4; ++n)
#pragma unroll
    for (int kk = 0; kk < 2; ++kk) {
      const int rb = wc * 64 + n * 16 + fr;
      bOff[n][kk] = rb * 128 + ((((kk << 2) | fq) ^ (fr & 7)) << 4);
    }

  f32x4 acc[MT][4] = {};
  for (int k0 = 0; k0 < K; k0 += 64) {
#pragma unroll
    for (int it = 0; it < MT; ++it)
      __builtin_amdgcn_global_load_lds(
          (const __attribute__((address_space(1))) void*)(aSrc[it] + k0),
          (__attribute__((address_space(3))) void*)((char*)As + (it * 256 + wid * 64) * 16),
          16, 0, 0);
#pragma unroll
    for (int it = 0; it < 4; ++it)
      __builtin_amdgcn_global_load_lds(
          (const __attribute__((address_space(1))) void*)(bSrc[it] + k0),
          (__attribute__((address_space(3))) void*)((char*)Bs + (it * 256 + wid * 64) * 16),
          16, 0, 0);
    __syncthreads();
#pragma unroll
    for (int kk = 0; kk < 2; ++kk) {
      bf16x8 af[MT], bfr[4];
#pragma unroll
      for (int m = 0; m < MT; ++m)
        af[m] = *(const bf16x8*)((const char*)As + aOff[m][kk]);
#pragma unroll
      for (int n = 0; n < 4; ++n)
        bfr[n] = *(const bf16x8*)((const char*)Bs + bOff[n][kk]);
#pragma unroll
      for (int m = 0; m < MT; ++m)
#pragma unroll
        for (int n = 0; n < 4; ++n)
          acc[m][n] = __builtin_amdgcn_mfma_f32_16x16x32_bf16(af[m], bfr[n], acc[m][n], 0, 0, 0);
    }
    __syncthreads();
  }
#pragma unroll
  for (int m = 0; m < MT; ++m)
#pragma unroll
    for (int n = 0; n < 4; ++n)
#pragma unroll
      for (int r = 0; r < 4; ++r) {
        const int gr = row0 + wr * (MT * 16) + m * 16 + fq * 4 + r;
        const int gc = col0 + wc * 64 + n * 16 + fr;
        storev(&C[(size_t)gr * N + gc], acc[m][n][r]);
      }
}

// ---------------- beta/g projections via split-precision MFMA skinny GEMM
__global__ __launch_bounds__(256) void small_mfma(
    const u16* __restrict__ hhi, const u16* __restrict__ hlo,
    const u16* __restrict__ whi, const u16* __restrict__ wlo,
    const float* __restrict__ A_log, const float* __restrict__ dtb,
    float* __restrict__ bbuf, float* __restrict__ gbuf) {
  extern __shared__ char smc[];
  u16* Ahi = (u16*)smc;
  u16* Alo = (u16*)(smc + 32768);
  float* Red = (float*)(smc + 65536);
  const int tid = threadIdx.x;
  const int row0 = blockIdx.x * 16;
#pragma unroll
  for (int i = 0; i < 8; ++i) {
    const int slot = tid + 256 * i;
    const int r = slot >> 7, s = slot & 127;
    const int ss = s ^ (r & 7);
    const size_t src = (size_t)(row0 + r) * 1024 + (size_t)ss * 8;
    __builtin_amdgcn_global_load_lds(
        (const __attribute__((address_space(1))) void*)(hhi + src),
        (__attribute__((address_space(3))) void*)(Ahi + (size_t)slot * 8), 16, 0, 0);
    __builtin_amdgcn_global_load_lds(
        (const __attribute__((address_space(1))) void*)(hlo + src),
        (__attribute__((address_space(3))) void*)(Alo + (size_t)slot * 8), 16, 0, 0);
  }
  __syncthreads();
  const int w = tid >> 6, lane = tid & 63, fr = lane & 15, fq = lane >> 4;
  f32x4 acc[2] = {};
#pragma unroll
  for (int kk = 0; kk < 8; ++kk) {
    const int s = w * 32 + kk * 4 + fq;
    const size_t k = (size_t)w * 256 + kk * 32 + fq * 8;
    const int aoff = ((fr << 7) + (s ^ (fr & 7))) * 8;
    bf16x8 ah = *(const bf16x8*)(Ahi + aoff);
    bf16x8 al = *(const bf16x8*)(Alo + aoff);
#pragma unroll
    for (int ct = 0; ct < 2; ++ct) {
      const size_t boff = (size_t)(ct * 16 + fr) * 1024 + k;
      bf16x8 bh = *(const bf16x8*)(whi + boff);
      bf16x8 bl = *(const bf16x8*)(wlo + boff);
      acc[ct] = __builtin_amdgcn_mfma_f32_16x16x32_bf16(ah, bh, acc[ct], 0, 0, 0);
      acc[ct] = __builtin_amdgcn_mfma_f32_16x16x32_bf16(ah, bl, acc[ct], 0, 0, 0);
      acc[ct] = __builtin_amdgcn_mfma_f32_16x16x32_bf16(al, bh, acc[ct], 0, 0, 0);
    }
  }
#pragma unroll
  for (int ct = 0; ct < 2; ++ct)
#pragma unroll
    for (int rr = 0; rr < 4; ++rr)
      Red[(w * 16 + fq * 4 + rr) * 33 + ct * 16 + fr] = acc[ct][rr];
  __syncthreads();
  if (tid < 128) {
    const int row = tid >> 3, cg = (tid & 7) * 4;
#pragma unroll
    for (int j = 0; j < 4; ++j) {
      const int col = cg + j;
      const float s = Red[(0 * 16 + row) * 33 + col] + Red[(1 * 16 + row) * 33 + col]
                    + Red[(2 * 16 + row) * 33 + col] + Red[(3 * 16 + row) * 33 + col];
      const int grow = row0 + row;
      if (col < 16) {
        bbuf[grow * NHEAD + col] = 1.f / (1.f + __expf(-s));
      } else {
        const int hh = col - 16;
        const float xs = s + dtb[hh];
        const float sp = (xs > 20.f) ? xs : log1pf(__expf(xs));
        gbuf[grow * NHEAD + hh] = -__expf(A_log[hh]) * sp;
      }
    }
  }
}

// ===================== chunk-parallel gated delta rule (MFMA) =================
__global__ __launch_bounds__(256) void chunk_local(
    const u16* __restrict__ qp, const u16* __restrict__ kp, const u16* __restrict__ vp,
    const float* __restrict__ cq, const float* __restrict__ ck, const float* __restrict__ cv,
    const float* __restrict__ gbuf, const float* __restrict__ bbuf,
    u16* __restrict__ Phi, u16* __restrict__ Plo, u16* __restrict__ Ug,
    u16* __restrict__ Rg, u16* __restrict__ Yg) {
  __shared__ __align__(16) u16 Kb[64 * 64];
  __shared__ __align__(16) u16 Qb[64 * 64];
  __shared__ __align__(16) u16 K2T[64 * 64];
  __shared__ __align__(16) u16 KWt[64 * 64];   // -> uTh
  __shared__ __align__(16) u16 Vt[64 * 64];    // -> Gb
  __shared__ __align__(16) u16 Zb[64 * 64];
  __shared__ __align__(16) u16 Zt[64 * 64];
  __shared__ __align__(16) u16 Mb[64 * 72];    // -> WTh
  __shared__ __align__(16) float Cb[16 * 64];
  __shared__ float bcs[64], bet[64], e2v[64], Bv[64];
  u16* WTh = Mb;
  u16* uTh = KWt;
  u16* Gb  = Vt;

  const int bid = blockIdx.x;
  const int c = bid & 31, bh = bid >> 5;
  const int b = bh >> 4, h = bh & 15;
  const int tid = threadIdx.x;

  {
    int* zp = (int*)Zt;
#pragma unroll
    for (int i = 0; i < 8; ++i) zp[tid + 256 * i] = 0;
  }
  if (tid < 64) {
    const size_t gi = (size_t)((b * TLEN + c * 64) + tid) * NHEAD + h;
    bet[tid] = bbuf[gi];
    float v = gbuf[gi];
#pragma unroll
    for (int ofs = 1; ofs < 64; ofs <<= 1) {
      float tt = __shfl_up(v, ofs);
      if (tid >= ofs) v += tt;
    }
    bcs[tid] = v;
  }
  __syncthreads();
  if (tid < 64) {
    const float blast = bcs[63];
    Bv[tid]  = __expf(bcs[tid]);
    e2v[tid] = __expf(blast - bcs[tid]);
  }
  __syncthreads();

  // ---- staging with fused conv+silu+l2norm (pk conversions)
  {
    const int dq = (tid & 15) * 4;
    const int col = h * 64 + dq;
    float4 wq4[4], wk4[4], wv4[4];
#pragma unroll
    for (int jj = 0; jj < 4; ++jj) {
      wq4[jj] = *(const float4*)(cq + (size_t)(col + jj) * 4);
      wk4[jj] = *(const float4*)(ck + (size_t)(col + jj) * 4);
      wv4[jj] = *(const float4*)(cv + (size_t)(col + jj) * 4);
    }
#pragma unroll
    for (int i = 0; i < 4; ++i) {
      const int r = i * 16 + (tid >> 4);
      const int tcur = c * 64 + r;
      ushort4 xq[4], xk[4], xv[4];
#pragma unroll
      for (int m = 0; m < 4; ++m) {
        const int tt = tcur - 3 + m;
        if (tt >= 0) {
          const size_t a = (size_t)(b * TLEN + tt) * HD + col;
          xq[m] = *(const ushort4*)(qp + a);
          xk[m] = *(const ushort4*)(kp + a);
          xv[m] = *(const ushort4*)(vp + a);
        } else {
          xq[m] = ushort4{0, 0, 0, 0}; xk[m] = xq[m]; xv[m] = xq[m];
        }
      }
      float yq[4], yk[4], yv[4];
      float ssq = 0.f, ssk = 0.f;
#pragma unroll
      for (int jj = 0; jj < 4; ++jj) {
        float aq = wq4[jj].x * bf2f(((const u16*)&xq[0])[jj]) +
                   wq4[jj].y * bf2f(((const u16*)&xq[1])[jj]) +
                   wq4[jj].z * bf2f(((const u16*)&xq[2])[jj]) +
                   wq4[jj].w * bf2f(((const u16*)&xq[3])[jj]);
        float ak = wk4[jj].x * bf2f(((const u16*)&xk[0])[jj]) +
                   wk4[jj].y * bf2f(((const u16*)&xk[1])[jj]) +
                   wk4[jj].z * bf2f(((const u16*)&xk[2])[jj]) +
                   wk4[jj].w * bf2f(((const u16*)&xk[3])[jj]);
        float av = wv4[jj].x * bf2f(((const u16*)&xv[0])[jj]) +
                   wv4[jj].y * bf2f(((const u16*)&xv[1])[jj]) +
                   wv4[jj].z * bf2f(((const u16*)&xv[2])[jj]) +
                   wv4[jj].w * bf2f(((const u16*)&xv[3])[jj]);
        yq[jj] = aq / (1.f + __expf(-aq));
        yk[jj] = ak / (1.f + __expf(-ak));
        yv[jj] = av / (1.f + __expf(-av));
        ssq += yq[jj] * yq[jj];
        ssk += yk[jj] * yk[jj];
      }
      ssq += __shfl_xor(ssq, 1); ssq += __shfl_xor(ssq, 2);
      ssq += __shfl_xor(ssq, 4); ssq += __shfl_xor(ssq, 8);
      ssk += __shfl_xor(ssk, 1); ssk += __shfl_xor(ssk, 2);
      ssk += __shfl_xor(ssk, 4); ssk += __shfl_xor(ssk, 8);
      const float qsc = rsqrtf(ssq + 1e-6f) * 0.125f;
      const float ksc = rsqrtf(ssk + 1e-6f);
      const float bR = bet[r], e2R = e2v[r], wscR = bR * Bv[r];
      float kvf[4];
#pragma unroll
      for (int jj = 0; jj < 4; ++jj) kvf[jj] = yk[jj] * ksc;
      uint2 qo2, ko2;
      qo2.x = pkbf(yq[0] * qsc, yq[1] * qsc);
      qo2.y = pkbf(yq[2] * qsc, yq[3] * qsc);
      ko2.x = pkbf(kvf[0], kvf[1]);
      ko2.y = pkbf(kvf[2], kvf[3]);
      *(uint2*)((char*)Qb + swz(r, dq)) = qo2;
      *(uint2*)((char*)Kb + swz(r, dq)) = ko2;
      const unsigned k2a = pkbf(kvf[0] * e2R, kvf[1] * e2R);
      const unsigned k2b = pkbf(kvf[2] * e2R, kvf[3] * e2R);
      const unsigned kwa = pkbf(kvf[0] * wscR, kvf[1] * wscR);
      const unsigned kwb = pkbf(kvf[2] * wscR, kvf[3] * wscR);
      const unsigned vta = pkbf(yv[0] * bR, yv[1] * bR);
      const unsigned vtb = pkbf(yv[2] * bR, yv[3] * bR);
      *(u16*)((char*)K2T + swz(dq + 0, r)) = (u16)k2a;
      *(u16*)((char*)K2T + swz(dq + 1, r)) = (u16)(k2a >> 16);
      *(u16*)((char*)K2T + swz(dq + 2, r)) = (u16)k2b;
      *(u16*)((char*)K2T + swz(dq + 3, r)) = (u16)(k2b >> 16);
      *(u16*)((char*)KWt + swz(dq + 0, r)) = (u16)kwa;
      *(u16*)((char*)KWt + swz(dq + 1, r)) = (u16)(kwa >> 16);
      *(u16*)((char*)KWt + swz(dq + 2, r)) = (u16)kwb;
      *(u16*)((char*)KWt + swz(dq + 3, r)) = (u16)(kwb >> 16);
      *(u16*)((char*)Vt + swz(dq + 0, r)) = (u16)vta;
      *(u16*)((char*)Vt + swz(dq + 1, r)) = (u16)(vta >> 16);
      *(u16*)((char*)Vt + swz(dq + 2, r)) = (u16)vtb;
      *(u16*)((char*)Vt + swz(dq + 3, r)) = (u16)(vtb >> 16);
    }
  }
  __syncthreads();

  const int w = tid >> 6, lane = tid & 63, fr = lane & 15, fq = lane >> 4;
  const int t0r = w * 16 + fq * 4;
  // ---- A = K K^T via MFMA -> masked M (bf16, stride 72)
  {
    bf16x8 ka0 = frag(Kb, w * 16 + fr, fq);
    bf16x8 ka1 = frag(Kb, w * 16 + fr, 4 + fq);
#pragma unroll
    for (int tc = 0; tc < 4; ++tc) {
      bf16x8 kb0 = frag(Kb, tc * 16 + fr, fq);
      bf16x8 kb1 = frag(Kb, tc * 16 + fr, 4 + fq);
      f32x4 a = {};
      a = __builtin_amdgcn_mfma_f32_16x16x32_bf16(ka0, kb0, a, 0, 0, 0);
      a = __builtin_amdgcn_mfma_f32_16x16x32_bf16(ka1, kb1, a, 0, 0, 0);
      const int s = tc * 16 + fr;
      float mv[4];
#pragma unroll
      for (int rr = 0; rr < 4; ++rr) {
        const int t = t0r + rr;
        mv[rr] = (s < t) ? bet[t] * __expf(bcs[t] - bcs[s]) * a[rr] : 0.f;
      }
      const unsigned m01 = pkbf(mv[0], mv[1]), m23 = pkbf(mv[2], mv[3]);
      Mb[(t0r + 0) * 72 + s] = (u16)m01;
      Mb[(t0r + 1) * 72 + s] = (u16)(m01 >> 16);
      Mb[(t0r + 2) * 72 + s] = (u16)m23;
      Mb[(t0r + 3) * 72 + s] = (u16)(m23 >> 16);
    }
  }
  __syncthreads();

  // ---- BLOCKED solve M Minv = I (4 blocks of 16 rows)
#pragma unroll 1
  for (int bi = 0; bi < 4; ++bi) {
    {
      const char* mrow = (const char*)Mb + (size_t)(bi * 16 + fr) * 144;
      bf16x8 ma0 = *(const bf16x8*)(mrow + fq * 16);
      bf16x8 ma1 = *(const bf16x8*)(mrow + 64 + fq * 16);
      bf16x8 zt0 = frag(Zt, w * 16 + fr, fq);
      bf16x8 zt1 = frag(Zt, w * 16 + fr, 4 + fq);
      f32x4 a = {};
      a = __builtin_amdgcn_mfma_f32_16x16x32_bf16(ma0, zt0, a, 0, 0, 0);
      a = __builtin_amdgcn_mfma_f32_16x16x32_bf16(ma1, zt1, a, 0, 0, 0);
#pragma unroll
      for (int rr = 0; rr < 4; ++rr)
        Cb[(fq * 4 + rr) * 64 + w * 16 + fr] = a[rr];
    }
    __syncthreads();
    if (tid < 64) {
      const int j = tid;
      float z[16];
#pragma unroll
      for (int t = 0; t < 16; ++t) {
        float acc = ((bi * 16 + t) == j ? 1.f : 0.f) - Cb[t * 64 + j];
        const u16* mrow = Mb + (size_t)(bi * 16 + t) * 72 + bi * 16;
#pragma unroll
        for (int s = 0; s < t; ++s) acc -= bf2f(mrow[s]) * z[s];
        z[t] = acc;
      }
      unsigned zw[8];
#pragma unroll
      for (int t2 = 0; t2 < 8; ++t2) zw[t2] = pkbf(z[2 * t2], z[2 * t2 + 1]);
#pragma unroll
      for (int t2 = 0; t2 < 8; ++t2) {
        *(u16*)((char*)Zb + swz(bi * 16 + 2 * t2, j)) = (u16)zw[t2];
        *(u16*)((char*)Zb + swz(bi * 16 + 2 * t2 + 1, j)) = (u16)(zw[t2] >> 16);
      }
#pragma unroll
      for (int t4 = 0; t4 < 4; ++t4) {
        uint2 zz; zz.x = zw[2 * t4]; zz.y = zw[2 * t4 + 1];
        *(uint2*)((char*)Zt + swz(j, bi * 16 + t4 * 4)) = zz;
      }
    }
    __syncthreads();
  }

  // ---- W = Minv*RHSw, u = Minv*RHSv (transposed out), G = QK^T
  f32x4 accW[4], accu[4], accG[4];
  {
    bf16x8 kw0 = frag(KWt, w * 16 + fr, fq), kw1 = frag(KWt, w * 16 + fr, 4 + fq);
    bf16x8 vt0 = frag(Vt,  w * 16 + fr, fq), vt1 = frag(Vt,  w * 16 + fr, 4 + fq);
    bf16x8 qa0 = frag(Qb,  w * 16 + fr, fq), qa1 = frag(Qb,  w * 16 + fr, 4 + fq);
#pragma unroll
    for (int tc = 0; tc < 4; ++tc) {
      bf16x8 z0 = frag(Zb, tc * 16 + fr, fq), z1 = frag(Zb, tc * 16 + fr, 4 + fq);
      bf16x8 kb0 = frag(Kb, tc * 16 + fr, fq), kb1 = frag(Kb, tc * 16 + fr, 4 + fq);
      f32x4 aw = {}, au = {}, ag = {};
      aw = __builtin_amdgcn_mfma_f32_16x16x32_bf16(kw0, z0, aw, 0, 0, 0);
      aw = __builtin_amdgcn_mfma_f32_16x16x32_bf16(kw1, z1, aw, 0, 0, 0);
      au = __builtin_amdgcn_mfma_f32_16x16x32_bf16(vt0, z0, au, 0, 0, 0);
      au = __builtin_amdgcn_mfma_f32_16x16x32_bf16(vt1, z1, au, 0, 0, 0);
      ag = __builtin_amdgcn_mfma_f32_16x16x32_bf16(qa0, kb0, ag, 0, 0, 0);
      ag = __builtin_amdgcn_mfma_f32_16x16x32_bf16(qa1, kb1, ag, 0, 0, 0);
      accW[tc] = aw; accu[tc] = au; accG[tc] = ag;
    }
  }
  __syncthreads();
#pragma unroll
  for (int tc = 0; tc < 4; ++tc) {
    const int co = tc * 16 + fr;
    const unsigned w01 = pkbf(accW[tc][0], accW[tc][1]);
    const unsigned w23 = pkbf(accW[tc][2], accW[tc][3]);
    const unsigned u01 = pkbf(accu[tc][0], accu[tc][1]);
    const unsigned u23 = pkbf(accu[tc][2], accu[tc][3]);
    float gv[4];
#pragma unroll
    for (int rr = 0; rr < 4; ++rr) {
      const int ro = t0r + rr;
      gv[rr] = (co <= ro) ? accG[tc][rr] * __expf(bcs[ro] - bcs[co]) : 0.f;
    }
    const unsigned g01 = pkbf(gv[0], gv[1]), g23 = pkbf(gv[2], gv[3]);
    *(u16*)((char*)WTh + swz(t0r + 0, co)) = (u16)w01;
    *(u16*)((char*)WTh + swz(t0r + 1, co)) = (u16)(w01 >> 16);
    *(u16*)((char*)WTh + swz(t0r + 2, co)) = (u16)w23;
    *(u16*)((char*)WTh + swz(t0r + 3, co)) = (u16)(w23 >> 16);
    *(u16*)((char*)uTh + swz(t0r + 0, co)) = (u16)u01;
    *(u16*)((char*)uTh + swz(t0r + 1, co)) = (u16)(u01 >> 16);
    *(u16*)((char*)uTh + swz(t0r + 2, co)) = (u16)u23;
    *(u16*)((char*)uTh + swz(t0r + 3, co)) = (u16)(u23 >> 16);
    *(u16*)((char*)Gb + swz(t0r + 0, co)) = (u16)g01;
    *(u16*)((char*)Gb + swz(t0r + 1, co)) = (u16)(g01 >> 16);
    *(u16*)((char*)Gb + swz(t0r + 2, co)) = (u16)g23;
    *(u16*)((char*)Gb + swz(t0r + 3, co)) = (u16)(g23 >> 16);
  }
  __syncthreads();

  // ---- P,U,R,Y via MFMA + epilogue (P hi/lo bf16; U,R,Y bf16; pk everywhere)
  {
    bf16x8 k20 = frag(K2T, w * 16 + fr, fq), k21 = frag(K2T, w * 16 + fr, 4 + fq);
    bf16x8 g0  = frag(Gb,  w * 16 + fr, fq), g1  = frag(Gb,  w * 16 + fr, 4 + fq);
    const float bl = Bv[63];
    const size_t off = (size_t)bid * 4096;
#pragma unroll
    for (int tc = 0; tc < 4; ++tc) {
      bf16x8 w0 = frag(WTh, tc * 16 + fr, fq), w1 = frag(WTh, tc * 16 + fr, 4 + fq);
      bf16x8 u0 = frag(uTh, tc * 16 + fr, fq), u1 = frag(uTh, tc * 16 + fr, 4 + fq);
      f32x4 aP = {}, aU = {}, aR = {}, aY = {};
      aP = __builtin_amdgcn_mfma_f32_16x16x32_bf16(k20, w0, aP, 0, 0, 0);
      aP = __builtin_amdgcn_mfma_f32_16x16x32_bf16(k21, w1, aP, 0, 0, 0);
      aU = __builtin_amdgcn_mfma_f32_16x16x32_bf16(k20, u0, aU, 0, 0, 0);
      aU = __builtin_amdgcn_mfma_f32_16x16x32_bf16(k21, u1, aU, 0, 0, 0);
      aR = __builtin_amdgcn_mfma_f32_16x16x32_bf16(g0, w0, aR, 0, 0, 0);
      aR = __builtin_amdgcn_mfma_f32_16x16x32_bf16(g1, w1, aR, 0, 0, 0);
      aY = __builtin_amdgcn_mfma_f32_16x16x32_bf16(g0, u0, aY, 0, 0, 0);
      aY = __builtin_amdgcn_mfma_f32_16x16x32_bf16(g1, u1, aY, 0, 0, 0);
      const int cb = tc * 16 + fr;
      float pv[4], rv[4];
#pragma unroll
      for (int rr = 0; rr < 4; ++rr) {
        const int ar = t0r + rr;
        pv[rr] = ((ar == cb) ? bl : 0.f) - aP[rr];
        const float qv = bf2f(*(const u16*)((const char*)Qb + swz(ar, cb)));
        rv[rr] = Bv[ar] * qv - aR[rr];
      }
      const unsigned p01 = pkbf(pv[0], pv[1]), p23 = pkbf(pv[2], pv[3]);
      const float l0 = pv[0] - bf2f((u16)p01), l1 = pv[1] - bf2f((u16)(p01 >> 16));
      const float l2 = pv[2] - bf2f((u16)p23), l3 = pv[3] - bf2f((u16)(p23 >> 16));
      const unsigned q01 = pkbf(l0, l1), q23 = pkbf(l2, l3);
      const unsigned u01 = pkbf(aU[0], aU[1]), u23 = pkbf(aU[2], aU[3]);
      const unsigned r01 = pkbf(rv[0], rv[1]), r23 = pkbf(rv[2], rv[3]);
      const unsigned y01 = pkbf(aY[0], aY[1]), y23 = pkbf(aY[2], aY[3]);
      const size_t o0 = off + (size_t)(t0r + 0) * 64 + cb;
      const size_t o1 = off + (size_t)(t0r + 1) * 64 + cb;
      const size_t o2 = off + (size_t)(t0r + 2) * 64 + cb;
      const size_t o3 = off + (size_t)(t0r + 3) * 64 + cb;
      Phi[o0] = (u16)p01; Phi[o1] = (u16)(p01 >> 16);
      Phi[o2] = (u16)p23; Phi[o3] = (u16)(p23 >> 16);
      Plo[o0] = (u16)q01; Plo[o1] = (u16)(q01 >> 16);
      Plo[o2] = (u16)q23; Plo[o3] = (u16)(q23 >> 16);
      Ug[o0] = (u16)u01; Ug[o1] = (u16)(u01 >> 16);
      Ug[o2] = (u16)u23; Ug[o3] = (u16)(u23 >> 16);
      Rg[o0] = (u16)r01; Rg[o1] = (u16)(r01 >> 16);
      Rg[o2] = (u16)r23; Rg[o3] = (u16)(r23 >> 16);
      Yg[o0] = (u16)y01; Yg[o1] = (u16)(y01 >> 16);
      Yg[o2] = (u16)y23; Yg[o3] = (u16)(y23 >> 16);
    }
  }
}

// ---- phase B: S_{c+1} = P_c S_c + U_c via split-precision MFMA.
// 32 blocks, 4 waves. S^T hi/lo in LDS (dbuf). Sst stored TRANSPOSED
// ([dv][dk]) so the store is a uint2 and chunk_out can MFMA directly.
__global__ __launch_bounds__(256) void state_step(
    const u16* __restrict__ Phi, const u16* __restrict__ Plo,
    const u16* __restrict__ Ug, u16* __restrict__ Sst) {
  __shared__ __align__(16) u16 Sth[2][64 * 64];
  __shared__ __align__(16) u16 Stl[2][64 * 64];
  const int bh = blockIdx.x;
  const int tid = threadIdx.x;
  const int w = tid >> 6, lane = tid & 63, fr = lane & 15, fq = lane >> 4;
  const int ar0 = w * 16 + fq * 4;
  const size_t bbase = (size_t)bh * 32 * 4096;
  {
    int* p0 = (int*)&Sth[0][0];
    int* p1 = (int*)&Stl[0][0];
#pragma unroll
    for (int i = 0; i < 8; ++i) { p0[tid + 256 * i] = 0; p1[tid + 256 * i] = 0; }
    const ushort4 z4 = {0, 0, 0, 0};
#pragma unroll
    for (int i = 0; i < 4; ++i)
      *(ushort4*)(Sst + bbase + (size_t)tid * 16 + i * 4) = z4;  // S_in[0] = 0
  }
  bf16x8 ph[2], pl[2];
  float uin[4][4];
#pragma unroll
  for (int kk = 0; kk < 2; ++kk) {
    const size_t ao = bbase + (size_t)(w * 16 + fr) * 64 + (kk * 4 + fq) * 8;
    ph[kk] = *(const bf16x8*)(Phi + ao);
    pl[kk] = *(const bf16x8*)(Plo + ao);
  }
#pragma unroll
  for (int tc = 0; tc < 4; ++tc)
#pragma unroll
    for (int rr = 0; rr < 4; ++rr)
      uin[tc][rr] = bf2f(Ug[bbase + (size_t)(ar0 + rr) * 64 + tc * 16 + fr]);
  __syncthreads();
  int cur = 0;
  for (int c = 0; c < 32; ++c) {
    f32x4 acc[4];
    bf16x8 phc[2] = {ph[0], ph[1]}, plc[2] = {pl[0], pl[1]};
#pragma unroll
    for (int tc = 0; tc < 4; ++tc)
#pragma unroll
      for (int rr = 0; rr < 4; ++rr) acc[tc][rr] = uin[tc][rr];
    if (c + 1 < 32) {
      const size_t off = bbase + (size_t)(c + 1) * 4096;
#pragma unroll
      for (int kk = 0; kk < 2; ++kk) {
        const size_t ao = off + (size_t)(w * 16 + fr) * 64 + (kk * 4 + fq) * 8;
        ph[kk] = *(const bf16x8*)(Phi + ao);
        pl[kk] = *(const bf16x8*)(Plo + ao);
      }
#pragma unroll
      for (int tc = 0; tc < 4; ++tc)
#pragma unroll
        for (int rr = 0; rr < 4; ++rr)
          uin[tc][rr] = bf2f(Ug[off + (size_t)(ar0 + rr) * 64 + tc * 16 + fr]);
    }
#pragma unroll
    for (int tc = 0; tc < 4; ++tc) {
#pragma unroll
      for (int kk = 0; kk < 2; ++kk) {
        bf16x8 sh = frag(&Sth[cur][0], tc * 16 + fr, kk * 4 + fq);
        bf16x8 sl = frag(&Stl[cur][0], tc * 16 + fr, kk * 4 + fq);
        acc[tc] = __builtin_amdgcn_mfma_f32_16x16x32_bf16(phc[kk], sh, acc[tc], 0, 0, 0);
        acc[tc] = __builtin_amdgcn_mfma_f32_16x16x32_bf16(phc[kk], sl, acc[tc], 0, 0, 0);
        acc[tc] = __builtin_amdgcn_mfma_f32_16x16x32_bf16(plc[kk], sh, acc[tc], 0, 0, 0);
      }
    }
    const int nxt = cur ^ 1;
    const size_t offn = bbase + (size_t)(c + 1) * 4096;
#pragma unroll
    for (int tc = 0; tc < 4; ++tc) {
      const int col = tc * 16 + fr;                // dv
      const unsigned h01 = pkbf(acc[tc][0], acc[tc][1]);
      const unsigned h23 = pkbf(acc[tc][2], acc[tc][3]);
      const float l0 = acc[tc][0] - bf2f((u16)h01);
      const float l1 = acc[tc][1] - bf2f((u16)(h01 >> 16));
      const float l2 = acc[tc][2] - bf2f((u16)h23);
      const float l3 = acc[tc][3] - bf2f((u16)(h23 >> 16));
      uint2 hh; hh.x = h01; hh.y = h23;
      uint2 ll; ll.x = pkbf(l0, l1); ll.y = pkbf(l2, l3);
      *(uint2*)((char*)&Sth[nxt][0] + swz(col, ar0)) = hh;
      *(uint2*)((char*)&Stl[nxt][0] + swz(col, ar0)) = ll;
      if (c + 1 < 32)
        *(uint2*)(Sst + offn + (size_t)col * 64 + ar0) = hh;  // transposed [dv][dk]
    }
    cur = nxt;
    __syncthreads();
  }
}

// ---- phase C: O = R S_in + Y via MFMA (R [t][dk], Sst^T [dv][dk], both
// straight from global), fused gated-RMSNorm epilogue -> bf16. No LDS.
__global__ __launch_bounds__(256) void chunk_out(
    const u16* __restrict__ Rg, const u16* __restrict__ Yg,
    const u16* __restrict__ SstT, const u16* __restrict__ gatep,
    const float* __restrict__ norm_w, u16* __restrict__ outb) {
  const int bid = blockIdx.x;
  const int c = bid & 31, bh = bid >> 5, b = bh >> 4, h = bh & 15;
  const int tid = threadIdx.x;
  const int w = tid >> 6, lane = tid & 63, fr = lane & 15, fq = lane >> 4;
  const int ar0 = w * 16 + fq * 4;
  const size_t off = (size_t)bid * 4096;
  bf16x8 ra[2];
#pragma unroll
  for (int kk = 0; kk < 2; ++kk)
    ra[kk] = *(const bf16x8*)(Rg + off + (size_t)(w * 16 + fr) * 64 + (kk * 4 + fq) * 8);
  f32x4 acc[4];
#pragma unroll
  for (int tc = 0; tc < 4; ++tc)
#pragma unroll
    for (int rr = 0; rr < 4; ++rr)
      acc[tc][rr] = bf2f(Yg[off + (size_t)(ar0 + rr) * 64 + tc * 16 + fr]);
#pragma unroll
  for (int tc = 0; tc < 4; ++tc)
#pragma unroll
    for (int kk = 0; kk < 2; ++kk) {
      bf16x8 sb = *(const bf16x8*)(SstT + off + (size_t)(tc * 16 + fr) * 64 + (kk * 4 + fq) * 8);
      acc[tc] = __builtin_amdgcn_mfma_f32_16x16x32_bf16(ra[kk], sb, acc[tc], 0, 0, 0);
    }
  float nwv[4];
#pragma unroll
  for (int tc = 0; tc < 4; ++tc) nwv[tc] = norm_w[tc * 16 + fr];
  const size_t btbase = (size_t)(b * TLEN + c * 64);
#pragma unroll
  for (int rr = 0; rr < 4; ++rr) {
    const int t = ar0 + rr;
    float rs = acc[0][rr] * acc[0][rr] + acc[1][rr] * acc[1][rr]
             + acc[2][rr] * acc[2][rr] + acc[3][rr] * acc[3][rr];
    rs += __shfl_xor(rs, 1); rs += __shfl_xor(rs, 2);
    rs += __shfl_xor(rs, 4); rs += __shfl_xor(rs, 8);
    const float inv = rsqrtf(rs * (1.0f / 64.0f) + 1e-5f);
    const size_t rowoff = (btbase + t) * 1024 + h * 64;
#pragma unroll
    for (int tc = 0; tc < 4; ++tc) {
      const int j = tc * 16 + fr;
      const float g = bf2f(gatep[rowoff + j]);
      const float val = acc[tc][rr] * inv * nwv[tc] * (g / (1.f + __expf(-g)));
      outb[rowoff + j] = f2bf(val);
    }
  }
}

extern "C" void kernel_launch(void* const* d_in, const int* in_sizes, int n_in,
                              void* d_out, int out_size, void* d_ws, size_t ws_size,
                              hipStream_t stream) {
  const float* hidden = (const float*)d_in[0];
  const float* Wq     = (const float*)d_in[1];
  const float* Wk     = (const float*)d_in[2];
  const float* Wv     = (const float*)d_in[3];
  const float* cq     = (const float*)d_in[4];
  const float* ck     = (const float*)d_in[5];
  const float* cv     = (const float*)d_in[6];
  const float* Wb     = (const float*)d_in[7];
  const float* Wa     = (const float*)d_in[8];
  const float* A_log  = (const float*)d_in[9];
  const float* dtb    = (const float*)d_in[10];
  const float* Wg     = (const float*)d_in[11];
  const float* nw     = (const float*)d_in[12];
  const float* Wo     = (const float*)d_in[13];

  char* p = (char*)d_ws;
  const size_t MB = 1u << 20;
  u16* h_bf = (u16*)(p + 0 * MB);     // 8 MB (dead after small_mfma)
  u16* wq_b = (u16*)(p + 8 * MB);     // 2 MB
  u16* wk_b = (u16*)(p + 10 * MB);
  u16* wv_b = (u16*)(p + 12 * MB);
  u16* wg_b = (u16*)(p + 14 * MB);
  u16* Phi = (u16*)(p + 0 * MB);      // 8 MB bf16, aliases h_bf (dead then)
  u16* Plo = (u16*)(p + 8 * MB);      // 8 MB bf16, aliases wq..wg (dead then)
  u16* wo_b = (u16*)(p + 16 * MB);    // 2 MB (live till end)
  u16* qp_b = (u16*)(p + 18 * MB);    // 8 MB
  u16* kp_b = (u16*)(p + 26 * MB);    // 8 MB
  u16* vp_b = (u16*)(p + 34 * MB);    // 8 MB
  u16* gp_b = (u16*)(p + 42 * MB);    // 8 MB (live till chunk_out)
  u16*   of_b = vp_b;                 // 8 MB, aliases vp (dead after chunk_local)
  float* gbuf = (float*)(p + 50 * MB);
  float* bbuf = (float*)(p + 50 * MB + 262144);
  u16* Ug  = (u16*)(p + 51 * MB);     // 8 MB bf16
  u16* Rg  = (u16*)(p + 59 * MB);     // 8 MB bf16
  u16* Yg  = (u16*)(p + 67 * MB);     // 8 MB bf16
  u16* Sst = (u16*)(p + 75 * MB);     // 8 MB bf16 (transposed per chunk)
  u16* hlo_b = (u16*)(p + 83 * MB);   // 8 MB
  u16* wba_h = (u16*)(p + 91 * MB);   // 64 KB
  u16* wba_l = (u16*)(p + 91 * MB + 65536);  // 64 KB (total ~91.2 MB)

  cvt_all<<<9248, 256, 0, stream>>>(hidden, Wq, Wk, Wv, Wg, Wo, Wb, Wa,
                                    h_bf, hlo_b, wq_b, wk_b, wv_b, wg_b, wo_b,
                                    wba_h, wba_l);

  gemm_big<<<dim3(8, 16, 4), 256, 0, stream>>>(
      h_bf, wq_b, wk_b, wv_b, wg_b, qp_b, kp_b, vp_b, gp_b, 4096, 1024, 1024);

  const int sm_lds = 65536 + 8448;
  hipFuncSetAttribute((const void*)small_mfma,
                      hipFuncAttributeMaxDynamicSharedMemorySize, sm_lds);
  small_mfma<<<256, 256, sm_lds, stream>>>(h_bf, hlo_b, wba_h, wba_l,
                                           A_log, dtb, bbuf, gbuf);

  chunk_local<<<1024, 256, 0, stream>>>(qp_b, kp_b, vp_b, cq, ck, cv,
                                        gbuf, bbuf, Phi, Plo, Ug, Rg, Yg);
  state_step<<<32, 256, 0, stream>>>(Phi, Plo, Ug, Sst);
  chunk_out<<<1024, 256, 0, stream>>>(Rg, Yg, Sst, gp_b, nw, of_b);

  gemm_lin<float, 2><<<dim3(8, 64, 1), 256, 0, stream>>>(
      of_b, wo_b, (float*)d_out, 4096, 1024, 1024);
}

// Round 11
// 168.405 us; speedup vs baseline: 10.0682x; 1.0125x over previous
//
#include <hip/hip_runtime.h>
#include <hip/hip_bf16.h>

typedef unsigned short u16;
typedef __attribute__((ext_vector_type(4))) float f32x4;
typedef __attribute__((ext_vector_type(8))) short bf16x8;

#define TLEN 2048
#define NHEAD 16
#define HD 1024

__device__ inline u16 f2bf(float f) {
  unsigned x = __float_as_uint(f);
  return (u16)((x + 0x7fffu + ((x >> 16) & 1u)) >> 16);
}
__device__ inline float bf2f(u16 u) { return __uint_as_float(((unsigned)u) << 16); }

// packed f32x2 -> bf16x2 (low half = first operand). 1 inst vs ~8.
__device__ inline unsigned pkbf(float lo, float hi) {
  unsigned r;
  asm("v_cvt_pk_bf16_f32 %0, %1, %2" : "=v"(r) : "v"(lo), "v"(hi));
  return r;
}

__device__ inline void storev(float* p, float v) { *p = v; }
__device__ inline void storev(u16* p, float v)   { *p = f2bf(v); }

// swizzle for [64 rows][64 bf16 = 128B] LDS tiles; XOR spreads both row&7
// and row>>3 so transposed (fixed-col) writes don't collide 8-way.
__device__ inline int rowx(int row) { return (row ^ (row >> 3)) & 7; }
__device__ inline int swz(int row, int col) {
  return (row << 7) + (((col >> 3) ^ rowx(row)) << 4) + ((col & 7) << 1);
}
__device__ inline bf16x8 frag(const u16* base, int row, int kslot) {
  return *(const bf16x8*)((const char*)base + (row << 7) +
                          ((kslot ^ rowx(row)) << 4));
}

// ------------------------------------------------- fused fp32 -> bf16 converts
__global__ __launch_bounds__(256) void cvt_all(
    const float* __restrict__ h,  const float* __restrict__ wq,
    const float* __restrict__ wk, const float* __restrict__ wv,
    const float* __restrict__ wg, const float* __restrict__ wo,
    const float* __restrict__ Wb, const float* __restrict__ Wa,
    u16* __restrict__ dh,  u16* __restrict__ dhlo,
    u16* __restrict__ dwq, u16* __restrict__ dwk,
    u16* __restrict__ dwv, u16* __restrict__ dwg, u16* __restrict__ dwo,
    u16* __restrict__ dwba_h, u16* __restrict__ dwba_l) {
  const int b = blockIdx.x;
  if (b < 4096) {
    const size_t i = (size_t)b * 256 + threadIdx.x;
    float4 v = *(const float4*)(h + i * 4);
    ushort4 hi, lo;
    hi.x = f2bf(v.x); lo.x = f2bf(v.x - bf2f(hi.x));
    hi.y = f2bf(v.y); lo.y = f2bf(v.y - bf2f(hi.y));
    hi.z = f2bf(v.z); lo.z = f2bf(v.z - bf2f(hi.z));
    hi.w = f2bf(v.w); lo.w = f2bf(v.w - bf2f(hi.w));
    *(ushort4*)(dh + i * 4) = hi;
    *(ushort4*)(dhlo + i * 4) = lo;
  } else if (b < 9216) {
    const int wsel = (b - 4096) >> 10;
    const size_t i = (size_t)((b - 4096) & 1023) * 256 + threadIdx.x;
    const float* s; u16* d;
    switch (wsel) {
      case 0: s = wq; d = dwq; break;
      case 1: s = wk; d = dwk; break;
      case 2: s = wv; d = dwv; break;
      case 3: s = wg; d = dwg; break;
      default: s = wo; d = dwo; break;
    }
    float4 v = *(const float4*)(s + i * 4);
    ushort4 u;
    u.x = f2bf(v.x); u.y = f2bf(v.y); u.z = f2bf(v.z); u.w = f2bf(v.w);
    *(ushort4*)(d + i * 4) = u;
  } else {
    const size_t i = (size_t)(b - 9216) * 256 + threadIdx.x;
    const size_t flat = i * 4;
    const float* src = (flat < 16384) ? (Wb + flat) : (Wa + (flat - 16384));
    float4 v = *(const float4*)src;
    ushort4 hi, lo;
    hi.x = f2bf(v.x); lo.x = f2bf(v.x - bf2f(hi.x));
    hi.y = f2bf(v.y); lo.y = f2bf(v.y - bf2f(hi.y));
    hi.z = f2bf(v.z); lo.z = f2bf(v.z - bf2f(hi.z));
    hi.w = f2bf(v.w); lo.w = f2bf(v.w - bf2f(hi.w));
    *(ushort4*)(dwba_h + flat) = hi;
    *(ushort4*)(dwba_l + flat) = lo;
  }
}

// ---------------- fused 4-projection GEMM: 256x128 tile, wave-tile 64x128
__global__ __launch_bounds__(256, 2) void gemm_big(
    const u16* __restrict__ A,
    const u16* __restrict__ W0p, const u16* __restrict__ W1p,
    const u16* __restrict__ W2p, const u16* __restrict__ W3p,
    u16* __restrict__ C0, u16* __restrict__ C1,
    u16* __restrict__ C2, u16* __restrict__ C3,
    int M, int N, int K) {
  const u16* W; u16* C;
  switch (blockIdx.z) {
    case 0: W = W0p; C = C0; break;
    case 1: W = W1p; C = C1; break;
    case 2: W = W2p; C = C2; break;
    default: W = W3p; C = C3; break;
  }
  const int tid = threadIdx.x;
  const int lane = tid & 63, wid = tid >> 6;
  const int fr = lane & 15, fq = lane >> 4;
  const int row0 = blockIdx.y * 256, col0 = blockIdx.x * 128;
  __shared__ __align__(16) u16 As[256 * 64];
  __shared__ __align__(16) u16 Bs[128 * 64];

  const u16* aSrc[8]; const u16* bSrc[4];
#pragma unroll
  for (int it = 0; it < 8; ++it) {
    const int s = it * 256 + tid;
    const int r = s >> 3, cc = s & 7;
    aSrc[it] = A + (size_t)(row0 + r) * K + (cc ^ (r & 7)) * 8;
  }
#pragma unroll
  for (int it = 0; it < 4; ++it) {
    const int s = it * 256 + tid;
    const int r = s >> 3, cc = s & 7;
    bSrc[it] = W + (size_t)(col0 + r) * K + (cc ^ (r & 7)) * 8;
  }
  int aOff[4][2], bOff[8][2];
#pragma unroll
  for (int m = 0; m < 4; ++m)
#pragma unroll
    for (int kk = 0; kk < 2; ++kk) {
      const int ra = wid * 64 + m * 16 + fr;
      aOff[m][kk] = ra * 128 + ((((kk << 2) | fq) ^ (ra & 7)) << 4);
    }
#pragma unroll
  for (int n = 0; n < 8; ++n)
#pragma unroll
    for (int kk = 0; kk < 2; ++kk) {
      const int rb = n * 16 + fr;
      bOff[n][kk] = rb * 128 + ((((kk << 2) | fq) ^ (rb & 7)) << 4);
    }

  f32x4 acc[4][8] = {};
  for (int k0 = 0; k0 < K; k0 += 64) {
#pragma unroll
    for (int it = 0; it < 8; ++it)
      __builtin_amdgcn_global_load_lds(
          (const __attribute__((address_space(1))) void*)(aSrc[it] + k0),
          (__attribute__((address_space(3))) void*)((char*)As + (it * 256 + tid) * 16),
          16, 0, 0);
#pragma unroll
    for (int it = 0; it < 4; ++it)
      __builtin_amdgcn_global_load_lds(
          (const __attribute__((address_space(1))) void*)(bSrc[it] + k0),
          (__attribute__((address_space(3))) void*)((char*)Bs + (it * 256 + tid) * 16),
          16, 0, 0);
    __syncthreads();
#pragma unroll
    for (int kk = 0; kk < 2; ++kk) {
      bf16x8 af[4], bfr[8];
#pragma unroll
      for (int m = 0; m < 4; ++m)
        af[m] = *(const bf16x8*)((const char*)As + aOff[m][kk]);
#pragma unroll
      for (int n = 0; n < 8; ++n)
        bfr[n] = *(const bf16x8*)((const char*)Bs + bOff[n][kk]);
#pragma unroll
      for (int m = 0; m < 4; ++m)
#pragma unroll
        for (int n = 0; n < 8; ++n)
          acc[m][n] = __builtin_amdgcn_mfma_f32_16x16x32_bf16(af[m], bfr[n], acc[m][n], 0, 0, 0);
    }
    __syncthreads();
  }
#pragma unroll
  for (int m = 0; m < 4; ++m)
#pragma unroll
    for (int n = 0; n < 8; ++n) {
      const int gr0 = row0 + wid * 64 + m * 16 + fq * 4;
      const int gc = col0 + n * 16 + fr;
      const unsigned c01 = pkbf(acc[m][n][0], acc[m][n][1]);
      const unsigned c23 = pkbf(acc[m][n][2], acc[m][n][3]);
      C[(size_t)(gr0 + 0) * N + gc] = (u16)c01;
      C[(size_t)(gr0 + 1) * N + gc] = (u16)(c01 >> 16);
      C[(size_t)(gr0 + 2) * N + gc] = (u16)c23;
      C[(size_t)(gr0 + 3) * N + gc] = (u16)(c23 >> 16);
    }
}

// ------------------------------------------------- bf16 MFMA linear: C = A*W^T
template <typename OutT, int MT>
__global__ __launch_bounds__(256) void gemm_lin(
    const u16* __restrict__ A, const u16* __restrict__ W,
    OutT* __restrict__ C, int M, int N, int K) {
  const int tid = threadIdx.x;
  const int lane = tid & 63, wid = tid >> 6;
  const int wr = wid >> 1, wc = wid & 1;
  const int fr = lane & 15, fq = lane >> 4;
  const int row0 = blockIdx.y * (MT * 32), col0 = blockIdx.x * 128;
  __shared__ __align__(16) u16 As[MT * 32 * 64];
  __shared__ __align__(16) u16 Bs[128 * 64];

  const u16* aSrc[MT]; const u16* bSrc[4];
#pragma unroll
  for (int it = 0; it < MT; ++it) {
    const int c = it * 256 + tid;
    const int r = c >> 3, cc = c & 7, sc = cc ^ (r & 7);
    aSrc[it] = A + (size_t)(row0 + r) * K + sc * 8;
  }
#pragma unroll
  for (int it = 0; it < 4; ++it) {
    const int c = it * 256 + tid;
    const int r = c >> 3, cc = c & 7, sc = cc ^ (r & 7);
    bSrc[it] = W + (size_t)(col0 + r) * K + sc * 8;
  }
  int aOff[MT][2], bOff[4][2];
#pragma unroll
  for (int m = 0; m < MT; ++m)
#pragma unroll
    for (int kk = 0; kk < 2; ++kk) {
      const int ra = wr * (MT * 16) + m * 16 + fr;
      aOff[m][kk] = ra * 128 + ((((kk << 2) | fq) ^ (fr & 7)) << 4);
    }
#pragma unroll
  for (int n = 0; n < 4; ++n)
#pragma unroll
    for (int kk = 0; kk < 2; ++kk) {
      const int rb = wc * 64 + n * 16 + fr;
      bOff[n][kk] = rb * 128 + ((((kk << 2) | fq) ^ (fr & 7)) << 4);
    }

  f32x4 acc[MT][4] = {};
  for (int k0 = 0; k0 < K; k0 += 64) {
#pragma unroll
    for (int it = 0; it < MT; ++it)
      __builtin_amdgcn_global_load_lds(
          (const __attribute__((address_space(1))) void*)(aSrc[it] + k0),
          (__attribute__((address_space(3))) void*)((char*)As + (it * 256 + wid * 64) * 16),
          16, 0, 0);
#pragma unroll
    for (int it = 0; it < 4; ++it)
      __builtin_amdgcn_global_load_lds(
          (const __attribute__((address_space(1))) void*)(bSrc[it] + k0),
          (__attribute__((address_space(3))) void*)((char*)Bs + (it * 256 + wid * 64) * 16),
          16, 0, 0);
    __syncthreads();
#pragma unroll
    for (int kk = 0; kk < 2; ++kk) {
      bf16x8 af[MT], bfr[4];
#pragma unroll
      for (int m = 0; m < MT; ++m)
        af[m] = *(const bf16x8*)((const char*)As + aOff[m][kk]);
#pragma unroll
      for (int n = 0; n < 4; ++n)
        bfr[n] = *(const bf16x8*)((const char*)Bs + bOff[n][kk]);
#pragma unroll
      for (int m = 0; m < MT; ++m)
#pragma unroll
        for (int n = 0; n < 4; ++n)
          acc[m][n] = __builtin_amdgcn_mfma_f32_16x16x32_bf16(af[m], bfr[n], acc[m][n], 0, 0, 0);
    }
    __syncthreads();
  }
#pragma unroll
  for (int m = 0; m < MT; ++m)
#pragma unroll
    for (int n = 0; n < 4; ++n)
#pragma unroll
      for (int r = 0; r < 4; ++r) {
        const int gr = row0 + wr * (MT * 16) + m * 16 + fq * 4 + r;
        const int gc = col0 + wc * 64 + n * 16 + fr;
        storev(&C[(size_t)gr * N + gc], acc[m][n][r]);
      }
}

// ---------------- beta/g projections via split-precision MFMA skinny GEMM
__global__ __launch_bounds__(256) void small_mfma(
    const u16* __restrict__ hhi, const u16* __restrict__ hlo,
    const u16* __restrict__ whi, const u16* __restrict__ wlo,
    const float* __restrict__ A_log, const float* __restrict__ dtb,
    float* __restrict__ bbuf, float* __restrict__ gbuf) {
  extern __shared__ char smc[];
  u16* Ahi = (u16*)smc;
  u16* Alo = (u16*)(smc + 32768);
  float* Red = (float*)(smc + 65536);
  const int tid = threadIdx.x;
  const int row0 = blockIdx.x * 16;
#pragma unroll
  for (int i = 0; i < 8; ++i) {
    const int slot = tid + 256 * i;
    const int r = slot >> 7, s = slot & 127;
    const int ss = s ^ (r & 7);
    const size_t src = (size_t)(row0 + r) * 1024 + (size_t)ss * 8;
    __builtin_amdgcn_global_load_lds(
        (const __attribute__((address_space(1))) void*)(hhi + src),
        (__attribute__((address_space(3))) void*)(Ahi + (size_t)slot * 8), 16, 0, 0);
    __builtin_amdgcn_global_load_lds(
        (const __attribute__((address_space(1))) void*)(hlo + src),
        (__attribute__((address_space(3))) void*)(Alo + (size_t)slot * 8), 16, 0, 0);
  }
  __syncthreads();
  const int w = tid >> 6, lane = tid & 63, fr = lane & 15, fq = lane >> 4;
  f32x4 acc[2] = {};
#pragma unroll
  for (int kk = 0; kk < 8; ++kk) {
    const int s = w * 32 + kk * 4 + fq;
    const size_t k = (size_t)w * 256 + kk * 32 + fq * 8;
    const int aoff = ((fr << 7) + (s ^ (fr & 7))) * 8;
    bf16x8 ah = *(const bf16x8*)(Ahi + aoff);
    bf16x8 al = *(const bf16x8*)(Alo + aoff);
#pragma unroll
    for (int ct = 0; ct < 2; ++ct) {
      const size_t boff = (size_t)(ct * 16 + fr) * 1024 + k;
      bf16x8 bh = *(const bf16x8*)(whi + boff);
      bf16x8 bl = *(const bf16x8*)(wlo + boff);
      acc[ct] = __builtin_amdgcn_mfma_f32_16x16x32_bf16(ah, bh, acc[ct], 0, 0, 0);
      acc[ct] = __builtin_amdgcn_mfma_f32_16x16x32_bf16(ah, bl, acc[ct], 0, 0, 0);
      acc[ct] = __builtin_amdgcn_mfma_f32_16x16x32_bf16(al, bh, acc[ct], 0, 0, 0);
    }
  }
#pragma unroll
  for (int ct = 0; ct < 2; ++ct)
#pragma unroll
    for (int rr = 0; rr < 4; ++rr)
      Red[(w * 16 + fq * 4 + rr) * 33 + ct * 16 + fr] = acc[ct][rr];
  __syncthreads();
  if (tid < 128) {
    const int row = tid >> 3, cg = (tid & 7) * 4;
#pragma unroll
    for (int j = 0; j < 4; ++j) {
      const int col = cg + j;
      const float s = Red[(0 * 16 + row) * 33 + col] + Red[(1 * 16 + row) * 33 + col]
                    + Red[(2 * 16 + row) * 33 + col] + Red[(3 * 16 + row) * 33 + col];
      const int grow = row0 + row;
      if (col < 16) {
        bbuf[grow * NHEAD + col] = 1.f / (1.f + __expf(-s));
      } else {
        const int hh = col - 16;
        const float xs = s + dtb[hh];
        const float sp = (xs > 20.f) ? xs : log1pf(__expf(xs));
        gbuf[grow * NHEAD + hh] = -__expf(A_log[hh]) * sp;
      }
    }
  }
}

// ===================== chunk-parallel gated delta rule (MFMA, 8 waves) ========
__global__ __launch_bounds__(512) void chunk_local(
    const u16* __restrict__ qp, const u16* __restrict__ kp, const u16* __restrict__ vp,
    const float* __restrict__ cq, const float* __restrict__ ck, const float* __restrict__ cv,
    const float* __restrict__ gbuf, const float* __restrict__ bbuf,
    u16* __restrict__ Phi, u16* __restrict__ Plo, u16* __restrict__ Ug,
    u16* __restrict__ Rg, u16* __restrict__ Yg) {
  __shared__ __align__(16) u16 Kb[64 * 64];
  __shared__ __align__(16) u16 Qb[64 * 64];
  __shared__ __align__(16) u16 K2T[64 * 64];
  __shared__ __align__(16) u16 KWt[64 * 64];   // -> uTh
  __shared__ __align__(16) u16 Vt[64 * 64];    // -> Gb
  __shared__ __align__(16) u16 Zb[64 * 64];
  __shared__ __align__(16) u16 Zt[64 * 64];
  __shared__ __align__(16) u16 Mb[64 * 72];    // -> WTh
  __shared__ __align__(16) float Cb[16 * 64];
  __shared__ float bcs[64], bet[64], e2v[64], Bv[64];
  u16* WTh = Mb;
  u16* uTh = KWt;
  u16* Gb  = Vt;

  const int bid = blockIdx.x;
  const int c = bid & 31, bh = bid >> 5;
  const int b = bh >> 4, h = bh & 15;
  const int tid = threadIdx.x;

  {
    int* zp = (int*)Zt;
#pragma unroll
    for (int i = 0; i < 4; ++i) zp[tid + 512 * i] = 0;
  }
  if (tid < 64) {
    const size_t gi = (size_t)((b * TLEN + c * 64) + tid) * NHEAD + h;
    bet[tid] = bbuf[gi];
    float v = gbuf[gi];
#pragma unroll
    for (int ofs = 1; ofs < 64; ofs <<= 1) {
      float tt = __shfl_up(v, ofs);
      if (tid >= ofs) v += tt;
    }
    bcs[tid] = v;
  }
  __syncthreads();
  if (tid < 64) {
    const float blast = bcs[63];
    Bv[tid]  = __expf(bcs[tid]);
    e2v[tid] = __expf(blast - bcs[tid]);
  }
  __syncthreads();

  // ---- staging with fused conv+silu+l2norm (32 rows/iter, 2 iters)
  {
    const int dq = (tid & 15) * 4;
    const int col = h * 64 + dq;
    float4 wq4[4], wk4[4], wv4[4];
#pragma unroll
    for (int jj = 0; jj < 4; ++jj) {
      wq4[jj] = *(const float4*)(cq + (size_t)(col + jj) * 4);
      wk4[jj] = *(const float4*)(ck + (size_t)(col + jj) * 4);
      wv4[jj] = *(const float4*)(cv + (size_t)(col + jj) * 4);
    }
#pragma unroll
    for (int i = 0; i < 2; ++i) {
      const int r = i * 32 + (tid >> 4);
      const int tcur = c * 64 + r;
      ushort4 xq[4], xk[4], xv[4];
#pragma unroll
      for (int m = 0; m < 4; ++m) {
        const int tt = tcur - 3 + m;
        if (tt >= 0) {
          const size_t a = (size_t)(b * TLEN + tt) * HD + col;
          xq[m] = *(const ushort4*)(qp + a);
          xk[m] = *(const ushort4*)(kp + a);
          xv[m] = *(const ushort4*)(vp + a);
        } else {
          xq[m] = ushort4{0, 0, 0, 0}; xk[m] = xq[m]; xv[m] = xq[m];
        }
      }
      float yq[4], yk[4], yv[4];
      float ssq = 0.f, ssk = 0.f;
#pragma unroll
      for (int jj = 0; jj < 4; ++jj) {
        float aq = wq4[jj].x * bf2f(((const u16*)&xq[0])[jj]) +
                   wq4[jj].y * bf2f(((const u16*)&xq[1])[jj]) +
                   wq4[jj].z * bf2f(((const u16*)&xq[2])[jj]) +
                   wq4[jj].w * bf2f(((const u16*)&xq[3])[jj]);
        float ak = wk4[jj].x * bf2f(((const u16*)&xk[0])[jj]) +
                   wk4[jj].y * bf2f(((const u16*)&xk[1])[jj]) +
                   wk4[jj].z * bf2f(((const u16*)&xk[2])[jj]) +
                   wk4[jj].w * bf2f(((const u16*)&xk[3])[jj]);
        float av = wv4[jj].x * bf2f(((const u16*)&xv[0])[jj]) +
                   wv4[jj].y * bf2f(((const u16*)&xv[1])[jj]) +
                   wv4[jj].z * bf2f(((const u16*)&xv[2])[jj]) +
                   wv4[jj].w * bf2f(((const u16*)&xv[3])[jj]);
        yq[jj] = aq / (1.f + __expf(-aq));
        yk[jj] = ak / (1.f + __expf(-ak));
        yv[jj] = av / (1.f + __expf(-av));
        ssq += yq[jj] * yq[jj];
        ssk += yk[jj] * yk[jj];
      }
      ssq += __shfl_xor(ssq, 1); ssq += __shfl_xor(ssq, 2);
      ssq += __shfl_xor(ssq, 4); ssq += __shfl_xor(ssq, 8);
      ssk += __shfl_xor(ssk, 1); ssk += __shfl_xor(ssk, 2);
      ssk += __shfl_xor(ssk, 4); ssk += __shfl_xor(ssk, 8);
      const float qsc = rsqrtf(ssq + 1e-6f) * 0.125f;
      const float ksc = rsqrtf(ssk + 1e-6f);
      const float bR = bet[r], e2R = e2v[r], wscR = bR * Bv[r];
      float kvf[4];
#pragma unroll
      for (int jj = 0; jj < 4; ++jj) kvf[jj] = yk[jj] * ksc;
      uint2 qo2, ko2;
      qo2.x = pkbf(yq[0] * qsc, yq[1] * qsc);
      qo2.y = pkbf(yq[2] * qsc, yq[3] * qsc);
      ko2.x = pkbf(kvf[0], kvf[1]);
      ko2.y = pkbf(kvf[2], kvf[3]);
      *(uint2*)((char*)Qb + swz(r, dq)) = qo2;
      *(uint2*)((char*)Kb + swz(r, dq)) = ko2;
      const unsigned k2a = pkbf(kvf[0] * e2R, kvf[1] * e2R);
      const unsigned k2b = pkbf(kvf[2] * e2R, kvf[3] * e2R);
      const unsigned kwa = pkbf(kvf[0] * wscR, kvf[1] * wscR);
      const unsigned kwb = pkbf(kvf[2] * wscR, kvf[3] * wscR);
      const unsigned vta = pkbf(yv[0] * bR, yv[1] * bR);
      const unsigned vtb = pkbf(yv[2] * bR, yv[3] * bR);
      *(u16*)((char*)K2T + swz(dq + 0, r)) = (u16)k2a;
      *(u16*)((char*)K2T + swz(dq + 1, r)) = (u16)(k2a >> 16);
      *(u16*)((char*)K2T + swz(dq + 2, r)) = (u16)k2b;
      *(u16*)((char*)K2T + swz(dq + 3, r)) = (u16)(k2b >> 16);
      *(u16*)((char*)KWt + swz(dq + 0, r)) = (u16)kwa;
      *(u16*)((char*)KWt + swz(dq + 1, r)) = (u16)(kwa >> 16);
      *(u16*)((char*)KWt + swz(dq + 2, r)) = (u16)kwb;
      *(u16*)((char*)KWt + swz(dq + 3, r)) = (u16)(kwb >> 16);
      *(u16*)((char*)Vt + swz(dq + 0, r)) = (u16)vta;
      *(u16*)((char*)Vt + swz(dq + 1, r)) = (u16)(vta >> 16);
      *(u16*)((char*)Vt + swz(dq + 2, r)) = (u16)vtb;
      *(u16*)((char*)Vt + swz(dq + 3, r)) = (u16)(vtb >> 16);
    }
  }
  __syncthreads();

  const int w = tid >> 6, lane = tid & 63, fr = lane & 15, fq = lane >> 4;
  const int wr = w >> 1;                 // row block 0..3
  const int tc0 = (w & 1) * 2;           // column half: 2 sub-tiles per wave
  const int t0r = wr * 16 + fq * 4;
  // ---- A = K K^T via MFMA -> masked M (bf16, stride 72)
  {
    bf16x8 ka0 = frag(Kb, wr * 16 + fr, fq);
    bf16x8 ka1 = frag(Kb, wr * 16 + fr, 4 + fq);
#pragma unroll
    for (int j = 0; j < 2; ++j) {
      const int tc = tc0 + j;
      bf16x8 kb0 = frag(Kb, tc * 16 + fr, fq);
      bf16x8 kb1 = frag(Kb, tc * 16 + fr, 4 + fq);
      f32x4 a = {};
      a = __builtin_amdgcn_mfma_f32_16x16x32_bf16(ka0, kb0, a, 0, 0, 0);
      a = __builtin_amdgcn_mfma_f32_16x16x32_bf16(ka1, kb1, a, 0, 0, 0);
      const int s = tc * 16 + fr;
      float mv[4];
#pragma unroll
      for (int rr = 0; rr < 4; ++rr) {
        const int t = t0r + rr;
        mv[rr] = (s < t) ? bet[t] * __expf(bcs[t] - bcs[s]) * a[rr] : 0.f;
      }
      const unsigned m01 = pkbf(mv[0], mv[1]), m23 = pkbf(mv[2], mv[3]);
      Mb[(t0r + 0) * 72 + s] = (u16)m01;
      Mb[(t0r + 1) * 72 + s] = (u16)(m01 >> 16);
      Mb[(t0r + 2) * 72 + s] = (u16)m23;
      Mb[(t0r + 3) * 72 + s] = (u16)(m23 >> 16);
    }
  }
  __syncthreads();

  // ---- BLOCKED solve M Minv = I (4 blocks of 16 rows); waves 4-7 idle at MFMA
#pragma unroll 1
  for (int bi = 0; bi < 4; ++bi) {
    if (w < 4) {
      const char* mrow = (const char*)Mb + (size_t)(bi * 16 + fr) * 144;
      bf16x8 ma0 = *(const bf16x8*)(mrow + fq * 16);
      bf16x8 ma1 = *(const bf16x8*)(mrow + 64 + fq * 16);
      bf16x8 zt0 = frag(Zt, w * 16 + fr, fq);
      bf16x8 zt1 = frag(Zt, w * 16 + fr, 4 + fq);
      f32x4 a = {};
      a = __builtin_amdgcn_mfma_f32_16x16x32_bf16(ma0, zt0, a, 0, 0, 0);
      a = __builtin_amdgcn_mfma_f32_16x16x32_bf16(ma1, zt1, a, 0, 0, 0);
#pragma unroll
      for (int rr = 0; rr < 4; ++rr)
        Cb[(fq * 4 + rr) * 64 + w * 16 + fr] = a[rr];
    }
    __syncthreads();
    if (tid < 64) {
      const int j = tid;
      float z[16];
#pragma unroll
      for (int t = 0; t < 16; ++t) {
        float acc = ((bi * 16 + t) == j ? 1.f : 0.f) - Cb[t * 64 + j];
        const u16* mrow = Mb + (size_t)(bi * 16 + t) * 72 + bi * 16;
#pragma unroll
        for (int s = 0; s < t; ++s) acc -= bf2f(mrow[s]) * z[s];
        z[t] = acc;
      }
      unsigned zw[8];
#pragma unroll
      for (int t2 = 0; t2 < 8; ++t2) zw[t2] = pkbf(z[2 * t2], z[2 * t2 + 1]);
#pragma unroll
      for (int t2 = 0; t2 < 8; ++t2) {
        *(u16*)((char*)Zb + swz(bi * 16 + 2 * t2, j)) = (u16)zw[t2];
        *(u16*)((char*)Zb + swz(bi * 16 + 2 * t2 + 1, j)) = (u16)(zw[t2] >> 16);
      }
#pragma unroll
      for (int t4 = 0; t4 < 4; ++t4) {
        uint2 zz; zz.x = zw[2 * t4]; zz.y = zw[2 * t4 + 1];
        *(uint2*)((char*)Zt + swz(j, bi * 16 + t4 * 4)) = zz;
      }
    }
    __syncthreads();
  }

  // ---- W = Minv*RHSw, u = Minv*RHSv (transposed out), G = QK^T
  f32x4 accW[2], accu[2], accG[2];
  {
    bf16x8 kw0 = frag(KWt, wr * 16 + fr, fq), kw1 = frag(KWt, wr * 16 + fr, 4 + fq);
    bf16x8 vt0 = frag(Vt,  wr * 16 + fr, fq), vt1 = frag(Vt,  wr * 16 + fr, 4 + fq);
    bf16x8 qa0 = frag(Qb,  wr * 16 + fr, fq), qa1 = frag(Qb,  wr * 16 + fr, 4 + fq);
#pragma unroll
    for (int j = 0; j < 2; ++j) {
      const int tc = tc0 + j;
      bf16x8 z0 = frag(Zb, tc * 16 + fr, fq), z1 = frag(Zb, tc * 16 + fr, 4 + fq);
      bf16x8 kb0 = frag(Kb, tc * 16 + fr, fq), kb1 = frag(Kb, tc * 16 + fr, 4 + fq);
      f32x4 aw = {}, au = {}, ag = {};
      aw = __builtin_amdgcn_mfma_f32_16x16x32_bf16(kw0, z0, aw, 0, 0, 0);
      aw = __builtin_amdgcn_mfma_f32_16x16x32_bf16(kw1, z1, aw, 0, 0, 0);
      au = __builtin_amdgcn_mfma_f32_16x16x32_bf16(vt0, z0, au, 0, 0, 0);
      au = __builtin_amdgcn_mfma_f32_16x16x32_bf16(vt1, z1, au, 0, 0, 0);
      ag = __builtin_amdgcn_mfma_f32_16x16x32_bf16(qa0, kb0, ag, 0, 0, 0);
      ag = __builtin_amdgcn_mfma_f32_16x16x32_bf16(qa1, kb1, ag, 0, 0, 0);
      accW[j] = aw; accu[j] = au; accG[j] = ag;
    }
  }
  __syncthreads();
#pragma unroll
  for (int j = 0; j < 2; ++j) {
    const int tc = tc0 + j;
    const int co = tc * 16 + fr;
    const unsigned w01 = pkbf(accW[j][0], accW[j][1]);
    const unsigned w23 = pkbf(accW[j][2], accW[j][3]);
    const unsigned u01 = pkbf(accu[j][0], accu[j][1]);
    const unsigned u23 = pkbf(accu[j][2], accu[j][3]);
    float gv[4];
#pragma unroll
    for (int rr = 0; rr < 4; ++rr) {
      const int ro = t0r + rr;
      gv[rr] = (co <= ro) ? accG[j][rr] * __expf(bcs[ro] - bcs[co]) : 0.f;
    }
    const unsigned g01 = pkbf(gv[0], gv[1]), g23 = pkbf(gv[2], gv[3]);
    *(u16*)((char*)WTh + swz(t0r + 0, co)) = (u16)w01;
    *(u16*)((char*)WTh + swz(t0r + 1, co)) = (u16)(w01 >> 16);
    *(u16*)((char*)WTh + swz(t0r + 2, co)) = (u16)w23;
    *(u16*)((char*)WTh + swz(t0r + 3, co)) = (u16)(w23 >> 16);
    *(u16*)((char*)uTh + swz(t0r + 0, co)) = (u16)u01;
    *(u16*)((char*)uTh + swz(t0r + 1, co)) = (u16)(u01 >> 16);
    *(u16*)((char*)uTh + swz(t0r + 2, co)) = (u16)u23;
    *(u16*)((char*)uTh + swz(t0r + 3, co)) = (u16)(u23 >> 16);
    *(u16*)((char*)Gb + swz(t0r + 0, co)) = (u16)g01;
    *(u16*)((char*)Gb + swz(t0r + 1, co)) = (u16)(g01 >> 16);
    *(u16*)((char*)Gb + swz(t0r + 2, co)) = (u16)g23;
    *(u16*)((char*)Gb + swz(t0r + 3, co)) = (u16)(g23 >> 16);
  }
  __syncthreads();

  // ---- P,U,R,Y via MFMA + epilogue (P hi/lo bf16; U,R,Y bf16; pk everywhere)
  {
    bf16x8 k20 = frag(K2T, wr * 16 + fr, fq), k21 = frag(K2T, wr * 16 + fr, 4 + fq);
    bf16x8 g0  = frag(Gb,  wr * 16 + fr, fq), g1  = frag(Gb,  wr * 16 + fr, 4 + fq);
    const float bl = Bv[63];
    const size_t off = (size_t)bid * 4096;
#pragma unroll
    for (int j = 0; j < 2; ++j) {
      const int tc = tc0 + j;
      bf16x8 w0 = frag(WTh, tc * 16 + fr, fq), w1 = frag(WTh, tc * 16 + fr, 4 + fq);
      bf16x8 u0 = frag(uTh, tc * 16 + fr, fq), u1 = frag(uTh, tc * 16 + fr, 4 + fq);
      f32x4 aP = {}, aU = {}, aR = {}, aY = {};
      aP = __builtin_amdgcn_mfma_f32_16x16x32_bf16(k20, w0, aP, 0, 0, 0);
      aP = __builtin_amdgcn_mfma_f32_16x16x32_bf16(k21, w1, aP, 0, 0, 0);
      aU = __builtin_amdgcn_mfma_f32_16x16x32_bf16(k20, u0, aU, 0, 0, 0);
      aU = __builtin_amdgcn_mfma_f32_16x16x32_bf16(k21, u1, aU, 0, 0, 0);
      aR = __builtin_amdgcn_mfma_f32_16x16x32_bf16(g0, w0, aR, 0, 0, 0);
      aR = __builtin_amdgcn_mfma_f32_16x16x32_bf16(g1, w1, aR, 0, 0, 0);
      aY = __builtin_amdgcn_mfma_f32_16x16x32_bf16(g0, u0, aY, 0, 0, 0);
      aY = __builtin_amdgcn_mfma_f32_16x16x32_bf16(g1, u1, aY, 0, 0, 0);
      const int cb = tc * 16 + fr;
      float pv[4], rv[4];
#pragma unroll
      for (int rr = 0; rr < 4; ++rr) {
        const int ar = t0r + rr;
        pv[rr] = ((ar == cb) ? bl : 0.f) - aP[rr];
        const float qv = bf2f(*(const u16*)((const char*)Qb + swz(ar, cb)));
        rv[rr] = Bv[ar] * qv - aR[rr];
      }
      const unsigned p01 = pkbf(pv[0], pv[1]), p23 = pkbf(pv[2], pv[3]);
      const float l0 = pv[0] - bf2f((u16)p01), l1 = pv[1] - bf2f((u16)(p01 >> 16));
      const float l2 = pv[2] - bf2f((u16)p23), l3 = pv[3] - bf2f((u16)(p23 >> 16));
      const unsigned q01 = pkbf(l0, l1), q23 = pkbf(l2, l3);
      const unsigned u01 = pkbf(aU[0], aU[1]), u23 = pkbf(aU[2], aU[3]);
      const unsigned r01 = pkbf(rv[0], rv[1]), r23 = pkbf(rv[2], rv[3]);
      const unsigned y01 = pkbf(aY[0], aY[1]), y23 = pkbf(aY[2], aY[3]);
      const size_t o0 = off + (size_t)(t0r + 0) * 64 + cb;
      const size_t o1 = off + (size_t)(t0r + 1) * 64 + cb;
      const size_t o2 = off + (size_t)(t0r + 2) * 64 + cb;
      const size_t o3 = off + (size_t)(t0r + 3) * 64 + cb;
      Phi[o0] = (u16)p01; Phi[o1] = (u16)(p01 >> 16);
      Phi[o2] = (u16)p23; Phi[o3] = (u16)(p23 >> 16);
      Plo[o0] = (u16)q01; Plo[o1] = (u16)(q01 >> 16);
      Plo[o2] = (u16)q23; Plo[o3] = (u16)(q23 >> 16);
      Ug[o0] = (u16)u01; Ug[o1] = (u16)(u01 >> 16);
      Ug[o2] = (u16)u23; Ug[o3] = (u16)(u23 >> 16);
      Rg[o0] = (u16)r01; Rg[o1] = (u16)(r01 >> 16);
      Rg[o2] = (u16)r23; Rg[o3] = (u16)(r23 >> 16);
      Yg[o0] = (u16)y01; Yg[o1] = (u16)(y01 >> 16);
      Yg[o2] = (u16)y23; Yg[o3] = (u16)(y23 >> 16);
    }
  }
}

// ---- phase B: S_{c+1} = P_c S_c + U_c via split-precision MFMA.
// 32 blocks, 4 waves. S^T hi/lo in LDS (dbuf). Sst stored TRANSPOSED
// ([dv][dk]) so the store is a uint2 and chunk_out can MFMA directly.
__global__ __launch_bounds__(256) void state_step(
    const u16* __restrict__ Phi, const u16* __restrict__ Plo,
    const u16* __restrict__ Ug, u16* __restrict__ Sst) {
  __shared__ __align__(16) u16 Sth[2][64 * 64];
  __shared__ __align__(16) u16 Stl[2][64 * 64];
  const int bh = blockIdx.x;
  const int tid = threadIdx.x;
  const int w = tid >> 6, lane = tid & 63, fr = lane & 15, fq = lane >> 4;
  const int ar0 = w * 16 + fq * 4;
  const size_t bbase = (size_t)bh * 32 * 4096;
  {
    int* p0 = (int*)&Sth[0][0];
    int* p1 = (int*)&Stl[0][0];
#pragma unroll
    for (int i = 0; i < 8; ++i) { p0[tid + 256 * i] = 0; p1[tid + 256 * i] = 0; }
    const ushort4 z4 = {0, 0, 0, 0};
#pragma unroll
    for (int i = 0; i < 4; ++i)
      *(ushort4*)(Sst + bbase + (size_t)tid * 16 + i * 4) = z4;  // S_in[0] = 0
  }
  bf16x8 ph[2], pl[2];
  float uin[4][4];
#pragma unroll
  for (int kk = 0; kk < 2; ++kk) {
    const size_t ao = bbase + (size_t)(w * 16 + fr) * 64 + (kk * 4 + fq) * 8;
    ph[kk] = *(const bf16x8*)(Phi + ao);
    pl[kk] = *(const bf16x8*)(Plo + ao);
  }
#pragma unroll
  for (int tc = 0; tc < 4; ++tc)
#pragma unroll
    for (int rr = 0; rr < 4; ++rr)
      uin[tc][rr] = bf2f(Ug[bbase + (size_t)(ar0 + rr) * 64 + tc * 16 + fr]);
  __syncthreads();
  int cur = 0;
  for (int c = 0; c < 32; ++c) {
    f32x4 acc[4];
    bf16x8 phc[2] = {ph[0], ph[1]}, plc[2] = {pl[0], pl[1]};
#pragma unroll
    for (int tc = 0; tc < 4; ++tc)
#pragma unroll
      for (int rr = 0; rr < 4; ++rr) acc[tc][rr] = uin[tc][rr];
    if (c + 1 < 32) {
      const size_t off = bbase + (size_t)(c + 1) * 4096;
#pragma unroll
      for (int kk = 0; kk < 2; ++kk) {
        const size_t ao = off + (size_t)(w * 16 + fr) * 64 + (kk * 4 + fq) * 8;
        ph[kk] = *(const bf16x8*)(Phi + ao);
        pl[kk] = *(const bf16x8*)(Plo + ao);
      }
#pragma unroll
      for (int tc = 0; tc < 4; ++tc)
#pragma unroll
        for (int rr = 0; rr < 4; ++rr)
          uin[tc][rr] = bf2f(Ug[off + (size_t)(ar0 + rr) * 64 + tc * 16 + fr]);
    }
#pragma unroll
    for (int tc = 0; tc < 4; ++tc) {
#pragma unroll
      for (int kk = 0; kk < 2; ++kk) {
        bf16x8 sh = frag(&Sth[cur][0], tc * 16 + fr, kk * 4 + fq);
        bf16x8 sl = frag(&Stl[cur][0], tc * 16 + fr, kk * 4 + fq);
        acc[tc] = __builtin_amdgcn_mfma_f32_16x16x32_bf16(phc[kk], sh, acc[tc], 0, 0, 0);
        acc[tc] = __builtin_amdgcn_mfma_f32_16x16x32_bf16(phc[kk], sl, acc[tc], 0, 0, 0);
        acc[tc] = __builtin_amdgcn_mfma_f32_16x16x32_bf16(plc[kk], sh, acc[tc], 0, 0, 0);
      }
    }
    const int nxt = cur ^ 1;
    const size_t offn = bbase + (size_t)(c + 1) * 4096;
#pragma unroll
    for (int tc = 0; tc < 4; ++tc) {
      const int col = tc * 16 + fr;                // dv
      const unsigned h01 = pkbf(acc[tc][0], acc[tc][1]);
      const unsigned h23 = pkbf(acc[tc][2], acc[tc][3]);
      const float l0 = acc[tc][0] - bf2f((u16)h01);
      const float l1 = acc[tc][1] - bf2f((u16)(h01 >> 16));
      const float l2 = acc[tc][2] - bf2f((u16)h23);
      const float l3 = acc[tc][3] - bf2f((u16)(h23 >> 16));
      uint2 hh; hh.x = h01; hh.y = h23;
      uint2 ll; ll.x = pkbf(l0, l1); ll.y = pkbf(l2, l3);
      *(uint2*)((char*)&Sth[nxt][0] + swz(col, ar0)) = hh;
      *(uint2*)((char*)&Stl[nxt][0] + swz(col, ar0)) = ll;
      if (c + 1 < 32)
        *(uint2*)(Sst + offn + (size_t)col * 64 + ar0) = hh;  // transposed [dv][dk]
    }
    cur = nxt;
    __syncthreads();
  }
}

// ---- phase C: O = R S_in + Y via MFMA (R [t][dk], Sst^T [dv][dk], both
// straight from global), fused gated-RMSNorm epilogue -> bf16. No LDS.
__global__ __launch_bounds__(256) void chunk_out(
    const u16* __restrict__ Rg, const u16* __restrict__ Yg,
    const u16* __restrict__ SstT, const u16* __restrict__ gatep,
    const float* __restrict__ norm_w, u16* __restrict__ outb) {
  const int bid = blockIdx.x;
  const int c = bid & 31, bh = bid >> 5, b = bh >> 4, h = bh & 15;
  const int tid = threadIdx.x;
  const int w = tid >> 6, lane = tid & 63, fr = lane & 15, fq = lane >> 4;
  const int ar0 = w * 16 + fq * 4;
  const size_t off = (size_t)bid * 4096;
  bf16x8 ra[2];
#pragma unroll
  for (int kk = 0; kk < 2; ++kk)
    ra[kk] = *(const bf16x8*)(Rg + off + (size_t)(w * 16 + fr) * 64 + (kk * 4 + fq) * 8);
  f32x4 acc[4];
#pragma unroll
  for (int tc = 0; tc < 4; ++tc)
#pragma unroll
    for (int rr = 0; rr < 4; ++rr)
      acc[tc][rr] = bf2f(Yg[off + (size_t)(ar0 + rr) * 64 + tc * 16 + fr]);
#pragma unroll
  for (int tc = 0; tc < 4; ++tc)
#pragma unroll
    for (int kk = 0; kk < 2; ++kk) {
      bf16x8 sb = *(const bf16x8*)(SstT + off + (size_t)(tc * 16 + fr) * 64 + (kk * 4 + fq) * 8);
      acc[tc] = __builtin_amdgcn_mfma_f32_16x16x32_bf16(ra[kk], sb, acc[tc], 0, 0, 0);
    }
  float nwv[4];
#pragma unroll
  for (int tc = 0; tc < 4; ++tc) nwv[tc] = norm_w[tc * 16 + fr];
  const size_t btbase = (size_t)(b * TLEN + c * 64);
#pragma unroll
  for (int rr = 0; rr < 4; ++rr) {
    const int t = ar0 + rr;
    float rs = acc[0][rr] * acc[0][rr] + acc[1][rr] * acc[1][rr]
             + acc[2][rr] * acc[2][rr] + acc[3][rr] * acc[3][rr];
    rs += __shfl_xor(rs, 1); rs += __shfl_xor(rs, 2);
    rs += __shfl_xor(rs, 4); rs += __shfl_xor(rs, 8);
    const float inv = rsqrtf(rs * (1.0f / 64.0f) + 1e-5f);
    const size_t rowoff = (btbase + t) * 1024 + h * 64;
#pragma unroll
    for (int tc = 0; tc < 4; ++tc) {
      const int j = tc * 16 + fr;
      const float g = bf2f(gatep[rowoff + j]);
      const float val = acc[tc][rr] * inv * nwv[tc] * (g / (1.f + __expf(-g)));
      outb[rowoff + j] = f2bf(val);
    }
  }
}

extern "C" void kernel_launch(void* const* d_in, const int* in_sizes, int n_in,
                              void* d_out, int out_size, void* d_ws, size_t ws_size,
                              hipStream_t stream) {
  const float* hidden = (const float*)d_in[0];
  const float* Wq     = (const float*)d_in[1];
  const float* Wk     = (const float*)d_in[2];
  const float* Wv     = (const float*)d_in[3];
  const float* cq     = (const float*)d_in[4];
  const float* ck     = (const float*)d_in[5];
  const float* cv     = (const float*)d_in[6];
  const float* Wb     = (const float*)d_in[7];
  const float* Wa     = (const float*)d_in[8];
  const float* A_log  = (const float*)d_in[9];
  const float* dtb    = (const float*)d_in[10];
  const float* Wg     = (const float*)d_in[11];
  const float* nw     = (const float*)d_in[12];
  const float* Wo     = (const float*)d_in[13];

  char* p = (char*)d_ws;
  const size_t MB = 1u << 20;
  u16* h_bf = (u16*)(p + 0 * MB);     // 8 MB (dead after small_mfma)
  u16* wq_b = (u16*)(p + 8 * MB);     // 2 MB
  u16* wk_b = (u16*)(p + 10 * MB);
  u16* wv_b = (u16*)(p + 12 * MB);
  u16* wg_b = (u16*)(p + 14 * MB);
  u16* Phi = (u16*)(p + 0 * MB);      // 8 MB bf16, aliases h_bf (dead then)
  u16* Plo = (u16*)(p + 8 * MB);      // 8 MB bf16, aliases wq..wg (dead then)
  u16* wo_b = (u16*)(p + 16 * MB);    // 2 MB (live till end)
  u16* qp_b = (u16*)(p + 18 * MB);    // 8 MB
  u16* kp_b = (u16*)(p + 26 * MB);    // 8 MB
  u16* vp_b = (u16*)(p + 34 * MB);    // 8 MB
  u16* gp_b = (u16*)(p + 42 * MB);    // 8 MB (live till chunk_out)
  u16*   of_b = vp_b;                 // 8 MB, aliases vp (dead after chunk_local)
  float* gbuf = (float*)(p + 50 * MB);
  float* bbuf = (float*)(p + 50 * MB + 262144);
  u16* Ug  = (u16*)(p + 51 * MB);     // 8 MB bf16
  u16* Rg  = (u16*)(p + 59 * MB);     // 8 MB bf16
  u16* Yg  = (u16*)(p + 67 * MB);     // 8 MB bf16
  u16* Sst = (u16*)(p + 75 * MB);     // 8 MB bf16 (transposed per chunk)
  u16* hlo_b = (u16*)(p + 83 * MB);   // 8 MB
  u16* wba_h = (u16*)(p + 91 * MB);   // 64 KB
  u16* wba_l = (u16*)(p + 91 * MB + 65536);  // 64 KB (total ~91.2 MB)

  cvt_all<<<9248, 256, 0, stream>>>(hidden, Wq, Wk, Wv, Wg, Wo, Wb, Wa,
                                    h_bf, hlo_b, wq_b, wk_b, wv_b, wg_b, wo_b,
                                    wba_h, wba_l);

  gemm_big<<<dim3(8, 16, 4), 256, 0, stream>>>(
      h_bf, wq_b, wk_b, wv_b, wg_b, qp_b, kp_b, vp_b, gp_b, 4096, 1024, 1024);

  const int sm_lds = 65536 + 8448;
  hipFuncSetAttribute((const void*)small_mfma,
                      hipFuncAttributeMaxDynamicSharedMemorySize, sm_lds);
  small_mfma<<<256, 256, sm_lds, stream>>>(h_bf, hlo_b, wba_h, wba_l,
                                           A_log, dtb, bbuf, gbuf);

  chunk_local<<<1024, 512, 0, stream>>>(qp_b, kp_b, vp_b, cq, ck, cv,
                                        gbuf, bbuf, Phi, Plo, Ug, Rg, Yg);
  state_step<<<32, 256, 0, stream>>>(Phi, Plo, Ug, Sst);
  chunk_out<<<1024, 256, 0, stream>>>(Rg, Yg, Sst, gp_b, nw, of_b);

  gemm_lin<float, 2><<<dim3(8, 64, 1), 256, 0, stream>>>(
      of_b, wo_b, (float*)d_out, 4096, 1024, 1024);
}

// Round 12
// 164.773 us; speedup vs baseline: 10.2901x; 1.0220x over previous
//
#include <hip/hip_runtime.h>
#include <hip/hip_bf16.h>

typedef unsigned short u16;
typedef __attribute__((ext_vector_type(4))) float f32x4;
typedef __attribute__((ext_vector_type(8))) short bf16x8;

#define TLEN 2048
#define NHEAD 16
#define HD 1024

__device__ inline u16 f2bf(float f) {
  unsigned x = __float_as_uint(f);
  return (u16)((x + 0x7fffu + ((x >> 16) & 1u)) >> 16);
}
__device__ inline float bf2f(u16 u) { return __uint_as_float(((unsigned)u) << 16); }

// packed f32x2 -> bf16x2 (low half = first operand). 1 inst vs ~8.
__device__ inline unsigned pkbf(float lo, float hi) {
  unsigned r;
  asm("v_cvt_pk_bf16_f32 %0, %1, %2" : "=v"(r) : "v"(lo), "v"(hi));
  return r;
}

// swizzle for [rows][64 bf16 = 128B] LDS tiles; XOR spreads both row&7
// and row>>3 so transposed (fixed-col) writes don't collide 8-way.
__device__ inline int rowx(int row) { return (row ^ (row >> 3)) & 7; }
__device__ inline int swz(int row, int col) {
  return (row << 7) + (((col >> 3) ^ rowx(row)) << 4) + ((col & 7) << 1);
}
__device__ inline bf16x8 frag(const u16* base, int row, int kslot) {
  return *(const bf16x8*)((const char*)base + (row << 7) +
                          ((kslot ^ rowx(row)) << 4));
}

// ------------------------------------------------- fused fp32 -> bf16 converts
__global__ __launch_bounds__(256) void cvt_all(
    const float* __restrict__ h,  const float* __restrict__ wq,
    const float* __restrict__ wk, const float* __restrict__ wv,
    const float* __restrict__ wg, const float* __restrict__ wo,
    const float* __restrict__ Wb, const float* __restrict__ Wa,
    u16* __restrict__ dh,  u16* __restrict__ dhlo,
    u16* __restrict__ dwq, u16* __restrict__ dwk,
    u16* __restrict__ dwv, u16* __restrict__ dwg, u16* __restrict__ dwo,
    u16* __restrict__ dwba_h, u16* __restrict__ dwba_l) {
  const int b = blockIdx.x;
  if (b < 4096) {
    const size_t i = (size_t)b * 256 + threadIdx.x;
    float4 v = *(const float4*)(h + i * 4);
    ushort4 hi, lo;
    hi.x = f2bf(v.x); lo.x = f2bf(v.x - bf2f(hi.x));
    hi.y = f2bf(v.y); lo.y = f2bf(v.y - bf2f(hi.y));
    hi.z = f2bf(v.z); lo.z = f2bf(v.z - bf2f(hi.z));
    hi.w = f2bf(v.w); lo.w = f2bf(v.w - bf2f(hi.w));
    *(ushort4*)(dh + i * 4) = hi;
    *(ushort4*)(dhlo + i * 4) = lo;
  } else if (b < 9216) {
    const int wsel = (b - 4096) >> 10;
    const size_t i = (size_t)((b - 4096) & 1023) * 256 + threadIdx.x;
    const float* s; u16* d;
    switch (wsel) {
      case 0: s = wq; d = dwq; break;
      case 1: s = wk; d = dwk; break;
      case 2: s = wv; d = dwv; break;
      case 3: s = wg; d = dwg; break;
      default: s = wo; d = dwo; break;
    }
    float4 v = *(const float4*)(s + i * 4);
    ushort4 u;
    u.x = f2bf(v.x); u.y = f2bf(v.y); u.z = f2bf(v.z); u.w = f2bf(v.w);
    *(ushort4*)(d + i * 4) = u;
  } else {
    const size_t i = (size_t)(b - 9216) * 256 + threadIdx.x;
    const size_t flat = i * 4;
    const float* src = (flat < 16384) ? (Wb + flat) : (Wa + (flat - 16384));
    float4 v = *(const float4*)src;
    ushort4 hi, lo;
    hi.x = f2bf(v.x); lo.x = f2bf(v.x - bf2f(hi.x));
    hi.y = f2bf(v.y); lo.y = f2bf(v.y - bf2f(hi.y));
    hi.z = f2bf(v.z); lo.z = f2bf(v.z - bf2f(hi.z));
    hi.w = f2bf(v.w); lo.w = f2bf(v.w - bf2f(hi.w));
    *(ushort4*)(dwba_h + flat) = hi;
    *(ushort4*)(dwba_l + flat) = lo;
  }
}

// ---------------- 256x128-tile GEMM (wave-tile 64x128): C = A*W^T
// OutT = u16 (bf16, pk-packed epilogue) or float.
template <typename OutT>
__global__ __launch_bounds__(256, 2) void gemm_big(
    const u16* __restrict__ A,
    const u16* __restrict__ W0p, const u16* __restrict__ W1p,
    const u16* __restrict__ W2p, const u16* __restrict__ W3p,
    OutT* __restrict__ C0, OutT* __restrict__ C1,
    OutT* __restrict__ C2, OutT* __restrict__ C3,
    int M, int N, int K) {
  const u16* W; OutT* C;
  switch (blockIdx.z) {
    case 0: W = W0p; C = C0; break;
    case 1: W = W1p; C = C1; break;
    case 2: W = W2p; C = C2; break;
    default: W = W3p; C = C3; break;
  }
  const int tid = threadIdx.x;
  const int lane = tid & 63, wid = tid >> 6;
  const int fr = lane & 15, fq = lane >> 4;
  const int row0 = blockIdx.y * 256, col0 = blockIdx.x * 128;
  __shared__ __align__(16) u16 As[256 * 64];
  __shared__ __align__(16) u16 Bs[128 * 64];

  const u16* aSrc[8]; const u16* bSrc[4];
#pragma unroll
  for (int it = 0; it < 8; ++it) {
    const int s = it * 256 + tid;
    const int r = s >> 3, cc = s & 7;
    aSrc[it] = A + (size_t)(row0 + r) * K + (cc ^ (r & 7)) * 8;
  }
#pragma unroll
  for (int it = 0; it < 4; ++it) {
    const int s = it * 256 + tid;
    const int r = s >> 3, cc = s & 7;
    bSrc[it] = W + (size_t)(col0 + r) * K + (cc ^ (r & 7)) * 8;
  }
  int aOff[4][2], bOff[8][2];
#pragma unroll
  for (int m = 0; m < 4; ++m)
#pragma unroll
    for (int kk = 0; kk < 2; ++kk) {
      const int ra = wid * 64 + m * 16 + fr;
      aOff[m][kk] = ra * 128 + ((((kk << 2) | fq) ^ (ra & 7)) << 4);
    }
#pragma unroll
  for (int n = 0; n < 8; ++n)
#pragma unroll
    for (int kk = 0; kk < 2; ++kk) {
      const int rb = n * 16 + fr;
      bOff[n][kk] = rb * 128 + ((((kk << 2) | fq) ^ (rb & 7)) << 4);
    }

  f32x4 acc[4][8] = {};
  for (int k0 = 0; k0 < K; k0 += 64) {
#pragma unroll
    for (int it = 0; it < 8; ++it)
      __builtin_amdgcn_global_load_lds(
          (const __attribute__((address_space(1))) void*)(aSrc[it] + k0),
          (__attribute__((address_space(3))) void*)((char*)As + (it * 256 + tid) * 16),
          16, 0, 0);
#pragma unroll
    for (int it = 0; it < 4; ++it)
      __builtin_amdgcn_global_load_lds(
          (const __attribute__((address_space(1))) void*)(bSrc[it] + k0),
          (__attribute__((address_space(3))) void*)((char*)Bs + (it * 256 + tid) * 16),
          16, 0, 0);
    __syncthreads();
#pragma unroll
    for (int kk = 0; kk < 2; ++kk) {
      bf16x8 af[4], bfr[8];
#pragma unroll
      for (int m = 0; m < 4; ++m)
        af[m] = *(const bf16x8*)((const char*)As + aOff[m][kk]);
#pragma unroll
      for (int n = 0; n < 8; ++n)
        bfr[n] = *(const bf16x8*)((const char*)Bs + bOff[n][kk]);
#pragma unroll
      for (int m = 0; m < 4; ++m)
#pragma unroll
        for (int n = 0; n < 8; ++n)
          acc[m][n] = __builtin_amdgcn_mfma_f32_16x16x32_bf16(af[m], bfr[n], acc[m][n], 0, 0, 0);
    }
    __syncthreads();
  }
#pragma unroll
  for (int m = 0; m < 4; ++m)
#pragma unroll
    for (int n = 0; n < 8; ++n) {
      const int gr0 = row0 + wid * 64 + m * 16 + fq * 4;
      const int gc = col0 + n * 16 + fr;
      if constexpr (sizeof(OutT) == 2) {
        const unsigned c01 = pkbf(acc[m][n][0], acc[m][n][1]);
        const unsigned c23 = pkbf(acc[m][n][2], acc[m][n][3]);
        C[(size_t)(gr0 + 0) * N + gc] = (OutT)(u16)c01;
        C[(size_t)(gr0 + 1) * N + gc] = (OutT)(u16)(c01 >> 16);
        C[(size_t)(gr0 + 2) * N + gc] = (OutT)(u16)c23;
        C[(size_t)(gr0 + 3) * N + gc] = (OutT)(u16)(c23 >> 16);
      } else {
#pragma unroll
        for (int r = 0; r < 4; ++r)
          C[(size_t)(gr0 + r) * N + gc] = acc[m][n][r];
      }
    }
}

// ---------------- beta/g projections via split-precision MFMA skinny GEMM
__global__ __launch_bounds__(256) void small_mfma(
    const u16* __restrict__ hhi, const u16* __restrict__ hlo,
    const u16* __restrict__ whi, const u16* __restrict__ wlo,
    const float* __restrict__ A_log, const float* __restrict__ dtb,
    float* __restrict__ bbuf, float* __restrict__ gbuf) {
  extern __shared__ char smc[];
  u16* Ahi = (u16*)smc;
  u16* Alo = (u16*)(smc + 32768);
  float* Red = (float*)(smc + 65536);
  const int tid = threadIdx.x;
  const int row0 = blockIdx.x * 16;
#pragma unroll
  for (int i = 0; i < 8; ++i) {
    const int slot = tid + 256 * i;
    const int r = slot >> 7, s = slot & 127;
    const int ss = s ^ (r & 7);
    const size_t src = (size_t)(row0 + r) * 1024 + (size_t)ss * 8;
    __builtin_amdgcn_global_load_lds(
        (const __attribute__((address_space(1))) void*)(hhi + src),
        (__attribute__((address_space(3))) void*)(Ahi + (size_t)slot * 8), 16, 0, 0);
    __builtin_amdgcn_global_load_lds(
        (const __attribute__((address_space(1))) void*)(hlo + src),
        (__attribute__((address_space(3))) void*)(Alo + (size_t)slot * 8), 16, 0, 0);
  }
  __syncthreads();
  const int w = tid >> 6, lane = tid & 63, fr = lane & 15, fq = lane >> 4;
  f32x4 acc[2] = {};
#pragma unroll
  for (int kk = 0; kk < 8; ++kk) {
    const int s = w * 32 + kk * 4 + fq;
    const size_t k = (size_t)w * 256 + kk * 32 + fq * 8;
    const int aoff = ((fr << 7) + (s ^ (fr & 7))) * 8;
    bf16x8 ah = *(const bf16x8*)(Ahi + aoff);
    bf16x8 al = *(const bf16x8*)(Alo + aoff);
#pragma unroll
    for (int ct = 0; ct < 2; ++ct) {
      const size_t boff = (size_t)(ct * 16 + fr) * 1024 + k;
      bf16x8 bh = *(const bf16x8*)(whi + boff);
      bf16x8 bl = *(const bf16x8*)(wlo + boff);
      acc[ct] = __builtin_amdgcn_mfma_f32_16x16x32_bf16(ah, bh, acc[ct], 0, 0, 0);
      acc[ct] = __builtin_amdgcn_mfma_f32_16x16x32_bf16(ah, bl, acc[ct], 0, 0, 0);
      acc[ct] = __builtin_amdgcn_mfma_f32_16x16x32_bf16(al, bh, acc[ct], 0, 0, 0);
    }
  }
#pragma unroll
  for (int ct = 0; ct < 2; ++ct)
#pragma unroll
    for (int rr = 0; rr < 4; ++rr)
      Red[(w * 16 + fq * 4 + rr) * 33 + ct * 16 + fr] = acc[ct][rr];
  __syncthreads();
  if (tid < 128) {
    const int row = tid >> 3, cg = (tid & 7) * 4;
#pragma unroll
    for (int j = 0; j < 4; ++j) {
      const int col = cg + j;
      const float s = Red[(0 * 16 + row) * 33 + col] + Red[(1 * 16 + row) * 33 + col]
                    + Red[(2 * 16 + row) * 33 + col] + Red[(3 * 16 + row) * 33 + col];
      const int grow = row0 + row;
      if (col < 16) {
        bbuf[grow * NHEAD + col] = 1.f / (1.f + __expf(-s));
      } else {
        const int hh = col - 16;
        const float xs = s + dtb[hh];
        const float sp = (xs > 20.f) ? xs : log1pf(__expf(xs));
        gbuf[grow * NHEAD + hh] = -__expf(A_log[hh]) * sp;
      }
    }
  }
}

// ===================== chunk-parallel gated delta rule (MFMA, 8 waves) ========
__global__ __launch_bounds__(512) void chunk_local(
    const u16* __restrict__ qp, const u16* __restrict__ kp, const u16* __restrict__ vp,
    const float* __restrict__ cq, const float* __restrict__ ck, const float* __restrict__ cv,
    const float* __restrict__ gbuf, const float* __restrict__ bbuf,
    u16* __restrict__ Phi, u16* __restrict__ Plo, u16* __restrict__ Ug,
    u16* __restrict__ Rg, u16* __restrict__ Yg) {
  __shared__ __align__(16) u16 Kb[64 * 64];
  __shared__ __align__(16) u16 Qb[64 * 64];
  __shared__ __align__(16) u16 K2T[64 * 64];
  __shared__ __align__(16) u16 KWt[64 * 64];   // -> uTh
  __shared__ __align__(16) u16 Vt[64 * 64];    // -> Gb
  __shared__ __align__(16) u16 Zb[64 * 64];
  __shared__ __align__(16) u16 Zt[64 * 64];
  __shared__ __align__(16) u16 Mb[64 * 72];    // -> WTh
  __shared__ __align__(16) float Cb[16 * 64];
  __shared__ float bcs[64], bet[64], e2v[64], Bv[64];
  u16* WTh = Mb;
  u16* uTh = KWt;
  u16* Gb  = Vt;

  const int bid = blockIdx.x;
  const int c = bid & 31, bh = bid >> 5;
  const int b = bh >> 4, h = bh & 15;
  const int tid = threadIdx.x;

  {
    int* zp = (int*)Zt;
#pragma unroll
    for (int i = 0; i < 4; ++i) zp[tid + 512 * i] = 0;
  }
  if (tid < 64) {
    const size_t gi = (size_t)((b * TLEN + c * 64) + tid) * NHEAD + h;
    bet[tid] = bbuf[gi];
    float v = gbuf[gi];
#pragma unroll
    for (int ofs = 1; ofs < 64; ofs <<= 1) {
      float tt = __shfl_up(v, ofs);
      if (tid >= ofs) v += tt;
    }
    bcs[tid] = v;
  }
  __syncthreads();
  if (tid < 64) {
    const float blast = bcs[63];
    Bv[tid]  = __expf(bcs[tid]);
    e2v[tid] = __expf(blast - bcs[tid]);
  }
  __syncthreads();

  // ---- staging with fused conv+silu+l2norm (32 rows/iter, 2 iters)
  {
    const int dq = (tid & 15) * 4;
    const int col = h * 64 + dq;
    float4 wq4[4], wk4[4], wv4[4];
#pragma unroll
    for (int jj = 0; jj < 4; ++jj) {
      wq4[jj] = *(const float4*)(cq + (size_t)(col + jj) * 4);
      wk4[jj] = *(const float4*)(ck + (size_t)(col + jj) * 4);
      wv4[jj] = *(const float4*)(cv + (size_t)(col + jj) * 4);
    }
#pragma unroll
    for (int i = 0; i < 2; ++i) {
      const int r = i * 32 + (tid >> 4);
      const int tcur = c * 64 + r;
      ushort4 xq[4], xk[4], xv[4];
#pragma unroll
      for (int m = 0; m < 4; ++m) {
        const int tt = tcur - 3 + m;
        if (tt >= 0) {
          const size_t a = (size_t)(b * TLEN + tt) * HD + col;
          xq[m] = *(const ushort4*)(qp + a);
          xk[m] = *(const ushort4*)(kp + a);
          xv[m] = *(const ushort4*)(vp + a);
        } else {
          xq[m] = ushort4{0, 0, 0, 0}; xk[m] = xq[m]; xv[m] = xq[m];
        }
      }
      float yq[4], yk[4], yv[4];
      float ssq = 0.f, ssk = 0.f;
#pragma unroll
      for (int jj = 0; jj < 4; ++jj) {
        float aq = wq4[jj].x * bf2f(((const u16*)&xq[0])[jj]) +
                   wq4[jj].y * bf2f(((const u16*)&xq[1])[jj]) +
                   wq4[jj].z * bf2f(((const u16*)&xq[2])[jj]) +
                   wq4[jj].w * bf2f(((const u16*)&xq[3])[jj]);
        float ak = wk4[jj].x * bf2f(((const u16*)&xk[0])[jj]) +
                   wk4[jj].y * bf2f(((const u16*)&xk[1])[jj]) +
                   wk4[jj].z * bf2f(((const u16*)&xk[2])[jj]) +
                   wk4[jj].w * bf2f(((const u16*)&xk[3])[jj]);
        float av = wv4[jj].x * bf2f(((const u16*)&xv[0])[jj]) +
                   wv4[jj].y * bf2f(((const u16*)&xv[1])[jj]) +
                   wv4[jj].z * bf2f(((const u16*)&xv[2])[jj]) +
                   wv4[jj].w * bf2f(((const u16*)&xv[3])[jj]);
        yq[jj] = aq / (1.f + __expf(-aq));
        yk[jj] = ak / (1.f + __expf(-ak));
        yv[jj] = av / (1.f + __expf(-av));
        ssq += yq[jj] * yq[jj];
        ssk += yk[jj] * yk[jj];
      }
      ssq += __shfl_xor(ssq, 1); ssq += __shfl_xor(ssq, 2);
      ssq += __shfl_xor(ssq, 4); ssq += __shfl_xor(ssq, 8);
      ssk += __shfl_xor(ssk, 1); ssk += __shfl_xor(ssk, 2);
      ssk += __shfl_xor(ssk, 4); ssk += __shfl_xor(ssk, 8);
      const float qsc = rsqrtf(ssq + 1e-6f) * 0.125f;
      const float ksc = rsqrtf(ssk + 1e-6f);
      const float bR = bet[r], e2R = e2v[r], wscR = bR * Bv[r];
      float kvf[4];
#pragma unroll
      for (int jj = 0; jj < 4; ++jj) kvf[jj] = yk[jj] * ksc;
      uint2 qo2, ko2;
      qo2.x = pkbf(yq[0] * qsc, yq[1] * qsc);
      qo2.y = pkbf(yq[2] * qsc, yq[3] * qsc);
      ko2.x = pkbf(kvf[0], kvf[1]);
      ko2.y = pkbf(kvf[2], kvf[3]);
      *(uint2*)((char*)Qb + swz(r, dq)) = qo2;
      *(uint2*)((char*)Kb + swz(r, dq)) = ko2;
      const unsigned k2a = pkbf(kvf[0] * e2R, kvf[1] * e2R);
      const unsigned k2b = pkbf(kvf[2] * e2R, kvf[3] * e2R);
      const unsigned kwa = pkbf(kvf[0] * wscR, kvf[1] * wscR);
      const unsigned kwb = pkbf(kvf[2] * wscR, kvf[3] * wscR);
      const unsigned vta = pkbf(yv[0] * bR, yv[1] * bR);
      const unsigned vtb = pkbf(yv[2] * bR, yv[3] * bR);
      *(u16*)((char*)K2T + swz(dq + 0, r)) = (u16)k2a;
      *(u16*)((char*)K2T + swz(dq + 1, r)) = (u16)(k2a >> 16);
      *(u16*)((char*)K2T + swz(dq + 2, r)) = (u16)k2b;
      *(u16*)((char*)K2T + swz(dq + 3, r)) = (u16)(k2b >> 16);
      *(u16*)((char*)KWt + swz(dq + 0, r)) = (u16)kwa;
      *(u16*)((char*)KWt + swz(dq + 1, r)) = (u16)(kwa >> 16);
      *(u16*)((char*)KWt + swz(dq + 2, r)) = (u16)kwb;
      *(u16*)((char*)KWt + swz(dq + 3, r)) = (u16)(kwb >> 16);
      *(u16*)((char*)Vt + swz(dq + 0, r)) = (u16)vta;
      *(u16*)((char*)Vt + swz(dq + 1, r)) = (u16)(vta >> 16);
      *(u16*)((char*)Vt + swz(dq + 2, r)) = (u16)vtb;
      *(u16*)((char*)Vt + swz(dq + 3, r)) = (u16)(vtb >> 16);
    }
  }
  __syncthreads();

  const int w = tid >> 6, lane = tid & 63, fr = lane & 15, fq = lane >> 4;
  const int wr = w >> 1;                 // row block 0..3
  const int tc0 = (w & 1) * 2;           // column half: 2 sub-tiles per wave
  const int t0r = wr * 16 + fq * 4;
  // ---- A = K K^T via MFMA -> masked M (bf16, stride 72)
  {
    bf16x8 ka0 = frag(Kb, wr * 16 + fr, fq);
    bf16x8 ka1 = frag(Kb, wr * 16 + fr, 4 + fq);
#pragma unroll
    for (int j = 0; j < 2; ++j) {
      const int tc = tc0 + j;
      bf16x8 kb0 = frag(Kb, tc * 16 + fr, fq);
      bf16x8 kb1 = frag(Kb, tc * 16 + fr, 4 + fq);
      f32x4 a = {};
      a = __builtin_amdgcn_mfma_f32_16x16x32_bf16(ka0, kb0, a, 0, 0, 0);
      a = __builtin_amdgcn_mfma_f32_16x16x32_bf16(ka1, kb1, a, 0, 0, 0);
      const int s = tc * 16 + fr;
      float mv[4];
#pragma unroll
      for (int rr = 0; rr < 4; ++rr) {
        const int t = t0r + rr;
        mv[rr] = (s < t) ? bet[t] * __expf(bcs[t] - bcs[s]) * a[rr] : 0.f;
      }
      const unsigned m01 = pkbf(mv[0], mv[1]), m23 = pkbf(mv[2], mv[3]);
      Mb[(t0r + 0) * 72 + s] = (u16)m01;
      Mb[(t0r + 1) * 72 + s] = (u16)(m01 >> 16);
      Mb[(t0r + 2) * 72 + s] = (u16)m23;
      Mb[(t0r + 3) * 72 + s] = (u16)(m23 >> 16);
    }
  }
  __syncthreads();

  // ---- BLOCKED solve M Minv = I (4 blocks of 16 rows); waves 4-7 idle at MFMA
#pragma unroll 1
  for (int bi = 0; bi < 4; ++bi) {
    if (w < 4) {
      const char* mrow = (const char*)Mb + (size_t)(bi * 16 + fr) * 144;
      bf16x8 ma0 = *(const bf16x8*)(mrow + fq * 16);
      bf16x8 ma1 = *(const bf16x8*)(mrow + 64 + fq * 16);
      bf16x8 zt0 = frag(Zt, w * 16 + fr, fq);
      bf16x8 zt1 = frag(Zt, w * 16 + fr, 4 + fq);
      f32x4 a = {};
      a = __builtin_amdgcn_mfma_f32_16x16x32_bf16(ma0, zt0, a, 0, 0, 0);
      a = __builtin_amdgcn_mfma_f32_16x16x32_bf16(ma1, zt1, a, 0, 0, 0);
#pragma unroll
      for (int rr = 0; rr < 4; ++rr)
        Cb[(fq * 4 + rr) * 64 + w * 16 + fr] = a[rr];
    }
    __syncthreads();
    if (tid < 64) {
      const int j = tid;
      float z[16];
#pragma unroll
      for (int t = 0; t < 16; ++t) {
        float acc = ((bi * 16 + t) == j ? 1.f : 0.f) - Cb[t * 64 + j];
        const u16* mrow = Mb + (size_t)(bi * 16 + t) * 72 + bi * 16;
#pragma unroll
        for (int s = 0; s < t; ++s) acc -= bf2f(mrow[s]) * z[s];
        z[t] = acc;
      }
      unsigned zw[8];
#pragma unroll
      for (int t2 = 0; t2 < 8; ++t2) zw[t2] = pkbf(z[2 * t2], z[2 * t2 + 1]);
#pragma unroll
      for (int t2 = 0; t2 < 8; ++t2) {
        *(u16*)((char*)Zb + swz(bi * 16 + 2 * t2, j)) = (u16)zw[t2];
        *(u16*)((char*)Zb + swz(bi * 16 + 2 * t2 + 1, j)) = (u16)(zw[t2] >> 16);
      }
#pragma unroll
      for (int t4 = 0; t4 < 4; ++t4) {
        uint2 zz; zz.x = zw[2 * t4]; zz.y = zw[2 * t4 + 1];
        *(uint2*)((char*)Zt + swz(j, bi * 16 + t4 * 4)) = zz;
      }
    }
    __syncthreads();
  }

  // ---- W = Minv*RHSw, u = Minv*RHSv (transposed out), G = QK^T
  f32x4 accW[2], accu[2], accG[2];
  {
    bf16x8 kw0 = frag(KWt, wr * 16 + fr, fq), kw1 = frag(KWt, wr * 16 + fr, 4 + fq);
    bf16x8 vt0 = frag(Vt,  wr * 16 + fr, fq), vt1 = frag(Vt,  wr * 16 + fr, 4 + fq);
    bf16x8 qa0 = frag(Qb,  wr * 16 + fr, fq), qa1 = frag(Qb,  wr * 16 + fr, 4 + fq);
#pragma unroll
    for (int j = 0; j < 2; ++j) {
      const int tc = tc0 + j;
      bf16x8 z0 = frag(Zb, tc * 16 + fr, fq), z1 = frag(Zb, tc * 16 + fr, 4 + fq);
      bf16x8 kb0 = frag(Kb, tc * 16 + fr, fq), kb1 = frag(Kb, tc * 16 + fr, 4 + fq);
      f32x4 aw = {}, au = {}, ag = {};
      aw = __builtin_amdgcn_mfma_f32_16x16x32_bf16(kw0, z0, aw, 0, 0, 0);
      aw = __builtin_amdgcn_mfma_f32_16x16x32_bf16(kw1, z1, aw, 0, 0, 0);
      au = __builtin_amdgcn_mfma_f32_16x16x32_bf16(vt0, z0, au, 0, 0, 0);
      au = __builtin_amdgcn_mfma_f32_16x16x32_bf16(vt1, z1, au, 0, 0, 0);
      ag = __builtin_amdgcn_mfma_f32_16x16x32_bf16(qa0, kb0, ag, 0, 0, 0);
      ag = __builtin_amdgcn_mfma_f32_16x16x32_bf16(qa1, kb1, ag, 0, 0, 0);
      accW[j] = aw; accu[j] = au; accG[j] = ag;
    }
  }
  __syncthreads();
#pragma unroll
  for (int j = 0; j < 2; ++j) {
    const int tc = tc0 + j;
    const int co = tc * 16 + fr;
    const unsigned w01 = pkbf(accW[j][0], accW[j][1]);
    const unsigned w23 = pkbf(accW[j][2], accW[j][3]);
    const unsigned u01 = pkbf(accu[j][0], accu[j][1]);
    const unsigned u23 = pkbf(accu[j][2], accu[j][3]);
    float gv[4];
#pragma unroll
    for (int rr = 0; rr < 4; ++rr) {
      const int ro = t0r + rr;
      gv[rr] = (co <= ro) ? accG[j][rr] * __expf(bcs[ro] - bcs[co]) : 0.f;
    }
    const unsigned g01 = pkbf(gv[0], gv[1]), g23 = pkbf(gv[2], gv[3]);
    *(u16*)((char*)WTh + swz(t0r + 0, co)) = (u16)w01;
    *(u16*)((char*)WTh + swz(t0r + 1, co)) = (u16)(w01 >> 16);
    *(u16*)((char*)WTh + swz(t0r + 2, co)) = (u16)w23;
    *(u16*)((char*)WTh + swz(t0r + 3, co)) = (u16)(w23 >> 16);
    *(u16*)((char*)uTh + swz(t0r + 0, co)) = (u16)u01;
    *(u16*)((char*)uTh + swz(t0r + 1, co)) = (u16)(u01 >> 16);
    *(u16*)((char*)uTh + swz(t0r + 2, co)) = (u16)u23;
    *(u16*)((char*)uTh + swz(t0r + 3, co)) = (u16)(u23 >> 16);
    *(u16*)((char*)Gb + swz(t0r + 0, co)) = (u16)g01;
    *(u16*)((char*)Gb + swz(t0r + 1, co)) = (u16)(g01 >> 16);
    *(u16*)((char*)Gb + swz(t0r + 2, co)) = (u16)g23;
    *(u16*)((char*)Gb + swz(t0r + 3, co)) = (u16)(g23 >> 16);
  }
  __syncthreads();

  // ---- P,U,R,Y via MFMA + epilogue (P hi/lo bf16; U,R,Y bf16; pk everywhere)
  {
    bf16x8 k20 = frag(K2T, wr * 16 + fr, fq), k21 = frag(K2T, wr * 16 + fr, 4 + fq);
    bf16x8 g0  = frag(Gb,  wr * 16 + fr, fq), g1  = frag(Gb,  wr * 16 + fr, 4 + fq);
    const float bl = Bv[63];
    const size_t off = (size_t)bid * 4096;
#pragma unroll
    for (int j = 0; j < 2; ++j) {
      const int tc = tc0 + j;
      bf16x8 w0 = frag(WTh, tc * 16 + fr, fq), w1 = frag(WTh, tc * 16 + fr, 4 + fq);
      bf16x8 u0 = frag(uTh, tc * 16 + fr, fq), u1 = frag(uTh, tc * 16 + fr, 4 + fq);
      f32x4 aP = {}, aU = {}, aR = {}, aY = {};
      aP = __builtin_amdgcn_mfma_f32_16x16x32_bf16(k20, w0, aP, 0, 0, 0);
      aP = __builtin_amdgcn_mfma_f32_16x16x32_bf16(k21, w1, aP, 0, 0, 0);
      aU = __builtin_amdgcn_mfma_f32_16x16x32_bf16(k20, u0, aU, 0, 0, 0);
      aU = __builtin_amdgcn_mfma_f32_16x16x32_bf16(k21, u1, aU, 0, 0, 0);
      aR = __builtin_amdgcn_mfma_f32_16x16x32_bf16(g0, w0, aR, 0, 0, 0);
      aR = __builtin_amdgcn_mfma_f32_16x16x32_bf16(g1, w1, aR, 0, 0, 0);
      aY = __builtin_amdgcn_mfma_f32_16x16x32_bf16(g0, u0, aY, 0, 0, 0);
      aY = __builtin_amdgcn_mfma_f32_16x16x32_bf16(g1, u1, aY, 0, 0, 0);
      const int cb = tc * 16 + fr;
      float pv[4], rv[4];
#pragma unroll
      for (int rr = 0; rr < 4; ++rr) {
        const int ar = t0r + rr;
        pv[rr] = ((ar == cb) ? bl : 0.f) - aP[rr];
        const float qv = bf2f(*(const u16*)((const char*)Qb + swz(ar, cb)));
        rv[rr] = Bv[ar] * qv - aR[rr];
      }
      const unsigned p01 = pkbf(pv[0], pv[1]), p23 = pkbf(pv[2], pv[3]);
      const float l0 = pv[0] - bf2f((u16)p01), l1 = pv[1] - bf2f((u16)(p01 >> 16));
      const float l2 = pv[2] - bf2f((u16)p23), l3 = pv[3] - bf2f((u16)(p23 >> 16));
      const unsigned q01 = pkbf(l0, l1), q23 = pkbf(l2, l3);
      const unsigned u01 = pkbf(aU[0], aU[1]), u23 = pkbf(aU[2], aU[3]);
      const unsigned r01 = pkbf(rv[0], rv[1]), r23 = pkbf(rv[2], rv[3]);
      const unsigned y01 = pkbf(aY[0], aY[1]), y23 = pkbf(aY[2], aY[3]);
      const size_t o0 = off + (size_t)(t0r + 0) * 64 + cb;
      const size_t o1 = off + (size_t)(t0r + 1) * 64 + cb;
      const size_t o2 = off + (size_t)(t0r + 2) * 64 + cb;
      const size_t o3 = off + (size_t)(t0r + 3) * 64 + cb;
      Phi[o0] = (u16)p01; Phi[o1] = (u16)(p01 >> 16);
      Phi[o2] = (u16)p23; Phi[o3] = (u16)(p23 >> 16);
      Plo[o0] = (u16)q01; Plo[o1] = (u16)(q01 >> 16);
      Plo[o2] = (u16)q23; Plo[o3] = (u16)(q23 >> 16);
      Ug[o0] = (u16)u01; Ug[o1] = (u16)(u01 >> 16);
      Ug[o2] = (u16)u23; Ug[o3] = (u16)(u23 >> 16);
      Rg[o0] = (u16)r01; Rg[o1] = (u16)(r01 >> 16);
      Rg[o2] = (u16)r23; Rg[o3] = (u16)(r23 >> 16);
      Yg[o0] = (u16)y01; Yg[o1] = (u16)(y01 >> 16);
      Yg[o2] = (u16)y23; Yg[o3] = (u16)(y23 >> 16);
    }
  }
}

// ---- phase B: S_{c+1} = P_c S_c + U_c via split-precision MFMA, dv-split.
// 128 blocks = (jg 0..3) x (bh 0..31); bid = jg*32+bh so same-bh blocks share
// an XCD (bid%8==bh%8) and P comes from L2. Each block owns a 16-wide dv slice;
// S^T slice hi/lo in LDS (2 KB dbuf). Sst stored transposed ([dv][dk]).
__global__ __launch_bounds__(256) void state_step(
    const u16* __restrict__ Phi, const u16* __restrict__ Plo,
    const u16* __restrict__ Ug, u16* __restrict__ Sst) {
  __shared__ __align__(16) u16 Sth[2][16 * 64];
  __shared__ __align__(16) u16 Stl[2][16 * 64];
  const int bid = blockIdx.x;
  const int bh = bid & 31, jg = bid >> 5;
  const int j0 = jg * 16;
  const int tid = threadIdx.x;
  const int w = tid >> 6, lane = tid & 63, fr = lane & 15, fq = lane >> 4;
  const int ar0 = w * 16 + fq * 4;
  const size_t bbase = (size_t)bh * 32 * 4096;
  {
    int* p0 = (int*)&Sth[0][0];
    int* p1 = (int*)&Stl[0][0];
#pragma unroll
    for (int i = 0; i < 2; ++i) { p0[tid + 256 * i] = 0; p1[tid + 256 * i] = 0; }
    const ushort4 z4 = {0, 0, 0, 0};
    const int e = tid * 4;
    *(ushort4*)(Sst + bbase + (size_t)(j0 + (e >> 6)) * 64 + (e & 63)) = z4;
  }
  bf16x8 ph[2], pl[2];
  float uin[4];
#pragma unroll
  for (int kk = 0; kk < 2; ++kk) {
    const size_t ao = bbase + (size_t)(w * 16 + fr) * 64 + (kk * 4 + fq) * 8;
    ph[kk] = *(const bf16x8*)(Phi + ao);
    pl[kk] = *(const bf16x8*)(Plo + ao);
  }
#pragma unroll
  for (int rr = 0; rr < 4; ++rr)
    uin[rr] = bf2f(Ug[bbase + (size_t)(ar0 + rr) * 64 + j0 + fr]);
  __syncthreads();
  int cur = 0;
  for (int c = 0; c < 32; ++c) {
    f32x4 acc;
    bf16x8 phc[2] = {ph[0], ph[1]}, plc[2] = {pl[0], pl[1]};
#pragma unroll
    for (int rr = 0; rr < 4; ++rr) acc[rr] = uin[rr];
    if (c + 1 < 32) {
      const size_t off = bbase + (size_t)(c + 1) * 4096;
#pragma unroll
      for (int kk = 0; kk < 2; ++kk) {
        const size_t ao = off + (size_t)(w * 16 + fr) * 64 + (kk * 4 + fq) * 8;
        ph[kk] = *(const bf16x8*)(Phi + ao);
        pl[kk] = *(const bf16x8*)(Plo + ao);
      }
#pragma unroll
      for (int rr = 0; rr < 4; ++rr)
        uin[rr] = bf2f(Ug[off + (size_t)(ar0 + rr) * 64 + j0 + fr]);
    }
#pragma unroll
    for (int kk = 0; kk < 2; ++kk) {
      bf16x8 sh = frag(&Sth[cur][0], fr, kk * 4 + fq);
      bf16x8 sl = frag(&Stl[cur][0], fr, kk * 4 + fq);
      acc = __builtin_amdgcn_mfma_f32_16x16x32_bf16(phc[kk], sh, acc, 0, 0, 0);
      acc = __builtin_amdgcn_mfma_f32_16x16x32_bf16(phc[kk], sl, acc, 0, 0, 0);
      acc = __builtin_amdgcn_mfma_f32_16x16x32_bf16(plc[kk], sh, acc, 0, 0, 0);
    }
    const int nxt = cur ^ 1;
    const size_t offn = bbase + (size_t)(c + 1) * 4096;
    {
      const unsigned h01 = pkbf(acc[0], acc[1]);
      const unsigned h23 = pkbf(acc[2], acc[3]);
      const float l0 = acc[0] - bf2f((u16)h01);
      const float l1 = acc[1] - bf2f((u16)(h01 >> 16));
      const float l2 = acc[2] - bf2f((u16)h23);
      const float l3 = acc[3] - bf2f((u16)(h23 >> 16));
      uint2 hh; hh.x = h01; hh.y = h23;
      uint2 ll; ll.x = pkbf(l0, l1); ll.y = pkbf(l2, l3);
      *(uint2*)((char*)&Sth[nxt][0] + swz(fr, ar0)) = hh;
      *(uint2*)((char*)&Stl[nxt][0] + swz(fr, ar0)) = ll;
      if (c + 1 < 32)
        *(uint2*)(Sst + offn + (size_t)(j0 + fr) * 64 + ar0) = hh;
    }
    cur = nxt;
    __syncthreads();
  }
}

// ---- phase C: O = R S_in + Y via MFMA (R [t][dk], Sst^T [dv][dk], both
// straight from global), fused gated-RMSNorm epilogue -> bf16. No LDS.
__global__ __launch_bounds__(256) void chunk_out(
    const u16* __restrict__ Rg, const u16* __restrict__ Yg,
    const u16* __restrict__ SstT, const u16* __restrict__ gatep,
    const float* __restrict__ norm_w, u16* __restrict__ outb) {
  const int bid = blockIdx.x;
  const int c = bid & 31, bh = bid >> 5, b = bh >> 4, h = bh & 15;
  const int tid = threadIdx.x;
  const int w = tid >> 6, lane = tid & 63, fr = lane & 15, fq = lane >> 4;
  const int ar0 = w * 16 + fq * 4;
  const size_t off = (size_t)bid * 4096;
  bf16x8 ra[2];
#pragma unroll
  for (int kk = 0; kk < 2; ++kk)
    ra[kk] = *(const bf16x8*)(Rg + off + (size_t)(w * 16 + fr) * 64 + (kk * 4 + fq) * 8);
  f32x4 acc[4];
#pragma unroll
  for (int tc = 0; tc < 4; ++tc)
#pragma unroll
    for (int rr = 0; rr < 4; ++rr)
      acc[tc][rr] = bf2f(Yg[off + (size_t)(ar0 + rr) * 64 + tc * 16 + fr]);
#pragma unroll
  for (int tc = 0; tc < 4; ++tc)
#pragma unroll
    for (int kk = 0; kk < 2; ++kk) {
      bf16x8 sb = *(const bf16x8*)(SstT + off + (size_t)(tc * 16 + fr) * 64 + (kk * 4 + fq) * 8);
      acc[tc] = __builtin_amdgcn_mfma_f32_16x16x32_bf16(ra[kk], sb, acc[tc], 0, 0, 0);
    }
  float nwv[4];
#pragma unroll
  for (int tc = 0; tc < 4; ++tc) nwv[tc] = norm_w[tc * 16 + fr];
  const size_t btbase = (size_t)(b * TLEN + c * 64);
#pragma unroll
  for (int rr = 0; rr < 4; ++rr) {
    const int t = ar0 + rr;
    float rs = acc[0][rr] * acc[0][rr] + acc[1][rr] * acc[1][rr]
             + acc[2][rr] * acc[2][rr] + acc[3][rr] * acc[3][rr];
    rs += __shfl_xor(rs, 1); rs += __shfl_xor(rs, 2);
    rs += __shfl_xor(rs, 4); rs += __shfl_xor(rs, 8);
    const float inv = rsqrtf(rs * (1.0f / 64.0f) + 1e-5f);
    const size_t rowoff = (btbase + t) * 1024 + h * 64;
#pragma unroll
    for (int tc = 0; tc < 4; ++tc) {
      const int j = tc * 16 + fr;
      const float g = bf2f(gatep[rowoff + j]);
      const float val = acc[tc][rr] * inv * nwv[tc] * (g / (1.f + __expf(-g)));
      outb[rowoff + j] = f2bf(val);
    }
  }
}

extern "C" void kernel_launch(void* const* d_in, const int* in_sizes, int n_in,
                              void* d_out, int out_size, void* d_ws, size_t ws_size,
                              hipStream_t stream) {
  const float* hidden = (const float*)d_in[0];
  const float* Wq     = (const float*)d_in[1];
  const float* Wk     = (const float*)d_in[2];
  const float* Wv     = (const float*)d_in[3];
  const float* cq     = (const float*)d_in[4];
  const float* ck     = (const float*)d_in[5];
  const float* cv     = (const float*)d_in[6];
  const float* Wb     = (const float*)d_in[7];
  const float* Wa     = (const float*)d_in[8];
  const float* A_log  = (const float*)d_in[9];
  const float* dtb    = (const float*)d_in[10];
  const float* Wg     = (const float*)d_in[11];
  const float* nw     = (const float*)d_in[12];
  const float* Wo     = (const float*)d_in[13];

  char* p = (char*)d_ws;
  const size_t MB = 1u << 20;
  u16* h_bf = (u16*)(p + 0 * MB);     // 8 MB (dead after small_mfma)
  u16* wq_b = (u16*)(p + 8 * MB);     // 2 MB
  u16* wk_b = (u16*)(p + 10 * MB);
  u16* wv_b = (u16*)(p + 12 * MB);
  u16* wg_b = (u16*)(p + 14 * MB);
  u16* Phi = (u16*)(p + 0 * MB);      // 8 MB bf16, aliases h_bf (dead then)
  u16* Plo = (u16*)(p + 8 * MB);      // 8 MB bf16, aliases wq..wg (dead then)
  u16* wo_b = (u16*)(p + 16 * MB);    // 2 MB (live till end)
  u16* qp_b = (u16*)(p + 18 * MB);    // 8 MB
  u16* kp_b = (u16*)(p + 26 * MB);    // 8 MB
  u16* vp_b = (u16*)(p + 34 * MB);    // 8 MB
  u16* gp_b = (u16*)(p + 42 * MB);    // 8 MB (live till chunk_out)
  u16*   of_b = vp_b;                 // 8 MB, aliases vp (dead after chunk_local)
  float* gbuf = (float*)(p + 50 * MB);
  float* bbuf = (float*)(p + 50 * MB + 262144);
  u16* Ug  = (u16*)(p + 51 * MB);     // 8 MB bf16
  u16* Rg  = (u16*)(p + 59 * MB);     // 8 MB bf16
  u16* Yg  = (u16*)(p + 67 * MB);     // 8 MB bf16
  u16* Sst = (u16*)(p + 75 * MB);     // 8 MB bf16 (transposed per chunk)
  u16* hlo_b = (u16*)(p + 83 * MB);   // 8 MB
  u16* wba_h = (u16*)(p + 91 * MB);   // 64 KB
  u16* wba_l = (u16*)(p + 91 * MB + 65536);  // 64 KB (total ~91.2 MB)

  cvt_all<<<9248, 256, 0, stream>>>(hidden, Wq, Wk, Wv, Wg, Wo, Wb, Wa,
                                    h_bf, hlo_b, wq_b, wk_b, wv_b, wg_b, wo_b,
                                    wba_h, wba_l);

  gemm_big<u16><<<dim3(8, 16, 4), 256, 0, stream>>>(
      h_bf, wq_b, wk_b, wv_b, wg_b, qp_b, kp_b, vp_b, gp_b, 4096, 1024, 1024);

  const int sm_lds = 65536 + 8448;
  hipFuncSetAttribute((const void*)small_mfma,
                      hipFuncAttributeMaxDynamicSharedMemorySize, sm_lds);
  small_mfma<<<256, 256, sm_lds, stream>>>(h_bf, hlo_b, wba_h, wba_l,
                                           A_log, dtb, bbuf, gbuf);

  chunk_local<<<1024, 512, 0, stream>>>(qp_b, kp_b, vp_b, cq, ck, cv,
                                        gbuf, bbuf, Phi, Plo, Ug, Rg, Yg);
  state_step<<<128, 256, 0, stream>>>(Phi, Plo, Ug, Sst);
  chunk_out<<<1024, 256, 0, stream>>>(Rg, Yg, Sst, gp_b, nw, of_b);

  gemm_big<float><<<dim3(8, 16, 1), 256, 0, stream>>>(
      of_b, wo_b, wo_b, wo_b, wo_b,
      (float*)d_out, (float*)d_out, (float*)d_out, (float*)d_out,
      4096, 1024, 1024);
}

// Round 15
// 164.570 us; speedup vs baseline: 10.3028x; 1.0012x over previous
//
#include <hip/hip_runtime.h>
#include <hip/hip_bf16.h>

typedef unsigned short u16;
typedef __attribute__((ext_vector_type(4))) float f32x4;
typedef __attribute__((ext_vector_type(8))) short bf16x8;

#define TLEN 2048
#define NHEAD 16
#define HD 1024

__device__ inline u16 f2bf(float f) {
  unsigned x = __float_as_uint(f);
  return (u16)((x + 0x7fffu + ((x >> 16) & 1u)) >> 16);
}
__device__ inline float bf2f(u16 u) { return __uint_as_float(((unsigned)u) << 16); }

// packed f32x2 -> bf16x2 (low half = first operand). 1 inst vs ~8.
__device__ inline unsigned pkbf(float lo, float hi) {
  unsigned r;
  asm("v_cvt_pk_bf16_f32 %0, %1, %2" : "=v"(r) : "v"(lo), "v"(hi));
  return r;
}

// swizzle for [rows][64 bf16 = 128B] LDS tiles; XOR spreads both row&7
// and row>>3 so transposed (fixed-col) writes don't collide 8-way.
__device__ inline int rowx(int row) { return (row ^ (row >> 3)) & 7; }
__device__ inline int swz(int row, int col) {
  return (row << 7) + (((col >> 3) ^ rowx(row)) << 4) + ((col & 7) << 1);
}
__device__ inline bf16x8 frag(const u16* base, int row, int kslot) {
  return *(const bf16x8*)((const char*)base + (row << 7) +
                          ((kslot ^ rowx(row)) << 4));
}

// ------------------------------------------------- fused fp32 -> bf16 converts
__global__ __launch_bounds__(256) void cvt_all(
    const float* __restrict__ h,  const float* __restrict__ wq,
    const float* __restrict__ wk, const float* __restrict__ wv,
    const float* __restrict__ wg, const float* __restrict__ wo,
    const float* __restrict__ Wb, const float* __restrict__ Wa,
    u16* __restrict__ dh,  u16* __restrict__ dhlo,
    u16* __restrict__ dwq, u16* __restrict__ dwk,
    u16* __restrict__ dwv, u16* __restrict__ dwg, u16* __restrict__ dwo,
    u16* __restrict__ dwba_h, u16* __restrict__ dwba_l) {
  const int b = blockIdx.x;
  if (b < 4096) {
    const size_t i = (size_t)b * 256 + threadIdx.x;
    float4 v = *(const float4*)(h + i * 4);
    ushort4 hi, lo;
    hi.x = f2bf(v.x); lo.x = f2bf(v.x - bf2f(hi.x));
    hi.y = f2bf(v.y); lo.y = f2bf(v.y - bf2f(hi.y));
    hi.z = f2bf(v.z); lo.z = f2bf(v.z - bf2f(hi.z));
    hi.w = f2bf(v.w); lo.w = f2bf(v.w - bf2f(hi.w));
    *(ushort4*)(dh + i * 4) = hi;
    *(ushort4*)(dhlo + i * 4) = lo;
  } else if (b < 9216) {
    const int wsel = (b - 4096) >> 10;
    const size_t i = (size_t)((b - 4096) & 1023) * 256 + threadIdx.x;
    const float* s; u16* d;
    switch (wsel) {
      case 0: s = wq; d = dwq; break;
      case 1: s = wk; d = dwk; break;
      case 2: s = wv; d = dwv; break;
      case 3: s = wg; d = dwg; break;
      default: s = wo; d = dwo; break;
    }
    float4 v = *(const float4*)(s + i * 4);
    ushort4 u;
    u.x = f2bf(v.x); u.y = f2bf(v.y); u.z = f2bf(v.z); u.w = f2bf(v.w);
    *(ushort4*)(d + i * 4) = u;
  } else {
    const size_t i = (size_t)(b - 9216) * 256 + threadIdx.x;
    const size_t flat = i * 4;
    const float* src = (flat < 16384) ? (Wb + flat) : (Wa + (flat - 16384));
    float4 v = *(const float4*)src;
    ushort4 hi, lo;
    hi.x = f2bf(v.x); lo.x = f2bf(v.x - bf2f(hi.x));
    hi.y = f2bf(v.y); lo.y = f2bf(v.y - bf2f(hi.y));
    hi.z = f2bf(v.z); lo.z = f2bf(v.z - bf2f(hi.z));
    hi.w = f2bf(v.w); lo.w = f2bf(v.w - bf2f(hi.w));
    *(ushort4*)(dwba_h + flat) = hi;
    *(ushort4*)(dwba_l + flat) = lo;
  }
}

// ---------------- 256x128-tile GEMM (wave-tile 64x128): C = A*W^T
// OutT = u16 (bf16, pk-packed epilogue) or float.
template <typename OutT>
__global__ __launch_bounds__(256, 2) void gemm_big(
    const u16* __restrict__ A,
    const u16* __restrict__ W0p, const u16* __restrict__ W1p,
    const u16* __restrict__ W2p, const u16* __restrict__ W3p,
    OutT* __restrict__ C0, OutT* __restrict__ C1,
    OutT* __restrict__ C2, OutT* __restrict__ C3,
    int M, int N, int K) {
  const u16* W; OutT* C;
  switch (blockIdx.z) {
    case 0: W = W0p; C = C0; break;
    case 1: W = W1p; C = C1; break;
    case 2: W = W2p; C = C2; break;
    default: W = W3p; C = C3; break;
  }
  const int tid = threadIdx.x;
  const int lane = tid & 63, wid = tid >> 6;
  const int fr = lane & 15, fq = lane >> 4;
  const int row0 = blockIdx.y * 256, col0 = blockIdx.x * 128;
  __shared__ __align__(16) u16 As[256 * 64];
  __shared__ __align__(16) u16 Bs[128 * 64];

  const u16* aSrc[8]; const u16* bSrc[4];
#pragma unroll
  for (int it = 0; it < 8; ++it) {
    const int s = it * 256 + tid;
    const int r = s >> 3, cc = s & 7;
    aSrc[it] = A + (size_t)(row0 + r) * K + (cc ^ (r & 7)) * 8;
  }
#pragma unroll
  for (int it = 0; it < 4; ++it) {
    const int s = it * 256 + tid;
    const int r = s >> 3, cc = s & 7;
    bSrc[it] = W + (size_t)(col0 + r) * K + (cc ^ (r & 7)) * 8;
  }
  int aOff[4][2], bOff[8][2];
#pragma unroll
  for (int m = 0; m < 4; ++m)
#pragma unroll
    for (int kk = 0; kk < 2; ++kk) {
      const int ra = wid * 64 + m * 16 + fr;
      aOff[m][kk] = ra * 128 + ((((kk << 2) | fq) ^ (ra & 7)) << 4);
    }
#pragma unroll
  for (int n = 0; n < 8; ++n)
#pragma unroll
    for (int kk = 0; kk < 2; ++kk) {
      const int rb = n * 16 + fr;
      bOff[n][kk] = rb * 128 + ((((kk << 2) | fq) ^ (rb & 7)) << 4);
    }

  f32x4 acc[4][8] = {};
  for (int k0 = 0; k0 < K; k0 += 64) {
#pragma unroll
    for (int it = 0; it < 8; ++it)
      __builtin_amdgcn_global_load_lds(
          (const __attribute__((address_space(1))) void*)(aSrc[it] + k0),
          (__attribute__((address_space(3))) void*)((char*)As + (it * 256 + tid) * 16),
          16, 0, 0);
#pragma unroll
    for (int it = 0; it < 4; ++it)
      __builtin_amdgcn_global_load_lds(
          (const __attribute__((address_space(1))) void*)(bSrc[it] + k0),
          (__attribute__((address_space(3))) void*)((char*)Bs + (it * 256 + tid) * 16),
          16, 0, 0);
    __syncthreads();
#pragma unroll
    for (int kk = 0; kk < 2; ++kk) {
      bf16x8 af[4], bfr[8];
#pragma unroll
      for (int m = 0; m < 4; ++m)
        af[m] = *(const bf16x8*)((const char*)As + aOff[m][kk]);
#pragma unroll
      for (int n = 0; n < 8; ++n)
        bfr[n] = *(const bf16x8*)((const char*)Bs + bOff[n][kk]);
#pragma unroll
      for (int m = 0; m < 4; ++m)
#pragma unroll
        for (int n = 0; n < 8; ++n)
          acc[m][n] = __builtin_amdgcn_mfma_f32_16x16x32_bf16(af[m], bfr[n], acc[m][n], 0, 0, 0);
    }
    __syncthreads();
  }
#pragma unroll
  for (int m = 0; m < 4; ++m)
#pragma unroll
    for (int n = 0; n < 8; ++n) {
      const int gr0 = row0 + wid * 64 + m * 16 + fq * 4;
      const int gc = col0 + n * 16 + fr;
      if constexpr (sizeof(OutT) == 2) {
        const unsigned c01 = pkbf(acc[m][n][0], acc[m][n][1]);
        const unsigned c23 = pkbf(acc[m][n][2], acc[m][n][3]);
        C[(size_t)(gr0 + 0) * N + gc] = (OutT)(u16)c01;
        C[(size_t)(gr0 + 1) * N + gc] = (OutT)(u16)(c01 >> 16);
        C[(size_t)(gr0 + 2) * N + gc] = (OutT)(u16)c23;
        C[(size_t)(gr0 + 3) * N + gc] = (OutT)(u16)(c23 >> 16);
      } else {
#pragma unroll
        for (int r = 0; r < 4; ++r)
          C[(size_t)(gr0 + r) * N + gc] = acc[m][n][r];
      }
    }
}

// ---------------- beta/g projections via split-precision MFMA skinny GEMM
__global__ __launch_bounds__(256) void small_mfma(
    const u16* __restrict__ hhi, const u16* __restrict__ hlo,
    const u16* __restrict__ whi, const u16* __restrict__ wlo,
    const float* __restrict__ A_log, const float* __restrict__ dtb,
    float* __restrict__ bbuf, float* __restrict__ gbuf) {
  extern __shared__ char smc[];
  u16* Ahi = (u16*)smc;
  u16* Alo = (u16*)(smc + 32768);
  float* Red = (float*)(smc + 65536);
  const int tid = threadIdx.x;
  const int row0 = blockIdx.x * 16;
#pragma unroll
  for (int i = 0; i < 8; ++i) {
    const int slot = tid + 256 * i;
    const int r = slot >> 7, s = slot & 127;
    const int ss = s ^ (r & 7);
    const size_t src = (size_t)(row0 + r) * 1024 + (size_t)ss * 8;
    __builtin_amdgcn_global_load_lds(
        (const __attribute__((address_space(1))) void*)(hhi + src),
        (__attribute__((address_space(3))) void*)(Ahi + (size_t)slot * 8), 16, 0, 0);
    __builtin_amdgcn_global_load_lds(
        (const __attribute__((address_space(1))) void*)(hlo + src),
        (__attribute__((address_space(3))) void*)(Alo + (size_t)slot * 8), 16, 0, 0);
  }
  __syncthreads();
  const int w = tid >> 6, lane = tid & 63, fr = lane & 15, fq = lane >> 4;
  f32x4 acc[2] = {};
#pragma unroll
  for (int kk = 0; kk < 8; ++kk) {
    const int s = w * 32 + kk * 4 + fq;
    const size_t k = (size_t)w * 256 + kk * 32 + fq * 8;
    const int aoff = ((fr << 7) + (s ^ (fr & 7))) * 8;
    bf16x8 ah = *(const bf16x8*)(Ahi + aoff);
    bf16x8 al = *(const bf16x8*)(Alo + aoff);
#pragma unroll
    for (int ct = 0; ct < 2; ++ct) {
      const size_t boff = (size_t)(ct * 16 + fr) * 1024 + k;
      bf16x8 bh = *(const bf16x8*)(whi + boff);
      bf16x8 bl = *(const bf16x8*)(wlo + boff);
      acc[ct] = __builtin_amdgcn_mfma_f32_16x16x32_bf16(ah, bh, acc[ct], 0, 0, 0);
      acc[ct] = __builtin_amdgcn_mfma_f32_16x16x32_bf16(ah, bl, acc[ct], 0, 0, 0);
      acc[ct] = __builtin_amdgcn_mfma_f32_16x16x32_bf16(al, bh, acc[ct], 0, 0, 0);
    }
  }
#pragma unroll
  for (int ct = 0; ct < 2; ++ct)
#pragma unroll
    for (int rr = 0; rr < 4; ++rr)
      Red[(w * 16 + fq * 4 + rr) * 33 + ct * 16 + fr] = acc[ct][rr];
  __syncthreads();
  if (tid < 128) {
    const int row = tid >> 3, cg = (tid & 7) * 4;
#pragma unroll
    for (int j = 0; j < 4; ++j) {
      const int col = cg + j;
      const float s = Red[(0 * 16 + row) * 33 + col] + Red[(1 * 16 + row) * 33 + col]
                    + Red[(2 * 16 + row) * 33 + col] + Red[(3 * 16 + row) * 33 + col];
      const int grow = row0 + row;
      if (col < 16) {
        bbuf[grow * NHEAD + col] = 1.f / (1.f + __expf(-s));
      } else {
        const int hh = col - 16;
        const float xs = s + dtb[hh];
        const float sp = (xs > 20.f) ? xs : log1pf(__expf(xs));
        gbuf[grow * NHEAD + hh] = -__expf(A_log[hh]) * sp;
      }
    }
  }
}

// ===================== chunk-parallel gated delta rule (MFMA, 8 waves) ========
__global__ __launch_bounds__(512) void chunk_local(
    const u16* __restrict__ qp, const u16* __restrict__ kp, const u16* __restrict__ vp,
    const float* __restrict__ cq, const float* __restrict__ ck, const float* __restrict__ cv,
    const float* __restrict__ gbuf, const float* __restrict__ bbuf,
    u16* __restrict__ Phi, u16* __restrict__ Plo, u16* __restrict__ Ug,
    u16* __restrict__ Rg, u16* __restrict__ Yg) {
  __shared__ __align__(16) u16 Kb[64 * 64];
  __shared__ __align__(16) u16 Qb[64 * 64];
  __shared__ __align__(16) u16 K2T[64 * 64];
  __shared__ __align__(16) u16 KWt[64 * 64];   // -> uTh
  __shared__ __align__(16) u16 Vt[64 * 64];    // -> Gb
  __shared__ __align__(16) u16 Zb[64 * 64];
  __shared__ __align__(16) u16 Zt[64 * 64];
  __shared__ __align__(16) u16 Mb[64 * 72];    // -> WTh
  __shared__ __align__(16) float Cb[16 * 64];
  __shared__ float bcs[64], bet[64], e2v[64], Bv[64];
  u16* WTh = Mb;
  u16* uTh = KWt;
  u16* Gb  = Vt;

  const int bid = blockIdx.x;
  const int c = bid & 31, bh = bid >> 5;
  const int b = bh >> 4, h = bh & 15;
  const int tid = threadIdx.x;

  {
    int* zp = (int*)Zt;
#pragma unroll
    for (int i = 0; i < 4; ++i) zp[tid + 512 * i] = 0;
  }
  if (tid < 64) {
    const size_t gi = (size_t)((b * TLEN + c * 64) + tid) * NHEAD + h;
    bet[tid] = bbuf[gi];
    float v = gbuf[gi];
#pragma unroll
    for (int ofs = 1; ofs < 64; ofs <<= 1) {
      float tt = __shfl_up(v, ofs);
      if (tid >= ofs) v += tt;
    }
    bcs[tid] = v;
  }
  __syncthreads();
  if (tid < 64) {
    const float blast = bcs[63];
    Bv[tid]  = __expf(bcs[tid]);
    e2v[tid] = __expf(blast - bcs[tid]);
  }
  __syncthreads();

  // ---- staging with fused conv+silu+l2norm (32 rows/iter, 2 iters)
  {
    const int dq = (tid & 15) * 4;
    const int col = h * 64 + dq;
    float4 wq4[4], wk4[4], wv4[4];
#pragma unroll
    for (int jj = 0; jj < 4; ++jj) {
      wq4[jj] = *(const float4*)(cq + (size_t)(col + jj) * 4);
      wk4[jj] = *(const float4*)(ck + (size_t)(col + jj) * 4);
      wv4[jj] = *(const float4*)(cv + (size_t)(col + jj) * 4);
    }
#pragma unroll
    for (int i = 0; i < 2; ++i) {
      const int r = i * 32 + (tid >> 4);
      const int tcur = c * 64 + r;
      ushort4 xq[4], xk[4], xv[4];
#pragma unroll
      for (int m = 0; m < 4; ++m) {
        const int tt = tcur - 3 + m;
        if (tt >= 0) {
          const size_t a = (size_t)(b * TLEN + tt) * HD + col;
          xq[m] = *(const ushort4*)(qp + a);
          xk[m] = *(const ushort4*)(kp + a);
          xv[m] = *(const ushort4*)(vp + a);
        } else {
          xq[m] = ushort4{0, 0, 0, 0}; xk[m] = xq[m]; xv[m] = xq[m];
        }
      }
      float yq[4], yk[4], yv[4];
      float ssq = 0.f, ssk = 0.f;
#pragma unroll
      for (int jj = 0; jj < 4; ++jj) {
        float aq = wq4[jj].x * bf2f(((const u16*)&xq[0])[jj]) +
                   wq4[jj].y * bf2f(((const u16*)&xq[1])[jj]) +
                   wq4[jj].z * bf2f(((const u16*)&xq[2])[jj]) +
                   wq4[jj].w * bf2f(((const u16*)&xq[3])[jj]);
        float ak = wk4[jj].x * bf2f(((const u16*)&xk[0])[jj]) +
                   wk4[jj].y * bf2f(((const u16*)&xk[1])[jj]) +
                   wk4[jj].z * bf2f(((const u16*)&xk[2])[jj]) +
                   wk4[jj].w * bf2f(((const u16*)&xk[3])[jj]);
        float av = wv4[jj].x * bf2f(((const u16*)&xv[0])[jj]) +
                   wv4[jj].y * bf2f(((const u16*)&xv[1])[jj]) +
                   wv4[jj].z * bf2f(((const u16*)&xv[2])[jj]) +
                   wv4[jj].w * bf2f(((const u16*)&xv[3])[jj]);
        yq[jj] = aq / (1.f + __expf(-aq));
        yk[jj] = ak / (1.f + __expf(-ak));
        yv[jj] = av / (1.f + __expf(-av));
        ssq += yq[jj] * yq[jj];
        ssk += yk[jj] * yk[jj];
      }
      ssq += __shfl_xor(ssq, 1); ssq += __shfl_xor(ssq, 2);
      ssq += __shfl_xor(ssq, 4); ssq += __shfl_xor(ssq, 8);
      ssk += __shfl_xor(ssk, 1); ssk += __shfl_xor(ssk, 2);
      ssk += __shfl_xor(ssk, 4); ssk += __shfl_xor(ssk, 8);
      const float qsc = rsqrtf(ssq + 1e-6f) * 0.125f;
      const float ksc = rsqrtf(ssk + 1e-6f);
      const float bR = bet[r], e2R = e2v[r], wscR = bR * Bv[r];
      float kvf[4];
#pragma unroll
      for (int jj = 0; jj < 4; ++jj) kvf[jj] = yk[jj] * ksc;
      uint2 qo2, ko2;
      qo2.x = pkbf(yq[0] * qsc, yq[1] * qsc);
      qo2.y = pkbf(yq[2] * qsc, yq[3] * qsc);
      ko2.x = pkbf(kvf[0], kvf[1]);
      ko2.y = pkbf(kvf[2], kvf[3]);
      *(uint2*)((char*)Qb + swz(r, dq)) = qo2;
      *(uint2*)((char*)Kb + swz(r, dq)) = ko2;
      const unsigned k2a = pkbf(kvf[0] * e2R, kvf[1] * e2R);
      const unsigned k2b = pkbf(kvf[2] * e2R, kvf[3] * e2R);
      const unsigned kwa = pkbf(kvf[0] * wscR, kvf[1] * wscR);
      const unsigned kwb = pkbf(kvf[2] * wscR, kvf[3] * wscR);
      const unsigned vta = pkbf(yv[0] * bR, yv[1] * bR);
      const unsigned vtb = pkbf(yv[2] * bR, yv[3] * bR);
      *(u16*)((char*)K2T + swz(dq + 0, r)) = (u16)k2a;
      *(u16*)((char*)K2T + swz(dq + 1, r)) = (u16)(k2a >> 16);
      *(u16*)((char*)K2T + swz(dq + 2, r)) = (u16)k2b;
      *(u16*)((char*)K2T + swz(dq + 3, r)) = (u16)(k2b >> 16);
      *(u16*)((char*)KWt + swz(dq + 0, r)) = (u16)kwa;
      *(u16*)((char*)KWt + swz(dq + 1, r)) = (u16)(kwa >> 16);
      *(u16*)((char*)KWt + swz(dq + 2, r)) = (u16)kwb;
      *(u16*)((char*)KWt + swz(dq + 3, r)) = (u16)(kwb >> 16);
      *(u16*)((char*)Vt + swz(dq + 0, r)) = (u16)vta;
      *(u16*)((char*)Vt + swz(dq + 1, r)) = (u16)(vta >> 16);
      *(u16*)((char*)Vt + swz(dq + 2, r)) = (u16)vtb;
      *(u16*)((char*)Vt + swz(dq + 3, r)) = (u16)(vtb >> 16);
    }
  }
  __syncthreads();

  const int w = tid >> 6, lane = tid & 63, fr = lane & 15, fq = lane >> 4;
  const int wr = w >> 1;                 // row block 0..3
  const int tc0 = (w & 1) * 2;           // column half: 2 sub-tiles per wave
  const int t0r = wr * 16 + fq * 4;
  // ---- A = K K^T via MFMA -> masked M (bf16, stride 72)
  {
    bf16x8 ka0 = frag(Kb, wr * 16 + fr, fq);
    bf16x8 ka1 = frag(Kb, wr * 16 + fr, 4 + fq);
#pragma unroll
    for (int j = 0; j < 2; ++j) {
      const int tc = tc0 + j;
      bf16x8 kb0 = frag(Kb, tc * 16 + fr, fq);
      bf16x8 kb1 = frag(Kb, tc * 16 + fr, 4 + fq);
      f32x4 a = {};
      a = __builtin_amdgcn_mfma_f32_16x16x32_bf16(ka0, kb0, a, 0, 0, 0);
      a = __builtin_amdgcn_mfma_f32_16x16x32_bf16(ka1, kb1, a, 0, 0, 0);
      const int s = tc * 16 + fr;
      float mv[4];
#pragma unroll
      for (int rr = 0; rr < 4; ++rr) {
        const int t = t0r + rr;
        mv[rr] = (s < t) ? bet[t] * __expf(bcs[t] - bcs[s]) * a[rr] : 0.f;
      }
      const unsigned m01 = pkbf(mv[0], mv[1]), m23 = pkbf(mv[2], mv[3]);
      Mb[(t0r + 0) * 72 + s] = (u16)m01;
      Mb[(t0r + 1) * 72 + s] = (u16)(m01 >> 16);
      Mb[(t0r + 2) * 72 + s] = (u16)m23;
      Mb[(t0r + 3) * 72 + s] = (u16)(m23 >> 16);
    }
  }
  __syncthreads();

  // ---- BLOCKED solve M Minv = I (4 blocks of 16 rows); waves 4-7 idle at MFMA
#pragma unroll 1
  for (int bi = 0; bi < 4; ++bi) {
    if (w < 4) {
      const char* mrow = (const char*)Mb + (size_t)(bi * 16 + fr) * 144;
      bf16x8 ma0 = *(const bf16x8*)(mrow + fq * 16);
      bf16x8 ma1 = *(const bf16x8*)(mrow + 64 + fq * 16);
      bf16x8 zt0 = frag(Zt, w * 16 + fr, fq);
      bf16x8 zt1 = frag(Zt, w * 16 + fr, 4 + fq);
      f32x4 a = {};
      a = __builtin_amdgcn_mfma_f32_16x16x32_bf16(ma0, zt0, a, 0, 0, 0);
      a = __builtin_amdgcn_mfma_f32_16x16x32_bf16(ma1, zt1, a, 0, 0, 0);
#pragma unroll
      for (int rr = 0; rr < 4; ++rr)
        Cb[(fq * 4 + rr) * 64 + w * 16 + fr] = a[rr];
    }
    __syncthreads();
    if (tid < 64) {
      const int j = tid;
      float z[16];
#pragma unroll
      for (int t = 0; t < 16; ++t) {
        float acc = ((bi * 16 + t) == j ? 1.f : 0.f) - Cb[t * 64 + j];
        const u16* mrow = Mb + (size_t)(bi * 16 + t) * 72 + bi * 16;
#pragma unroll
        for (int s = 0; s < t; ++s) acc -= bf2f(mrow[s]) * z[s];
        z[t] = acc;
      }
      unsigned zw[8];
#pragma unroll
      for (int t2 = 0; t2 < 8; ++t2) zw[t2] = pkbf(z[2 * t2], z[2 * t2 + 1]);
#pragma unroll
      for (int t2 = 0; t2 < 8; ++t2) {
        *(u16*)((char*)Zb + swz(bi * 16 + 2 * t2, j)) = (u16)zw[t2];
        *(u16*)((char*)Zb + swz(bi * 16 + 2 * t2 + 1, j)) = (u16)(zw[t2] >> 16);
      }
#pragma unroll
      for (int t4 = 0; t4 < 4; ++t4) {
        uint2 zz; zz.x = zw[2 * t4]; zz.y = zw[2 * t4 + 1];
        *(uint2*)((char*)Zt + swz(j, bi * 16 + t4 * 4)) = zz;
      }
    }
    __syncthreads();
  }

  // ---- W = Minv*RHSw, u = Minv*RHSv (transposed out), G = QK^T
  f32x4 accW[2], accu[2], accG[2];
  {
    bf16x8 kw0 = frag(KWt, wr * 16 + fr, fq), kw1 = frag(KWt, wr * 16 + fr, 4 + fq);
    bf16x8 vt0 = frag(Vt,  wr * 16 + fr, fq), vt1 = frag(Vt,  wr * 16 + fr, 4 + fq);
    bf16x8 qa0 = frag(Qb,  wr * 16 + fr, fq), qa1 = frag(Qb,  wr * 16 + fr, 4 + fq);
#pragma unroll
    for (int j = 0; j < 2; ++j) {
      const int tc = tc0 + j;
      bf16x8 z0 = frag(Zb, tc * 16 + fr, fq), z1 = frag(Zb, tc * 16 + fr, 4 + fq);
      bf16x8 kb0 = frag(Kb, tc * 16 + fr, fq), kb1 = frag(Kb, tc * 16 + fr, 4 + fq);
      f32x4 aw = {}, au = {}, ag = {};
      aw = __builtin_amdgcn_mfma_f32_16x16x32_bf16(kw0, z0, aw, 0, 0, 0);
      aw = __builtin_amdgcn_mfma_f32_16x16x32_bf16(kw1, z1, aw, 0, 0, 0);
      au = __builtin_amdgcn_mfma_f32_16x16x32_bf16(vt0, z0, au, 0, 0, 0);
      au = __builtin_amdgcn_mfma_f32_16x16x32_bf16(vt1, z1, au, 0, 0, 0);
      ag = __builtin_amdgcn_mfma_f32_16x16x32_bf16(qa0, kb0, ag, 0, 0, 0);
      ag = __builtin_amdgcn_mfma_f32_16x16x32_bf16(qa1, kb1, ag, 0, 0, 0);
      accW[j] = aw; accu[j] = au; accG[j] = ag;
    }
  }
  __syncthreads();
#pragma unroll
  for (int j = 0; j < 2; ++j) {
    const int tc = tc0 + j;
    const int co = tc * 16 + fr;
    const unsigned w01 = pkbf(accW[j][0], accW[j][1]);
    const unsigned w23 = pkbf(accW[j][2], accW[j][3]);
    const unsigned u01 = pkbf(accu[j][0], accu[j][1]);
    const unsigned u23 = pkbf(accu[j][2], accu[j][3]);
    float gv[4];
#pragma unroll
    for (int rr = 0; rr < 4; ++rr) {
      const int ro = t0r + rr;
      gv[rr] = (co <= ro) ? accG[j][rr] * __expf(bcs[ro] - bcs[co]) : 0.f;
    }
    const unsigned g01 = pkbf(gv[0], gv[1]), g23 = pkbf(gv[2], gv[3]);
    *(u16*)((char*)WTh + swz(t0r + 0, co)) = (u16)w01;
    *(u16*)((char*)WTh + swz(t0r + 1, co)) = (u16)(w01 >> 16);
    *(u16*)((char*)WTh + swz(t0r + 2, co)) = (u16)w23;
    *(u16*)((char*)WTh + swz(t0r + 3, co)) = (u16)(w23 >> 16);
    *(u16*)((char*)uTh + swz(t0r + 0, co)) = (u16)u01;
    *(u16*)((char*)uTh + swz(t0r + 1, co)) = (u16)(u01 >> 16);
    *(u16*)((char*)uTh + swz(t0r + 2, co)) = (u16)u23;
    *(u16*)((char*)uTh + swz(t0r + 3, co)) = (u16)(u23 >> 16);
    *(u16*)((char*)Gb + swz(t0r + 0, co)) = (u16)g01;
    *(u16*)((char*)Gb + swz(t0r + 1, co)) = (u16)(g01 >> 16);
    *(u16*)((char*)Gb + swz(t0r + 2, co)) = (u16)g23;
    *(u16*)((char*)Gb + swz(t0r + 3, co)) = (u16)(g23 >> 16);
  }
  __syncthreads();

  // ---- P,U,R,Y via MFMA + epilogue (P hi/lo bf16; U,R,Y bf16; pk everywhere)
  {
    bf16x8 k20 = frag(K2T, wr * 16 + fr, fq), k21 = frag(K2T, wr * 16 + fr, 4 + fq);
    bf16x8 g0  = frag(Gb,  wr * 16 + fr, fq), g1  = frag(Gb,  wr * 16 + fr, 4 + fq);
    const float bl = Bv[63];
    const size_t off = (size_t)bid * 4096;
#pragma unroll
    for (int j = 0; j < 2; ++j) {
      const int tc = tc0 + j;
      bf16x8 w0 = frag(WTh, tc * 16 + fr, fq), w1 = frag(WTh, tc * 16 + fr, 4 + fq);
      bf16x8 u0 = frag(uTh, tc * 16 + fr, fq), u1 = frag(uTh, tc * 16 + fr, 4 + fq);
      f32x4 aP = {}, aU = {}, aR = {}, aY = {};
      aP = __builtin_amdgcn_mfma_f32_16x16x32_bf16(k20, w0, aP, 0, 0, 0);
      aP = __builtin_amdgcn_mfma_f32_16x16x32_bf16(k21, w1, aP, 0, 0, 0);
      aU = __builtin_amdgcn_mfma_f32_16x16x32_bf16(k20, u0, aU, 0, 0, 0);
      aU = __builtin_amdgcn_mfma_f32_16x16x32_bf16(k21, u1, aU, 0, 0, 0);
      aR = __builtin_amdgcn_mfma_f32_16x16x32_bf16(g0, w0, aR, 0, 0, 0);
      aR = __builtin_amdgcn_mfma_f32_16x16x32_bf16(g1, w1, aR, 0, 0, 0);
      aY = __builtin_amdgcn_mfma_f32_16x16x32_bf16(g0, u0, aY, 0, 0, 0);
      aY = __builtin_amdgcn_mfma_f32_16x16x32_bf16(g1, u1, aY, 0, 0, 0);
      const int cb = tc * 16 + fr;
      float pv[4], rv[4];
#pragma unroll
      for (int rr = 0; rr < 4; ++rr) {
        const int ar = t0r + rr;
        pv[rr] = ((ar == cb) ? bl : 0.f) - aP[rr];
        const float qv = bf2f(*(const u16*)((const char*)Qb + swz(ar, cb)));
        rv[rr] = Bv[ar] * qv - aR[rr];
      }
      const unsigned p01 = pkbf(pv[0], pv[1]), p23 = pkbf(pv[2], pv[3]);
      const float l0 = pv[0] - bf2f((u16)p01), l1 = pv[1] - bf2f((u16)(p01 >> 16));
      const float l2 = pv[2] - bf2f((u16)p23), l3 = pv[3] - bf2f((u16)(p23 >> 16));
      const unsigned q01 = pkbf(l0, l1), q23 = pkbf(l2, l3);
      const unsigned u01 = pkbf(aU[0], aU[1]), u23 = pkbf(aU[2], aU[3]);
      const unsigned r01 = pkbf(rv[0], rv[1]), r23 = pkbf(rv[2], rv[3]);
      const unsigned y01 = pkbf(aY[0], aY[1]), y23 = pkbf(aY[2], aY[3]);
      const size_t o0 = off + (size_t)(t0r + 0) * 64 + cb;
      const size_t o1 = off + (size_t)(t0r + 1) * 64 + cb;
      const size_t o2 = off + (size_t)(t0r + 2) * 64 + cb;
      const size_t o3 = off + (size_t)(t0r + 3) * 64 + cb;
      Phi[o0] = (u16)p01; Phi[o1] = (u16)(p01 >> 16);
      Phi[o2] = (u16)p23; Phi[o3] = (u16)(p23 >> 16);
      Plo[o0] = (u16)q01; Plo[o1] = (u16)(q01 >> 16);
      Plo[o2] = (u16)q23; Plo[o3] = (u16)(q23 >> 16);
      Ug[o0] = (u16)u01; Ug[o1] = (u16)(u01 >> 16);
      Ug[o2] = (u16)u23; Ug[o3] = (u16)(u23 >> 16);
      Rg[o0] = (u16)r01; Rg[o1] = (u16)(r01 >> 16);
      Rg[o2] = (u16)r23; Rg[o3] = (u16)(r23 >> 16);
      Yg[o0] = (u16)y01; Yg[o1] = (u16)(y01 >> 16);
      Yg[o2] = (u16)y23; Yg[o3] = (u16)(y23 >> 16);
    }
  }
}

// ---- phase B: S_{c+1} = P_c S_c + U_c via split-precision MFMA, dv-split.
// 128 blocks = (jg 0..3) x (bh 0..31); bid = jg*32+bh so same-bh blocks share
// an XCD (bid%8==bh%8) and P comes from L2. Each block owns a 16-wide dv slice;
// S^T slice hi/lo in LDS (2 KB dbuf). Sst stored transposed ([dv][dk]).
__global__ __launch_bounds__(256) void state_step(
    const u16* __restrict__ Phi, const u16* __restrict__ Plo,
    const u16* __restrict__ Ug, u16* __restrict__ Sst) {
  __shared__ __align__(16) u16 Sth[2][16 * 64];
  __shared__ __align__(16) u16 Stl[2][16 * 64];
  const int bid = blockIdx.x;
  const int bh = bid & 31, jg = bid >> 5;
  const int j0 = jg * 16;
  const int tid = threadIdx.x;
  const int w = tid >> 6, lane = tid & 63, fr = lane & 15, fq = lane >> 4;
  const int ar0 = w * 16 + fq * 4;
  const size_t bbase = (size_t)bh * 32 * 4096;
  {
    int* p0 = (int*)&Sth[0][0];
    int* p1 = (int*)&Stl[0][0];
#pragma unroll
    for (int i = 0; i < 2; ++i) { p0[tid + 256 * i] = 0; p1[tid + 256 * i] = 0; }
    const ushort4 z4 = {0, 0, 0, 0};
    const int e = tid * 4;
    *(ushort4*)(Sst + bbase + (size_t)(j0 + (e >> 6)) * 64 + (e & 63)) = z4;
  }
  bf16x8 ph[2], pl[2];
  float uin[4];
#pragma unroll
  for (int kk = 0; kk < 2; ++kk) {
    const size_t ao = bbase + (size_t)(w * 16 + fr) * 64 + (kk * 4 + fq) * 8;
    ph[kk] = *(const bf16x8*)(Phi + ao);
    pl[kk] = *(const bf16x8*)(Plo + ao);
  }
#pragma unroll
  for (int rr = 0; rr < 4; ++rr)
    uin[rr] = bf2f(Ug[bbase + (size_t)(ar0 + rr) * 64 + j0 + fr]);
  __syncthreads();
  int cur = 0;
  for (int c = 0; c < 32; ++c) {
    f32x4 acc;
    bf16x8 phc[2] = {ph[0], ph[1]}, plc[2] = {pl[0], pl[1]};
#pragma unroll
    for (int rr = 0; rr < 4; ++rr) acc[rr] = uin[rr];
    if (c + 1 < 32) {
      const size_t off = bbase + (size_t)(c + 1) * 4096;
#pragma unroll
      for (int kk = 0; kk < 2; ++kk) {
        const size_t ao = off + (size_t)(w * 16 + fr) * 64 + (kk * 4 + fq) * 8;
        ph[kk] = *(const bf16x8*)(Phi + ao);
        pl[kk] = *(const bf16x8*)(Plo + ao);
      }
#pragma unroll
      for (int rr = 0; rr < 4; ++rr)
        uin[rr] = bf2f(Ug[off + (size_t)(ar0 + rr) * 64 + j0 + fr]);
    }
#pragma unroll
    for (int kk = 0; kk < 2; ++kk) {
      bf16x8 sh = frag(&Sth[cur][0], fr, kk * 4 + fq);
      bf16x8 sl = frag(&Stl[cur][0], fr, kk * 4 + fq);
      acc = __builtin_amdgcn_mfma_f32_16x16x32_bf16(phc[kk], sh, acc, 0, 0, 0);
      acc = __builtin_amdgcn_mfma_f32_16x16x32_bf16(phc[kk], sl, acc, 0, 0, 0);
      acc = __builtin_amdgcn_mfma_f32_16x16x32_bf16(plc[kk], sh, acc, 0, 0, 0);
    }
    const int nxt = cur ^ 1;
    const size_t offn = bbase + (size_t)(c + 1) * 4096;
    {
      const unsigned h01 = pkbf(acc[0], acc[1]);
      const unsigned h23 = pkbf(acc[2], acc[3]);
      const float l0 = acc[0] - bf2f((u16)h01);
      const float l1 = acc[1] - bf2f((u16)(h01 >> 16));
      const float l2 = acc[2] - bf2f((u16)h23);
      const float l3 = acc[3] - bf2f((u16)(h23 >> 16));
      uint2 hh; hh.x = h01; hh.y = h23;
      uint2 ll; ll.x = pkbf(l0, l1); ll.y = pkbf(l2, l3);
      *(uint2*)((char*)&Sth[nxt][0] + swz(fr, ar0)) = hh;
      *(uint2*)((char*)&Stl[nxt][0] + swz(fr, ar0)) = ll;
      if (c + 1 < 32)
        *(uint2*)(Sst + offn + (size_t)(j0 + fr) * 64 + ar0) = hh;
    }
    cur = nxt;
    __syncthreads();
  }
}

// ---- phase C: O = R S_in + Y via MFMA (R [t][dk], Sst^T [dv][dk], both
// straight from global), fused gated-RMSNorm epilogue -> bf16. No LDS.
__global__ __launch_bounds__(256) void chunk_out(
    const u16* __restrict__ Rg, const u16* __restrict__ Yg,
    const u16* __restrict__ SstT, const u16* __restrict__ gatep,
    const float* __restrict__ norm_w, u16* __restrict__ outb) {
  const int bid = blockIdx.x;
  const int c = bid & 31, bh = bid >> 5, b = bh >> 4, h = bh & 15;
  const int tid = threadIdx.x;
  const int w = tid >> 6, lane = tid & 63, fr = lane & 15, fq = lane >> 4;
  const int ar0 = w * 16 + fq * 4;
  const size_t off = (size_t)bid * 4096;
  bf16x8 ra[2];
#pragma unroll
  for (int kk = 0; kk < 2; ++kk)
    ra[kk] = *(const bf16x8*)(Rg + off + (size_t)(w * 16 + fr) * 64 + (kk * 4 + fq) * 8);
  f32x4 acc[4];
#pragma unroll
  for (int tc = 0; tc < 4; ++tc)
#pragma unroll
    for (int rr = 0; rr < 4; ++rr)
      acc[tc][rr] = bf2f(Yg[off + (size_t)(ar0 + rr) * 64 + tc * 16 + fr]);
#pragma unroll
  for (int tc = 0; tc < 4; ++tc)
#pragma unroll
    for (int kk = 0; kk < 2; ++kk) {
      bf16x8 sb = *(const bf16x8*)(SstT + off + (size_t)(tc * 16 + fr) * 64 + (kk * 4 + fq) * 8);
      acc[tc] = __builtin_amdgcn_mfma_f32_16x16x32_bf16(ra[kk], sb, acc[tc], 0, 0, 0);
    }
  float nwv[4];
#pragma unroll
  for (int tc = 0; tc < 4; ++tc) nwv[tc] = norm_w[tc * 16 + fr];
  const size_t btbase = (size_t)(b * TLEN + c * 64);
#pragma unroll
  for (int rr = 0; rr < 4; ++rr) {
    const int t = ar0 + rr;
    float rs = acc[0][rr] * acc[0][rr] + acc[1][rr] * acc[1][rr]
             + acc[2][rr] * acc[2][rr] + acc[3][rr] * acc[3][rr];
    rs += __shfl_xor(rs, 1); rs += __shfl_xor(rs, 2);
    rs += __shfl_xor(rs, 4); rs += __shfl_xor(rs, 8);
    const float inv = rsqrtf(rs * (1.0f / 64.0f) + 1e-5f);
    const size_t rowoff = (btbase + t) * 1024 + h * 64;
#pragma unroll
    for (int tc = 0; tc < 4; ++tc) {
      const int j = tc * 16 + fr;
      const float g = bf2f(gatep[rowoff + j]);
      const float val = acc[tc][rr] * inv * nwv[tc] * (g / (1.f + __expf(-g)));
      outb[rowoff + j] = f2bf(val);
    }
  }
}

extern "C" void kernel_launch(void* const* d_in, const int* in_sizes, int n_in,
                              void* d_out, int out_size, void* d_ws, size_t ws_size,
                              hipStream_t stream) {
  const float* hidden = (const float*)d_in[0];
  const float* Wq     = (const float*)d_in[1];
  const float* Wk     = (const float*)d_in[2];
  const float* Wv     = (const float*)d_in[3];
  const float* cq     = (const float*)d_in[4];
  const float* ck     = (const float*)d_in[5];
  const float* cv     = (const float*)d_in[6];
  const float* Wb     = (const float*)d_in[7];
  const float* Wa     = (const float*)d_in[8];
  const float* A_log  = (const float*)d_in[9];
  const float* dtb    = (const float*)d_in[10];
  const float* Wg     = (const float*)d_in[11];
  const float* nw     = (const float*)d_in[12];
  const float* Wo     = (const float*)d_in[13];

  char* p = (char*)d_ws;
  const size_t MB = 1u << 20;
  u16* h_bf = (u16*)(p + 0 * MB);     // 8 MB (dead after small_mfma)
  u16* wq_b = (u16*)(p + 8 * MB);     // 2 MB
  u16* wk_b = (u16*)(p + 10 * MB);
  u16* wv_b = (u16*)(p + 12 * MB);
  u16* wg_b = (u16*)(p + 14 * MB);
  u16* Phi = (u16*)(p + 0 * MB);      // 8 MB bf16, aliases h_bf (dead then)
  u16* Plo = (u16*)(p + 8 * MB);      // 8 MB bf16, aliases wq..wg (dead then)
  u16* wo_b = (u16*)(p + 16 * MB);    // 2 MB (live till end)
  u16* qp_b = (u16*)(p + 18 * MB);    // 8 MB
  u16* kp_b = (u16*)(p + 26 * MB);    // 8 MB
  u16* vp_b = (u16*)(p + 34 * MB);    // 8 MB
  u16* gp_b = (u16*)(p + 42 * MB);    // 8 MB (live till chunk_out)
  u16*   of_b = vp_b;                 // 8 MB, aliases vp (dead after chunk_local)
  float* gbuf = (float*)(p + 50 * MB);
  float* bbuf = (float*)(p + 50 * MB + 262144);
  u16* Ug  = (u16*)(p + 51 * MB);     // 8 MB bf16
  u16* Rg  = (u16*)(p + 59 * MB);     // 8 MB bf16
  u16* Yg  = (u16*)(p + 67 * MB);     // 8 MB bf16
  u16* Sst = (u16*)(p + 75 * MB);     // 8 MB bf16 (transposed per chunk)
  u16* hlo_b = (u16*)(p + 83 * MB);   // 8 MB
  u16* wba_h = (u16*)(p + 91 * MB);   // 64 KB
  u16* wba_l = (u16*)(p + 91 * MB + 65536);  // 64 KB (total ~91.2 MB)

  cvt_all<<<9248, 256, 0, stream>>>(hidden, Wq, Wk, Wv, Wg, Wo, Wb, Wa,
                                    h_bf, hlo_b, wq_b, wk_b, wv_b, wg_b, wo_b,
                                    wba_h, wba_l);

  gemm_big<u16><<<dim3(8, 16, 4), 256, 0, stream>>>(
      h_bf, wq_b, wk_b, wv_b, wg_b, qp_b, kp_b, vp_b, gp_b, 4096, 1024, 1024);

  const int sm_lds = 65536 + 8448;
  hipFuncSetAttribute((const void*)small_mfma,
                      hipFuncAttributeMaxDynamicSharedMemorySize, sm_lds);
  small_mfma<<<256, 256, sm_lds, stream>>>(h_bf, hlo_b, wba_h, wba_l,
                                           A_log, dtb, bbuf, gbuf);

  chunk_local<<<1024, 512, 0, stream>>>(qp_b, kp_b, vp_b, cq, ck, cv,
                                        gbuf, bbuf, Phi, Plo, Ug, Rg, Yg);
  state_step<<<128, 256, 0, stream>>>(Phi, Plo, Ug, Sst);
  chunk_out<<<1024, 256, 0, stream>>>(Rg, Yg, Sst, gp_b, nw, of_b);

  gemm_big<float><<<dim3(8, 16, 1), 256, 0, stream>>>(
      of_b, wo_b, wo_b, wo_b, wo_b,
      (float*)d_out, (float*)d_out, (float*)d_out, (float*)d_out,
      4096, 1024, 1024);
}